// Round 1
// baseline (3602.391 us; speedup 1.0000x reference)
//
#include <hip/hip_runtime.h>
#include <hip/hip_bf16.h>

// ---------------- constants ----------------
#define N_NODES 51200
#define N_EDGES 204800
#define N_HNNZ  102400
#define N_HEDGES 10240
#define NB 1024          // batch (graphs)
#define NPG 50           // nodes per graph (51200/1024)
#define FXD 84
#define FP_DIM 2513
#define FP2 128
#define HID 512

// ---------------- generic GEMM: C = act(A @ W^T + b) ----------------
// A: [M,K] row-major; W: [N,K] row-major; C: [M,N] row-major.
template<bool RELU>
__global__ __launch_bounds__(256) void gemm_bt(const float* __restrict__ A,
                                               const float* __restrict__ W,
                                               const float* __restrict__ bias,
                                               float* __restrict__ C,
                                               int M, int N, int K) {
    __shared__ float As[16][68];
    __shared__ float Bs[16][68];
    const int bm = blockIdx.y * 64, bn = blockIdx.x * 64;
    const int tid = threadIdx.x;
    const int tx = tid & 15, ty = tid >> 4;
    float acc[4][4] = {};
    const int r = tid >> 2, c4 = (tid & 3) << 2;
    for (int k0 = 0; k0 < K; k0 += 16) {
#pragma unroll
        for (int i = 0; i < 4; i++) {
            int k = k0 + c4 + i;
            int m = bm + r;
            As[c4 + i][r] = (m < M && k < K) ? A[(size_t)m * K + k] : 0.f;
            int n = bn + r;
            Bs[c4 + i][r] = (n < N && k < K) ? W[(size_t)n * K + k] : 0.f;
        }
        __syncthreads();
#pragma unroll
        for (int k = 0; k < 16; k++) {
            float a[4], b[4];
#pragma unroll
            for (int i = 0; i < 4; i++) a[i] = As[k][ty * 4 + i];
#pragma unroll
            for (int j = 0; j < 4; j++) b[j] = Bs[k][tx * 4 + j];
#pragma unroll
            for (int i = 0; i < 4; i++)
#pragma unroll
                for (int j = 0; j < 4; j++) acc[i][j] += a[i] * b[j];
        }
        __syncthreads();
    }
#pragma unroll
    for (int i = 0; i < 4; i++) {
        int m = bm + ty * 4 + i;
        if (m >= M) continue;
#pragma unroll
        for (int j = 0; j < 4; j++) {
            int n = bn + tx * 4 + j;
            if (n >= N) continue;
            float v = acc[i][j] + (bias ? bias[n] : 0.f);
            if (RELU) v = fmaxf(v, 0.f);
            C[(size_t)m * N + n] = v;
        }
    }
}

// ---------------- scatter-add: dst[dmap[j]][:] += src[smap[j]][:] ----------------
__global__ void scatter_add_feat(const float* __restrict__ src,
                                 const int* __restrict__ smap,
                                 const int* __restrict__ dmap,
                                 float* __restrict__ dst, int nnz, int F) {
    int i = blockIdx.x * blockDim.x + threadIdx.x;
    int total = nnz * F;
    if (i >= total) return;
    int j = i / F, f = i - j * F;
    atomicAdd(&dst[(size_t)dmap[j] * F + f], src[(size_t)smap[j] * F + f]);
}

__global__ void count_incidence(const int* __restrict__ nid, const int* __restrict__ eid,
                                float* __restrict__ deg, float* __restrict__ ecnt, int nnz) {
    int i = blockIdx.x * blockDim.x + threadIdx.x;
    if (i >= nnz) return;
    atomicAdd(&deg[nid[i]], 1.f);
    atomicAdd(&ecnt[eid[i]], 1.f);
}

__global__ void scale_binv(float* __restrict__ e, const float* __restrict__ ecnt, int R, int F) {
    int i = blockIdx.x * blockDim.x + threadIdx.x;
    if (i >= R * F) return;
    int r = i / F;
    e[i] *= 1.f / fmaxf(ecnt[r], 1.f);
}

__global__ void scale_dinv_bias(float* __restrict__ h, const float* __restrict__ deg,
                                const float* __restrict__ b, int R, int F) {
    int i = blockIdx.x * blockDim.x + threadIdx.x;
    if (i >= R * F) return;
    int r = i / F, f = i - r * F;
    float d = deg[r];
    float inv = d > 0.f ? 1.f / d : 0.f;
    h[i] = h[i] * inv + b[f];
}

__global__ void add_inplace(float* __restrict__ a, const float* __restrict__ b, int n) {
    int i = blockIdx.x * blockDim.x + threadIdx.x;
    if (i < n) a[i] += b[i];
}

// ---------------- pool: out[g] = [max | mean] over 50 consecutive rows ----------------
__global__ void pool_maxmean(const float* __restrict__ h, float* __restrict__ out, int F) {
    int i = blockIdx.x * blockDim.x + threadIdx.x;
    if (i >= NB * F) return;
    int o = i % F, g = i / F;
    const float* base = h + (size_t)g * NPG * F + o;
    float mx = -1e30f, sm = 0.f;
    for (int n = 0; n < NPG; n++) {
        float v = base[(size_t)n * F];
        mx = fmaxf(mx, v);
        sm += v;
    }
    out[(size_t)g * (2 * F) + o] = mx;
    out[(size_t)g * (2 * F) + F + o] = sm / (float)NPG;
}

// ---------------- pack fusion tokens: in_t[(b*4+tok)][d] ----------------
__global__ void pack_tokens(const float* __restrict__ fp_o, const float* __restrict__ xg,
                            const float* __restrict__ hxg, const float* __restrict__ t,
                            float* __restrict__ in_t) {
    int i = blockIdx.x * blockDim.x + threadIdx.x;
    if (i >= 4096 * 512) return;
    int d = i & 511;
    int row = i >> 9;
    int tok = row & 3, b = row >> 2;
    const float* s = (tok == 0) ? fp_o : (tok == 1) ? xg : (tok == 2) ? hxg : t;
    in_t[i] = s[b * 512 + d];
}

// ---------------- fused 4x4 attention per (b,h): one wave each ----------------
__global__ __launch_bounds__(256) void attn_kernel(const float* __restrict__ Q,
                                                   const float* __restrict__ Kk,
                                                   const float* __restrict__ V,
                                                   float* __restrict__ att) {
    int wid = threadIdx.x >> 6, lane = threadIdx.x & 63;
    int bh = blockIdx.x * 4 + wid;   // 0..4095
    int b = bh >> 2, h = bh & 3;
    const float* qb = Q + (size_t)b * 4 * 2048 + h * 512;
    const float* kb = Kk + (size_t)b * 4 * 2048 + h * 512;
    const float* vb = V + (size_t)b * 4 * 2048 + h * 512;
    float qr[4][8], kr[4][8];
#pragma unroll
    for (int n = 0; n < 4; n++)
#pragma unroll
        for (int c = 0; c < 8; c++) {
            qr[n][c] = qb[n * 2048 + c * 64 + lane];
            kr[n][c] = kb[n * 2048 + c * 64 + lane];
        }
    float s[4][4];
#pragma unroll
    for (int n = 0; n < 4; n++)
#pragma unroll
        for (int m = 0; m < 4; m++) {
            float p = 0.f;
#pragma unroll
            for (int c = 0; c < 8; c++) p += qr[n][c] * kr[m][c];
#pragma unroll
            for (int off = 32; off > 0; off >>= 1) p += __shfl_xor(p, off, 64);
            s[n][m] = p * 0.04419417382415922f;  // 1/sqrt(512)
        }
    float pm[4][4];
#pragma unroll
    for (int n = 0; n < 4; n++) {
        float mx = fmaxf(fmaxf(s[n][0], s[n][1]), fmaxf(s[n][2], s[n][3]));
        float e0 = expf(s[n][0] - mx), e1 = expf(s[n][1] - mx);
        float e2 = expf(s[n][2] - mx), e3 = expf(s[n][3] - mx);
        float inv = 1.f / (e0 + e1 + e2 + e3);
        pm[n][0] = e0 * inv; pm[n][1] = e1 * inv; pm[n][2] = e2 * inv; pm[n][3] = e3 * inv;
    }
    float* ab = att + (size_t)bh * 4 * 512;
#pragma unroll
    for (int c = 0; c < 8; c++) {
        float v0 = vb[0 * 2048 + c * 64 + lane];
        float v1 = vb[1 * 2048 + c * 64 + lane];
        float v2 = vb[2 * 2048 + c * 64 + lane];
        float v3 = vb[3 * 2048 + c * 64 + lane];
#pragma unroll
        for (int n = 0; n < 4; n++) {
            float o = pm[n][0] * v0 + pm[n][1] * v1 + pm[n][2] * v2 + pm[n][3] * v3;
            ab[n * 512 + c * 64 + lane] = o;
        }
    }
}

// ---------------- conv 3x3 VALID on [4ch,4,512] -> relu -> [4,2,510] ----------------
__global__ void conv_relu(const float* __restrict__ att, const float* __restrict__ cw,
                          const float* __restrict__ cb, float* __restrict__ c) {
    __shared__ float w[144];
    __shared__ float bias[4];
    int t = threadIdx.x;
    if (t < 144) w[t] = cw[t];
    if (t < 4) bias[t] = cb[t];
    __syncthreads();
    int i = blockIdx.x * blockDim.x + t;   // over 1024*4*2*510
    if (i >= 1024 * 4 * 2 * 510) return;
    int wo = i % 510;
    int r = i / 510;
    int ho = r & 1; r >>= 1;
    int co = r & 3; int b = r >> 2;
    float acc = bias[co];
#pragma unroll
    for (int ci = 0; ci < 4; ci++)
#pragma unroll
        for (int kh = 0; kh < 3; kh++)
#pragma unroll
            for (int kw = 0; kw < 3; kw++)
                acc += att[(((size_t)b * 4 + ci) * 4 + ho + kh) * 512 + wo + kw] *
                       w[((co * 4 + ci) * 3 + kh) * 3 + kw];
    c[i] = fmaxf(acc, 0.f);
}

// ---------------- host side ----------------
static inline void launch_gemm(const float* A, const float* W, const float* b, float* C,
                               int M, int N, int K, bool relu, hipStream_t s) {
    dim3 g((N + 63) / 64, (M + 63) / 64);
    if (relu) gemm_bt<true><<<g, 256, 0, s>>>(A, W, b, C, M, N, K);
    else      gemm_bt<false><<<g, 256, 0, s>>>(A, W, b, C, M, N, K);
}

extern "C" void kernel_launch(void* const* d_in, const int* in_sizes, int n_in,
                              void* d_out, int out_size, void* d_ws, size_t ws_size,
                              hipStream_t stream) {
    const float* x       = (const float*)d_in[0];
    const int*   edge    = (const int*)d_in[1];
    const int*   hedge   = (const int*)d_in[3];
    const float* fp      = (const float*)d_in[4];
    const float* text_em = (const float*)d_in[5];
    const float* fc1_W = (const float*)d_in[7];  const float* fc1_b = (const float*)d_in[8];
    const float* fc2_W = (const float*)d_in[9];  const float* fc2_b = (const float*)d_in[10];
    const float* fc3_W = (const float*)d_in[11]; const float* fc3_b = (const float*)d_in[12];
    const float* fcg1_W = (const float*)d_in[13]; const float* fcg1_b = (const float*)d_in[14];
    const float* fcg2_W = (const float*)d_in[15]; const float* fcg2_b = (const float*)d_in[16];
    const float* fchg1_W = (const float*)d_in[17]; const float* fchg1_b = (const float*)d_in[18];
    const float* fchg2_W = (const float*)d_in[19]; const float* fchg2_b = (const float*)d_in[20];
    const float* gin1_W = (const float*)d_in[21]; const float* gin1_b = (const float*)d_in[22];
    const float* gin2_W = (const float*)d_in[23]; const float* gin2_b = (const float*)d_in[24];
    const float* h3_W = (const float*)d_in[25]; const float* h3_b = (const float*)d_in[26];
    const float* h4_W = (const float*)d_in[27]; const float* h4_b = (const float*)d_in[28];
    const float* Wq = (const float*)d_in[29];
    const float* Wk = (const float*)d_in[30];
    const float* Wv = (const float*)d_in[31];
    const float* conv_W = (const float*)d_in[32]; const float* conv_b = (const float*)d_in[33];
    const float* mlp1_W = (const float*)d_in[34]; const float* mlp1_b = (const float*)d_in[35];
    const float* mlp2_W = (const float*)d_in[36]; const float* mlp2_b = (const float*)d_in[37];

    const int* e_src = edge;                 // edge_index[0]
    const int* e_dst = edge + N_EDGES;       // edge_index[1]
    const int* h_nid = hedge;                // hedge_index[0]
    const int* h_eid = hedge + N_HNNZ;       // hedge_index[1]

    float* ws = (float*)d_ws;
    // shared zone (phases overlaid): 51,609,600 floats
    const size_t ZONE = 51609600;
    // phase A (GIN)
    float* agg = ws;                          // 4,300,800
    float* xg1 = ws + 4300800;                // 4,300,800
    float* xg2 = ws + 8601600;                // 43,008,000
    // phase H (hypergraph)
    float* xw    = ws;                        // 8,601,600
    float* e1    = ws + 8601600;              // 1,720,320
    float* hnode = ws + 10321920;             // 8,601,600
    float* xw2   = ws + 18923520;             // 13,107,200
    float* e2    = ws + 32030720;             // 2,621,440
    float* hn2   = ws + 34652160;             // 13,107,200
    // phase D (attention)
    float* in_t = ws;                         // 2,097,152
    float* q    = ws + 2097152;               // 8,388,608
    float* kk   = ws + 10485760;              // 8,388,608
    float* v    = ws + 18874368;              // 8,388,608
    float* att  = ws + 27262976;              // 8,388,608
    float* cbuf = ws + 35651584;              // 4,177,920
    float* m1   = ws + 39829504;              // 1,048,576
    // persistent region
    float* xg_raw = ws + ZONE;                // 1,720,320
    float* xg_mid = ws + ZONE + 1720320;      // 1,048,576
    float* hx_raw = ws + ZONE + 2768896;      // 524,288
    float* hx_mid = ws + ZONE + 3293184;      // 1,048,576
    float* h1     = ws + ZONE + 4341760;      // 131,072
    float* fp_o   = ws + ZONE + 4472832;      // 524,288
    float* tt     = ws + ZONE + 4997120;      // 524,288
    float* ecnt   = ws + ZONE + 5521408;      // 10,240
    float* deg    = ws + ZONE + 5531648;      // 51,200
    const size_t NEED = (ZONE + 5582848) * sizeof(float);
    if (ws_size < NEED) return;  // workspace too small — cannot run

    float* out_y  = (float*)d_out;            // [1024]
    float* xg_out = out_y + 1024;             // [1024,512]
    float* hx_out = out_y + 1024 + 1024 * 512;// [1024,512]

    const int BT = 256;
    // ---------- GIN branch ----------
    hipMemsetAsync(agg, 0, (size_t)N_NODES * FXD * 4, stream);
    scatter_add_feat<<<(N_EDGES * FXD + BT - 1) / BT, BT, 0, stream>>>(x, e_src, e_dst, agg, N_EDGES, FXD);
    add_inplace<<<(N_NODES * FXD + BT - 1) / BT, BT, 0, stream>>>(agg, x, N_NODES * FXD);
    launch_gemm(agg, gin1_W, gin1_b, xg1, N_NODES, FXD, FXD, true, stream);
    hipMemsetAsync(agg, 0, (size_t)N_NODES * FXD * 4, stream);
    scatter_add_feat<<<(N_EDGES * FXD + BT - 1) / BT, BT, 0, stream>>>(xg1, e_src, e_dst, agg, N_EDGES, FXD);
    add_inplace<<<(N_NODES * FXD + BT - 1) / BT, BT, 0, stream>>>(agg, xg1, N_NODES * FXD);
    launch_gemm(agg, gin2_W, gin2_b, xg2, N_NODES, FXD * 10, FXD, true, stream);
    pool_maxmean<<<(NB * 840 + BT - 1) / BT, BT, 0, stream>>>(xg2, xg_raw, 840);
    launch_gemm(xg_raw, fcg1_W, fcg1_b, xg_mid, NB, 1024, 1680, true, stream);
    launch_gemm(xg_mid, fcg2_W, fcg2_b, xg_out, NB, 512, 1024, false, stream);

    // ---------- hypergraph branch ----------
    hipMemsetAsync(ecnt, 0, N_HEDGES * 4, stream);
    hipMemsetAsync(deg, 0, N_NODES * 4, stream);
    hipMemsetAsync(e1, 0, (size_t)N_HEDGES * 168 * 4, stream);
    hipMemsetAsync(hnode, 0, (size_t)N_NODES * 168 * 4, stream);
    count_incidence<<<(N_HNNZ + BT - 1) / BT, BT, 0, stream>>>(h_nid, h_eid, deg, ecnt, N_HNNZ);
    launch_gemm(x, h3_W, nullptr, xw, N_NODES, 168, FXD, false, stream);
    scatter_add_feat<<<(N_HNNZ * 168 + BT - 1) / BT, BT, 0, stream>>>(xw, h_nid, h_eid, e1, N_HNNZ, 168);
    scale_binv<<<(N_HEDGES * 168 + BT - 1) / BT, BT, 0, stream>>>(e1, ecnt, N_HEDGES, 168);
    scatter_add_feat<<<(N_HNNZ * 168 + BT - 1) / BT, BT, 0, stream>>>(e1, h_eid, h_nid, hnode, N_HNNZ, 168);
    scale_dinv_bias<<<(N_NODES * 168 + BT - 1) / BT, BT, 0, stream>>>(hnode, deg, h3_b, N_NODES, 168);
    launch_gemm(hnode, h4_W, nullptr, xw2, N_NODES, 256, 168, false, stream);
    hipMemsetAsync(e2, 0, (size_t)N_HEDGES * 256 * 4, stream);
    hipMemsetAsync(hn2, 0, (size_t)N_NODES * 256 * 4, stream);
    scatter_add_feat<<<(N_HNNZ * 256 + BT - 1) / BT, BT, 0, stream>>>(xw2, h_nid, h_eid, e2, N_HNNZ, 256);
    scale_binv<<<(N_HEDGES * 256 + BT - 1) / BT, BT, 0, stream>>>(e2, ecnt, N_HEDGES, 256);
    scatter_add_feat<<<(N_HNNZ * 256 + BT - 1) / BT, BT, 0, stream>>>(e2, h_eid, h_nid, hn2, N_HNNZ, 256);
    scale_dinv_bias<<<(N_NODES * 256 + BT - 1) / BT, BT, 0, stream>>>(hn2, deg, h4_b, N_NODES, 256);
    pool_maxmean<<<(NB * 256 + BT - 1) / BT, BT, 0, stream>>>(hn2, hx_raw, 256);
    launch_gemm(hx_raw, fchg1_W, fchg1_b, hx_mid, NB, 1024, 512, true, stream);
    launch_gemm(hx_mid, fchg2_W, fchg2_b, hx_out, NB, 512, 1024, false, stream);

    // ---------- fingerprint + text ----------
    launch_gemm(fp, fc1_W, fc1_b, h1, NB, FP2, FP_DIM, true, stream);
    launch_gemm(h1, fc2_W, fc2_b, fp_o, NB, HID, FP2, false, stream);
    launch_gemm(text_em, fc3_W, fc3_b, tt, NB, HID, 768, false, stream);

    // ---------- fusion attention ----------
    pack_tokens<<<(4096 * 512 + BT - 1) / BT, BT, 0, stream>>>(fp_o, xg_out, hx_out, tt, in_t);
    launch_gemm(in_t, Wq, nullptr, q, 4096, 2048, 512, false, stream);
    launch_gemm(in_t, Wk, nullptr, kk, 4096, 2048, 512, false, stream);
    launch_gemm(in_t, Wv, nullptr, v, 4096, 2048, 512, false, stream);
    attn_kernel<<<1024, 256, 0, stream>>>(q, kk, v, att);
    conv_relu<<<(1024 * 4 * 2 * 510 + BT - 1) / BT, BT, 0, stream>>>(att, conv_W, conv_b, cbuf);
    launch_gemm(cbuf, mlp1_W, mlp1_b, m1, NB, 1024, 4080, true, stream);
    launch_gemm(m1, mlp2_W, mlp2_b, out_y, NB, 1, 1024, false, stream);
}

// Round 2
// 2831.976 us; speedup vs baseline: 1.2720x; 1.2720x over previous
//
#include <hip/hip_runtime.h>
#include <hip/hip_bf16.h>

// ---------------- constants ----------------
#define N_NODES 51200
#define N_EDGES 204800
#define N_HNNZ  102400
#define N_HEDGES 10240
#define NB 1024          // batch (graphs)
#define NPG 50           // nodes per graph (51200/1024)
#define FXD 84
#define FP_DIM 2513
#define FP2 128
#define HID 512

typedef __attribute__((ext_vector_type(4))) float f32x4;
typedef __attribute__((ext_vector_type(8))) __bf16 bf16x8;
typedef __attribute__((ext_vector_type(4))) short short4_t;

static __device__ __forceinline__ unsigned short f2bf(float f) {
    unsigned u = __builtin_bit_cast(unsigned, f);
    u += 0x7FFFu + ((u >> 16) & 1u);   // round-to-nearest-even
    return (unsigned short)(u >> 16);
}

// ---------------- MFMA GEMM: C = act(A @ W^T + b) ----------------
// A: [M,K] f32 row-major; W: [N,K] f32 row-major; C: [M,N] f32.
// 128x128 tile, 4 waves (2x2), each wave 64x64 via 4x4 mfma_16x16x32_bf16.
template<bool RELU>
__global__ __launch_bounds__(256) void gemm_mfma(const float* __restrict__ A,
                                                 const float* __restrict__ W,
                                                 const float* __restrict__ bias,
                                                 float* __restrict__ C,
                                                 int M, int N, int K) {
    __shared__ unsigned short Asm[128][32];
    __shared__ unsigned short Bsm[128][32];
    const int tid = threadIdx.x;
    const int bm = blockIdx.y * 128, bn = blockIdx.x * 128;
    const int wid = tid >> 6, lane = tid & 63;
    const int wm = (wid >> 1) * 64, wn = (wid & 1) * 64;
    const int lr = lane & 15, lg = lane >> 4;     // frag row/col, k-group
    const bool kvec = ((K & 3) == 0);             // rows 16B-aligned & k-quad safe

    f32x4 zero = {0.f, 0.f, 0.f, 0.f};
    f32x4 acc[4][4];
#pragma unroll
    for (int i = 0; i < 4; i++)
#pragma unroll
        for (int j = 0; j < 4; j++) acc[i][j] = zero;

    for (int k0 = 0; k0 < K; k0 += 32) {
        // ---- stage A-tile and B-tile (f32 -> bf16) ----
#pragma unroll
        for (int i = 0; i < 4; i++) {
            int fidx = i * 256 + tid;            // 0..1023 float4-slots
            int row = fidx >> 3, kq = (fidx & 7) << 2;
            int gk = k0 + kq;
            float v0 = 0.f, v1 = 0.f, v2 = 0.f, v3 = 0.f;
            int gm = bm + row;
            if (gm < M && gk < K) {
                const float* p = A + (size_t)gm * K + gk;
                if (kvec && gk + 4 <= K) {
                    float4 f = *(const float4*)p;
                    v0 = f.x; v1 = f.y; v2 = f.z; v3 = f.w;
                } else {
                    v0 = p[0];
                    if (gk + 1 < K) v1 = p[1];
                    if (gk + 2 < K) v2 = p[2];
                    if (gk + 3 < K) v3 = p[3];
                }
            }
            short4_t sv;
            sv[0] = (short)f2bf(v0); sv[1] = (short)f2bf(v1);
            sv[2] = (short)f2bf(v2); sv[3] = (short)f2bf(v3);
            *(short4_t*)&Asm[row][kq] = sv;

            v0 = v1 = v2 = v3 = 0.f;
            int gn = bn + row;
            if (gn < N && gk < K) {
                const float* p = W + (size_t)gn * K + gk;
                if (kvec && gk + 4 <= K) {
                    float4 f = *(const float4*)p;
                    v0 = f.x; v1 = f.y; v2 = f.z; v3 = f.w;
                } else {
                    v0 = p[0];
                    if (gk + 1 < K) v1 = p[1];
                    if (gk + 2 < K) v2 = p[2];
                    if (gk + 3 < K) v3 = p[3];
                }
            }
            sv[0] = (short)f2bf(v0); sv[1] = (short)f2bf(v1);
            sv[2] = (short)f2bf(v2); sv[3] = (short)f2bf(v3);
            *(short4_t*)&Bsm[row][kq] = sv;
        }
        __syncthreads();

        // ---- fragments + MFMA ----
        bf16x8 af[4], bf[4];
#pragma unroll
        for (int m = 0; m < 4; m++)
            af[m] = *(const bf16x8*)&Asm[wm + m * 16 + lr][lg * 8];
#pragma unroll
        for (int n = 0; n < 4; n++)
            bf[n] = *(const bf16x8*)&Bsm[wn + n * 16 + lr][lg * 8];
#pragma unroll
        for (int m = 0; m < 4; m++)
#pragma unroll
            for (int n = 0; n < 4; n++)
                acc[m][n] = __builtin_amdgcn_mfma_f32_16x16x32_bf16(af[m], bf[n], acc[m][n], 0, 0, 0);
        __syncthreads();
    }

    // ---- epilogue: C[row][col], row = (lane>>4)*4+r, col = lane&15 ----
#pragma unroll
    for (int m = 0; m < 4; m++) {
#pragma unroll
        for (int n = 0; n < 4; n++) {
            int col = bn + wn + n * 16 + lr;
            if (col >= N) continue;
            float bv = bias ? bias[col] : 0.f;
#pragma unroll
            for (int r = 0; r < 4; r++) {
                int row = bm + wm + m * 16 + lg * 4 + r;
                if (row >= M) continue;
                float v = acc[m][n][r] + bv;
                if (RELU) v = fmaxf(v, 0.f);
                C[(size_t)row * N + col] = v;
            }
        }
    }
}

// ---------------- N=1 GEMM: out[m] = A[m]·w + b ----------------
__global__ __launch_bounds__(256) void rowdot(const float* __restrict__ A,
                                              const float* __restrict__ w,
                                              const float* __restrict__ b,
                                              float* __restrict__ out, int Mrows, int K) {
    int row = blockIdx.x * 4 + (threadIdx.x >> 6);
    int lane = threadIdx.x & 63;
    if (row >= Mrows) return;
    float s = 0.f;
    for (int k = lane; k < K; k += 64) s += A[(size_t)row * K + k] * w[k];
#pragma unroll
    for (int off = 32; off > 0; off >>= 1) s += __shfl_xor(s, off, 64);
    if (lane == 0) out[row] = s + b[0];
}

// ---------------- scatter-add: dst[dmap[j]][:] += src[smap[j]][:] ----------------
__global__ void scatter_add_feat(const float* __restrict__ src,
                                 const int* __restrict__ smap,
                                 const int* __restrict__ dmap,
                                 float* __restrict__ dst, int nnz, int F) {
    int i = blockIdx.x * blockDim.x + threadIdx.x;
    int total = nnz * F;
    if (i >= total) return;
    int j = i / F, f = i - j * F;
    atomicAdd(&dst[(size_t)dmap[j] * F + f], src[(size_t)smap[j] * F + f]);
}

__global__ void count_incidence(const int* __restrict__ nid, const int* __restrict__ eid,
                                float* __restrict__ deg, float* __restrict__ ecnt, int nnz) {
    int i = blockIdx.x * blockDim.x + threadIdx.x;
    if (i >= nnz) return;
    atomicAdd(&deg[nid[i]], 1.f);
    atomicAdd(&ecnt[eid[i]], 1.f);
}

__global__ void scale_binv(float* __restrict__ e, const float* __restrict__ ecnt, int R, int F) {
    int i = blockIdx.x * blockDim.x + threadIdx.x;
    if (i >= R * F) return;
    int r = i / F;
    e[i] *= 1.f / fmaxf(ecnt[r], 1.f);
}

__global__ void scale_dinv_bias(float* __restrict__ h, const float* __restrict__ deg,
                                const float* __restrict__ b, int R, int F) {
    int i = blockIdx.x * blockDim.x + threadIdx.x;
    if (i >= R * F) return;
    int r = i / F, f = i - r * F;
    float d = deg[r];
    float inv = d > 0.f ? 1.f / d : 0.f;
    h[i] = h[i] * inv + b[f];
}

__global__ void add_inplace(float* __restrict__ a, const float* __restrict__ b, int n) {
    int i = blockIdx.x * blockDim.x + threadIdx.x;
    if (i < n) a[i] += b[i];
}

// ---------------- pool: out[g] = [max | mean] over 50 consecutive rows ----------------
__global__ void pool_maxmean(const float* __restrict__ h, float* __restrict__ out, int F) {
    int i = blockIdx.x * blockDim.x + threadIdx.x;
    if (i >= NB * F) return;
    int o = i % F, g = i / F;
    const float* base = h + (size_t)g * NPG * F + o;
    float mx = -1e30f, sm = 0.f;
    for (int n = 0; n < NPG; n++) {
        float v = base[(size_t)n * F];
        mx = fmaxf(mx, v);
        sm += v;
    }
    out[(size_t)g * (2 * F) + o] = mx;
    out[(size_t)g * (2 * F) + F + o] = sm / (float)NPG;
}

// ---------------- pack fusion tokens ----------------
__global__ void pack_tokens(const float* __restrict__ fp_o, const float* __restrict__ xg,
                            const float* __restrict__ hxg, const float* __restrict__ t,
                            float* __restrict__ in_t) {
    int i = blockIdx.x * blockDim.x + threadIdx.x;
    if (i >= 4096 * 512) return;
    int d = i & 511;
    int row = i >> 9;
    int tok = row & 3, b = row >> 2;
    const float* s = (tok == 0) ? fp_o : (tok == 1) ? xg : (tok == 2) ? hxg : t;
    in_t[i] = s[b * 512 + d];
}

// ---------------- fused 4x4 attention per (b,h): one wave each ----------------
__global__ __launch_bounds__(256) void attn_kernel(const float* __restrict__ Q,
                                                   const float* __restrict__ Kk,
                                                   const float* __restrict__ V,
                                                   float* __restrict__ att) {
    int wid = threadIdx.x >> 6, lane = threadIdx.x & 63;
    int bh = blockIdx.x * 4 + wid;   // 0..4095
    int b = bh >> 2, h = bh & 3;
    const float* qb = Q + (size_t)b * 4 * 2048 + h * 512;
    const float* kb = Kk + (size_t)b * 4 * 2048 + h * 512;
    const float* vb = V + (size_t)b * 4 * 2048 + h * 512;
    float qr[4][8], kr[4][8];
#pragma unroll
    for (int n = 0; n < 4; n++)
#pragma unroll
        for (int c = 0; c < 8; c++) {
            qr[n][c] = qb[n * 2048 + c * 64 + lane];
            kr[n][c] = kb[n * 2048 + c * 64 + lane];
        }
    float s[4][4];
#pragma unroll
    for (int n = 0; n < 4; n++)
#pragma unroll
        for (int m = 0; m < 4; m++) {
            float p = 0.f;
#pragma unroll
            for (int c = 0; c < 8; c++) p += qr[n][c] * kr[m][c];
#pragma unroll
            for (int off = 32; off > 0; off >>= 1) p += __shfl_xor(p, off, 64);
            s[n][m] = p * 0.04419417382415922f;  // 1/sqrt(512)
        }
    float pm[4][4];
#pragma unroll
    for (int n = 0; n < 4; n++) {
        float mx = fmaxf(fmaxf(s[n][0], s[n][1]), fmaxf(s[n][2], s[n][3]));
        float e0 = expf(s[n][0] - mx), e1 = expf(s[n][1] - mx);
        float e2 = expf(s[n][2] - mx), e3 = expf(s[n][3] - mx);
        float inv = 1.f / (e0 + e1 + e2 + e3);
        pm[n][0] = e0 * inv; pm[n][1] = e1 * inv; pm[n][2] = e2 * inv; pm[n][3] = e3 * inv;
    }
    float* ab = att + (size_t)bh * 4 * 512;
#pragma unroll
    for (int c = 0; c < 8; c++) {
        float v0 = vb[0 * 2048 + c * 64 + lane];
        float v1 = vb[1 * 2048 + c * 64 + lane];
        float v2 = vb[2 * 2048 + c * 64 + lane];
        float v3 = vb[3 * 2048 + c * 64 + lane];
#pragma unroll
        for (int n = 0; n < 4; n++) {
            float o = pm[n][0] * v0 + pm[n][1] * v1 + pm[n][2] * v2 + pm[n][3] * v3;
            ab[n * 512 + c * 64 + lane] = o;
        }
    }
}

// ---------------- conv 3x3 VALID on [4ch,4,512] -> relu -> [4,2,510] ----------------
__global__ void conv_relu(const float* __restrict__ att, const float* __restrict__ cw,
                          const float* __restrict__ cb, float* __restrict__ c) {
    __shared__ float w[144];
    __shared__ float bias[4];
    int t = threadIdx.x;
    if (t < 144) w[t] = cw[t];
    if (t < 4) bias[t] = cb[t];
    __syncthreads();
    int i = blockIdx.x * blockDim.x + t;   // over 1024*4*2*510
    if (i >= 1024 * 4 * 2 * 510) return;
    int wo = i % 510;
    int r = i / 510;
    int ho = r & 1; r >>= 1;
    int co = r & 3; int b = r >> 2;
    float acc = bias[co];
#pragma unroll
    for (int ci = 0; ci < 4; ci++)
#pragma unroll
        for (int kh = 0; kh < 3; kh++)
#pragma unroll
            for (int kw = 0; kw < 3; kw++)
                acc += att[(((size_t)b * 4 + ci) * 4 + ho + kh) * 512 + wo + kw] *
                       w[((co * 4 + ci) * 3 + kh) * 3 + kw];
    c[i] = fmaxf(acc, 0.f);
}

// ---------------- host side ----------------
static inline void launch_gemm(const float* A, const float* W, const float* b, float* C,
                               int M, int N, int K, bool relu, hipStream_t s) {
    dim3 g((N + 127) / 128, (M + 127) / 128);
    if (relu) gemm_mfma<true><<<g, 256, 0, s>>>(A, W, b, C, M, N, K);
    else      gemm_mfma<false><<<g, 256, 0, s>>>(A, W, b, C, M, N, K);
}

extern "C" void kernel_launch(void* const* d_in, const int* in_sizes, int n_in,
                              void* d_out, int out_size, void* d_ws, size_t ws_size,
                              hipStream_t stream) {
    const float* x       = (const float*)d_in[0];
    const int*   edge    = (const int*)d_in[1];
    const int*   hedge   = (const int*)d_in[3];
    const float* fp      = (const float*)d_in[4];
    const float* text_em = (const float*)d_in[5];
    const float* fc1_W = (const float*)d_in[7];  const float* fc1_b = (const float*)d_in[8];
    const float* fc2_W = (const float*)d_in[9];  const float* fc2_b = (const float*)d_in[10];
    const float* fc3_W = (const float*)d_in[11]; const float* fc3_b = (const float*)d_in[12];
    const float* fcg1_W = (const float*)d_in[13]; const float* fcg1_b = (const float*)d_in[14];
    const float* fcg2_W = (const float*)d_in[15]; const float* fcg2_b = (const float*)d_in[16];
    const float* fchg1_W = (const float*)d_in[17]; const float* fchg1_b = (const float*)d_in[18];
    const float* fchg2_W = (const float*)d_in[19]; const float* fchg2_b = (const float*)d_in[20];
    const float* gin1_W = (const float*)d_in[21]; const float* gin1_b = (const float*)d_in[22];
    const float* gin2_W = (const float*)d_in[23]; const float* gin2_b = (const float*)d_in[24];
    const float* h3_W = (const float*)d_in[25]; const float* h3_b = (const float*)d_in[26];
    const float* h4_W = (const float*)d_in[27]; const float* h4_b = (const float*)d_in[28];
    const float* Wq = (const float*)d_in[29];
    const float* Wk = (const float*)d_in[30];
    const float* Wv = (const float*)d_in[31];
    const float* conv_W = (const float*)d_in[32]; const float* conv_b = (const float*)d_in[33];
    const float* mlp1_W = (const float*)d_in[34]; const float* mlp1_b = (const float*)d_in[35];
    const float* mlp2_W = (const float*)d_in[36]; const float* mlp2_b = (const float*)d_in[37];

    const int* e_src = edge;                 // edge_index[0]
    const int* e_dst = edge + N_EDGES;       // edge_index[1]
    const int* h_nid = hedge;                // hedge_index[0]
    const int* h_eid = hedge + N_HNNZ;       // hedge_index[1]

    float* ws = (float*)d_ws;
    // shared zone (phases overlaid): 51,609,600 floats
    const size_t ZONE = 51609600;
    // phase A (GIN)
    float* agg = ws;                          // 4,300,800
    float* xg1 = ws + 4300800;                // 4,300,800
    float* xg2 = ws + 8601600;                // 43,008,000
    // phase H (hypergraph)
    float* xw    = ws;                        // 8,601,600
    float* e1    = ws + 8601600;              // 1,720,320
    float* hnode = ws + 10321920;             // 8,601,600
    float* xw2   = ws + 18923520;             // 13,107,200
    float* e2    = ws + 32030720;             // 2,621,440
    float* hn2   = ws + 34652160;             // 13,107,200
    // phase D (attention)
    float* in_t = ws;                         // 2,097,152
    float* q    = ws + 2097152;               // 8,388,608
    float* kk   = ws + 10485760;              // 8,388,608
    float* v    = ws + 18874368;              // 8,388,608
    float* att  = ws + 27262976;              // 8,388,608
    float* cbuf = ws + 35651584;              // 4,177,920
    float* m1   = ws + 39829504;              // 1,048,576
    // persistent region
    float* xg_raw = ws + ZONE;                // 1,720,320
    float* xg_mid = ws + ZONE + 1720320;      // 1,048,576
    float* hx_raw = ws + ZONE + 2768896;      // 524,288
    float* hx_mid = ws + ZONE + 3293184;      // 1,048,576
    float* h1     = ws + ZONE + 4341760;      // 131,072
    float* fp_o   = ws + ZONE + 4472832;      // 524,288
    float* tt     = ws + ZONE + 4997120;      // 524,288
    float* ecnt   = ws + ZONE + 5521408;      // 10,240
    float* deg    = ws + ZONE + 5531648;      // 51,200
    const size_t NEED = (ZONE + 5582848) * sizeof(float);
    if (ws_size < NEED) return;  // workspace too small — cannot run

    float* out_y  = (float*)d_out;            // [1024]
    float* xg_out = out_y + 1024;             // [1024,512]
    float* hx_out = out_y + 1024 + 1024 * 512;// [1024,512]

    const int BT = 256;
    // ---------- GIN branch ----------
    hipMemsetAsync(agg, 0, (size_t)N_NODES * FXD * 4, stream);
    scatter_add_feat<<<(N_EDGES * FXD + BT - 1) / BT, BT, 0, stream>>>(x, e_src, e_dst, agg, N_EDGES, FXD);
    add_inplace<<<(N_NODES * FXD + BT - 1) / BT, BT, 0, stream>>>(agg, x, N_NODES * FXD);
    launch_gemm(agg, gin1_W, gin1_b, xg1, N_NODES, FXD, FXD, true, stream);
    hipMemsetAsync(agg, 0, (size_t)N_NODES * FXD * 4, stream);
    scatter_add_feat<<<(N_EDGES * FXD + BT - 1) / BT, BT, 0, stream>>>(xg1, e_src, e_dst, agg, N_EDGES, FXD);
    add_inplace<<<(N_NODES * FXD + BT - 1) / BT, BT, 0, stream>>>(agg, xg1, N_NODES * FXD);
    launch_gemm(agg, gin2_W, gin2_b, xg2, N_NODES, FXD * 10, FXD, true, stream);
    pool_maxmean<<<(NB * 840 + BT - 1) / BT, BT, 0, stream>>>(xg2, xg_raw, 840);
    launch_gemm(xg_raw, fcg1_W, fcg1_b, xg_mid, NB, 1024, 1680, true, stream);
    launch_gemm(xg_mid, fcg2_W, fcg2_b, xg_out, NB, 512, 1024, false, stream);

    // ---------- hypergraph branch ----------
    hipMemsetAsync(ecnt, 0, N_HEDGES * 4, stream);
    hipMemsetAsync(deg, 0, N_NODES * 4, stream);
    hipMemsetAsync(e1, 0, (size_t)N_HEDGES * 168 * 4, stream);
    hipMemsetAsync(hnode, 0, (size_t)N_NODES * 168 * 4, stream);
    count_incidence<<<(N_HNNZ + BT - 1) / BT, BT, 0, stream>>>(h_nid, h_eid, deg, ecnt, N_HNNZ);
    launch_gemm(x, h3_W, nullptr, xw, N_NODES, 168, FXD, false, stream);
    scatter_add_feat<<<(N_HNNZ * 168 + BT - 1) / BT, BT, 0, stream>>>(xw, h_nid, h_eid, e1, N_HNNZ, 168);
    scale_binv<<<(N_HEDGES * 168 + BT - 1) / BT, BT, 0, stream>>>(e1, ecnt, N_HEDGES, 168);
    scatter_add_feat<<<(N_HNNZ * 168 + BT - 1) / BT, BT, 0, stream>>>(e1, h_eid, h_nid, hnode, N_HNNZ, 168);
    scale_dinv_bias<<<(N_NODES * 168 + BT - 1) / BT, BT, 0, stream>>>(hnode, deg, h3_b, N_NODES, 168);
    launch_gemm(hnode, h4_W, nullptr, xw2, N_NODES, 256, 168, false, stream);
    hipMemsetAsync(e2, 0, (size_t)N_HEDGES * 256 * 4, stream);
    hipMemsetAsync(hn2, 0, (size_t)N_NODES * 256 * 4, stream);
    scatter_add_feat<<<(N_HNNZ * 256 + BT - 1) / BT, BT, 0, stream>>>(xw2, h_nid, h_eid, e2, N_HNNZ, 256);
    scale_binv<<<(N_HEDGES * 256 + BT - 1) / BT, BT, 0, stream>>>(e2, ecnt, N_HEDGES, 256);
    scatter_add_feat<<<(N_HNNZ * 256 + BT - 1) / BT, BT, 0, stream>>>(e2, h_eid, h_nid, hn2, N_HNNZ, 256);
    scale_dinv_bias<<<(N_NODES * 256 + BT - 1) / BT, BT, 0, stream>>>(hn2, deg, h4_b, N_NODES, 256);
    pool_maxmean<<<(NB * 256 + BT - 1) / BT, BT, 0, stream>>>(hn2, hx_raw, 256);
    launch_gemm(hx_raw, fchg1_W, fchg1_b, hx_mid, NB, 1024, 512, true, stream);
    launch_gemm(hx_mid, fchg2_W, fchg2_b, hx_out, NB, 512, 1024, false, stream);

    // ---------- fingerprint + text ----------
    launch_gemm(fp, fc1_W, fc1_b, h1, NB, FP2, FP_DIM, true, stream);
    launch_gemm(h1, fc2_W, fc2_b, fp_o, NB, HID, FP2, false, stream);
    launch_gemm(text_em, fc3_W, fc3_b, tt, NB, HID, 768, false, stream);

    // ---------- fusion attention ----------
    pack_tokens<<<(4096 * 512 + BT - 1) / BT, BT, 0, stream>>>(fp_o, xg_out, hx_out, tt, in_t);
    launch_gemm(in_t, Wq, nullptr, q, 4096, 2048, 512, false, stream);
    launch_gemm(in_t, Wk, nullptr, kk, 4096, 2048, 512, false, stream);
    launch_gemm(in_t, Wv, nullptr, v, 4096, 2048, 512, false, stream);
    attn_kernel<<<1024, 256, 0, stream>>>(q, kk, v, att);
    conv_relu<<<(1024 * 4 * 2 * 510 + BT - 1) / BT, BT, 0, stream>>>(att, conv_W, conv_b, cbuf);
    launch_gemm(cbuf, mlp1_W, mlp1_b, m1, NB, 1024, 4080, true, stream);
    launch_gemm(m1, mlp2_W, mlp2_b, out_y, NB, 1, 1024, false, stream);
}

// Round 4
// 1977.370 us; speedup vs baseline: 1.8218x; 1.4322x over previous
//
#include <hip/hip_runtime.h>
#include <hip/hip_bf16.h>

// ---------------- constants ----------------
#define N_NODES 51200
#define N_EDGES 204800
#define N_HNNZ  102400
#define N_HEDGES 10240
#define NB 1024          // batch (graphs)
#define NPG 50           // nodes per graph (51200/1024)
#define FXD 84
#define FP_DIM 2513
#define FP2 128
#define HID 512

typedef __attribute__((ext_vector_type(4))) float f32x4;
typedef __attribute__((ext_vector_type(8))) __bf16 bf16x8;
typedef __attribute__((ext_vector_type(4))) short short4_t;

static __device__ __forceinline__ unsigned short f2bf(float f) {
    unsigned u = __builtin_bit_cast(unsigned, f);
    u += 0x7FFFu + ((u >> 16) & 1u);   // round-to-nearest-even
    return (unsigned short)(u >> 16);
}

// ---------------- MFMA GEMM 128x128: C = act((A[+Aadd]) @ W^T + b) ----------------
// A: [M,K] f32 row-major; optional Aadd: [M,K] f64 added elementwise (GIN fuse);
// W: [N,K] f32 row-major; C: [M,N] f32. 4 waves (2x2), 4x4 mfma_16x16x32_bf16 each.
template<bool RELU>
__global__ __launch_bounds__(256) void gemm_mfma(const float* __restrict__ A,
                                                 const double* __restrict__ Aadd,
                                                 const float* __restrict__ W,
                                                 const float* __restrict__ bias,
                                                 float* __restrict__ C,
                                                 int M, int N, int K) {
    __shared__ unsigned short Asm[128][32];
    __shared__ unsigned short Bsm[128][32];
    const int tid = threadIdx.x;
    const int bm = blockIdx.y * 128, bn = blockIdx.x * 128;
    const int wid = tid >> 6, lane = tid & 63;
    const int wm = (wid >> 1) * 64, wn = (wid & 1) * 64;
    const int lr = lane & 15, lg = lane >> 4;
    const bool kvec = ((K & 3) == 0);

    f32x4 zero = {0.f, 0.f, 0.f, 0.f};
    f32x4 acc[4][4];
#pragma unroll
    for (int i = 0; i < 4; i++)
#pragma unroll
        for (int j = 0; j < 4; j++) acc[i][j] = zero;

    for (int k0 = 0; k0 < K; k0 += 32) {
#pragma unroll
        for (int i = 0; i < 4; i++) {
            int fidx = i * 256 + tid;
            int row = fidx >> 3, kq = (fidx & 7) << 2;
            int gk = k0 + kq;
            float v0 = 0.f, v1 = 0.f, v2 = 0.f, v3 = 0.f;
            int gm = bm + row;
            if (gm < M && gk < K) {
                const float* p = A + (size_t)gm * K + gk;
                if (Aadd) {
                    const double* pa = Aadd + (size_t)gm * K + gk;
                    v0 = p[0] + (float)pa[0];
                    if (gk + 1 < K) v1 = p[1] + (float)pa[1];
                    if (gk + 2 < K) v2 = p[2] + (float)pa[2];
                    if (gk + 3 < K) v3 = p[3] + (float)pa[3];
                } else if (kvec && gk + 4 <= K) {
                    float4 f = *(const float4*)p;
                    v0 = f.x; v1 = f.y; v2 = f.z; v3 = f.w;
                } else {
                    v0 = p[0];
                    if (gk + 1 < K) v1 = p[1];
                    if (gk + 2 < K) v2 = p[2];
                    if (gk + 3 < K) v3 = p[3];
                }
            }
            short4_t sv;
            sv[0] = (short)f2bf(v0); sv[1] = (short)f2bf(v1);
            sv[2] = (short)f2bf(v2); sv[3] = (short)f2bf(v3);
            *(short4_t*)&Asm[row][kq] = sv;

            v0 = v1 = v2 = v3 = 0.f;
            int gn = bn + row;
            if (gn < N && gk < K) {
                const float* p = W + (size_t)gn * K + gk;
                if (kvec && gk + 4 <= K) {
                    float4 f = *(const float4*)p;
                    v0 = f.x; v1 = f.y; v2 = f.z; v3 = f.w;
                } else {
                    v0 = p[0];
                    if (gk + 1 < K) v1 = p[1];
                    if (gk + 2 < K) v2 = p[2];
                    if (gk + 3 < K) v3 = p[3];
                }
            }
            sv[0] = (short)f2bf(v0); sv[1] = (short)f2bf(v1);
            sv[2] = (short)f2bf(v2); sv[3] = (short)f2bf(v3);
            *(short4_t*)&Bsm[row][kq] = sv;
        }
        __syncthreads();

        bf16x8 af[4], bf[4];
#pragma unroll
        for (int m = 0; m < 4; m++)
            af[m] = *(const bf16x8*)&Asm[wm + m * 16 + lr][lg * 8];
#pragma unroll
        for (int n = 0; n < 4; n++)
            bf[n] = *(const bf16x8*)&Bsm[wn + n * 16 + lr][lg * 8];
#pragma unroll
        for (int m = 0; m < 4; m++)
#pragma unroll
            for (int n = 0; n < 4; n++)
                acc[m][n] = __builtin_amdgcn_mfma_f32_16x16x32_bf16(af[m], bf[n], acc[m][n], 0, 0, 0);
        __syncthreads();
    }

#pragma unroll
    for (int m = 0; m < 4; m++) {
#pragma unroll
        for (int n = 0; n < 4; n++) {
            int col = bn + wn + n * 16 + lr;
            if (col >= N) continue;
            float bv = bias ? bias[col] : 0.f;
#pragma unroll
            for (int r = 0; r < 4; r++) {
                int row = bm + wm + m * 16 + lg * 4 + r;
                if (row >= M) continue;
                float v = acc[m][n][r] + bv;
                if (RELU) v = fmaxf(v, 0.f);
                C[(size_t)row * N + col] = v;
            }
        }
    }
}

// ---------------- MFMA GEMM 64x64 with intra-block wave K-split ----------------
template<bool RELU, bool PARTIAL>
__global__ __launch_bounds__(256) void gemm64(const float* __restrict__ A,
                                              const float* __restrict__ W,
                                              const float* __restrict__ bias,
                                              float* __restrict__ C,
                                              int M, int N, int K, int kchunk) {
    __shared__ __align__(16) char pool[65536];   // A:16K | B:16K ; reused as 64K f32 red
    char* Ab = pool;
    char* Bb = pool + 16384;
    const int tid = threadIdx.x;
    const int bm = blockIdx.y * 64, bn = blockIdx.x * 64;
    const int wid = tid >> 6, lane = tid & 63;
    const int lr = lane & 15, lg = lane >> 4;
    const int kbeg = blockIdx.z * kchunk;
    const int kend = min(K, kbeg + kchunk);
    const bool kvec = ((K & 3) == 0);

    f32x4 zero = {0.f, 0.f, 0.f, 0.f};
    f32x4 acc[4][4];
#pragma unroll
    for (int i = 0; i < 4; i++)
#pragma unroll
        for (int j = 0; j < 4; j++) acc[i][j] = zero;

    for (int kc = kbeg; kc < kend; kc += 128) {
#pragma unroll
        for (int u = 0; u < 8; u++) {
            int s = u * 256 + tid;               // 2048 8B-slots per matrix
            int row = s >> 5, kq = (s & 31) << 2;
            int gk = kc + kq;
            int off = (row * 256 + (s & 31) * 8) ^ ((row & 7) << 4);

            float v0 = 0.f, v1 = 0.f, v2 = 0.f, v3 = 0.f;
            int gm = bm + row;
            if (gm < M && gk < kend) {
                const float* p = A + (size_t)gm * K + gk;
                if (kvec && gk + 4 <= kend) {
                    float4 f = *(const float4*)p;
                    v0 = f.x; v1 = f.y; v2 = f.z; v3 = f.w;
                } else {
                    v0 = p[0];
                    if (gk + 1 < kend) v1 = p[1];
                    if (gk + 2 < kend) v2 = p[2];
                    if (gk + 3 < kend) v3 = p[3];
                }
            }
            short4_t sv;
            sv[0] = (short)f2bf(v0); sv[1] = (short)f2bf(v1);
            sv[2] = (short)f2bf(v2); sv[3] = (short)f2bf(v3);
            *(short4_t*)(Ab + off) = sv;

            v0 = v1 = v2 = v3 = 0.f;
            int gn = bn + row;
            if (gn < N && gk < kend) {
                const float* p = W + (size_t)gn * K + gk;
                if (kvec && gk + 4 <= kend) {
                    float4 f = *(const float4*)p;
                    v0 = f.x; v1 = f.y; v2 = f.z; v3 = f.w;
                } else {
                    v0 = p[0];
                    if (gk + 1 < kend) v1 = p[1];
                    if (gk + 2 < kend) v2 = p[2];
                    if (gk + 3 < kend) v3 = p[3];
                }
            }
            sv[0] = (short)f2bf(v0); sv[1] = (short)f2bf(v1);
            sv[2] = (short)f2bf(v2); sv[3] = (short)f2bf(v3);
            *(short4_t*)(Bb + off) = sv;
        }
        __syncthreads();

        bf16x8 af[4], bf[4];
        const int kb = wid * 64 + lg * 16;       // byte offset in row
#pragma unroll
        for (int m = 0; m < 4; m++) {
            int row = m * 16 + lr;
            af[m] = *(const bf16x8*)(Ab + ((row * 256 + kb) ^ ((row & 7) << 4)));
        }
#pragma unroll
        for (int n = 0; n < 4; n++) {
            int row = n * 16 + lr;
            bf[n] = *(const bf16x8*)(Bb + ((row * 256 + kb) ^ ((row & 7) << 4)));
        }
#pragma unroll
        for (int m = 0; m < 4; m++)
#pragma unroll
            for (int n = 0; n < 4; n++)
                acc[m][n] = __builtin_amdgcn_mfma_f32_16x16x32_bf16(af[m], bf[n], acc[m][n], 0, 0, 0);
        __syncthreads();
    }

    float* red = (float*)pool;                   // 4 x 4096 f32
#pragma unroll
    for (int m = 0; m < 4; m++)
#pragma unroll
        for (int n = 0; n < 4; n++)
#pragma unroll
            for (int r = 0; r < 4; r++)
                red[wid * 4096 + (m * 16 + lg * 4 + r) * 64 + n * 16 + lr] = acc[m][n][r];
    __syncthreads();
#pragma unroll
    for (int u = 0; u < 16; u++) {
        int idx = u * 256 + tid;
        int row = idx >> 6, col = idx & 63;
        int gm = bm + row, gn = bn + col;
        if (gm >= M || gn >= N) continue;
        float s = red[idx] + red[4096 + idx] + red[8192 + idx] + red[12288 + idx];
        if (PARTIAL) {
            C[(size_t)blockIdx.z * M * N + (size_t)gm * N + gn] = s;
        } else {
            s += bias ? bias[gn] : 0.f;
            if (RELU) s = fmaxf(s, 0.f);
            C[(size_t)gm * N + gn] = s;
        }
    }
}

template<bool RELU>
__global__ void reduce_partial(const float* __restrict__ part, const float* __restrict__ bias,
                               float* __restrict__ C, int MN, int N, int SK) {
    int i = blockIdx.x * 256 + threadIdx.x;
    if (i >= MN) return;
    float s = 0.f;
    for (int z = 0; z < SK; z++) s += part[(size_t)z * MN + i];
    s += bias ? bias[i % N] : 0.f;
    if (RELU) s = fmaxf(s, 0.f);
    C[i] = s;
}

// ---------------- fused GIN2 GEMM + bias + relu + 50-row max/mean pool ----------------
// Block = (graph g, 64-col tile). C-rows are exactly graph g's 50 nodes.
// A = xg1 + (float)agg64 (elementwise), W = gin2_W [840x84], out = xg_raw [1024][1680].
__global__ __launch_bounds__(256) void gin2pool(const float* __restrict__ xg1,
                                                const double* __restrict__ agg,
                                                const float* __restrict__ W,
                                                const float* __restrict__ bias,
                                                float* __restrict__ out) {
    __shared__ __align__(16) char lds[65536];
    char* Ab = lds;
    char* Bb = lds + 16384;
    const int tid = threadIdx.x;
    const int g = blockIdx.y;
    const int bn = blockIdx.x * 64;
    const int wid = tid >> 6, lane = tid & 63;
    const int lr = lane & 15, lg = lane >> 4;
    const int K = FXD, N = 840;

    // stage A (rows = g*50 + 0..49, zero-pad rows 50..63, K padded to 128) and B
#pragma unroll
    for (int u = 0; u < 8; u++) {
        int s = u * 256 + tid;
        int row = s >> 5, kq = (s & 31) << 2;
        int off = (row * 256 + (s & 31) * 8) ^ ((row & 7) << 4);
        float v0 = 0.f, v1 = 0.f, v2 = 0.f, v3 = 0.f;
        if (row < NPG && kq < K) {
            const float* p = xg1 + ((size_t)g * NPG + row) * K + kq;
            const double* pa = agg + ((size_t)g * NPG + row) * K + kq;
            v0 = p[0] + (float)pa[0];
            if (kq + 1 < K) v1 = p[1] + (float)pa[1];
            if (kq + 2 < K) v2 = p[2] + (float)pa[2];
            if (kq + 3 < K) v3 = p[3] + (float)pa[3];
        }
        short4_t sv;
        sv[0] = (short)f2bf(v0); sv[1] = (short)f2bf(v1);
        sv[2] = (short)f2bf(v2); sv[3] = (short)f2bf(v3);
        *(short4_t*)(Ab + off) = sv;

        v0 = v1 = v2 = v3 = 0.f;
        int gn = bn + row;
        if (gn < N && kq < K) {
            const float* p = W + (size_t)gn * K + kq;
            v0 = p[0];
            if (kq + 1 < K) v1 = p[1];
            if (kq + 2 < K) v2 = p[2];
            if (kq + 3 < K) v3 = p[3];
        }
        sv[0] = (short)f2bf(v0); sv[1] = (short)f2bf(v1);
        sv[2] = (short)f2bf(v2); sv[3] = (short)f2bf(v3);
        *(short4_t*)(Bb + off) = sv;
    }
    __syncthreads();

    f32x4 zero = {0.f, 0.f, 0.f, 0.f};
    f32x4 acc[4][4];
#pragma unroll
    for (int i = 0; i < 4; i++)
#pragma unroll
        for (int j = 0; j < 4; j++) acc[i][j] = zero;

    bf16x8 af[4], bf[4];
    const int kb = wid * 64 + lg * 16;
#pragma unroll
    for (int m = 0; m < 4; m++) {
        int row = m * 16 + lr;
        af[m] = *(const bf16x8*)(Ab + ((row * 256 + kb) ^ ((row & 7) << 4)));
    }
#pragma unroll
    for (int n = 0; n < 4; n++) {
        int row = n * 16 + lr;
        bf[n] = *(const bf16x8*)(Bb + ((row * 256 + kb) ^ ((row & 7) << 4)));
    }
#pragma unroll
    for (int m = 0; m < 4; m++)
#pragma unroll
        for (int n = 0; n < 4; n++)
            acc[m][n] = __builtin_amdgcn_mfma_f32_16x16x32_bf16(af[m], bf[n], acc[m][n], 0, 0, 0);
    __syncthreads();

    float* red = (float*)lds;
#pragma unroll
    for (int m = 0; m < 4; m++)
#pragma unroll
        for (int n = 0; n < 4; n++)
#pragma unroll
            for (int r = 0; r < 4; r++)
                red[wid * 4096 + (m * 16 + lg * 4 + r) * 64 + n * 16 + lr] = acc[m][n][r];
    __syncthreads();
    // wave-sum + bias + relu -> red[0..4096)
#pragma unroll
    for (int u = 0; u < 16; u++) {
        int idx = u * 256 + tid;
        int col = idx & 63;
        float s = red[idx] + red[4096 + idx] + red[8192 + idx] + red[12288 + idx];
        s += (bn + col < N) ? bias[bn + col] : 0.f;
        red[idx] = fmaxf(s, 0.f);
    }
    __syncthreads();
    // pool rows 0..49 per column
    if (tid < 64) {
        int col = bn + tid;
        if (col < N) {
            float mx = -1e30f, sm = 0.f;
            for (int r = 0; r < NPG; r++) {
                float v = red[r * 64 + tid];
                mx = fmaxf(mx, v);
                sm += v;
            }
            out[(size_t)g * 1680 + col] = mx;
            out[(size_t)g * 1680 + 840 + col] = sm * (1.f / NPG);
        }
    }
}

// ---------------- N=1 GEMM: out[m] = A[m]·w + b ----------------
__global__ __launch_bounds__(256) void rowdot(const float* __restrict__ A,
                                              const float* __restrict__ w,
                                              const float* __restrict__ b,
                                              float* __restrict__ out, int Mrows, int K) {
    int row = blockIdx.x * 4 + (threadIdx.x >> 6);
    int lane = threadIdx.x & 63;
    if (row >= Mrows) return;
    float s = 0.f;
    for (int k = lane; k < K; k += 64) s += A[(size_t)row * K + k] * w[k];
#pragma unroll
    for (int off = 32; off > 0; off >>= 1) s += __shfl_xor(s, off, 64);
    if (lane == 0) out[row] = s + b[0];
}

// ---------------- deterministic-enough scatter-add: f64 accumulation ----------------
__global__ void scatter_add_feat_d(const float* __restrict__ src,
                                   const int* __restrict__ smap,
                                   const int* __restrict__ dmap,
                                   double* __restrict__ dst, int nnz, int F) {
    int i = blockIdx.x * blockDim.x + threadIdx.x;
    int total = nnz * F;
    if (i >= total) return;
    int j = i / F, f = i - j * F;
    unsafeAtomicAdd(&dst[(size_t)dmap[j] * F + f], (double)src[(size_t)smap[j] * F + f]);
}

// counts: f32 sums of 1.0 are exact integers -> order-invariant
__global__ void count_incidence(const int* __restrict__ nid, const int* __restrict__ eid,
                                float* __restrict__ deg, float* __restrict__ ecnt, int nnz) {
    int i = blockIdx.x * blockDim.x + threadIdx.x;
    if (i >= nnz) return;
    atomicAdd(&deg[nid[i]], 1.f);
    atomicAdd(&ecnt[eid[i]], 1.f);
}

__global__ void scale_binv_d2f(const double* __restrict__ e64, const float* __restrict__ ecnt,
                               float* __restrict__ e32, int R, int F) {
    int i = blockIdx.x * blockDim.x + threadIdx.x;
    if (i >= R * F) return;
    int r = i / F;
    e32[i] = (float)e64[i] * (1.f / fmaxf(ecnt[r], 1.f));
}

__global__ void scale_dinv_bias_d2f(const double* __restrict__ h64, const float* __restrict__ deg,
                                    const float* __restrict__ b, float* __restrict__ h32,
                                    int R, int F) {
    int i = blockIdx.x * blockDim.x + threadIdx.x;
    if (i >= R * F) return;
    int r = i / F, f = i - r * F;
    float d = deg[r];
    float inv = d > 0.f ? 1.f / d : 0.f;
    h32[i] = (float)h64[i] * inv + b[f];
}

// ---------------- fused hyper scale + 50-row max/mean pool ----------------
__global__ void pool_hyper(const double* __restrict__ hn64, const float* __restrict__ deg,
                           const float* __restrict__ b, float* __restrict__ out) {
    int i = blockIdx.x * blockDim.x + threadIdx.x;    // over 1024*256
    if (i >= NB * 256) return;
    int o = i & 255, g = i >> 8;
    float bo = b[o];
    const double* base = hn64 + (size_t)g * NPG * 256 + o;
    const float* dg = deg + g * NPG;
    float mx = -1e30f, sm = 0.f;
    for (int n = 0; n < NPG; n++) {
        float d = dg[n];
        float inv = d > 0.f ? 1.f / d : 0.f;
        float v = (float)base[(size_t)n * 256] * inv + bo;
        mx = fmaxf(mx, v);
        sm += v;
    }
    out[(size_t)g * 512 + o] = mx;
    out[(size_t)g * 512 + 256 + o] = sm * (1.f / NPG);
}

// ---------------- pack fusion tokens ----------------
__global__ void pack_tokens(const float* __restrict__ fp_o, const float* __restrict__ xg,
                            const float* __restrict__ hxg, const float* __restrict__ t,
                            float* __restrict__ in_t) {
    int i = blockIdx.x * blockDim.x + threadIdx.x;
    if (i >= 4096 * 512) return;
    int d = i & 511;
    int row = i >> 9;
    int tok = row & 3, b = row >> 2;
    const float* s = (tok == 0) ? fp_o : (tok == 1) ? xg : (tok == 2) ? hxg : t;
    in_t[i] = s[b * 512 + d];
}

// ---------------- fused 4x4 attention per (b,h) ----------------
__global__ __launch_bounds__(256) void attn_kernel(const float* __restrict__ Q,
                                                   const float* __restrict__ Kk,
                                                   const float* __restrict__ V,
                                                   float* __restrict__ att) {
    int wid = threadIdx.x >> 6, lane = threadIdx.x & 63;
    int bh = blockIdx.x * 4 + wid;
    int b = bh >> 2, h = bh & 3;
    const float* qb = Q + (size_t)b * 4 * 2048 + h * 512;
    const float* kb = Kk + (size_t)b * 4 * 2048 + h * 512;
    const float* vb = V + (size_t)b * 4 * 2048 + h * 512;
    float qr[4][8], kr[4][8];
#pragma unroll
    for (int n = 0; n < 4; n++)
#pragma unroll
        for (int c = 0; c < 8; c++) {
            qr[n][c] = qb[n * 2048 + c * 64 + lane];
            kr[n][c] = kb[n * 2048 + c * 64 + lane];
        }
    float s[4][4];
#pragma unroll
    for (int n = 0; n < 4; n++)
#pragma unroll
        for (int m = 0; m < 4; m++) {
            float p = 0.f;
#pragma unroll
            for (int c = 0; c < 8; c++) p += qr[n][c] * kr[m][c];
#pragma unroll
            for (int off = 32; off > 0; off >>= 1) p += __shfl_xor(p, off, 64);
            s[n][m] = p * 0.04419417382415922f;
        }
    float pm[4][4];
#pragma unroll
    for (int n = 0; n < 4; n++) {
        float mx = fmaxf(fmaxf(s[n][0], s[n][1]), fmaxf(s[n][2], s[n][3]));
        float e0 = expf(s[n][0] - mx), e1 = expf(s[n][1] - mx);
        float e2 = expf(s[n][2] - mx), e3 = expf(s[n][3] - mx);
        float inv = 1.f / (e0 + e1 + e2 + e3);
        pm[n][0] = e0 * inv; pm[n][1] = e1 * inv; pm[n][2] = e2 * inv; pm[n][3] = e3 * inv;
    }
    float* ab = att + (size_t)bh * 4 * 512;
#pragma unroll
    for (int c = 0; c < 8; c++) {
        float v0 = vb[0 * 2048 + c * 64 + lane];
        float v1 = vb[1 * 2048 + c * 64 + lane];
        float v2 = vb[2 * 2048 + c * 64 + lane];
        float v3 = vb[3 * 2048 + c * 64 + lane];
#pragma unroll
        for (int n = 0; n < 4; n++) {
            float o = pm[n][0] * v0 + pm[n][1] * v1 + pm[n][2] * v2 + pm[n][3] * v3;
            ab[n * 512 + c * 64 + lane] = o;
        }
    }
}

// ---------------- conv 3x3 VALID + relu ----------------
__global__ void conv_relu(const float* __restrict__ att, const float* __restrict__ cw,
                          const float* __restrict__ cb, float* __restrict__ c) {
    __shared__ float w[144];
    __shared__ float bias[4];
    int t = threadIdx.x;
    if (t < 144) w[t] = cw[t];
    if (t < 4) bias[t] = cb[t];
    __syncthreads();
    int i = blockIdx.x * blockDim.x + t;
    if (i >= 1024 * 4 * 2 * 510) return;
    int wo = i % 510;
    int r = i / 510;
    int ho = r & 1; r >>= 1;
    int co = r & 3; int b = r >> 2;
    float acc = bias[co];
#pragma unroll
    for (int ci = 0; ci < 4; ci++)
#pragma unroll
        for (int kh = 0; kh < 3; kh++)
#pragma unroll
            for (int kw = 0; kw < 3; kw++)
                acc += att[(((size_t)b * 4 + ci) * 4 + ho + kh) * 512 + wo + kw] *
                       w[((co * 4 + ci) * 3 + kh) * 3 + kw];
    c[i] = fmaxf(acc, 0.f);
}

// ---------------- host side ----------------
static inline void launch_gemm(const float* A, const double* Aadd, const float* W,
                               const float* b, float* C,
                               int M, int N, int K, bool relu, hipStream_t s) {
    dim3 g((N + 127) / 128, (M + 127) / 128);
    if (relu) gemm_mfma<true><<<g, 256, 0, s>>>(A, Aadd, W, b, C, M, N, K);
    else      gemm_mfma<false><<<g, 256, 0, s>>>(A, Aadd, W, b, C, M, N, K);
}

static inline void launch_gemm64(const float* A, const float* W, const float* b, float* C,
                                 int M, int N, int K, bool relu, float* part, hipStream_t s) {
    int gx = (N + 63) / 64, gy = (M + 63) / 64;
    int targetSK = 256 / (gx * gy);
    if (targetSK < 1) targetSK = 1;
    if (targetSK > 8) targetSK = 8;
    int kchunk = K, SK = 1;
    if (targetSK > 1) {
        kchunk = (((K + targetSK - 1) / targetSK) + 127) & ~127;
        SK = (K + kchunk - 1) / kchunk;
    }
    if (SK <= 1) {
        dim3 g(gx, gy);
        if (relu) gemm64<true, false><<<g, 256, 0, s>>>(A, W, b, C, M, N, K, K);
        else      gemm64<false, false><<<g, 256, 0, s>>>(A, W, b, C, M, N, K, K);
    } else {
        dim3 g(gx, gy, SK);
        gemm64<false, true><<<g, 256, 0, s>>>(A, W, nullptr, part, M, N, K, kchunk);
        int MN = M * N;
        if (relu) reduce_partial<true><<<(MN + 255) / 256, 256, 0, s>>>(part, b, C, MN, N, SK);
        else      reduce_partial<false><<<(MN + 255) / 256, 256, 0, s>>>(part, b, C, MN, N, SK);
    }
}

extern "C" void kernel_launch(void* const* d_in, const int* in_sizes, int n_in,
                              void* d_out, int out_size, void* d_ws, size_t ws_size,
                              hipStream_t stream) {
    const float* x       = (const float*)d_in[0];
    const int*   edge    = (const int*)d_in[1];
    const int*   hedge   = (const int*)d_in[3];
    const float* fp      = (const float*)d_in[4];
    const float* text_em = (const float*)d_in[5];
    const float* fc1_W = (const float*)d_in[7];  const float* fc1_b = (const float*)d_in[8];
    const float* fc2_W = (const float*)d_in[9];  const float* fc2_b = (const float*)d_in[10];
    const float* fc3_W = (const float*)d_in[11]; const float* fc3_b = (const float*)d_in[12];
    const float* fcg1_W = (const float*)d_in[13]; const float* fcg1_b = (const float*)d_in[14];
    const float* fcg2_W = (const float*)d_in[15]; const float* fcg2_b = (const float*)d_in[16];
    const float* fchg1_W = (const float*)d_in[17]; const float* fchg1_b = (const float*)d_in[18];
    const float* fchg2_W = (const float*)d_in[19]; const float* fchg2_b = (const float*)d_in[20];
    const float* gin1_W = (const float*)d_in[21]; const float* gin1_b = (const float*)d_in[22];
    const float* gin2_W = (const float*)d_in[23]; const float* gin2_b = (const float*)d_in[24];
    const float* h3_W = (const float*)d_in[25]; const float* h3_b = (const float*)d_in[26];
    const float* h4_W = (const float*)d_in[27]; const float* h4_b = (const float*)d_in[28];
    const float* Wq = (const float*)d_in[29];
    const float* Wk = (const float*)d_in[30];
    const float* Wv = (const float*)d_in[31];
    const float* conv_W = (const float*)d_in[32]; const float* conv_b = (const float*)d_in[33];
    const float* mlp1_W = (const float*)d_in[34]; const float* mlp1_b = (const float*)d_in[35];
    const float* mlp2_W = (const float*)d_in[36]; const float* mlp2_b = (const float*)d_in[37];

    const int* e_src = edge;
    const int* e_dst = edge + N_EDGES;
    const int* h_nid = hedge;
    const int* h_eid = hedge + N_HNNZ;

    float* ws = (float*)d_ws;
    const size_t ZONE = 51609600;
    // ---- phase A (GIN) ----
    double* agg64 = (double*)ws;                    // 4,300,800 d = 8,601,600 f
    float*  xg1   = ws + 8601600;                   // 4,300,800 f
    // ---- phase H (hypergraph) ----
    float*  xw      = ws;                           // 8,601,600 f
    double* e1_64   = (double*)(ws + 8601600);      // 1,720,320 d
    float*  e1_32   = ws + 12042240;                // 1,720,320 f
    double* hnode64 = (double*)(ws + 13762560);     // 8,601,600 d
    float*  hnode32 = ws + 30965760;                // 8,601,600 f
    float*  xw2     = ws + 39567360;                // 13,107,200 f (overlaps dead xg_raw tail)
    double* e2_64   = (double*)ws;                  // 2,621,440 d
    double* hn2_64  = (double*)(ws + 5242880);      // 13,107,200 d
    float*  e2_32   = ws + 31457280;                // 2,621,440 f
    // ---- phase D (attention) ----
    float* in_t = ws;
    float* q    = ws + 2097152;
    float* kk   = ws + 10485760;
    float* v    = ws + 18874368;
    float* att  = ws + 27262976;
    float* cbuf = ws + 35651584;
    float* m1   = ws + 39829504;
    float* part = ws;                               // split-K scratch (zone-dead phases only)
    // ---- persistent ----
    float* xg_raw = ws + ZONE;                      // 1,720,320
    float* xg_mid = ws + ZONE + 1720320;            // 1,048,576
    float* hx_raw = ws + ZONE + 2768896;            // 524,288
    float* hx_mid = ws + ZONE + 3293184;            // 1,048,576
    float* h1     = ws + ZONE + 4341760;            // 131,072
    float* fp_o   = ws + ZONE + 4472832;            // 524,288
    float* tt     = ws + ZONE + 4997120;            // 524,288
    float* ecnt   = ws + ZONE + 5521408;            // 10,240
    float* deg    = ws + ZONE + 5531648;            // 51,200
    const size_t NEED = (ZONE + 5582848) * sizeof(float);
    if (ws_size < NEED) return;

    float* out_y  = (float*)d_out;
    float* xg_out = out_y + 1024;
    float* hx_out = out_y + 1024 + 1024 * 512;

    const int BT = 256;
    // ---------- GIN branch ----------
    hipMemsetAsync(agg64, 0, (size_t)N_NODES * FXD * 8, stream);
    scatter_add_feat_d<<<(N_EDGES * FXD + BT - 1) / BT, BT, 0, stream>>>(x, e_src, e_dst, agg64, N_EDGES, FXD);
    launch_gemm(x, agg64, gin1_W, gin1_b, xg1, N_NODES, FXD, FXD, true, stream);
    hipMemsetAsync(agg64, 0, (size_t)N_NODES * FXD * 8, stream);
    scatter_add_feat_d<<<(N_EDGES * FXD + BT - 1) / BT, BT, 0, stream>>>(xg1, e_src, e_dst, agg64, N_EDGES, FXD);
    gin2pool<<<dim3(14, NB), 256, 0, stream>>>(xg1, agg64, gin2_W, gin2_b, xg_raw);
    launch_gemm64(xg_raw, fcg1_W, fcg1_b, xg_mid, NB, 1024, 1680, true, part, stream);
    launch_gemm64(xg_mid, fcg2_W, fcg2_b, xg_out, NB, 512, 1024, false, part, stream);

    // ---------- hypergraph branch ----------
    hipMemsetAsync(ecnt, 0, N_HEDGES * 4, stream);
    hipMemsetAsync(deg, 0, N_NODES * 4, stream);
    count_incidence<<<(N_HNNZ + BT - 1) / BT, BT, 0, stream>>>(h_nid, h_eid, deg, ecnt, N_HNNZ);
    launch_gemm(x, nullptr, h3_W, nullptr, xw, N_NODES, 168, FXD, false, stream);
    hipMemsetAsync(e1_64, 0, (size_t)N_HEDGES * 168 * 8, stream);
    scatter_add_feat_d<<<(N_HNNZ * 168 + BT - 1) / BT, BT, 0, stream>>>(xw, h_nid, h_eid, e1_64, N_HNNZ, 168);
    scale_binv_d2f<<<(N_HEDGES * 168 + BT - 1) / BT, BT, 0, stream>>>(e1_64, ecnt, e1_32, N_HEDGES, 168);
    hipMemsetAsync(hnode64, 0, (size_t)N_NODES * 168 * 8, stream);
    scatter_add_feat_d<<<(N_HNNZ * 168 + BT - 1) / BT, BT, 0, stream>>>(e1_32, h_eid, h_nid, hnode64, N_HNNZ, 168);
    scale_dinv_bias_d2f<<<(N_NODES * 168 + BT - 1) / BT, BT, 0, stream>>>(hnode64, deg, h3_b, hnode32, N_NODES, 168);
    launch_gemm(hnode32, nullptr, h4_W, nullptr, xw2, N_NODES, 256, 168, false, stream);
    hipMemsetAsync(e2_64, 0, (size_t)N_HEDGES * 256 * 8, stream);
    scatter_add_feat_d<<<(N_HNNZ * 256 + BT - 1) / BT, BT, 0, stream>>>(xw2, h_nid, h_eid, e2_64, N_HNNZ, 256);
    scale_binv_d2f<<<(N_HEDGES * 256 + BT - 1) / BT, BT, 0, stream>>>(e2_64, ecnt, e2_32, N_HEDGES, 256);
    hipMemsetAsync(hn2_64, 0, (size_t)N_NODES * 256 * 8, stream);
    scatter_add_feat_d<<<(N_HNNZ * 256 + BT - 1) / BT, BT, 0, stream>>>(e2_32, h_eid, h_nid, hn2_64, N_HNNZ, 256);
    pool_hyper<<<(NB * 256 + BT - 1) / BT, BT, 0, stream>>>(hn2_64, deg, h4_b, hx_raw);
    launch_gemm64(hx_raw, fchg1_W, fchg1_b, hx_mid, NB, 1024, 512, true, part, stream);
    launch_gemm64(hx_mid, fchg2_W, fchg2_b, hx_out, NB, 512, 1024, false, part, stream);

    // ---------- fingerprint + text (zone dead -> part scratch OK) ----------
    launch_gemm64(fp, fc1_W, fc1_b, h1, NB, FP2, FP_DIM, true, part, stream);
    launch_gemm64(h1, fc2_W, fc2_b, fp_o, NB, HID, FP2, false, part, stream);
    launch_gemm64(text_em, fc3_W, fc3_b, tt, NB, HID, 768, false, part, stream);

    // ---------- fusion attention ----------
    pack_tokens<<<(4096 * 512 + BT - 1) / BT, BT, 0, stream>>>(fp_o, xg_out, hx_out, tt, in_t);
    launch_gemm(in_t, nullptr, Wq, nullptr, q, 4096, 2048, 512, false, stream);
    launch_gemm(in_t, nullptr, Wk, nullptr, kk, 4096, 2048, 512, false, stream);
    launch_gemm(in_t, nullptr, Wv, nullptr, v, 4096, 2048, 512, false, stream);
    attn_kernel<<<1024, 256, 0, stream>>>(q, kk, v, att);
    conv_relu<<<(1024 * 4 * 2 * 510 + BT - 1) / BT, BT, 0, stream>>>(att, conv_W, conv_b, cbuf);
    launch_gemm64(cbuf, mlp1_W, mlp1_b, m1, NB, 1024, 4080, true, part, stream);
    rowdot<<<256, 256, 0, stream>>>(m1, mlp2_W, mlp2_b, out_y, NB, 1024);
}

// Round 5
// 1711.954 us; speedup vs baseline: 2.1043x; 1.1550x over previous
//
#include <hip/hip_runtime.h>
#include <hip/hip_bf16.h>

// ---------------- constants ----------------
#define N_NODES 51200
#define N_EDGES 204800
#define N_HNNZ  102400
#define N_HEDGES 10240
#define NB 1024          // batch (graphs)
#define NPG 50           // nodes per graph (51200/1024)
#define FXD 84
#define FP_DIM 2513
#define FP2 128
#define HID 512

typedef __attribute__((ext_vector_type(4))) float f32x4;
typedef __attribute__((ext_vector_type(8))) __bf16 bf16x8;
typedef __attribute__((ext_vector_type(4))) short short4_t;

static __device__ __forceinline__ unsigned short f2bf(float f) {
    unsigned u = __builtin_bit_cast(unsigned, f);
    u += 0x7FFFu + ((u >> 16) & 1u);   // round-to-nearest-even
    return (unsigned short)(u >> 16);
}

// ---------------- MFMA GEMM 128x128: C = act(Asrc @ W^T + b) ----------------
// Asrc modes: (A)               : plain f32 [M,K]
//             (A, Aadd)         : f32 + (float)f64  (GIN fuse)
//             (A64, rowcnt)     : (float)f64 * 1/max(rowcnt[m],1)  (hyper fuse)
// W: [N,K] f32 row-major; C: [M,N] f32. 4 waves (2x2), 4x4 mfma_16x16x32_bf16.
template<bool RELU>
__global__ __launch_bounds__(256) void gemm_mfma(const float* __restrict__ A,
                                                 const double* __restrict__ Aadd,
                                                 const double* __restrict__ A64,
                                                 const float* __restrict__ rowcnt,
                                                 const float* __restrict__ W,
                                                 const float* __restrict__ bias,
                                                 float* __restrict__ C,
                                                 int M, int N, int K) {
    __shared__ unsigned short Asm[128][32];
    __shared__ unsigned short Bsm[128][32];
    const int tid = threadIdx.x;
    const int bm = blockIdx.y * 128, bn = blockIdx.x * 128;
    const int wid = tid >> 6, lane = tid & 63;
    const int wm = (wid >> 1) * 64, wn = (wid & 1) * 64;
    const int lr = lane & 15, lg = lane >> 4;
    const bool kvec = ((K & 3) == 0);

    f32x4 zero = {0.f, 0.f, 0.f, 0.f};
    f32x4 acc[4][4];
#pragma unroll
    for (int i = 0; i < 4; i++)
#pragma unroll
        for (int j = 0; j < 4; j++) acc[i][j] = zero;

    for (int k0 = 0; k0 < K; k0 += 32) {
#pragma unroll
        for (int i = 0; i < 4; i++) {
            int fidx = i * 256 + tid;
            int row = fidx >> 3, kq = (fidx & 7) << 2;
            int gk = k0 + kq;
            float v0 = 0.f, v1 = 0.f, v2 = 0.f, v3 = 0.f;
            int gm = bm + row;
            if (gm < M && gk < K) {
                if (A64) {
                    const double* p64 = A64 + (size_t)gm * K + gk;
                    float rs = rowcnt ? 1.f / fmaxf(rowcnt[gm], 1.f) : 1.f;
                    v0 = (float)p64[0] * rs;
                    if (gk + 1 < K) v1 = (float)p64[1] * rs;
                    if (gk + 2 < K) v2 = (float)p64[2] * rs;
                    if (gk + 3 < K) v3 = (float)p64[3] * rs;
                } else if (Aadd) {
                    const float* p = A + (size_t)gm * K + gk;
                    const double* pa = Aadd + (size_t)gm * K + gk;
                    v0 = p[0] + (float)pa[0];
                    if (gk + 1 < K) v1 = p[1] + (float)pa[1];
                    if (gk + 2 < K) v2 = p[2] + (float)pa[2];
                    if (gk + 3 < K) v3 = p[3] + (float)pa[3];
                } else {
                    const float* p = A + (size_t)gm * K + gk;
                    if (kvec && gk + 4 <= K) {
                        float4 f = *(const float4*)p;
                        v0 = f.x; v1 = f.y; v2 = f.z; v3 = f.w;
                    } else {
                        v0 = p[0];
                        if (gk + 1 < K) v1 = p[1];
                        if (gk + 2 < K) v2 = p[2];
                        if (gk + 3 < K) v3 = p[3];
                    }
                }
            }
            short4_t sv;
            sv[0] = (short)f2bf(v0); sv[1] = (short)f2bf(v1);
            sv[2] = (short)f2bf(v2); sv[3] = (short)f2bf(v3);
            *(short4_t*)&Asm[row][kq] = sv;

            v0 = v1 = v2 = v3 = 0.f;
            int gn = bn + row;
            if (gn < N && gk < K) {
                const float* p = W + (size_t)gn * K + gk;
                if (kvec && gk + 4 <= K) {
                    float4 f = *(const float4*)p;
                    v0 = f.x; v1 = f.y; v2 = f.z; v3 = f.w;
                } else {
                    v0 = p[0];
                    if (gk + 1 < K) v1 = p[1];
                    if (gk + 2 < K) v2 = p[2];
                    if (gk + 3 < K) v3 = p[3];
                }
            }
            sv[0] = (short)f2bf(v0); sv[1] = (short)f2bf(v1);
            sv[2] = (short)f2bf(v2); sv[3] = (short)f2bf(v3);
            *(short4_t*)&Bsm[row][kq] = sv;
        }
        __syncthreads();

        bf16x8 af[4], bf[4];
#pragma unroll
        for (int m = 0; m < 4; m++)
            af[m] = *(const bf16x8*)&Asm[wm + m * 16 + lr][lg * 8];
#pragma unroll
        for (int n = 0; n < 4; n++)
            bf[n] = *(const bf16x8*)&Bsm[wn + n * 16 + lr][lg * 8];
#pragma unroll
        for (int m = 0; m < 4; m++)
#pragma unroll
            for (int n = 0; n < 4; n++)
                acc[m][n] = __builtin_amdgcn_mfma_f32_16x16x32_bf16(af[m], bf[n], acc[m][n], 0, 0, 0);
        __syncthreads();
    }

#pragma unroll
    for (int m = 0; m < 4; m++) {
#pragma unroll
        for (int n = 0; n < 4; n++) {
            int col = bn + wn + n * 16 + lr;
            if (col >= N) continue;
            float bv = bias ? bias[col] : 0.f;
#pragma unroll
            for (int r = 0; r < 4; r++) {
                int row = bm + wm + m * 16 + lg * 4 + r;
                if (row >= M) continue;
                float v = acc[m][n][r] + bv;
                if (RELU) v = fmaxf(v, 0.f);
                C[(size_t)row * N + col] = v;
            }
        }
    }
}

// ---------------- MFMA GEMM 64x64 with intra-block wave K-split ----------------
template<bool RELU, bool PARTIAL>
__global__ __launch_bounds__(256) void gemm64(const float* __restrict__ A,
                                              const float* __restrict__ W,
                                              const float* __restrict__ bias,
                                              float* __restrict__ C,
                                              int M, int N, int K, int kchunk) {
    __shared__ __align__(16) char pool[65536];   // A:16K | B:16K ; reused as 64K f32 red
    char* Ab = pool;
    char* Bb = pool + 16384;
    const int tid = threadIdx.x;
    const int bm = blockIdx.y * 64, bn = blockIdx.x * 64;
    const int wid = tid >> 6, lane = tid & 63;
    const int lr = lane & 15, lg = lane >> 4;
    const int kbeg = blockIdx.z * kchunk;
    const int kend = min(K, kbeg + kchunk);
    const bool kvec = ((K & 3) == 0);

    f32x4 zero = {0.f, 0.f, 0.f, 0.f};
    f32x4 acc[4][4];
#pragma unroll
    for (int i = 0; i < 4; i++)
#pragma unroll
        for (int j = 0; j < 4; j++) acc[i][j] = zero;

    for (int kc = kbeg; kc < kend; kc += 128) {
#pragma unroll
        for (int u = 0; u < 8; u++) {
            int s = u * 256 + tid;               // 2048 8B-slots per matrix
            int row = s >> 5, kq = (s & 31) << 2;
            int gk = kc + kq;
            int off = (row * 256 + (s & 31) * 8) ^ ((row & 7) << 4);

            float v0 = 0.f, v1 = 0.f, v2 = 0.f, v3 = 0.f;
            int gm = bm + row;
            if (gm < M && gk < kend) {
                const float* p = A + (size_t)gm * K + gk;
                if (kvec && gk + 4 <= kend) {
                    float4 f = *(const float4*)p;
                    v0 = f.x; v1 = f.y; v2 = f.z; v3 = f.w;
                } else {
                    v0 = p[0];
                    if (gk + 1 < kend) v1 = p[1];
                    if (gk + 2 < kend) v2 = p[2];
                    if (gk + 3 < kend) v3 = p[3];
                }
            }
            short4_t sv;
            sv[0] = (short)f2bf(v0); sv[1] = (short)f2bf(v1);
            sv[2] = (short)f2bf(v2); sv[3] = (short)f2bf(v3);
            *(short4_t*)(Ab + off) = sv;

            v0 = v1 = v2 = v3 = 0.f;
            int gn = bn + row;
            if (gn < N && gk < kend) {
                const float* p = W + (size_t)gn * K + gk;
                if (kvec && gk + 4 <= kend) {
                    float4 f = *(const float4*)p;
                    v0 = f.x; v1 = f.y; v2 = f.z; v3 = f.w;
                } else {
                    v0 = p[0];
                    if (gk + 1 < kend) v1 = p[1];
                    if (gk + 2 < kend) v2 = p[2];
                    if (gk + 3 < kend) v3 = p[3];
                }
            }
            sv[0] = (short)f2bf(v0); sv[1] = (short)f2bf(v1);
            sv[2] = (short)f2bf(v2); sv[3] = (short)f2bf(v3);
            *(short4_t*)(Bb + off) = sv;
        }
        __syncthreads();

        bf16x8 af[4], bf[4];
        const int kb = wid * 64 + lg * 16;       // byte offset in row
#pragma unroll
        for (int m = 0; m < 4; m++) {
            int row = m * 16 + lr;
            af[m] = *(const bf16x8*)(Ab + ((row * 256 + kb) ^ ((row & 7) << 4)));
        }
#pragma unroll
        for (int n = 0; n < 4; n++) {
            int row = n * 16 + lr;
            bf[n] = *(const bf16x8*)(Bb + ((row * 256 + kb) ^ ((row & 7) << 4)));
        }
#pragma unroll
        for (int m = 0; m < 4; m++)
#pragma unroll
            for (int n = 0; n < 4; n++)
                acc[m][n] = __builtin_amdgcn_mfma_f32_16x16x32_bf16(af[m], bf[n], acc[m][n], 0, 0, 0);
        __syncthreads();
    }

    float* red = (float*)pool;                   // 4 x 4096 f32
#pragma unroll
    for (int m = 0; m < 4; m++)
#pragma unroll
        for (int n = 0; n < 4; n++)
#pragma unroll
            for (int r = 0; r < 4; r++)
                red[wid * 4096 + (m * 16 + lg * 4 + r) * 64 + n * 16 + lr] = acc[m][n][r];
    __syncthreads();
#pragma unroll
    for (int u = 0; u < 16; u++) {
        int idx = u * 256 + tid;
        int row = idx >> 6, col = idx & 63;
        int gm = bm + row, gn = bn + col;
        if (gm >= M || gn >= N) continue;
        float s = red[idx] + red[4096 + idx] + red[8192 + idx] + red[12288 + idx];
        if (PARTIAL) {
            C[(size_t)blockIdx.z * M * N + (size_t)gm * N + gn] = s;
        } else {
            s += bias ? bias[gn] : 0.f;
            if (RELU) s = fmaxf(s, 0.f);
            C[(size_t)gm * N + gn] = s;
        }
    }
}

template<bool RELU>
__global__ void reduce_partial(const float* __restrict__ part, const float* __restrict__ bias,
                               float* __restrict__ C, int MN, int N, int SK) {
    int i = blockIdx.x * 256 + threadIdx.x;
    if (i >= MN) return;
    float s = 0.f;
    for (int z = 0; z < SK; z++) s += part[(size_t)z * MN + i];
    s += bias ? bias[i % N] : 0.f;
    if (RELU) s = fmaxf(s, 0.f);
    C[i] = s;
}

// ---------------- fused GIN2 GEMM + bias + relu + 50-row max/mean pool ----------------
// ONE BLOCK PER GRAPH; loops over all 14 column tiles so A stays in this CU's
// L1/L2 (fixes cross-XCD re-fetch). LDS 34KB: Ab|Bb (staging) reused as redA|redB.
__global__ __launch_bounds__(256) void gin2pool(const float* __restrict__ xg1,
                                                const double* __restrict__ agg,
                                                const float* __restrict__ W,
                                                const float* __restrict__ bias,
                                                float* __restrict__ out) {
    __shared__ __align__(16) char lds[34816];   // 16K A | 16K B | 2K pool partials
    char* Ab = lds;
    char* Bb = lds + 16384;
    float* redA = (float*)lds;                  // 4096 f32 (over Ab)
    float* redB = (float*)(lds + 16384);        // 4096 f32 (over Bb)
    float* pr   = (float*)(lds + 32768);        // 512 f32
    const int tid = threadIdx.x;
    const int g = blockIdx.x;
    const int wid = tid >> 6, lane = tid & 63;
    const int lr = lane & 15, lg = lane >> 4;
    const int K = FXD, N = 840;

    for (int t = 0; t < 14; t++) {
        const int bn = t * 64;
        __syncthreads();   // previous tile's redA/pr reads done before restage
        // ---- stage A (graph rows, zero-pad to 64x128) and B (64 W-rows) ----
#pragma unroll
        for (int u = 0; u < 8; u++) {
            int s = u * 256 + tid;
            int row = s >> 5, kq = (s & 31) << 2;
            int off = (row * 256 + (s & 31) * 8) ^ ((row & 7) << 4);
            float v0 = 0.f, v1 = 0.f, v2 = 0.f, v3 = 0.f;
            if (row < NPG && kq < K) {
                const float* p = xg1 + ((size_t)g * NPG + row) * K + kq;
                const double* pa = agg + ((size_t)g * NPG + row) * K + kq;
                v0 = p[0] + (float)pa[0];
                if (kq + 1 < K) v1 = p[1] + (float)pa[1];
                if (kq + 2 < K) v2 = p[2] + (float)pa[2];
                if (kq + 3 < K) v3 = p[3] + (float)pa[3];
            }
            short4_t sv;
            sv[0] = (short)f2bf(v0); sv[1] = (short)f2bf(v1);
            sv[2] = (short)f2bf(v2); sv[3] = (short)f2bf(v3);
            *(short4_t*)(Ab + off) = sv;

            v0 = v1 = v2 = v3 = 0.f;
            int gn = bn + row;
            if (gn < N && kq < K) {
                const float* p = W + (size_t)gn * K + kq;
                v0 = p[0];
                if (kq + 1 < K) v1 = p[1];
                if (kq + 2 < K) v2 = p[2];
                if (kq + 3 < K) v3 = p[3];
            }
            sv[0] = (short)f2bf(v0); sv[1] = (short)f2bf(v1);
            sv[2] = (short)f2bf(v2); sv[3] = (short)f2bf(v3);
            *(short4_t*)(Bb + off) = sv;
        }
        __syncthreads();

        // ---- MFMA: wave wid takes k-slice wid*32 of the 128-padded K ----
        f32x4 zero = {0.f, 0.f, 0.f, 0.f};
        f32x4 acc[4][4];
#pragma unroll
        for (int i = 0; i < 4; i++)
#pragma unroll
            for (int j = 0; j < 4; j++) acc[i][j] = zero;
        bf16x8 af[4], bf[4];
        const int kb = wid * 64 + lg * 16;
#pragma unroll
        for (int m = 0; m < 4; m++) {
            int row = m * 16 + lr;
            af[m] = *(const bf16x8*)(Ab + ((row * 256 + kb) ^ ((row & 7) << 4)));
        }
#pragma unroll
        for (int n = 0; n < 4; n++) {
            int row = n * 16 + lr;
            bf[n] = *(const bf16x8*)(Bb + ((row * 256 + kb) ^ ((row & 7) << 4)));
        }
#pragma unroll
        for (int m = 0; m < 4; m++)
#pragma unroll
            for (int n = 0; n < 4; n++)
                acc[m][n] = __builtin_amdgcn_mfma_f32_16x16x32_bf16(af[m], bf[n], acc[m][n], 0, 0, 0);
        __syncthreads();   // frag reads done; safe to overwrite Ab/Bb with red

        // ---- cross-wave reduce (2-phase, 32KB) ----
        if (wid == 0 || wid == 1) {
            float* r = (wid == 0) ? redA : redB;
#pragma unroll
            for (int m = 0; m < 4; m++)
#pragma unroll
                for (int n = 0; n < 4; n++)
#pragma unroll
                    for (int r4 = 0; r4 < 4; r4++)
                        r[(m * 16 + lg * 4 + r4) * 64 + n * 16 + lr] = acc[m][n][r4];
        }
        __syncthreads();
        if (wid == 2 || wid == 3) {
            float* r = (wid == 2) ? redA : redB;
#pragma unroll
            for (int m = 0; m < 4; m++)
#pragma unroll
                for (int n = 0; n < 4; n++)
#pragma unroll
                    for (int r4 = 0; r4 < 4; r4++)
                        r[(m * 16 + lg * 4 + r4) * 64 + n * 16 + lr] += acc[m][n][r4];
        }
        __syncthreads();
        // ---- combine + bias + relu into redA ----
#pragma unroll
        for (int u = 0; u < 16; u++) {
            int idx = u * 256 + tid;
            int col = idx & 63;
            float s = redA[idx] + redB[idx];
            s += (bn + col < N) ? bias[bn + col] : 0.f;
            redA[idx] = fmaxf(s, 0.f);
        }
        __syncthreads();
        // ---- pool rows 0..49 per column (4 row-segments in parallel) ----
        {
            int col = tid & 63, seg = tid >> 6;
            int r0 = seg * 13, r1 = (seg < 3) ? r0 + 13 : 50;
            float mx = -1e30f, sm = 0.f;
            for (int r = r0; r < r1; r++) {
                float v = redA[r * 64 + col];
                mx = fmaxf(mx, v);
                sm += v;
            }
            pr[seg * 128 + col] = mx;
            pr[seg * 128 + 64 + col] = sm;
        }
        __syncthreads();
        if (tid < 64) {
            int col = bn + tid;
            if (col < N) {
                float mx = fmaxf(fmaxf(pr[tid], pr[128 + tid]), fmaxf(pr[256 + tid], pr[384 + tid]));
                float sm = pr[64 + tid] + pr[192 + tid] + pr[320 + tid] + pr[448 + tid];
                out[(size_t)g * 1680 + col] = mx;
                out[(size_t)g * 1680 + 840 + col] = sm * (1.f / NPG);
            }
        }
    }
}

// ---------------- N=1 GEMM: out[m] = A[m]·w + b ----------------
__global__ __launch_bounds__(256) void rowdot(const float* __restrict__ A,
                                              const float* __restrict__ w,
                                              const float* __restrict__ b,
                                              float* __restrict__ out, int Mrows, int K) {
    int row = blockIdx.x * 4 + (threadIdx.x >> 6);
    int lane = threadIdx.x & 63;
    if (row >= Mrows) return;
    float s = 0.f;
    for (int k = lane; k < K; k += 64) s += A[(size_t)row * K + k] * w[k];
#pragma unroll
    for (int off = 32; off > 0; off >>= 1) s += __shfl_xor(s, off, 64);
    if (lane == 0) out[row] = s + b[0];
}

// ---------------- f64-accumulating scatter-add (replay-deterministic) ----------------
__global__ void scatter_add_feat_d(const float* __restrict__ src,
                                   const int* __restrict__ smap,
                                   const int* __restrict__ dmap,
                                   double* __restrict__ dst, int nnz, int F) {
    int i = blockIdx.x * blockDim.x + threadIdx.x;
    int total = nnz * F;
    if (i >= total) return;
    int j = i / F, f = i - j * F;
    unsafeAtomicAdd(&dst[(size_t)dmap[j] * F + f], (double)src[(size_t)smap[j] * F + f]);
}

// scatter node->edge with fused Dinv scale + bias: src = (f64 node feat)*Dinv + b
__global__ void scatter_n2e_scaled(const double* __restrict__ hnode64,
                                   const float* __restrict__ deg,
                                   const float* __restrict__ b,
                                   const int* __restrict__ nid,
                                   const int* __restrict__ eid,
                                   double* __restrict__ dst, int nnz, int F) {
    int i = blockIdx.x * blockDim.x + threadIdx.x;
    int total = nnz * F;
    if (i >= total) return;
    int j = i / F, f = i - j * F;
    int n = nid[j], e = eid[j];
    float d = deg[n];
    float inv = d > 0.f ? 1.f / d : 0.f;
    float v = (float)hnode64[(size_t)n * F + f] * inv + b[f];
    unsafeAtomicAdd(&dst[(size_t)e * F + f], (double)v);
}

// counts: f32 sums of 1.0 are exact integers -> order-invariant
__global__ void count_incidence(const int* __restrict__ nid, const int* __restrict__ eid,
                                float* __restrict__ deg, float* __restrict__ ecnt, int nnz) {
    int i = blockIdx.x * blockDim.x + threadIdx.x;
    if (i >= nnz) return;
    atomicAdd(&deg[nid[i]], 1.f);
    atomicAdd(&ecnt[eid[i]], 1.f);
}

// ---------------- fused hyper scale + 50-row max/mean pool ----------------
__global__ void pool_hyper(const double* __restrict__ hn64, const float* __restrict__ deg,
                           const float* __restrict__ b, float* __restrict__ out) {
    int i = blockIdx.x * blockDim.x + threadIdx.x;    // over 1024*256
    if (i >= NB * 256) return;
    int o = i & 255, g = i >> 8;
    float bo = b[o];
    const double* base = hn64 + (size_t)g * NPG * 256 + o;
    const float* dg = deg + g * NPG;
    float mx = -1e30f, sm = 0.f;
    for (int n = 0; n < NPG; n++) {
        float d = dg[n];
        float inv = d > 0.f ? 1.f / d : 0.f;
        float v = (float)base[(size_t)n * 256] * inv + bo;
        mx = fmaxf(mx, v);
        sm += v;
    }
    out[(size_t)g * 512 + o] = mx;
    out[(size_t)g * 512 + 256 + o] = sm * (1.f / NPG);
}

// ---------------- pack fusion tokens ----------------
__global__ void pack_tokens(const float* __restrict__ fp_o, const float* __restrict__ xg,
                            const float* __restrict__ hxg, const float* __restrict__ t,
                            float* __restrict__ in_t) {
    int i = blockIdx.x * blockDim.x + threadIdx.x;
    if (i >= 4096 * 512) return;
    int d = i & 511;
    int row = i >> 9;
    int tok = row & 3, b = row >> 2;
    const float* s = (tok == 0) ? fp_o : (tok == 1) ? xg : (tok == 2) ? hxg : t;
    in_t[i] = s[b * 512 + d];
}

// ---------------- fused 4x4 attention per (b,h); qkv fused layout [4096][6144] ----------------
__global__ __launch_bounds__(256) void attn_kernel(const float* __restrict__ QKV,
                                                   float* __restrict__ att) {
    int wid = threadIdx.x >> 6, lane = threadIdx.x & 63;
    int bh = blockIdx.x * 4 + wid;
    int b = bh >> 2, h = bh & 3;
    const float* qb = QKV + (size_t)b * 4 * 6144 + h * 512;
    const float* kb = qb + 2048;
    const float* vb = qb + 4096;
    float qr[4][8], kr[4][8];
#pragma unroll
    for (int n = 0; n < 4; n++)
#pragma unroll
        for (int c = 0; c < 8; c++) {
            qr[n][c] = qb[n * 6144 + c * 64 + lane];
            kr[n][c] = kb[n * 6144 + c * 64 + lane];
        }
    float s[4][4];
#pragma unroll
    for (int n = 0; n < 4; n++)
#pragma unroll
        for (int m = 0; m < 4; m++) {
            float p = 0.f;
#pragma unroll
            for (int c = 0; c < 8; c++) p += qr[n][c] * kr[m][c];
#pragma unroll
            for (int off = 32; off > 0; off >>= 1) p += __shfl_xor(p, off, 64);
            s[n][m] = p * 0.04419417382415922f;   // 1/sqrt(512)
        }
    float pm[4][4];
#pragma unroll
    for (int n = 0; n < 4; n++) {
        float mx = fmaxf(fmaxf(s[n][0], s[n][1]), fmaxf(s[n][2], s[n][3]));
        float e0 = expf(s[n][0] - mx), e1 = expf(s[n][1] - mx);
        float e2 = expf(s[n][2] - mx), e3 = expf(s[n][3] - mx);
        float inv = 1.f / (e0 + e1 + e2 + e3);
        pm[n][0] = e0 * inv; pm[n][1] = e1 * inv; pm[n][2] = e2 * inv; pm[n][3] = e3 * inv;
    }
    float* ab = att + (size_t)bh * 4 * 512;
#pragma unroll
    for (int c = 0; c < 8; c++) {
        float v0 = vb[0 * 6144 + c * 64 + lane];
        float v1 = vb[1 * 6144 + c * 64 + lane];
        float v2 = vb[2 * 6144 + c * 64 + lane];
        float v3 = vb[3 * 6144 + c * 64 + lane];
#pragma unroll
        for (int n = 0; n < 4; n++) {
            float o = pm[n][0] * v0 + pm[n][1] * v1 + pm[n][2] * v2 + pm[n][3] * v3;
            ab[n * 512 + c * 64 + lane] = o;
        }
    }
}

// ---------------- conv 3x3 VALID + relu ----------------
__global__ void conv_relu(const float* __restrict__ att, const float* __restrict__ cw,
                          const float* __restrict__ cb, float* __restrict__ c) {
    __shared__ float w[144];
    __shared__ float bias[4];
    int t = threadIdx.x;
    if (t < 144) w[t] = cw[t];
    if (t < 4) bias[t] = cb[t];
    __syncthreads();
    int i = blockIdx.x * blockDim.x + t;
    if (i >= 1024 * 4 * 2 * 510) return;
    int wo = i % 510;
    int r = i / 510;
    int ho = r & 1; r >>= 1;
    int co = r & 3; int b = r >> 2;
    float acc = bias[co];
#pragma unroll
    for (int ci = 0; ci < 4; ci++)
#pragma unroll
        for (int kh = 0; kh < 3; kh++)
#pragma unroll
            for (int kw = 0; kw < 3; kw++)
                acc += att[(((size_t)b * 4 + ci) * 4 + ho + kh) * 512 + wo + kw] *
                       w[((co * 4 + ci) * 3 + kh) * 3 + kw];
    c[i] = fmaxf(acc, 0.f);
}

// ---------------- host side ----------------
static inline void launch_gemm(const float* A, const double* Aadd,
                               const double* A64, const float* rowcnt,
                               const float* W, const float* b, float* C,
                               int M, int N, int K, bool relu, hipStream_t s) {
    dim3 g((N + 127) / 128, (M + 127) / 128);
    if (relu) gemm_mfma<true><<<g, 256, 0, s>>>(A, Aadd, A64, rowcnt, W, b, C, M, N, K);
    else      gemm_mfma<false><<<g, 256, 0, s>>>(A, Aadd, A64, rowcnt, W, b, C, M, N, K);
}

static inline void launch_gemm64(const float* A, const float* W, const float* b, float* C,
                                 int M, int N, int K, bool relu, float* part, hipStream_t s) {
    int gx = (N + 63) / 64, gy = (M + 63) / 64;
    int targetSK = 256 / (gx * gy);
    if (targetSK < 1) targetSK = 1;
    if (targetSK > 8) targetSK = 8;
    int kchunk = K, SK = 1;
    if (targetSK > 1) {
        kchunk = (((K + targetSK - 1) / targetSK) + 127) & ~127;
        SK = (K + kchunk - 1) / kchunk;
    }
    if (SK <= 1) {
        dim3 g(gx, gy);
        if (relu) gemm64<true, false><<<g, 256, 0, s>>>(A, W, b, C, M, N, K, K);
        else      gemm64<false, false><<<g, 256, 0, s>>>(A, W, b, C, M, N, K, K);
    } else {
        dim3 g(gx, gy, SK);
        gemm64<false, true><<<g, 256, 0, s>>>(A, W, nullptr, part, M, N, K, kchunk);
        int MN = M * N;
        if (relu) reduce_partial<true><<<(MN + 255) / 256, 256, 0, s>>>(part, b, C, MN, N, SK);
        else      reduce_partial<false><<<(MN + 255) / 256, 256, 0, s>>>(part, b, C, MN, N, SK);
    }
}

extern "C" void kernel_launch(void* const* d_in, const int* in_sizes, int n_in,
                              void* d_out, int out_size, void* d_ws, size_t ws_size,
                              hipStream_t stream) {
    const float* x       = (const float*)d_in[0];
    const int*   edge    = (const int*)d_in[1];
    const int*   hedge   = (const int*)d_in[3];
    const float* fp      = (const float*)d_in[4];
    const float* text_em = (const float*)d_in[5];
    const float* fc1_W = (const float*)d_in[7];  const float* fc1_b = (const float*)d_in[8];
    const float* fc2_W = (const float*)d_in[9];  const float* fc2_b = (const float*)d_in[10];
    const float* fc3_W = (const float*)d_in[11]; const float* fc3_b = (const float*)d_in[12];
    const float* fcg1_W = (const float*)d_in[13]; const float* fcg1_b = (const float*)d_in[14];
    const float* fcg2_W = (const float*)d_in[15]; const float* fcg2_b = (const float*)d_in[16];
    const float* fchg1_W = (const float*)d_in[17]; const float* fchg1_b = (const float*)d_in[18];
    const float* fchg2_W = (const float*)d_in[19]; const float* fchg2_b = (const float*)d_in[20];
    const float* gin1_W = (const float*)d_in[21]; const float* gin1_b = (const float*)d_in[22];
    const float* gin2_W = (const float*)d_in[23]; const float* gin2_b = (const float*)d_in[24];
    const float* h3_W = (const float*)d_in[25]; const float* h3_b = (const float*)d_in[26];
    const float* h4_W = (const float*)d_in[27]; const float* h4_b = (const float*)d_in[28];
    const float* Wq = (const float*)d_in[29];
    const float* Wk = (const float*)d_in[30];
    const float* Wv = (const float*)d_in[31];
    const float* conv_W = (const float*)d_in[32]; const float* conv_b = (const float*)d_in[33];
    const float* mlp1_W = (const float*)d_in[34]; const float* mlp1_b = (const float*)d_in[35];
    const float* mlp2_W = (const float*)d_in[36]; const float* mlp2_b = (const float*)d_in[37];

    const int* e_src = edge;
    const int* e_dst = edge + N_EDGES;
    const int* h_nid = hedge;
    const int* h_eid = hedge + N_HNNZ;

    float* ws = (float*)d_ws;
    const size_t ZONE = 51609600;
    // ---- phase A (GIN) ----
    double* agg64 = (double*)ws;                    // [0, 8.6M f)
    float*  xg1   = ws + 8601600;                   // [8.6M, 12.9M)
    // ---- phase H (hypergraph, linearity-reordered) ----
    double* eagg64  = (double*)ws;                  // [0, 1,720,320 f)
    float*  e1_32   = ws + 1720320;                 // [1.72M, 3.44M)
    double* hnode64 = (double*)(ws + 3440640);      // [3.44M, 20.64M)
    double* hn2_64  = (double*)ws;                  // [0, 26.21M)  (after hnode64 dead)
    double* eagg2_64= (double*)(ws + 26214400);     // [26.21M, 29.66M)
    float*  e2_32   = ws + 29655040;                // [29.66M, 32.28M)
    // ---- phase D (attention) ----
    float* in_t = ws;                               // [0, 2.1M)
    float* qkv  = ws + 2097152;                     // [2.1M, 27.26M) 4096x6144
    float* att  = ws + 27262976;                    // [27.26M, 35.65M)
    float* cbuf = ws + 35651584;                    // [35.65M, 39.83M)
    float* m1   = ws + 39829504;                    // [39.83M, 40.88M)
    float* Wqkv = ws + 40878080;                    // [40.88M, 44.02M) 6144x512
    float* part = ws;                               // split-K scratch (zone-dead windows)
    // ---- persistent ----
    float* xg_raw = ws + ZONE;
    float* xg_mid = ws + ZONE + 1720320;
    float* hx_raw = ws + ZONE + 2768896;
    float* hx_mid = ws + ZONE + 3293184;
    float* h1     = ws + ZONE + 4341760;
    float* fp_o   = ws + ZONE + 4472832;
    float* tt     = ws + ZONE + 4997120;
    float* ecnt   = ws + ZONE + 5521408;
    float* deg    = ws + ZONE + 5531648;
    const size_t NEED = (ZONE + 5582848) * sizeof(float);
    if (ws_size < NEED) return;

    float* out_y  = (float*)d_out;
    float* xg_out = out_y + 1024;
    float* hx_out = out_y + 1024 + 1024 * 512;

    const int BT = 256;
    // ---------- GIN branch ----------
    hipMemsetAsync(agg64, 0, (size_t)N_NODES * FXD * 8, stream);
    scatter_add_feat_d<<<(N_EDGES * FXD + BT - 1) / BT, BT, 0, stream>>>(x, e_src, e_dst, agg64, N_EDGES, FXD);
    launch_gemm(x, agg64, nullptr, nullptr, gin1_W, gin1_b, xg1, N_NODES, FXD, FXD, true, stream);
    hipMemsetAsync(agg64, 0, (size_t)N_NODES * FXD * 8, stream);
    scatter_add_feat_d<<<(N_EDGES * FXD + BT - 1) / BT, BT, 0, stream>>>(xg1, e_src, e_dst, agg64, N_EDGES, FXD);
    gin2pool<<<NB, 256, 0, stream>>>(xg1, agg64, gin2_W, gin2_b, xg_raw);
    launch_gemm64(xg_raw, fcg1_W, fcg1_b, xg_mid, NB, 1024, 1680, true, part, stream);
    launch_gemm64(xg_mid, fcg2_W, fcg2_b, xg_out, NB, 512, 1024, false, part, stream);

    // ---------- hypergraph branch (GEMM commutes with segment-sum) ----------
    hipMemsetAsync(ecnt, 0, N_HEDGES * 4, stream);
    hipMemsetAsync(deg, 0, N_NODES * 4, stream);
    count_incidence<<<(N_HNNZ + BT - 1) / BT, BT, 0, stream>>>(h_nid, h_eid, deg, ecnt, N_HNNZ);
    // layer 1: eagg = seg_e sum x[nid]; e1 = (eagg*Binv) @ h3_W^T
    hipMemsetAsync(eagg64, 0, (size_t)N_HEDGES * FXD * 8, stream);
    scatter_add_feat_d<<<(N_HNNZ * FXD + BT - 1) / BT, BT, 0, stream>>>(x, h_nid, h_eid, eagg64, N_HNNZ, FXD);
    launch_gemm(nullptr, nullptr, eagg64, ecnt, h3_W, nullptr, e1_32, N_HEDGES, 168, FXD, false, stream);
    // hnode64 = seg_n sum e1[eid]   (Dinv+bias fused into next scatter's source)
    hipMemsetAsync(hnode64, 0, (size_t)N_NODES * 168 * 8, stream);
    scatter_add_feat_d<<<(N_HNNZ * 168 + BT - 1) / BT, BT, 0, stream>>>(e1_32, h_eid, h_nid, hnode64, N_HNNZ, 168);
    // layer 2: eagg2 = seg_e sum (hnode*Dinv + b3)[nid]; e2 = (eagg2*Binv) @ h4_W^T
    hipMemsetAsync(eagg2_64, 0, (size_t)N_HEDGES * 168 * 8, stream);
    scatter_n2e_scaled<<<(N_HNNZ * 168 + BT - 1) / BT, BT, 0, stream>>>(hnode64, deg, h3_b, h_nid, h_eid, eagg2_64, N_HNNZ, 168);
    launch_gemm(nullptr, nullptr, eagg2_64, ecnt, h4_W, nullptr, e2_32, N_HEDGES, 256, 168, false, stream);
    // hn2 = seg_n sum e2[eid]; pool fuses Dinv + b4
    hipMemsetAsync(hn2_64, 0, (size_t)N_NODES * 256 * 8, stream);
    scatter_add_feat_d<<<(N_HNNZ * 256 + BT - 1) / BT, BT, 0, stream>>>(e2_32, h_eid, h_nid, hn2_64, N_HNNZ, 256);
    pool_hyper<<<(NB * 256 + BT - 1) / BT, BT, 0, stream>>>(hn2_64, deg, h4_b, hx_raw);
    launch_gemm64(hx_raw, fchg1_W, fchg1_b, hx_mid, NB, 1024, 512, true, part, stream);
    launch_gemm64(hx_mid, fchg2_W, fchg2_b, hx_out, NB, 512, 1024, false, part, stream);

    // ---------- fingerprint + text (zone dead -> part scratch OK) ----------
    launch_gemm64(fp, fc1_W, fc1_b, h1, NB, FP2, FP_DIM, true, part, stream);
    launch_gemm64(h1, fc2_W, fc2_b, fp_o, NB, HID, FP2, false, part, stream);
    launch_gemm64(text_em, fc3_W, fc3_b, tt, NB, HID, 768, false, part, stream);

    // ---------- fusion attention ----------
    pack_tokens<<<(4096 * 512 + BT - 1) / BT, BT, 0, stream>>>(fp_o, xg_out, hx_out, tt, in_t);
    hipMemcpyAsync(Wqkv,                (void*)Wq, (size_t)2048 * 512 * 4, hipMemcpyDeviceToDevice, stream);
    hipMemcpyAsync(Wqkv + 2048 * 512,   (void*)Wk, (size_t)2048 * 512 * 4, hipMemcpyDeviceToDevice, stream);
    hipMemcpyAsync(Wqkv + 4096 * 512,   (void*)Wv, (size_t)2048 * 512 * 4, hipMemcpyDeviceToDevice, stream);
    launch_gemm(in_t, nullptr, nullptr, nullptr, Wqkv, nullptr, qkv, 4096, 6144, 512, false, stream);
    attn_kernel<<<1024, 256, 0, stream>>>(qkv, att);
    conv_relu<<<(1024 * 4 * 2 * 510 + BT - 1) / BT, BT, 0, stream>>>(att, conv_W, conv_b, cbuf);
    launch_gemm64(cbuf, mlp1_W, mlp1_b, m1, NB, 1024, 4080, true, part, stream);
    rowdot<<<256, 256, 0, stream>>>(m1, mlp2_W, mlp2_b, out_y, NB, 1024);
}

// Round 6
// 1557.428 us; speedup vs baseline: 2.3130x; 1.0992x over previous
//
#include <hip/hip_runtime.h>
#include <hip/hip_bf16.h>

// ---------------- constants ----------------
#define N_NODES 51200
#define N_EDGES 204800
#define N_HNNZ  102400
#define N_HEDGES 10240
#define NB 1024          // batch (graphs)
#define NPG 50           // nodes per graph (51200/1024)
#define FXD 84
#define FP_DIM 2513
#define FP2 128
#define HID 512

typedef __attribute__((ext_vector_type(4))) float f32x4;
typedef __attribute__((ext_vector_type(8))) __bf16 bf16x8;
typedef __attribute__((ext_vector_type(4))) short short4_t;

static __device__ __forceinline__ unsigned short f2bf(float f) {
    unsigned u = __builtin_bit_cast(unsigned, f);
    u += 0x7FFFu + ((u >> 16) & 1u);   // round-to-nearest-even
    return (unsigned short)(u >> 16);
}

// ---------------- MFMA GEMM 128x128: C = act(Asrc @ W^T + b) ----------------
// Asrc modes: (A) plain f32 | (A,Aadd) f32+(float)f64 | (A64,rowcnt) (float)f64/max(cnt,1)
template<bool RELU>
__global__ __launch_bounds__(256) void gemm_mfma(const float* __restrict__ A,
                                                 const double* __restrict__ Aadd,
                                                 const double* __restrict__ A64,
                                                 const float* __restrict__ rowcnt,
                                                 const float* __restrict__ W,
                                                 const float* __restrict__ bias,
                                                 float* __restrict__ C,
                                                 int M, int N, int K) {
    __shared__ unsigned short Asm[128][32];
    __shared__ unsigned short Bsm[128][32];
    const int tid = threadIdx.x;
    const int bm = blockIdx.y * 128, bn = blockIdx.x * 128;
    const int wid = tid >> 6, lane = tid & 63;
    const int wm = (wid >> 1) * 64, wn = (wid & 1) * 64;
    const int lr = lane & 15, lg = lane >> 4;
    const bool kvec = ((K & 3) == 0);

    f32x4 zero = {0.f, 0.f, 0.f, 0.f};
    f32x4 acc[4][4];
#pragma unroll
    for (int i = 0; i < 4; i++)
#pragma unroll
        for (int j = 0; j < 4; j++) acc[i][j] = zero;

    for (int k0 = 0; k0 < K; k0 += 32) {
#pragma unroll
        for (int i = 0; i < 4; i++) {
            int fidx = i * 256 + tid;
            int row = fidx >> 3, kq = (fidx & 7) << 2;
            int gk = k0 + kq;
            float v0 = 0.f, v1 = 0.f, v2 = 0.f, v3 = 0.f;
            int gm = bm + row;
            if (gm < M && gk < K) {
                if (A64) {
                    const double* p64 = A64 + (size_t)gm * K + gk;
                    float rs = rowcnt ? 1.f / fmaxf(rowcnt[gm], 1.f) : 1.f;
                    v0 = (float)p64[0] * rs;
                    if (gk + 1 < K) v1 = (float)p64[1] * rs;
                    if (gk + 2 < K) v2 = (float)p64[2] * rs;
                    if (gk + 3 < K) v3 = (float)p64[3] * rs;
                } else if (Aadd) {
                    const float* p = A + (size_t)gm * K + gk;
                    const double* pa = Aadd + (size_t)gm * K + gk;
                    v0 = p[0] + (float)pa[0];
                    if (gk + 1 < K) v1 = p[1] + (float)pa[1];
                    if (gk + 2 < K) v2 = p[2] + (float)pa[2];
                    if (gk + 3 < K) v3 = p[3] + (float)pa[3];
                } else {
                    const float* p = A + (size_t)gm * K + gk;
                    if (kvec && gk + 4 <= K) {
                        float4 f = *(const float4*)p;
                        v0 = f.x; v1 = f.y; v2 = f.z; v3 = f.w;
                    } else {
                        v0 = p[0];
                        if (gk + 1 < K) v1 = p[1];
                        if (gk + 2 < K) v2 = p[2];
                        if (gk + 3 < K) v3 = p[3];
                    }
                }
            }
            short4_t sv;
            sv[0] = (short)f2bf(v0); sv[1] = (short)f2bf(v1);
            sv[2] = (short)f2bf(v2); sv[3] = (short)f2bf(v3);
            *(short4_t*)&Asm[row][kq] = sv;

            v0 = v1 = v2 = v3 = 0.f;
            int gn = bn + row;
            if (gn < N && gk < K) {
                const float* p = W + (size_t)gn * K + gk;
                if (kvec && gk + 4 <= K) {
                    float4 f = *(const float4*)p;
                    v0 = f.x; v1 = f.y; v2 = f.z; v3 = f.w;
                } else {
                    v0 = p[0];
                    if (gk + 1 < K) v1 = p[1];
                    if (gk + 2 < K) v2 = p[2];
                    if (gk + 3 < K) v3 = p[3];
                }
            }
            sv[0] = (short)f2bf(v0); sv[1] = (short)f2bf(v1);
            sv[2] = (short)f2bf(v2); sv[3] = (short)f2bf(v3);
            *(short4_t*)&Bsm[row][kq] = sv;
        }
        __syncthreads();

        bf16x8 af[4], bf[4];
#pragma unroll
        for (int m = 0; m < 4; m++)
            af[m] = *(const bf16x8*)&Asm[wm + m * 16 + lr][lg * 8];
#pragma unroll
        for (int n = 0; n < 4; n++)
            bf[n] = *(const bf16x8*)&Bsm[wn + n * 16 + lr][lg * 8];
#pragma unroll
        for (int m = 0; m < 4; m++)
#pragma unroll
            for (int n = 0; n < 4; n++)
                acc[m][n] = __builtin_amdgcn_mfma_f32_16x16x32_bf16(af[m], bf[n], acc[m][n], 0, 0, 0);
        __syncthreads();
    }

#pragma unroll
    for (int m = 0; m < 4; m++) {
#pragma unroll
        for (int n = 0; n < 4; n++) {
            int col = bn + wn + n * 16 + lr;
            if (col >= N) continue;
            float bv = bias ? bias[col] : 0.f;
#pragma unroll
            for (int r = 0; r < 4; r++) {
                int row = bm + wm + m * 16 + lg * 4 + r;
                if (row >= M) continue;
                float v = acc[m][n][r] + bv;
                if (RELU) v = fmaxf(v, 0.f);
                C[(size_t)row * N + col] = v;
            }
        }
    }
}

// ---------------- MFMA GEMM 64x64 with intra-block wave K-split ----------------
template<bool RELU, bool PARTIAL>
__global__ __launch_bounds__(256) void gemm64(const float* __restrict__ A,
                                              const float* __restrict__ W,
                                              const float* __restrict__ bias,
                                              float* __restrict__ C,
                                              int M, int N, int K, int kchunk) {
    __shared__ __align__(16) char pool[65536];   // A:16K | B:16K ; reused as 64K f32 red
    char* Ab = pool;
    char* Bb = pool + 16384;
    const int tid = threadIdx.x;
    const int bm = blockIdx.y * 64, bn = blockIdx.x * 64;
    const int wid = tid >> 6, lane = tid & 63;
    const int lr = lane & 15, lg = lane >> 4;
    const int kbeg = blockIdx.z * kchunk;
    const int kend = min(K, kbeg + kchunk);
    const bool kvec = ((K & 3) == 0);

    f32x4 zero = {0.f, 0.f, 0.f, 0.f};
    f32x4 acc[4][4];
#pragma unroll
    for (int i = 0; i < 4; i++)
#pragma unroll
        for (int j = 0; j < 4; j++) acc[i][j] = zero;

    for (int kc = kbeg; kc < kend; kc += 128) {
#pragma unroll
        for (int u = 0; u < 8; u++) {
            int s = u * 256 + tid;               // 2048 8B-slots per matrix
            int row = s >> 5, kq = (s & 31) << 2;
            int gk = kc + kq;
            int off = (row * 256 + (s & 31) * 8) ^ ((row & 7) << 4);

            float v0 = 0.f, v1 = 0.f, v2 = 0.f, v3 = 0.f;
            int gm = bm + row;
            if (gm < M && gk < kend) {
                const float* p = A + (size_t)gm * K + gk;
                if (kvec && gk + 4 <= kend) {
                    float4 f = *(const float4*)p;
                    v0 = f.x; v1 = f.y; v2 = f.z; v3 = f.w;
                } else {
                    v0 = p[0];
                    if (gk + 1 < kend) v1 = p[1];
                    if (gk + 2 < kend) v2 = p[2];
                    if (gk + 3 < kend) v3 = p[3];
                }
            }
            short4_t sv;
            sv[0] = (short)f2bf(v0); sv[1] = (short)f2bf(v1);
            sv[2] = (short)f2bf(v2); sv[3] = (short)f2bf(v3);
            *(short4_t*)(Ab + off) = sv;

            v0 = v1 = v2 = v3 = 0.f;
            int gn = bn + row;
            if (gn < N && gk < kend) {
                const float* p = W + (size_t)gn * K + gk;
                if (kvec && gk + 4 <= kend) {
                    float4 f = *(const float4*)p;
                    v0 = f.x; v1 = f.y; v2 = f.z; v3 = f.w;
                } else {
                    v0 = p[0];
                    if (gk + 1 < kend) v1 = p[1];
                    if (gk + 2 < kend) v2 = p[2];
                    if (gk + 3 < kend) v3 = p[3];
                }
            }
            sv[0] = (short)f2bf(v0); sv[1] = (short)f2bf(v1);
            sv[2] = (short)f2bf(v2); sv[3] = (short)f2bf(v3);
            *(short4_t*)(Bb + off) = sv;
        }
        __syncthreads();

        bf16x8 af[4], bf[4];
        const int kb = wid * 64 + lg * 16;       // byte offset in row
#pragma unroll
        for (int m = 0; m < 4; m++) {
            int row = m * 16 + lr;
            af[m] = *(const bf16x8*)(Ab + ((row * 256 + kb) ^ ((row & 7) << 4)));
        }
#pragma unroll
        for (int n = 0; n < 4; n++) {
            int row = n * 16 + lr;
            bf[n] = *(const bf16x8*)(Bb + ((row * 256 + kb) ^ ((row & 7) << 4)));
        }
#pragma unroll
        for (int m = 0; m < 4; m++)
#pragma unroll
            for (int n = 0; n < 4; n++)
                acc[m][n] = __builtin_amdgcn_mfma_f32_16x16x32_bf16(af[m], bf[n], acc[m][n], 0, 0, 0);
        __syncthreads();
    }

    float* red = (float*)pool;                   // 4 x 4096 f32
#pragma unroll
    for (int m = 0; m < 4; m++)
#pragma unroll
        for (int n = 0; n < 4; n++)
#pragma unroll
            for (int r = 0; r < 4; r++)
                red[wid * 4096 + (m * 16 + lg * 4 + r) * 64 + n * 16 + lr] = acc[m][n][r];
    __syncthreads();
#pragma unroll
    for (int u = 0; u < 16; u++) {
        int idx = u * 256 + tid;
        int row = idx >> 6, col = idx & 63;
        int gm = bm + row, gn = bn + col;
        if (gm >= M || gn >= N) continue;
        float s = red[idx] + red[4096 + idx] + red[8192 + idx] + red[12288 + idx];
        if (PARTIAL) {
            C[(size_t)blockIdx.z * M * N + (size_t)gm * N + gn] = s;
        } else {
            s += bias ? bias[gn] : 0.f;
            if (RELU) s = fmaxf(s, 0.f);
            C[(size_t)gm * N + gn] = s;
        }
    }
}

template<bool RELU>
__global__ void reduce_partial(const float* __restrict__ part, const float* __restrict__ bias,
                               float* __restrict__ C, int MN, int N, int SK) {
    int i = blockIdx.x * 256 + threadIdx.x;
    if (i >= MN) return;
    float s = 0.f;
    for (int z = 0; z < SK; z++) s += part[(size_t)z * MN + i];
    s += bias ? bias[i % N] : 0.f;
    if (RELU) s = fmaxf(s, 0.f);
    C[i] = s;
}

// ---------------- fused GIN2 GEMM + bias + relu + 50-row max/mean pool ----------------
// ONE BLOCK PER GRAPH. A (50x84 + f64 agg) staged to LDS ONCE, its 12 MFMA
// fragments pinned in VGPRs for the whole kernel. Waves are N-split (each owns a
// 16-col strip per 64-col tile), so there is NO cross-wave reduce: bias+relu+pool
// happen on the C-fragment in-register, finished by 2 shfl_xor steps.
// ZERO barriers in the tile loop. LDS = 16 KB.
__global__ __launch_bounds__(256) void gin2pool(const float* __restrict__ xg1,
                                                const double* __restrict__ agg,
                                                const float* __restrict__ W,
                                                const float* __restrict__ bias,
                                                float* __restrict__ out) {
    __shared__ __align__(16) char Ab[16384];    // 64x128 bf16, swizzled
    const int tid = threadIdx.x;
    const int g = blockIdx.x;
    const int wid = tid >> 6, lane = tid & 63;
    const int lr = lane & 15, lg = lane >> 4;
    const int K = FXD;      // 84 (padded to 96 in compute, 128 in LDS)
    const int N = 840;

    // ---- stage A once ----
#pragma unroll
    for (int u = 0; u < 8; u++) {
        int s = u * 256 + tid;
        int row = s >> 5, kq = (s & 31) << 2;
        int off = (row * 256 + (s & 31) * 8) ^ ((row & 7) << 4);
        float v0 = 0.f, v1 = 0.f, v2 = 0.f, v3 = 0.f;
        if (row < NPG && kq < K) {
            const float* p = xg1 + ((size_t)g * NPG + row) * K + kq;
            const double* pa = agg + ((size_t)g * NPG + row) * K + kq;
            v0 = p[0] + (float)pa[0];
            if (kq + 1 < K) v1 = p[1] + (float)pa[1];
            if (kq + 2 < K) v2 = p[2] + (float)pa[2];
            if (kq + 3 < K) v3 = p[3] + (float)pa[3];
        }
        short4_t sv;
        sv[0] = (short)f2bf(v0); sv[1] = (short)f2bf(v1);
        sv[2] = (short)f2bf(v2); sv[3] = (short)f2bf(v3);
        *(short4_t*)(Ab + off) = sv;
    }
    __syncthreads();

    // ---- A fragments pinned in registers: af[m][kk] (rows m*16+lr, k-slice kk) ----
    bf16x8 af[4][3];
#pragma unroll
    for (int m = 0; m < 4; m++)
#pragma unroll
        for (int kk = 0; kk < 3; kk++) {
            int row = m * 16 + lr;
            af[m][kk] = *(const bf16x8*)(Ab + ((row * 256 + kk * 64 + lg * 16) ^ ((row & 7) << 4)));
        }

    // ---- loop over 14 column tiles; wave owns strip [t*64 + wid*16, +16) ----
    for (int t = 0; t < 14; t++) {
        const int n0 = t * 64 + wid * 16;
        const int wrow = n0 + lr;           // this lane's W row (output column)
        // build B fragments directly from W (L2-resident)
        bf16x8 bf[3];
#pragma unroll
        for (int kk = 0; kk < 3; kk++) {
            int k0 = kk * 32 + lg * 8;
#pragma unroll
            for (int e = 0; e < 8; e++) {
                float v = (wrow < N && k0 + e < K) ? W[(size_t)wrow * K + k0 + e] : 0.f;
                bf[kk][e] = __builtin_bit_cast(__bf16, f2bf(v));
            }
        }
        f32x4 zero = {0.f, 0.f, 0.f, 0.f};
        f32x4 acc[4] = {zero, zero, zero, zero};
#pragma unroll
        for (int m = 0; m < 4; m++)
#pragma unroll
            for (int kk = 0; kk < 3; kk++)
                acc[m] = __builtin_amdgcn_mfma_f32_16x16x32_bf16(af[m][kk], bf[kk], acc[m], 0, 0, 0);

        // ---- bias + relu + row-filtered pool, all in-register ----
        const int c = n0 + lr;              // output column (C layout: col = lane&15)
        float bv = (c < N) ? bias[c] : 0.f;
        float mx = -1e30f, sm = 0.f;
#pragma unroll
        for (int m = 0; m < 4; m++)
#pragma unroll
            for (int r = 0; r < 4; r++) {
                int row = m * 16 + lg * 4 + r;
                if (row < NPG) {
                    float v = fmaxf(acc[m][r] + bv, 0.f);
                    mx = fmaxf(mx, v);
                    sm += v;
                }
            }
        // combine the 4 lg groups (lanes c, c+16, c+32, c+48)
        mx = fmaxf(mx, __shfl_xor(mx, 16, 64));
        sm += __shfl_xor(sm, 16, 64);
        mx = fmaxf(mx, __shfl_xor(mx, 32, 64));
        sm += __shfl_xor(sm, 32, 64);
        if (lg == 0 && c < N) {
            out[(size_t)g * 1680 + c] = mx;
            out[(size_t)g * 1680 + 840 + c] = sm * (1.f / NPG);
        }
    }
}

// ---------------- N=1 GEMM: out[m] = A[m]·w + b ----------------
__global__ __launch_bounds__(256) void rowdot(const float* __restrict__ A,
                                              const float* __restrict__ w,
                                              const float* __restrict__ b,
                                              float* __restrict__ out, int Mrows, int K) {
    int row = blockIdx.x * 4 + (threadIdx.x >> 6);
    int lane = threadIdx.x & 63;
    if (row >= Mrows) return;
    float s = 0.f;
    for (int k = lane; k < K; k += 64) s += A[(size_t)row * K + k] * w[k];
#pragma unroll
    for (int off = 32; off > 0; off >>= 1) s += __shfl_xor(s, off, 64);
    if (lane == 0) out[row] = s + b[0];
}

// ---------------- f64-accumulating scatter-add (replay-deterministic) ----------------
__global__ void scatter_add_feat_d(const float* __restrict__ src,
                                   const int* __restrict__ smap,
                                   const int* __restrict__ dmap,
                                   double* __restrict__ dst, int nnz, int F) {
    int i = blockIdx.x * blockDim.x + threadIdx.x;
    int total = nnz * F;
    if (i >= total) return;
    int j = i / F, f = i - j * F;
    unsafeAtomicAdd(&dst[(size_t)dmap[j] * F + f], (double)src[(size_t)smap[j] * F + f]);
}

// scatter node->edge with fused Dinv scale + bias: src = (f64 node feat)*Dinv + b
__global__ void scatter_n2e_scaled(const double* __restrict__ hnode64,
                                   const float* __restrict__ deg,
                                   const float* __restrict__ b,
                                   const int* __restrict__ nid,
                                   const int* __restrict__ eid,
                                   double* __restrict__ dst, int nnz, int F) {
    int i = blockIdx.x * blockDim.x + threadIdx.x;
    int total = nnz * F;
    if (i >= total) return;
    int j = i / F, f = i - j * F;
    int n = nid[j], e = eid[j];
    float d = deg[n];
    float inv = d > 0.f ? 1.f / d : 0.f;
    float v = (float)hnode64[(size_t)n * F + f] * inv + b[f];
    unsafeAtomicAdd(&dst[(size_t)e * F + f], (double)v);
}

// counts: f32 sums of 1.0 are exact integers -> order-invariant
__global__ void count_incidence(const int* __restrict__ nid, const int* __restrict__ eid,
                                float* __restrict__ deg, float* __restrict__ ecnt, int nnz) {
    int i = blockIdx.x * blockDim.x + threadIdx.x;
    if (i >= nnz) return;
    atomicAdd(&deg[nid[i]], 1.f);
    atomicAdd(&ecnt[eid[i]], 1.f);
}

// ---------------- fused hyper scale + 50-row max/mean pool ----------------
__global__ void pool_hyper(const double* __restrict__ hn64, const float* __restrict__ deg,
                           const float* __restrict__ b, float* __restrict__ out) {
    int i = blockIdx.x * blockDim.x + threadIdx.x;    // over 1024*256
    if (i >= NB * 256) return;
    int o = i & 255, g = i >> 8;
    float bo = b[o];
    const double* base = hn64 + (size_t)g * NPG * 256 + o;
    const float* dg = deg + g * NPG;
    float mx = -1e30f, sm = 0.f;
    for (int n = 0; n < NPG; n++) {
        float d = dg[n];
        float inv = d > 0.f ? 1.f / d : 0.f;
        float v = (float)base[(size_t)n * 256] * inv + bo;
        mx = fmaxf(mx, v);
        sm += v;
    }
    out[(size_t)g * 512 + o] = mx;
    out[(size_t)g * 512 + 256 + o] = sm * (1.f / NPG);
}

// ---------------- pack fusion tokens ----------------
__global__ void pack_tokens(const float* __restrict__ fp_o, const float* __restrict__ xg,
                            const float* __restrict__ hxg, const float* __restrict__ t,
                            float* __restrict__ in_t) {
    int i = blockIdx.x * blockDim.x + threadIdx.x;
    if (i >= 4096 * 512) return;
    int d = i & 511;
    int row = i >> 9;
    int tok = row & 3, b = row >> 2;
    const float* s = (tok == 0) ? fp_o : (tok == 1) ? xg : (tok == 2) ? hxg : t;
    in_t[i] = s[b * 512 + d];
}

// ---------------- fused 4x4 attention per (b,h); qkv fused layout [4096][6144] ----------------
__global__ __launch_bounds__(256) void attn_kernel(const float* __restrict__ QKV,
                                                   float* __restrict__ att) {
    int wid = threadIdx.x >> 6, lane = threadIdx.x & 63;
    int bh = blockIdx.x * 4 + wid;
    int b = bh >> 2, h = bh & 3;
    const float* qb = QKV + (size_t)b * 4 * 6144 + h * 512;
    const float* kb = qb + 2048;
    const float* vb = qb + 4096;
    float qr[4][8], kr[4][8];
#pragma unroll
    for (int n = 0; n < 4; n++)
#pragma unroll
        for (int c = 0; c < 8; c++) {
            qr[n][c] = qb[n * 6144 + c * 64 + lane];
            kr[n][c] = kb[n * 6144 + c * 64 + lane];
        }
    float s[4][4];
#pragma unroll
    for (int n = 0; n < 4; n++)
#pragma unroll
        for (int m = 0; m < 4; m++) {
            float p = 0.f;
#pragma unroll
            for (int c = 0; c < 8; c++) p += qr[n][c] * kr[m][c];
#pragma unroll
            for (int off = 32; off > 0; off >>= 1) p += __shfl_xor(p, off, 64);
            s[n][m] = p * 0.04419417382415922f;   // 1/sqrt(512)
        }
    float pm[4][4];
#pragma unroll
    for (int n = 0; n < 4; n++) {
        float mx = fmaxf(fmaxf(s[n][0], s[n][1]), fmaxf(s[n][2], s[n][3]));
        float e0 = expf(s[n][0] - mx), e1 = expf(s[n][1] - mx);
        float e2 = expf(s[n][2] - mx), e3 = expf(s[n][3] - mx);
        float inv = 1.f / (e0 + e1 + e2 + e3);
        pm[n][0] = e0 * inv; pm[n][1] = e1 * inv; pm[n][2] = e2 * inv; pm[n][3] = e3 * inv;
    }
    float* ab = att + (size_t)bh * 4 * 512;
#pragma unroll
    for (int c = 0; c < 8; c++) {
        float v0 = vb[0 * 6144 + c * 64 + lane];
        float v1 = vb[1 * 6144 + c * 64 + lane];
        float v2 = vb[2 * 6144 + c * 64 + lane];
        float v3 = vb[3 * 6144 + c * 64 + lane];
#pragma unroll
        for (int n = 0; n < 4; n++) {
            float o = pm[n][0] * v0 + pm[n][1] * v1 + pm[n][2] * v2 + pm[n][3] * v3;
            ab[n * 512 + c * 64 + lane] = o;
        }
    }
}

// ---------------- conv 3x3 VALID + relu ----------------
__global__ void conv_relu(const float* __restrict__ att, const float* __restrict__ cw,
                          const float* __restrict__ cb, float* __restrict__ c) {
    __shared__ float w[144];
    __shared__ float bias[4];
    int t = threadIdx.x;
    if (t < 144) w[t] = cw[t];
    if (t < 4) bias[t] = cb[t];
    __syncthreads();
    int i = blockIdx.x * blockDim.x + t;
    if (i >= 1024 * 4 * 2 * 510) return;
    int wo = i % 510;
    int r = i / 510;
    int ho = r & 1; r >>= 1;
    int co = r & 3; int b = r >> 2;
    float acc = bias[co];
#pragma unroll
    for (int ci = 0; ci < 4; ci++)
#pragma unroll
        for (int kh = 0; kh < 3; kh++)
#pragma unroll
            for (int kw = 0; kw < 3; kw++)
                acc += att[(((size_t)b * 4 + ci) * 4 + ho + kh) * 512 + wo + kw] *
                       w[((co * 4 + ci) * 3 + kh) * 3 + kw];
    c[i] = fmaxf(acc, 0.f);
}

// ---------------- host side ----------------
static inline void launch_gemm(const float* A, const double* Aadd,
                               const double* A64, const float* rowcnt,
                               const float* W, const float* b, float* C,
                               int M, int N, int K, bool relu, hipStream_t s) {
    dim3 g((N + 127) / 128, (M + 127) / 128);
    if (relu) gemm_mfma<true><<<g, 256, 0, s>>>(A, Aadd, A64, rowcnt, W, b, C, M, N, K);
    else      gemm_mfma<false><<<g, 256, 0, s>>>(A, Aadd, A64, rowcnt, W, b, C, M, N, K);
}

static inline void launch_gemm64(const float* A, const float* W, const float* b, float* C,
                                 int M, int N, int K, bool relu, float* part, hipStream_t s) {
    int gx = (N + 63) / 64, gy = (M + 63) / 64;
    int targetSK = 256 / (gx * gy);
    if (targetSK < 1) targetSK = 1;
    if (targetSK > 8) targetSK = 8;
    int kchunk = K, SK = 1;
    if (targetSK > 1) {
        kchunk = (((K + targetSK - 1) / targetSK) + 127) & ~127;
        SK = (K + kchunk - 1) / kchunk;
    }
    if (SK <= 1) {
        dim3 g(gx, gy);
        if (relu) gemm64<true, false><<<g, 256, 0, s>>>(A, W, b, C, M, N, K, K);
        else      gemm64<false, false><<<g, 256, 0, s>>>(A, W, b, C, M, N, K, K);
    } else {
        dim3 g(gx, gy, SK);
        gemm64<false, true><<<g, 256, 0, s>>>(A, W, nullptr, part, M, N, K, kchunk);
        int MN = M * N;
        if (relu) reduce_partial<true><<<(MN + 255) / 256, 256, 0, s>>>(part, b, C, MN, N, SK);
        else      reduce_partial<false><<<(MN + 255) / 256, 256, 0, s>>>(part, b, C, MN, N, SK);
    }
}

extern "C" void kernel_launch(void* const* d_in, const int* in_sizes, int n_in,
                              void* d_out, int out_size, void* d_ws, size_t ws_size,
                              hipStream_t stream) {
    const float* x       = (const float*)d_in[0];
    const int*   edge    = (const int*)d_in[1];
    const int*   hedge   = (const int*)d_in[3];
    const float* fp      = (const float*)d_in[4];
    const float* text_em = (const float*)d_in[5];
    const float* fc1_W = (const float*)d_in[7];  const float* fc1_b = (const float*)d_in[8];
    const float* fc2_W = (const float*)d_in[9];  const float* fc2_b = (const float*)d_in[10];
    const float* fc3_W = (const float*)d_in[11]; const float* fc3_b = (const float*)d_in[12];
    const float* fcg1_W = (const float*)d_in[13]; const float* fcg1_b = (const float*)d_in[14];
    const float* fcg2_W = (const float*)d_in[15]; const float* fcg2_b = (const float*)d_in[16];
    const float* fchg1_W = (const float*)d_in[17]; const float* fchg1_b = (const float*)d_in[18];
    const float* fchg2_W = (const float*)d_in[19]; const float* fchg2_b = (const float*)d_in[20];
    const float* gin1_W = (const float*)d_in[21]; const float* gin1_b = (const float*)d_in[22];
    const float* gin2_W = (const float*)d_in[23]; const float* gin2_b = (const float*)d_in[24];
    const float* h3_W = (const float*)d_in[25]; const float* h3_b = (const float*)d_in[26];
    const float* h4_W = (const float*)d_in[27]; const float* h4_b = (const float*)d_in[28];
    const float* Wq = (const float*)d_in[29];
    const float* Wk = (const float*)d_in[30];
    const float* Wv = (const float*)d_in[31];
    const float* conv_W = (const float*)d_in[32]; const float* conv_b = (const float*)d_in[33];
    const float* mlp1_W = (const float*)d_in[34]; const float* mlp1_b = (const float*)d_in[35];
    const float* mlp2_W = (const float*)d_in[36]; const float* mlp2_b = (const float*)d_in[37];

    const int* e_src = edge;
    const int* e_dst = edge + N_EDGES;
    const int* h_nid = hedge;
    const int* h_eid = hedge + N_HNNZ;

    float* ws = (float*)d_ws;
    const size_t ZONE = 51609600;
    // ---- phase A (GIN) ----
    double* agg64 = (double*)ws;                    // [0, 8.6M f)
    float*  xg1   = ws + 8601600;                   // [8.6M, 12.9M)
    // ---- phase H (hypergraph, linearity-reordered) ----
    double* eagg64  = (double*)ws;                  // [0, 1,720,320 f)
    float*  e1_32   = ws + 1720320;                 // [1.72M, 3.44M)
    double* hnode64 = (double*)(ws + 3440640);      // [3.44M, 20.64M)
    double* hn2_64  = (double*)ws;                  // [0, 26.21M)  (after hnode64 dead)
    double* eagg2_64= (double*)(ws + 26214400);     // [26.21M, 29.66M)
    float*  e2_32   = ws + 29655040;                // [29.66M, 32.28M)
    // ---- phase D (attention) ----
    float* in_t = ws;                               // [0, 2.1M)
    float* qkv  = ws + 2097152;                     // [2.1M, 27.26M) 4096x6144
    float* att  = ws + 27262976;                    // [27.26M, 35.65M)
    float* cbuf = ws + 35651584;                    // [35.65M, 39.83M)
    float* m1   = ws + 39829504;                    // [39.83M, 40.88M)
    float* Wqkv = ws + 40878080;                    // [40.88M, 44.02M) 6144x512
    float* part = ws;                               // split-K scratch (zone-dead windows)
    // ---- persistent ----
    float* xg_raw = ws + ZONE;
    float* xg_mid = ws + ZONE + 1720320;
    float* hx_raw = ws + ZONE + 2768896;
    float* hx_mid = ws + ZONE + 3293184;
    float* h1     = ws + ZONE + 4341760;
    float* fp_o   = ws + ZONE + 4472832;
    float* tt     = ws + ZONE + 4997120;
    float* ecnt   = ws + ZONE + 5521408;
    float* deg    = ws + ZONE + 5531648;
    const size_t NEED = (ZONE + 5582848) * sizeof(float);
    if (ws_size < NEED) return;

    float* out_y  = (float*)d_out;
    float* xg_out = out_y + 1024;
    float* hx_out = out_y + 1024 + 1024 * 512;

    const int BT = 256;
    // ---------- GIN branch ----------
    hipMemsetAsync(agg64, 0, (size_t)N_NODES * FXD * 8, stream);
    scatter_add_feat_d<<<(N_EDGES * FXD + BT - 1) / BT, BT, 0, stream>>>(x, e_src, e_dst, agg64, N_EDGES, FXD);
    launch_gemm(x, agg64, nullptr, nullptr, gin1_W, gin1_b, xg1, N_NODES, FXD, FXD, true, stream);
    hipMemsetAsync(agg64, 0, (size_t)N_NODES * FXD * 8, stream);
    scatter_add_feat_d<<<(N_EDGES * FXD + BT - 1) / BT, BT, 0, stream>>>(xg1, e_src, e_dst, agg64, N_EDGES, FXD);
    gin2pool<<<NB, 256, 0, stream>>>(xg1, agg64, gin2_W, gin2_b, xg_raw);
    launch_gemm64(xg_raw, fcg1_W, fcg1_b, xg_mid, NB, 1024, 1680, true, part, stream);
    launch_gemm64(xg_mid, fcg2_W, fcg2_b, xg_out, NB, 512, 1024, false, part, stream);

    // ---------- hypergraph branch (GEMM commutes with segment-sum) ----------
    hipMemsetAsync(ecnt, 0, N_HEDGES * 4, stream);
    hipMemsetAsync(deg, 0, N_NODES * 4, stream);
    count_incidence<<<(N_HNNZ + BT - 1) / BT, BT, 0, stream>>>(h_nid, h_eid, deg, ecnt, N_HNNZ);
    // layer 1: eagg = seg_e sum x[nid]; e1 = (eagg*Binv) @ h3_W^T
    hipMemsetAsync(eagg64, 0, (size_t)N_HEDGES * FXD * 8, stream);
    scatter_add_feat_d<<<(N_HNNZ * FXD + BT - 1) / BT, BT, 0, stream>>>(x, h_nid, h_eid, eagg64, N_HNNZ, FXD);
    launch_gemm(nullptr, nullptr, eagg64, ecnt, h3_W, nullptr, e1_32, N_HEDGES, 168, FXD, false, stream);
    // hnode64 = seg_n sum e1[eid]   (Dinv+bias fused into next scatter's source)
    hipMemsetAsync(hnode64, 0, (size_t)N_NODES * 168 * 8, stream);
    scatter_add_feat_d<<<(N_HNNZ * 168 + BT - 1) / BT, BT, 0, stream>>>(e1_32, h_eid, h_nid, hnode64, N_HNNZ, 168);
    // layer 2: eagg2 = seg_e sum (hnode*Dinv + b3)[nid]; e2 = (eagg2*Binv) @ h4_W^T
    hipMemsetAsync(eagg2_64, 0, (size_t)N_HEDGES * 168 * 8, stream);
    scatter_n2e_scaled<<<(N_HNNZ * 168 + BT - 1) / BT, BT, 0, stream>>>(hnode64, deg, h3_b, h_nid, h_eid, eagg2_64, N_HNNZ, 168);
    launch_gemm(nullptr, nullptr, eagg2_64, ecnt, h4_W, nullptr, e2_32, N_HEDGES, 256, 168, false, stream);
    // hn2 = seg_n sum e2[eid]; pool fuses Dinv + b4
    hipMemsetAsync(hn2_64, 0, (size_t)N_NODES * 256 * 8, stream);
    scatter_add_feat_d<<<(N_HNNZ * 256 + BT - 1) / BT, BT, 0, stream>>>(e2_32, h_eid, h_nid, hn2_64, N_HNNZ, 256);
    pool_hyper<<<(NB * 256 + BT - 1) / BT, BT, 0, stream>>>(hn2_64, deg, h4_b, hx_raw);
    launch_gemm64(hx_raw, fchg1_W, fchg1_b, hx_mid, NB, 1024, 512, true, part, stream);
    launch_gemm64(hx_mid, fchg2_W, fchg2_b, hx_out, NB, 512, 1024, false, part, stream);

    // ---------- fingerprint + text (zone dead -> part scratch OK) ----------
    launch_gemm64(fp, fc1_W, fc1_b, h1, NB, FP2, FP_DIM, true, part, stream);
    launch_gemm64(h1, fc2_W, fc2_b, fp_o, NB, HID, FP2, false, part, stream);
    launch_gemm64(text_em, fc3_W, fc3_b, tt, NB, HID, 768, false, part, stream);

    // ---------- fusion attention ----------
    pack_tokens<<<(4096 * 512 + BT - 1) / BT, BT, 0, stream>>>(fp_o, xg_out, hx_out, tt, in_t);
    hipMemcpyAsync(Wqkv,                (void*)Wq, (size_t)2048 * 512 * 4, hipMemcpyDeviceToDevice, stream);
    hipMemcpyAsync(Wqkv + 2048 * 512,   (void*)Wk, (size_t)2048 * 512 * 4, hipMemcpyDeviceToDevice, stream);
    hipMemcpyAsync(Wqkv + 4096 * 512,   (void*)Wv, (size_t)2048 * 512 * 4, hipMemcpyDeviceToDevice, stream);
    launch_gemm(in_t, nullptr, nullptr, nullptr, Wqkv, nullptr, qkv, 4096, 6144, 512, false, stream);
    attn_kernel<<<1024, 256, 0, stream>>>(qkv, att);
    conv_relu<<<(1024 * 4 * 2 * 510 + BT - 1) / BT, BT, 0, stream>>>(att, conv_W, conv_b, cbuf);
    launch_gemm64(cbuf, mlp1_W, mlp1_b, m1, NB, 1024, 4080, true, part, stream);
    rowdot<<<256, 256, 0, stream>>>(m1, mlp2_W, mlp2_b, out_y, NB, 1024);
}

// Round 7
// 1408.994 us; speedup vs baseline: 2.5567x; 1.1053x over previous
//
#include <hip/hip_runtime.h>
#include <hip/hip_bf16.h>

// ---------------- constants ----------------
#define N_NODES 51200
#define N_EDGES 204800
#define N_HNNZ  102400
#define N_HEDGES 10240
#define NB 1024          // batch (graphs)
#define NPG 50           // nodes per graph (51200/1024)
#define FXD 84
#define FP_DIM 2513
#define FP2 128
#define HID 512

typedef __attribute__((ext_vector_type(4))) float f32x4;
typedef __attribute__((ext_vector_type(8))) __bf16 bf16x8;
typedef __attribute__((ext_vector_type(4))) short short4_t;

static __device__ __forceinline__ unsigned short f2bf(float f) {
    unsigned u = __builtin_bit_cast(unsigned, f);
    u += 0x7FFFu + ((u >> 16) & 1u);   // round-to-nearest-even
    return (unsigned short)(u >> 16);
}

// bijective XCD-aware remap of a flat workgroup id (m204 formula):
// consecutive remapped ids land on the same XCD -> L2 panel sharing.
static __device__ __forceinline__ int xcd_swizzle(int orig, int nwg) {
    int q = nwg >> 3, r = nwg & 7;
    int xcd = orig & 7, off = orig >> 3;
    return (xcd < r ? xcd * (q + 1) : r * (q + 1) + (xcd - r) * q) + off;
}

// ---------------- MFMA GEMM 128x128: C = act(Asrc @ W^T + b) ----------------
// Asrc modes: (A) plain f32 | (A,Aadd) f32+(float)f64 | (A64,rowcnt) (float)f64/max(cnt,1)
template<bool RELU>
__global__ __launch_bounds__(256) void gemm_mfma(const float* __restrict__ A,
                                                 const double* __restrict__ Aadd,
                                                 const double* __restrict__ A64,
                                                 const float* __restrict__ rowcnt,
                                                 const float* __restrict__ W,
                                                 const float* __restrict__ bias,
                                                 float* __restrict__ C,
                                                 int M, int N, int K) {
    __shared__ unsigned short Asm[128][32];
    __shared__ unsigned short Bsm[128][32];
    const int tid = threadIdx.x;
    const int nwg = gridDim.x * gridDim.y;
    const int wg = xcd_swizzle(blockIdx.y * gridDim.x + blockIdx.x, nwg);
    const int bm = (wg / gridDim.x) * 128, bn = (wg % gridDim.x) * 128;
    const int wid = tid >> 6, lane = tid & 63;
    const int wm = (wid >> 1) * 64, wn = (wid & 1) * 64;
    const int lr = lane & 15, lg = lane >> 4;
    const bool kvec = ((K & 3) == 0);

    f32x4 zero = {0.f, 0.f, 0.f, 0.f};
    f32x4 acc[4][4];
#pragma unroll
    for (int i = 0; i < 4; i++)
#pragma unroll
        for (int j = 0; j < 4; j++) acc[i][j] = zero;

    for (int k0 = 0; k0 < K; k0 += 32) {
#pragma unroll
        for (int i = 0; i < 4; i++) {
            int fidx = i * 256 + tid;
            int row = fidx >> 3, kq = (fidx & 7) << 2;
            int gk = k0 + kq;
            float v0 = 0.f, v1 = 0.f, v2 = 0.f, v3 = 0.f;
            int gm = bm + row;
            if (gm < M && gk < K) {
                if (A64) {
                    const double* p64 = A64 + (size_t)gm * K + gk;
                    float rs = rowcnt ? 1.f / fmaxf(rowcnt[gm], 1.f) : 1.f;
                    v0 = (float)p64[0] * rs;
                    if (gk + 1 < K) v1 = (float)p64[1] * rs;
                    if (gk + 2 < K) v2 = (float)p64[2] * rs;
                    if (gk + 3 < K) v3 = (float)p64[3] * rs;
                } else if (Aadd) {
                    const float* p = A + (size_t)gm * K + gk;
                    const double* pa = Aadd + (size_t)gm * K + gk;
                    v0 = p[0] + (float)pa[0];
                    if (gk + 1 < K) v1 = p[1] + (float)pa[1];
                    if (gk + 2 < K) v2 = p[2] + (float)pa[2];
                    if (gk + 3 < K) v3 = p[3] + (float)pa[3];
                } else {
                    const float* p = A + (size_t)gm * K + gk;
                    if (kvec && gk + 4 <= K) {
                        float4 f = *(const float4*)p;
                        v0 = f.x; v1 = f.y; v2 = f.z; v3 = f.w;
                    } else {
                        v0 = p[0];
                        if (gk + 1 < K) v1 = p[1];
                        if (gk + 2 < K) v2 = p[2];
                        if (gk + 3 < K) v3 = p[3];
                    }
                }
            }
            short4_t sv;
            sv[0] = (short)f2bf(v0); sv[1] = (short)f2bf(v1);
            sv[2] = (short)f2bf(v2); sv[3] = (short)f2bf(v3);
            *(short4_t*)&Asm[row][kq] = sv;

            v0 = v1 = v2 = v3 = 0.f;
            int gn = bn + row;
            if (gn < N && gk < K) {
                const float* p = W + (size_t)gn * K + gk;
                if (kvec && gk + 4 <= K) {
                    float4 f = *(const float4*)p;
                    v0 = f.x; v1 = f.y; v2 = f.z; v3 = f.w;
                } else {
                    v0 = p[0];
                    if (gk + 1 < K) v1 = p[1];
                    if (gk + 2 < K) v2 = p[2];
                    if (gk + 3 < K) v3 = p[3];
                }
            }
            sv[0] = (short)f2bf(v0); sv[1] = (short)f2bf(v1);
            sv[2] = (short)f2bf(v2); sv[3] = (short)f2bf(v3);
            *(short4_t*)&Bsm[row][kq] = sv;
        }
        __syncthreads();

        bf16x8 af[4], bf[4];
#pragma unroll
        for (int m = 0; m < 4; m++)
            af[m] = *(const bf16x8*)&Asm[wm + m * 16 + lr][lg * 8];
#pragma unroll
        for (int n = 0; n < 4; n++)
            bf[n] = *(const bf16x8*)&Bsm[wn + n * 16 + lr][lg * 8];
#pragma unroll
        for (int m = 0; m < 4; m++)
#pragma unroll
            for (int n = 0; n < 4; n++)
                acc[m][n] = __builtin_amdgcn_mfma_f32_16x16x32_bf16(af[m], bf[n], acc[m][n], 0, 0, 0);
        __syncthreads();
    }

#pragma unroll
    for (int m = 0; m < 4; m++) {
#pragma unroll
        for (int n = 0; n < 4; n++) {
            int col = bn + wn + n * 16 + lr;
            if (col >= N) continue;
            float bv = bias ? bias[col] : 0.f;
#pragma unroll
            for (int r = 0; r < 4; r++) {
                int row = bm + wm + m * 16 + lg * 4 + r;
                if (row >= M) continue;
                float v = acc[m][n][r] + bv;
                if (RELU) v = fmaxf(v, 0.f);
                C[(size_t)row * N + col] = v;
            }
        }
    }
}

// ---------------- MFMA GEMM 64x64, wave-K-split, 32KB LDS, grid.z split-K ----------------
template<bool RELU, bool PARTIAL>
__global__ __launch_bounds__(256) void gemm64(const float* __restrict__ A,
                                              const float* __restrict__ W,
                                              const float* __restrict__ bias,
                                              float* __restrict__ C,
                                              int M, int N, int K, int kchunk) {
    __shared__ __align__(16) char pool[32768];   // A:16K | B:16K ; reused as redA|redB
    char* Ab = pool;
    char* Bb = pool + 16384;
    const int tid = threadIdx.x;
    const int nwg = gridDim.x * gridDim.y;
    const int wg = xcd_swizzle(blockIdx.y * gridDim.x + blockIdx.x, nwg);
    const int bm = (wg / gridDim.x) * 64, bn = (wg % gridDim.x) * 64;
    const int wid = tid >> 6, lane = tid & 63;
    const int lr = lane & 15, lg = lane >> 4;
    const int kbeg = blockIdx.z * kchunk;
    const int kend = min(K, kbeg + kchunk);
    const bool kvec = ((K & 3) == 0);

    f32x4 zero = {0.f, 0.f, 0.f, 0.f};
    f32x4 acc[4][4];
#pragma unroll
    for (int i = 0; i < 4; i++)
#pragma unroll
        for (int j = 0; j < 4; j++) acc[i][j] = zero;

    for (int kc = kbeg; kc < kend; kc += 128) {
#pragma unroll
        for (int u = 0; u < 8; u++) {
            int s = u * 256 + tid;               // 2048 8B-slots per matrix
            int row = s >> 5, kq = (s & 31) << 2;
            int gk = kc + kq;
            int off = (row * 256 + (s & 31) * 8) ^ ((row & 7) << 4);

            float v0 = 0.f, v1 = 0.f, v2 = 0.f, v3 = 0.f;
            int gm = bm + row;
            if (gm < M && gk < kend) {
                const float* p = A + (size_t)gm * K + gk;
                if (kvec && gk + 4 <= kend) {
                    float4 f = *(const float4*)p;
                    v0 = f.x; v1 = f.y; v2 = f.z; v3 = f.w;
                } else {
                    v0 = p[0];
                    if (gk + 1 < kend) v1 = p[1];
                    if (gk + 2 < kend) v2 = p[2];
                    if (gk + 3 < kend) v3 = p[3];
                }
            }
            short4_t sv;
            sv[0] = (short)f2bf(v0); sv[1] = (short)f2bf(v1);
            sv[2] = (short)f2bf(v2); sv[3] = (short)f2bf(v3);
            *(short4_t*)(Ab + off) = sv;

            v0 = v1 = v2 = v3 = 0.f;
            int gn = bn + row;
            if (gn < N && gk < kend) {
                const float* p = W + (size_t)gn * K + gk;
                if (kvec && gk + 4 <= kend) {
                    float4 f = *(const float4*)p;
                    v0 = f.x; v1 = f.y; v2 = f.z; v3 = f.w;
                } else {
                    v0 = p[0];
                    if (gk + 1 < kend) v1 = p[1];
                    if (gk + 2 < kend) v2 = p[2];
                    if (gk + 3 < kend) v3 = p[3];
                }
            }
            sv[0] = (short)f2bf(v0); sv[1] = (short)f2bf(v1);
            sv[2] = (short)f2bf(v2); sv[3] = (short)f2bf(v3);
            *(short4_t*)(Bb + off) = sv;
        }
        __syncthreads();

        bf16x8 af[4], bf[4];
        const int kb = wid * 64 + lg * 16;       // byte offset in row
#pragma unroll
        for (int m = 0; m < 4; m++) {
            int row = m * 16 + lr;
            af[m] = *(const bf16x8*)(Ab + ((row * 256 + kb) ^ ((row & 7) << 4)));
        }
#pragma unroll
        for (int n = 0; n < 4; n++) {
            int row = n * 16 + lr;
            bf[n] = *(const bf16x8*)(Bb + ((row * 256 + kb) ^ ((row & 7) << 4)));
        }
#pragma unroll
        for (int m = 0; m < 4; m++)
#pragma unroll
            for (int n = 0; n < 4; n++)
                acc[m][n] = __builtin_amdgcn_mfma_f32_16x16x32_bf16(af[m], bf[n], acc[m][n], 0, 0, 0);
        __syncthreads();
    }

    // ---- 2-phase cross-wave reduce in 32KB ----
    float* redA = (float*)pool;                  // 4096 f32
    float* redB = (float*)(pool + 16384);        // 4096 f32
    if (wid < 2) {
        float* r = (wid == 0) ? redA : redB;
#pragma unroll
        for (int m = 0; m < 4; m++)
#pragma unroll
            for (int n = 0; n < 4; n++)
#pragma unroll
                for (int r4 = 0; r4 < 4; r4++)
                    r[(m * 16 + lg * 4 + r4) * 64 + n * 16 + lr] = acc[m][n][r4];
    }
    __syncthreads();
    if (wid >= 2) {
        float* r = (wid == 2) ? redA : redB;
#pragma unroll
        for (int m = 0; m < 4; m++)
#pragma unroll
            for (int n = 0; n < 4; n++)
#pragma unroll
                for (int r4 = 0; r4 < 4; r4++)
                    r[(m * 16 + lg * 4 + r4) * 64 + n * 16 + lr] += acc[m][n][r4];
    }
    __syncthreads();
#pragma unroll
    for (int u = 0; u < 16; u++) {
        int idx = u * 256 + tid;
        int row = idx >> 6, col = idx & 63;
        int gm = bm + row, gn = bn + col;
        if (gm >= M || gn >= N) continue;
        float s = redA[idx] + redB[idx];
        if (PARTIAL) {
            C[(size_t)blockIdx.z * M * N + (size_t)gm * N + gn] = s;
        } else {
            s += bias ? bias[gn] : 0.f;
            if (RELU) s = fmaxf(s, 0.f);
            C[(size_t)gm * N + gn] = s;
        }
    }
}

template<bool RELU>
__global__ void reduce_partial(const float* __restrict__ part, const float* __restrict__ bias,
                               float* __restrict__ C, int MN, int N, int SK) {
    int i = blockIdx.x * 256 + threadIdx.x;
    if (i >= MN) return;
    float s = 0.f;
    for (int z = 0; z < SK; z++) s += part[(size_t)z * MN + i];
    s += bias ? bias[i % N] : 0.f;
    if (RELU) s = fmaxf(s, 0.f);
    C[i] = s;
}

// ---------------- fused GIN2 GEMM + bias + relu + 50-row max/mean pool ----------------
// ONE BLOCK PER GRAPH. A staged to LDS ONCE, fragments pinned in VGPRs; waves
// N-split; pool in-register finished by 2 shfl_xor. Zero barriers in tile loop.
__global__ __launch_bounds__(256) void gin2pool(const float* __restrict__ xg1,
                                                const double* __restrict__ agg,
                                                const float* __restrict__ W,
                                                const float* __restrict__ bias,
                                                float* __restrict__ out) {
    __shared__ __align__(16) char Ab[16384];    // 64x128 bf16, swizzled
    const int tid = threadIdx.x;
    const int g = blockIdx.x;
    const int wid = tid >> 6, lane = tid & 63;
    const int lr = lane & 15, lg = lane >> 4;
    const int K = FXD;
    const int N = 840;

#pragma unroll
    for (int u = 0; u < 8; u++) {
        int s = u * 256 + tid;
        int row = s >> 5, kq = (s & 31) << 2;
        int off = (row * 256 + (s & 31) * 8) ^ ((row & 7) << 4);
        float v0 = 0.f, v1 = 0.f, v2 = 0.f, v3 = 0.f;
        if (row < NPG && kq < K) {
            const float* p = xg1 + ((size_t)g * NPG + row) * K + kq;
            const double* pa = agg + ((size_t)g * NPG + row) * K + kq;
            v0 = p[0] + (float)pa[0];
            if (kq + 1 < K) v1 = p[1] + (float)pa[1];
            if (kq + 2 < K) v2 = p[2] + (float)pa[2];
            if (kq + 3 < K) v3 = p[3] + (float)pa[3];
        }
        short4_t sv;
        sv[0] = (short)f2bf(v0); sv[1] = (short)f2bf(v1);
        sv[2] = (short)f2bf(v2); sv[3] = (short)f2bf(v3);
        *(short4_t*)(Ab + off) = sv;
    }
    __syncthreads();

    bf16x8 af[4][3];
#pragma unroll
    for (int m = 0; m < 4; m++)
#pragma unroll
        for (int kk = 0; kk < 3; kk++) {
            int row = m * 16 + lr;
            af[m][kk] = *(const bf16x8*)(Ab + ((row * 256 + kk * 64 + lg * 16) ^ ((row & 7) << 4)));
        }

    for (int t = 0; t < 14; t++) {
        const int n0 = t * 64 + wid * 16;
        const int wrow = n0 + lr;
        bf16x8 bf[3];
#pragma unroll
        for (int kk = 0; kk < 3; kk++) {
            int k0 = kk * 32 + lg * 8;
#pragma unroll
            for (int e = 0; e < 8; e++) {
                float v = (wrow < N && k0 + e < K) ? W[(size_t)wrow * K + k0 + e] : 0.f;
                bf[kk][e] = __builtin_bit_cast(__bf16, f2bf(v));
            }
        }
        f32x4 zero = {0.f, 0.f, 0.f, 0.f};
        f32x4 acc[4] = {zero, zero, zero, zero};
#pragma unroll
        for (int m = 0; m < 4; m++)
#pragma unroll
            for (int kk = 0; kk < 3; kk++)
                acc[m] = __builtin_amdgcn_mfma_f32_16x16x32_bf16(af[m][kk], bf[kk], acc[m], 0, 0, 0);

        const int c = n0 + lr;
        float bv = (c < N) ? bias[c] : 0.f;
        float mx = -1e30f, sm = 0.f;
#pragma unroll
        for (int m = 0; m < 4; m++)
#pragma unroll
            for (int r = 0; r < 4; r++) {
                int row = m * 16 + lg * 4 + r;
                if (row < NPG) {
                    float v = fmaxf(acc[m][r] + bv, 0.f);
                    mx = fmaxf(mx, v);
                    sm += v;
                }
            }
        mx = fmaxf(mx, __shfl_xor(mx, 16, 64));
        sm += __shfl_xor(sm, 16, 64);
        mx = fmaxf(mx, __shfl_xor(mx, 32, 64));
        sm += __shfl_xor(sm, 32, 64);
        if (lg == 0 && c < N) {
            out[(size_t)g * 1680 + c] = mx;
            out[(size_t)g * 1680 + 840 + c] = sm * (1.f / NPG);
        }
    }
}

// ---------------- N=1 GEMM: out[m] = A[m]·w + b ----------------
__global__ __launch_bounds__(256) void rowdot(const float* __restrict__ A,
                                              const float* __restrict__ w,
                                              const float* __restrict__ b,
                                              float* __restrict__ out, int Mrows, int K) {
    int row = blockIdx.x * 4 + (threadIdx.x >> 6);
    int lane = threadIdx.x & 63;
    if (row >= Mrows) return;
    float s = 0.f;
    for (int k = lane; k < K; k += 64) s += A[(size_t)row * K + k] * w[k];
#pragma unroll
    for (int off = 32; off > 0; off >>= 1) s += __shfl_xor(s, off, 64);
    if (lane == 0) out[row] = s + b[0];
}

// ---------------- f64-accumulating scatter-add (replay-deterministic) ----------------
__global__ void scatter_add_feat_d(const float* __restrict__ src,
                                   const int* __restrict__ smap,
                                   const int* __restrict__ dmap,
                                   double* __restrict__ dst, int nnz, int F) {
    int i = blockIdx.x * blockDim.x + threadIdx.x;
    int total = nnz * F;
    if (i >= total) return;
    int j = i / F, f = i - j * F;
    unsafeAtomicAdd(&dst[(size_t)dmap[j] * F + f], (double)src[(size_t)smap[j] * F + f]);
}

// scatter node->edge with fused Dinv scale + bias
__global__ void scatter_n2e_scaled(const double* __restrict__ hnode64,
                                   const float* __restrict__ deg,
                                   const float* __restrict__ b,
                                   const int* __restrict__ nid,
                                   const int* __restrict__ eid,
                                   double* __restrict__ dst, int nnz, int F) {
    int i = blockIdx.x * blockDim.x + threadIdx.x;
    int total = nnz * F;
    if (i >= total) return;
    int j = i / F, f = i - j * F;
    int n = nid[j], e = eid[j];
    float d = deg[n];
    float inv = d > 0.f ? 1.f / d : 0.f;
    float v = (float)hnode64[(size_t)n * F + f] * inv + b[f];
    unsafeAtomicAdd(&dst[(size_t)e * F + f], (double)v);
}

__global__ void count_incidence(const int* __restrict__ nid, const int* __restrict__ eid,
                                float* __restrict__ deg, float* __restrict__ ecnt, int nnz) {
    int i = blockIdx.x * blockDim.x + threadIdx.x;
    if (i >= nnz) return;
    atomicAdd(&deg[nid[i]], 1.f);
    atomicAdd(&ecnt[eid[i]], 1.f);
}

// ---------------- fused hyper scale + 50-row max/mean pool ----------------
__global__ void pool_hyper(const double* __restrict__ hn64, const float* __restrict__ deg,
                           const float* __restrict__ b, float* __restrict__ out) {
    int i = blockIdx.x * blockDim.x + threadIdx.x;
    if (i >= NB * 256) return;
    int o = i & 255, g = i >> 8;
    float bo = b[o];
    const double* base = hn64 + (size_t)g * NPG * 256 + o;
    const float* dg = deg + g * NPG;
    float mx = -1e30f, sm = 0.f;
    for (int n = 0; n < NPG; n++) {
        float d = dg[n];
        float inv = d > 0.f ? 1.f / d : 0.f;
        float v = (float)base[(size_t)n * 256] * inv + bo;
        mx = fmaxf(mx, v);
        sm += v;
    }
    out[(size_t)g * 512 + o] = mx;
    out[(size_t)g * 512 + 256 + o] = sm * (1.f / NPG);
}

// ---------------- pack fusion tokens ----------------
__global__ void pack_tokens(const float* __restrict__ fp_o, const float* __restrict__ xg,
                            const float* __restrict__ hxg, const float* __restrict__ t,
                            float* __restrict__ in_t) {
    int i = blockIdx.x * blockDim.x + threadIdx.x;
    if (i >= 4096 * 512) return;
    int d = i & 511;
    int row = i >> 9;
    int tok = row & 3, b = row >> 2;
    const float* s = (tok == 0) ? fp_o : (tok == 1) ? xg : (tok == 2) ? hxg : t;
    in_t[i] = s[b * 512 + d];
}

// ---------------- fused 4x4 attention per (b,h); qkv fused layout [4096][6144] ----------------
__global__ __launch_bounds__(256) void attn_kernel(const float* __restrict__ QKV,
                                                   float* __restrict__ att) {
    int wid = threadIdx.x >> 6, lane = threadIdx.x & 63;
    int bh = blockIdx.x * 4 + wid;
    int b = bh >> 2, h = bh & 3;
    const float* qb = QKV + (size_t)b * 4 * 6144 + h * 512;
    const float* kb = qb + 2048;
    const float* vb = qb + 4096;
    float qr[4][8], kr[4][8];
#pragma unroll
    for (int n = 0; n < 4; n++)
#pragma unroll
        for (int c = 0; c < 8; c++) {
            qr[n][c] = qb[n * 6144 + c * 64 + lane];
            kr[n][c] = kb[n * 6144 + c * 64 + lane];
        }
    float s[4][4];
#pragma unroll
    for (int n = 0; n < 4; n++)
#pragma unroll
        for (int m = 0; m < 4; m++) {
            float p = 0.f;
#pragma unroll
            for (int c = 0; c < 8; c++) p += qr[n][c] * kr[m][c];
#pragma unroll
            for (int off = 32; off > 0; off >>= 1) p += __shfl_xor(p, off, 64);
            s[n][m] = p * 0.04419417382415922f;   // 1/sqrt(512)
        }
    float pm[4][4];
#pragma unroll
    for (int n = 0; n < 4; n++) {
        float mx = fmaxf(fmaxf(s[n][0], s[n][1]), fmaxf(s[n][2], s[n][3]));
        float e0 = expf(s[n][0] - mx), e1 = expf(s[n][1] - mx);
        float e2 = expf(s[n][2] - mx), e3 = expf(s[n][3] - mx);
        float inv = 1.f / (e0 + e1 + e2 + e3);
        pm[n][0] = e0 * inv; pm[n][1] = e1 * inv; pm[n][2] = e2 * inv; pm[n][3] = e3 * inv;
    }
    float* ab = att + (size_t)bh * 4 * 512;
#pragma unroll
    for (int c = 0; c < 8; c++) {
        float v0 = vb[0 * 6144 + c * 64 + lane];
        float v1 = vb[1 * 6144 + c * 64 + lane];
        float v2 = vb[2 * 6144 + c * 64 + lane];
        float v3 = vb[3 * 6144 + c * 64 + lane];
#pragma unroll
        for (int n = 0; n < 4; n++) {
            float o = pm[n][0] * v0 + pm[n][1] * v1 + pm[n][2] * v2 + pm[n][3] * v3;
            ab[n * 512 + c * 64 + lane] = o;
        }
    }
}

// ---------------- conv 3x3 VALID + relu ----------------
__global__ void conv_relu(const float* __restrict__ att, const float* __restrict__ cw,
                          const float* __restrict__ cb, float* __restrict__ c) {
    __shared__ float w[144];
    __shared__ float bias[4];
    int t = threadIdx.x;
    if (t < 144) w[t] = cw[t];
    if (t < 4) bias[t] = cb[t];
    __syncthreads();
    int i = blockIdx.x * blockDim.x + t;
    if (i >= 1024 * 4 * 2 * 510) return;
    int wo = i % 510;
    int r = i / 510;
    int ho = r & 1; r >>= 1;
    int co = r & 3; int b = r >> 2;
    float acc = bias[co];
#pragma unroll
    for (int ci = 0; ci < 4; ci++)
#pragma unroll
        for (int kh = 0; kh < 3; kh++)
#pragma unroll
            for (int kw = 0; kw < 3; kw++)
                acc += att[(((size_t)b * 4 + ci) * 4 + ho + kh) * 512 + wo + kw] *
                       w[((co * 4 + ci) * 3 + kh) * 3 + kw];
    c[i] = fmaxf(acc, 0.f);
}

// ---------------- host side ----------------
static inline void launch_gemm(const float* A, const double* Aadd,
                               const double* A64, const float* rowcnt,
                               const float* W, const float* b, float* C,
                               int M, int N, int K, bool relu, hipStream_t s) {
    dim3 g((N + 127) / 128, (M + 127) / 128);
    if (relu) gemm_mfma<true><<<g, 256, 0, s>>>(A, Aadd, A64, rowcnt, W, b, C, M, N, K);
    else      gemm_mfma<false><<<g, 256, 0, s>>>(A, Aadd, A64, rowcnt, W, b, C, M, N, K);
}

static inline void launch_gemm64(const float* A, const float* W, const float* b, float* C,
                                 int M, int N, int K, bool relu, float* part, hipStream_t s) {
    int gx = (N + 63) / 64, gy = (M + 63) / 64;
    int targetSK = 1024 / (gx * gy);      // aim ~1024 blocks -> 4 blocks/CU
    if (targetSK < 1) targetSK = 1;
    if (targetSK > 8) targetSK = 8;
    int kchunk = K, SK = 1;
    if (targetSK > 1) {
        kchunk = (((K + targetSK - 1) / targetSK) + 127) & ~127;
        SK = (K + kchunk - 1) / kchunk;
    }
    if (SK <= 1) {
        dim3 g(gx, gy);
        if (relu) gemm64<true, false><<<g, 256, 0, s>>>(A, W, b, C, M, N, K, K);
        else      gemm64<false, false><<<g, 256, 0, s>>>(A, W, b, C, M, N, K, K);
    } else {
        dim3 g(gx, gy, SK);
        gemm64<false, true><<<g, 256, 0, s>>>(A, W, nullptr, part, M, N, K, kchunk);
        int MN = M * N;
        if (relu) reduce_partial<true><<<(MN + 255) / 256, 256, 0, s>>>(part, b, C, MN, N, SK);
        else      reduce_partial<false><<<(MN + 255) / 256, 256, 0, s>>>(part, b, C, MN, N, SK);
    }
}

extern "C" void kernel_launch(void* const* d_in, const int* in_sizes, int n_in,
                              void* d_out, int out_size, void* d_ws, size_t ws_size,
                              hipStream_t stream) {
    const float* x       = (const float*)d_in[0];
    const int*   edge    = (const int*)d_in[1];
    const int*   hedge   = (const int*)d_in[3];
    const float* fp      = (const float*)d_in[4];
    const float* text_em = (const float*)d_in[5];
    const float* fc1_W = (const float*)d_in[7];  const float* fc1_b = (const float*)d_in[8];
    const float* fc2_W = (const float*)d_in[9];  const float* fc2_b = (const float*)d_in[10];
    const float* fc3_W = (const float*)d_in[11]; const float* fc3_b = (const float*)d_in[12];
    const float* fcg1_W = (const float*)d_in[13]; const float* fcg1_b = (const float*)d_in[14];
    const float* fcg2_W = (const float*)d_in[15]; const float* fcg2_b = (const float*)d_in[16];
    const float* fchg1_W = (const float*)d_in[17]; const float* fchg1_b = (const float*)d_in[18];
    const float* fchg2_W = (const float*)d_in[19]; const float* fchg2_b = (const float*)d_in[20];
    const float* gin1_W = (const float*)d_in[21]; const float* gin1_b = (const float*)d_in[22];
    const float* gin2_W = (const float*)d_in[23]; const float* gin2_b = (const float*)d_in[24];
    const float* h3_W = (const float*)d_in[25]; const float* h3_b = (const float*)d_in[26];
    const float* h4_W = (const float*)d_in[27]; const float* h4_b = (const float*)d_in[28];
    const float* Wq = (const float*)d_in[29];
    const float* Wk = (const float*)d_in[30];
    const float* Wv = (const float*)d_in[31];
    const float* conv_W = (const float*)d_in[32]; const float* conv_b = (const float*)d_in[33];
    const float* mlp1_W = (const float*)d_in[34]; const float* mlp1_b = (const float*)d_in[35];
    const float* mlp2_W = (const float*)d_in[36]; const float* mlp2_b = (const float*)d_in[37];

    const int* e_src = edge;
    const int* e_dst = edge + N_EDGES;
    const int* h_nid = hedge;
    const int* h_eid = hedge + N_HNNZ;

    float* ws = (float*)d_ws;
    const size_t ZONE = 51609600;
    // ---- phase A (GIN) ----
    double* agg64 = (double*)ws;                    // [0, 8.6M f)
    float*  xg1   = ws + 8601600;                   // [8.6M, 12.9M)
    // ---- phase H (hypergraph, linearity-reordered) ----
    double* eagg64  = (double*)ws;                  // [0, 1,720,320 f)
    float*  e1_32   = ws + 1720320;                 // [1.72M, 3.44M)
    double* hnode64 = (double*)(ws + 3440640);      // [3.44M, 20.64M)
    double* hn2_64  = (double*)ws;                  // [0, 26.21M)  (after hnode64 dead)
    double* eagg2_64= (double*)(ws + 26214400);     // [26.21M, 29.66M)
    float*  e2_32   = ws + 29655040;                // [29.66M, 32.28M)
    // ---- phase D (attention) ----
    float* in_t = ws;                               // [0, 2.1M)
    float* qkv  = ws + 2097152;                     // [2.1M, 27.26M) 4096x6144
    float* att  = ws + 27262976;                    // [27.26M, 35.65M)
    float* cbuf = ws + 35651584;                    // [35.65M, 39.83M)
    float* m1   = ws + 39829504;                    // [39.83M, 40.88M)
    float* Wqkv = ws + 40878080;                    // [40.88M, 44.02M) 6144x512
    float* part = ws;                               // split-K scratch (zone-dead windows)
    // ---- persistent ----
    float* xg_raw = ws + ZONE;
    float* xg_mid = ws + ZONE + 1720320;
    float* hx_raw = ws + ZONE + 2768896;
    float* hx_mid = ws + ZONE + 3293184;
    float* h1     = ws + ZONE + 4341760;
    float* fp_o   = ws + ZONE + 4472832;
    float* tt     = ws + ZONE + 4997120;
    float* ecnt   = ws + ZONE + 5521408;
    float* deg    = ws + ZONE + 5531648;
    const size_t NEED = (ZONE + 5582848) * sizeof(float);
    if (ws_size < NEED) return;

    float* out_y  = (float*)d_out;
    float* xg_out = out_y + 1024;
    float* hx_out = out_y + 1024 + 1024 * 512;

    const int BT = 256;
    // ---------- GIN branch ----------
    hipMemsetAsync(agg64, 0, (size_t)N_NODES * FXD * 8, stream);
    scatter_add_feat_d<<<(N_EDGES * FXD + BT - 1) / BT, BT, 0, stream>>>(x, e_src, e_dst, agg64, N_EDGES, FXD);
    launch_gemm(x, agg64, nullptr, nullptr, gin1_W, gin1_b, xg1, N_NODES, FXD, FXD, true, stream);
    hipMemsetAsync(agg64, 0, (size_t)N_NODES * FXD * 8, stream);
    scatter_add_feat_d<<<(N_EDGES * FXD + BT - 1) / BT, BT, 0, stream>>>(xg1, e_src, e_dst, agg64, N_EDGES, FXD);
    gin2pool<<<NB, 256, 0, stream>>>(xg1, agg64, gin2_W, gin2_b, xg_raw);
    launch_gemm64(xg_raw, fcg1_W, fcg1_b, xg_mid, NB, 1024, 1680, true, part, stream);
    launch_gemm64(xg_mid, fcg2_W, fcg2_b, xg_out, NB, 512, 1024, false, part, stream);

    // ---------- hypergraph branch (GEMM commutes with segment-sum) ----------
    hipMemsetAsync(ecnt, 0, N_HEDGES * 4, stream);
    hipMemsetAsync(deg, 0, N_NODES * 4, stream);
    count_incidence<<<(N_HNNZ + BT - 1) / BT, BT, 0, stream>>>(h_nid, h_eid, deg, ecnt, N_HNNZ);
    hipMemsetAsync(eagg64, 0, (size_t)N_HEDGES * FXD * 8, stream);
    scatter_add_feat_d<<<(N_HNNZ * FXD + BT - 1) / BT, BT, 0, stream>>>(x, h_nid, h_eid, eagg64, N_HNNZ, FXD);
    launch_gemm(nullptr, nullptr, eagg64, ecnt, h3_W, nullptr, e1_32, N_HEDGES, 168, FXD, false, stream);
    hipMemsetAsync(hnode64, 0, (size_t)N_NODES * 168 * 8, stream);
    scatter_add_feat_d<<<(N_HNNZ * 168 + BT - 1) / BT, BT, 0, stream>>>(e1_32, h_eid, h_nid, hnode64, N_HNNZ, 168);
    hipMemsetAsync(eagg2_64, 0, (size_t)N_HEDGES * 168 * 8, stream);
    scatter_n2e_scaled<<<(N_HNNZ * 168 + BT - 1) / BT, BT, 0, stream>>>(hnode64, deg, h3_b, h_nid, h_eid, eagg2_64, N_HNNZ, 168);
    launch_gemm(nullptr, nullptr, eagg2_64, ecnt, h4_W, nullptr, e2_32, N_HEDGES, 256, 168, false, stream);
    hipMemsetAsync(hn2_64, 0, (size_t)N_NODES * 256 * 8, stream);
    scatter_add_feat_d<<<(N_HNNZ * 256 + BT - 1) / BT, BT, 0, stream>>>(e2_32, h_eid, h_nid, hn2_64, N_HNNZ, 256);
    pool_hyper<<<(NB * 256 + BT - 1) / BT, BT, 0, stream>>>(hn2_64, deg, h4_b, hx_raw);
    launch_gemm64(hx_raw, fchg1_W, fchg1_b, hx_mid, NB, 1024, 512, true, part, stream);
    launch_gemm64(hx_mid, fchg2_W, fchg2_b, hx_out, NB, 512, 1024, false, part, stream);

    // ---------- fingerprint + text (zone dead -> part scratch OK) ----------
    launch_gemm64(fp, fc1_W, fc1_b, h1, NB, FP2, FP_DIM, true, part, stream);
    launch_gemm64(h1, fc2_W, fc2_b, fp_o, NB, HID, FP2, false, part, stream);
    launch_gemm64(text_em, fc3_W, fc3_b, tt, NB, HID, 768, false, part, stream);

    // ---------- fusion attention ----------
    pack_tokens<<<(4096 * 512 + BT - 1) / BT, BT, 0, stream>>>(fp_o, xg_out, hx_out, tt, in_t);
    hipMemcpyAsync(Wqkv,                (void*)Wq, (size_t)2048 * 512 * 4, hipMemcpyDeviceToDevice, stream);
    hipMemcpyAsync(Wqkv + 2048 * 512,   (void*)Wk, (size_t)2048 * 512 * 4, hipMemcpyDeviceToDevice, stream);
    hipMemcpyAsync(Wqkv + 4096 * 512,   (void*)Wv, (size_t)2048 * 512 * 4, hipMemcpyDeviceToDevice, stream);
    launch_gemm(in_t, nullptr, nullptr, nullptr, Wqkv, nullptr, qkv, 4096, 6144, 512, false, stream);
    attn_kernel<<<1024, 256, 0, stream>>>(qkv, att);
    conv_relu<<<(1024 * 4 * 2 * 510 + BT - 1) / BT, BT, 0, stream>>>(att, conv_W, conv_b, cbuf);
    launch_gemm64(cbuf, mlp1_W, mlp1_b, m1, NB, 1024, 4080, true, part, stream);
    rowdot<<<256, 256, 0, stream>>>(m1, mlp2_W, mlp2_b, out_y, NB, 1024);
}

// Round 8
// 1083.563 us; speedup vs baseline: 3.3246x; 1.3003x over previous
//
#include <hip/hip_runtime.h>
#include <hip/hip_bf16.h>

// ---------------- constants ----------------
#define N_NODES 51200
#define N_EDGES 204800
#define N_HNNZ  102400
#define N_HEDGES 10240
#define NB 1024          // batch (graphs)
#define NPG 50           // nodes per graph (51200/1024)
#define FXD 84
#define FP_DIM 2513
#define FP2 128
#define HID 512

typedef __attribute__((ext_vector_type(4))) float f32x4;
typedef __attribute__((ext_vector_type(8))) __bf16 bf16x8;
typedef __attribute__((ext_vector_type(4))) short short4_t;

static __device__ __forceinline__ unsigned short f2bf(float f) {
    unsigned u = __builtin_bit_cast(unsigned, f);
    u += 0x7FFFu + ((u >> 16) & 1u);   // round-to-nearest-even
    return (unsigned short)(u >> 16);
}

// bijective XCD-aware remap (m204 formula)
static __device__ __forceinline__ int xcd_swizzle(int orig, int nwg) {
    int q = nwg >> 3, r = nwg & 7;
    int xcd = orig & 7, off = orig >> 3;
    return (xcd < r ? xcd * (q + 1) : r * (q + 1) + (xcd - r) * q) + off;
}

// ---------------- CSR build ----------------
__global__ void histo_i(const int* __restrict__ keys, int* __restrict__ cnt, int n) {
    int i = blockIdx.x * 256 + threadIdx.x;
    if (i < n) atomicAdd(&cnt[keys[i]], 1);
}

// 3 independent exclusive scans (one per block), two-pass chunked
__global__ __launch_bounds__(1024) void exscan3(const int* __restrict__ c0, int* __restrict__ o0, int B0,
                                                const int* __restrict__ c1, int* __restrict__ o1, int B1,
                                                const int* __restrict__ c2, int* __restrict__ o2, int B2) {
    const int* cnt = blockIdx.x == 0 ? c0 : blockIdx.x == 1 ? c1 : c2;
    int* off = blockIdx.x == 0 ? o0 : blockIdx.x == 1 ? o1 : o2;
    int B = blockIdx.x == 0 ? B0 : blockIdx.x == 1 ? B1 : B2;
    __shared__ int part[1024];
    int t = threadIdx.x;
    int C = (B + 1023) >> 10;
    int s0 = t * C, s1 = min(B, s0 + C);
    int sum = 0;
    for (int i = s0; i < s1; i++) sum += cnt[i];
    part[t] = sum;
    __syncthreads();
    for (int d = 1; d < 1024; d <<= 1) {
        int x = (t >= d) ? part[t - d] : 0;
        __syncthreads();
        part[t] += x;
        __syncthreads();
    }
    int run = (t == 0) ? 0 : part[t - 1];
    for (int i = s0; i < s1; i++) { off[i] = run; run += cnt[i]; }
    if (t == 1023) off[B] = part[1023];
}

// place payload[i] at a claimed slot in bucket keys[i]
__global__ void place_pay(const int* __restrict__ keys, const int* __restrict__ payload,
                          int* __restrict__ cursor, int* __restrict__ pay, int n) {
    int i = blockIdx.x * 256 + threadIdx.x;
    if (i < n) {
        int p = atomicAdd(&cursor[keys[i]], 1);
        pay[p] = payload[i];
    }
}

// ---------------- CSR gather: out[r][f] = scale * Σ_{j∈bucket r} src[pay[j]][f] (+self) ----------------
// f64 register accumulation -> replay-stable despite nondeterministic bucket order.
template<bool SELF, bool SCALE>
__global__ void gather_rows(const float* __restrict__ src,
                            const int* __restrict__ off, const int* __restrict__ pay,
                            const float* __restrict__ self_src,
                            float* __restrict__ out, int R, int F) {
    int i = blockIdx.x * 256 + threadIdx.x;
    if (i >= R * F) return;
    int r = i / F, f = i - r * F;
    int b = off[r], e = off[r + 1];
    double acc = 0.0;
    for (int j = b; j < e; j++)
        acc += (double)src[(size_t)pay[j] * F + f];
    float s = (float)acc;
    if (SCALE) s *= 1.f / fmaxf((float)(e - b), 1.f);
    if (SELF) s += self_src[i];
    out[i] = s;
}

// ---------------- MFMA GEMM 128x128: C = act(A @ W^T + b) ----------------
template<bool RELU>
__global__ __launch_bounds__(256) void gemm_mfma(const float* __restrict__ A,
                                                 const float* __restrict__ W,
                                                 const float* __restrict__ bias,
                                                 float* __restrict__ C,
                                                 int M, int N, int K) {
    __shared__ unsigned short Asm[128][32];
    __shared__ unsigned short Bsm[128][32];
    const int tid = threadIdx.x;
    const int nwg = gridDim.x * gridDim.y;
    const int wg = xcd_swizzle(blockIdx.y * gridDim.x + blockIdx.x, nwg);
    const int bm = (wg / gridDim.x) * 128, bn = (wg % gridDim.x) * 128;
    const int wid = tid >> 6, lane = tid & 63;
    const int wm = (wid >> 1) * 64, wn = (wid & 1) * 64;
    const int lr = lane & 15, lg = lane >> 4;
    const bool kvec = ((K & 3) == 0);

    f32x4 zero = {0.f, 0.f, 0.f, 0.f};
    f32x4 acc[4][4];
#pragma unroll
    for (int i = 0; i < 4; i++)
#pragma unroll
        for (int j = 0; j < 4; j++) acc[i][j] = zero;

    for (int k0 = 0; k0 < K; k0 += 32) {
#pragma unroll
        for (int i = 0; i < 4; i++) {
            int fidx = i * 256 + tid;
            int row = fidx >> 3, kq = (fidx & 7) << 2;
            int gk = k0 + kq;
            float v0 = 0.f, v1 = 0.f, v2 = 0.f, v3 = 0.f;
            int gm = bm + row;
            if (gm < M && gk < K) {
                const float* p = A + (size_t)gm * K + gk;
                if (kvec && gk + 4 <= K) {
                    float4 f = *(const float4*)p;
                    v0 = f.x; v1 = f.y; v2 = f.z; v3 = f.w;
                } else {
                    v0 = p[0];
                    if (gk + 1 < K) v1 = p[1];
                    if (gk + 2 < K) v2 = p[2];
                    if (gk + 3 < K) v3 = p[3];
                }
            }
            short4_t sv;
            sv[0] = (short)f2bf(v0); sv[1] = (short)f2bf(v1);
            sv[2] = (short)f2bf(v2); sv[3] = (short)f2bf(v3);
            *(short4_t*)&Asm[row][kq] = sv;

            v0 = v1 = v2 = v3 = 0.f;
            int gn = bn + row;
            if (gn < N && gk < K) {
                const float* p = W + (size_t)gn * K + gk;
                if (kvec && gk + 4 <= K) {
                    float4 f = *(const float4*)p;
                    v0 = f.x; v1 = f.y; v2 = f.z; v3 = f.w;
                } else {
                    v0 = p[0];
                    if (gk + 1 < K) v1 = p[1];
                    if (gk + 2 < K) v2 = p[2];
                    if (gk + 3 < K) v3 = p[3];
                }
            }
            sv[0] = (short)f2bf(v0); sv[1] = (short)f2bf(v1);
            sv[2] = (short)f2bf(v2); sv[3] = (short)f2bf(v3);
            *(short4_t*)&Bsm[row][kq] = sv;
        }
        __syncthreads();

        bf16x8 af[4], bf[4];
#pragma unroll
        for (int m = 0; m < 4; m++)
            af[m] = *(const bf16x8*)&Asm[wm + m * 16 + lr][lg * 8];
#pragma unroll
        for (int n = 0; n < 4; n++)
            bf[n] = *(const bf16x8*)&Bsm[wn + n * 16 + lr][lg * 8];
#pragma unroll
        for (int m = 0; m < 4; m++)
#pragma unroll
            for (int n = 0; n < 4; n++)
                acc[m][n] = __builtin_amdgcn_mfma_f32_16x16x32_bf16(af[m], bf[n], acc[m][n], 0, 0, 0);
        __syncthreads();
    }

#pragma unroll
    for (int m = 0; m < 4; m++) {
#pragma unroll
        for (int n = 0; n < 4; n++) {
            int col = bn + wn + n * 16 + lr;
            if (col >= N) continue;
            float bv = bias ? bias[col] : 0.f;
#pragma unroll
            for (int r = 0; r < 4; r++) {
                int row = bm + wm + m * 16 + lg * 4 + r;
                if (row >= M) continue;
                float v = acc[m][n][r] + bv;
                if (RELU) v = fmaxf(v, 0.f);
                C[(size_t)row * N + col] = v;
            }
        }
    }
}

// ---------------- MFMA GEMM 64x64, wave-K-split, 32KB LDS, grid.z split-K ----------------
template<bool RELU, bool PARTIAL>
__global__ __launch_bounds__(256) void gemm64(const float* __restrict__ A,
                                              const float* __restrict__ W,
                                              const float* __restrict__ bias,
                                              float* __restrict__ C,
                                              int M, int N, int K, int kchunk) {
    __shared__ __align__(16) char pool[32768];
    char* Ab = pool;
    char* Bb = pool + 16384;
    const int tid = threadIdx.x;
    const int nwg = gridDim.x * gridDim.y;
    const int wg = xcd_swizzle(blockIdx.y * gridDim.x + blockIdx.x, nwg);
    const int bm = (wg / gridDim.x) * 64, bn = (wg % gridDim.x) * 64;
    const int wid = tid >> 6, lane = tid & 63;
    const int lr = lane & 15, lg = lane >> 4;
    const int kbeg = blockIdx.z * kchunk;
    const int kend = min(K, kbeg + kchunk);
    const bool kvec = ((K & 3) == 0);

    f32x4 zero = {0.f, 0.f, 0.f, 0.f};
    f32x4 acc[4][4];
#pragma unroll
    for (int i = 0; i < 4; i++)
#pragma unroll
        for (int j = 0; j < 4; j++) acc[i][j] = zero;

    for (int kc = kbeg; kc < kend; kc += 128) {
#pragma unroll
        for (int u = 0; u < 8; u++) {
            int s = u * 256 + tid;
            int row = s >> 5, kq = (s & 31) << 2;
            int gk = kc + kq;
            int off = (row * 256 + (s & 31) * 8) ^ ((row & 7) << 4);

            float v0 = 0.f, v1 = 0.f, v2 = 0.f, v3 = 0.f;
            int gm = bm + row;
            if (gm < M && gk < kend) {
                const float* p = A + (size_t)gm * K + gk;
                if (kvec && gk + 4 <= kend) {
                    float4 f = *(const float4*)p;
                    v0 = f.x; v1 = f.y; v2 = f.z; v3 = f.w;
                } else {
                    v0 = p[0];
                    if (gk + 1 < kend) v1 = p[1];
                    if (gk + 2 < kend) v2 = p[2];
                    if (gk + 3 < kend) v3 = p[3];
                }
            }
            short4_t sv;
            sv[0] = (short)f2bf(v0); sv[1] = (short)f2bf(v1);
            sv[2] = (short)f2bf(v2); sv[3] = (short)f2bf(v3);
            *(short4_t*)(Ab + off) = sv;

            v0 = v1 = v2 = v3 = 0.f;
            int gn = bn + row;
            if (gn < N && gk < kend) {
                const float* p = W + (size_t)gn * K + gk;
                if (kvec && gk + 4 <= kend) {
                    float4 f = *(const float4*)p;
                    v0 = f.x; v1 = f.y; v2 = f.z; v3 = f.w;
                } else {
                    v0 = p[0];
                    if (gk + 1 < kend) v1 = p[1];
                    if (gk + 2 < kend) v2 = p[2];
                    if (gk + 3 < kend) v3 = p[3];
                }
            }
            sv[0] = (short)f2bf(v0); sv[1] = (short)f2bf(v1);
            sv[2] = (short)f2bf(v2); sv[3] = (short)f2bf(v3);
            *(short4_t*)(Bb + off) = sv;
        }
        __syncthreads();

        bf16x8 af[4], bf[4];
        const int kb = wid * 64 + lg * 16;
#pragma unroll
        for (int m = 0; m < 4; m++) {
            int row = m * 16 + lr;
            af[m] = *(const bf16x8*)(Ab + ((row * 256 + kb) ^ ((row & 7) << 4)));
        }
#pragma unroll
        for (int n = 0; n < 4; n++) {
            int row = n * 16 + lr;
            bf[n] = *(const bf16x8*)(Bb + ((row * 256 + kb) ^ ((row & 7) << 4)));
        }
#pragma unroll
        for (int m = 0; m < 4; m++)
#pragma unroll
            for (int n = 0; n < 4; n++)
                acc[m][n] = __builtin_amdgcn_mfma_f32_16x16x32_bf16(af[m], bf[n], acc[m][n], 0, 0, 0);
        __syncthreads();
    }

    float* redA = (float*)pool;
    float* redB = (float*)(pool + 16384);
    if (wid < 2) {
        float* r = (wid == 0) ? redA : redB;
#pragma unroll
        for (int m = 0; m < 4; m++)
#pragma unroll
            for (int n = 0; n < 4; n++)
#pragma unroll
                for (int r4 = 0; r4 < 4; r4++)
                    r[(m * 16 + lg * 4 + r4) * 64 + n * 16 + lr] = acc[m][n][r4];
    }
    __syncthreads();
    if (wid >= 2) {
        float* r = (wid == 2) ? redA : redB;
#pragma unroll
        for (int m = 0; m < 4; m++)
#pragma unroll
            for (int n = 0; n < 4; n++)
#pragma unroll
                for (int r4 = 0; r4 < 4; r4++)
                    r[(m * 16 + lg * 4 + r4) * 64 + n * 16 + lr] += acc[m][n][r4];
    }
    __syncthreads();
#pragma unroll
    for (int u = 0; u < 16; u++) {
        int idx = u * 256 + tid;
        int row = idx >> 6, col = idx & 63;
        int gm = bm + row, gn = bn + col;
        if (gm >= M || gn >= N) continue;
        float s = redA[idx] + redB[idx];
        if (PARTIAL) {
            C[(size_t)blockIdx.z * M * N + (size_t)gm * N + gn] = s;
        } else {
            s += bias ? bias[gn] : 0.f;
            if (RELU) s = fmaxf(s, 0.f);
            C[(size_t)gm * N + gn] = s;
        }
    }
}

template<bool RELU>
__global__ void reduce_partial(const float* __restrict__ part, const float* __restrict__ bias,
                               float* __restrict__ C, int MN, int N, int SK) {
    int i = blockIdx.x * 256 + threadIdx.x;
    if (i >= MN) return;
    float s = 0.f;
    for (int z = 0; z < SK; z++) s += part[(size_t)z * MN + i];
    s += bias ? bias[i % N] : 0.f;
    if (RELU) s = fmaxf(s, 0.f);
    C[i] = s;
}

// ---------------- fused GIN2 GEMM + bias + relu + 50-row max/mean pool (f32 input) ----------------
__global__ __launch_bounds__(256) void gin2pool(const float* __restrict__ xin2,
                                                const float* __restrict__ W,
                                                const float* __restrict__ bias,
                                                float* __restrict__ out) {
    __shared__ __align__(16) char Ab[16384];    // 64x128 bf16, swizzled
    const int tid = threadIdx.x;
    const int g = blockIdx.x;
    const int wid = tid >> 6, lane = tid & 63;
    const int lr = lane & 15, lg = lane >> 4;
    const int K = FXD;
    const int N = 840;

#pragma unroll
    for (int u = 0; u < 8; u++) {
        int s = u * 256 + tid;
        int row = s >> 5, kq = (s & 31) << 2;
        int off = (row * 256 + (s & 31) * 8) ^ ((row & 7) << 4);
        float v0 = 0.f, v1 = 0.f, v2 = 0.f, v3 = 0.f;
        if (row < NPG && kq < K) {
            float4 f = *(const float4*)(xin2 + ((size_t)g * NPG + row) * K + kq);
            v0 = f.x; v1 = f.y; v2 = f.z; v3 = f.w;
        }
        short4_t sv;
        sv[0] = (short)f2bf(v0); sv[1] = (short)f2bf(v1);
        sv[2] = (short)f2bf(v2); sv[3] = (short)f2bf(v3);
        *(short4_t*)(Ab + off) = sv;
    }
    __syncthreads();

    bf16x8 af[4][3];
#pragma unroll
    for (int m = 0; m < 4; m++)
#pragma unroll
        for (int kk = 0; kk < 3; kk++) {
            int row = m * 16 + lr;
            af[m][kk] = *(const bf16x8*)(Ab + ((row * 256 + kk * 64 + lg * 16) ^ ((row & 7) << 4)));
        }

    for (int t = 0; t < 14; t++) {
        const int n0 = t * 64 + wid * 16;
        const int wrow = n0 + lr;
        bf16x8 bf[3];
#pragma unroll
        for (int kk = 0; kk < 3; kk++) {
            int k0 = kk * 32 + lg * 8;
#pragma unroll
            for (int e = 0; e < 8; e++) {
                float v = (wrow < N && k0 + e < K) ? W[(size_t)wrow * K + k0 + e] : 0.f;
                bf[kk][e] = __builtin_bit_cast(__bf16, f2bf(v));
            }
        }
        f32x4 zero = {0.f, 0.f, 0.f, 0.f};
        f32x4 acc[4] = {zero, zero, zero, zero};
#pragma unroll
        for (int m = 0; m < 4; m++)
#pragma unroll
            for (int kk = 0; kk < 3; kk++)
                acc[m] = __builtin_amdgcn_mfma_f32_16x16x32_bf16(af[m][kk], bf[kk], acc[m], 0, 0, 0);

        const int c = n0 + lr;
        float bv = (c < N) ? bias[c] : 0.f;
        float mx = -1e30f, sm = 0.f;
#pragma unroll
        for (int m = 0; m < 4; m++)
#pragma unroll
            for (int r = 0; r < 4; r++) {
                int row = m * 16 + lg * 4 + r;
                if (row < NPG) {
                    float v = fmaxf(acc[m][r] + bv, 0.f);
                    mx = fmaxf(mx, v);
                    sm += v;
                }
            }
        mx = fmaxf(mx, __shfl_xor(mx, 16, 64));
        sm += __shfl_xor(sm, 16, 64);
        mx = fmaxf(mx, __shfl_xor(mx, 32, 64));
        sm += __shfl_xor(sm, 32, 64);
        if (lg == 0 && c < N) {
            out[(size_t)g * 1680 + c] = mx;
            out[(size_t)g * 1680 + 840 + c] = sm * (1.f / NPG);
        }
    }
}

// ---------------- N=1 GEMM ----------------
__global__ __launch_bounds__(256) void rowdot(const float* __restrict__ A,
                                              const float* __restrict__ w,
                                              const float* __restrict__ b,
                                              float* __restrict__ out, int Mrows, int K) {
    int row = blockIdx.x * 4 + (threadIdx.x >> 6);
    int lane = threadIdx.x & 63;
    if (row >= Mrows) return;
    float s = 0.f;
    for (int k = lane; k < K; k += 64) s += A[(size_t)row * K + k] * w[k];
#pragma unroll
    for (int off = 32; off > 0; off >>= 1) s += __shfl_xor(s, off, 64);
    if (lane == 0) out[row] = s + b[0];
}

// ---------------- hnode transform: h*Dinv + bias ----------------
__global__ void transform_dinv_bias(const float* __restrict__ h, const int* __restrict__ off_n,
                                    const float* __restrict__ b, float* __restrict__ o, int R, int F) {
    int i = blockIdx.x * 256 + threadIdx.x;
    if (i >= R * F) return;
    int r = i / F, f = i - r * F;
    int d = off_n[r + 1] - off_n[r];
    float inv = d > 0 ? 1.f / d : 0.f;
    o[i] = h[i] * inv + b[f];
}

// ---------------- fused hyper Dinv+bias + 50-row max/mean pool ----------------
__global__ void pool_hyper(const float* __restrict__ hn, const int* __restrict__ off_n,
                           const float* __restrict__ b, float* __restrict__ out) {
    int i = blockIdx.x * 256 + threadIdx.x;
    if (i >= NB * 256) return;
    int o = i & 255, g = i >> 8;
    float bo = b[o];
    const float* base = hn + (size_t)g * NPG * 256 + o;
    float mx = -1e30f, sm = 0.f;
    for (int n = 0; n < NPG; n++) {
        int node = g * NPG + n;
        int d = off_n[node + 1] - off_n[node];
        float inv = d > 0 ? 1.f / d : 0.f;
        float v = base[(size_t)n * 256] * inv + bo;
        mx = fmaxf(mx, v);
        sm += v;
    }
    out[(size_t)g * 512 + o] = mx;
    out[(size_t)g * 512 + 256 + o] = sm * (1.f / NPG);
}

// ---------------- pack fusion tokens ----------------
__global__ void pack_tokens(const float* __restrict__ fp_o, const float* __restrict__ xg,
                            const float* __restrict__ hxg, const float* __restrict__ t,
                            float* __restrict__ in_t) {
    int i = blockIdx.x * 256 + threadIdx.x;
    if (i >= 4096 * 512) return;
    int d = i & 511;
    int row = i >> 9;
    int tok = row & 3, b = row >> 2;
    const float* s = (tok == 0) ? fp_o : (tok == 1) ? xg : (tok == 2) ? hxg : t;
    in_t[i] = s[b * 512 + d];
}

// ---------------- fused 4x4 attention per (b,h); qkv layout [4096][6144] ----------------
__global__ __launch_bounds__(256) void attn_kernel(const float* __restrict__ QKV,
                                                   float* __restrict__ att) {
    int wid = threadIdx.x >> 6, lane = threadIdx.x & 63;
    int bh = blockIdx.x * 4 + wid;
    int b = bh >> 2, h = bh & 3;
    const float* qb = QKV + (size_t)b * 4 * 6144 + h * 512;
    const float* kb = qb + 2048;
    const float* vb = qb + 4096;
    float qr[4][8], kr[4][8];
#pragma unroll
    for (int n = 0; n < 4; n++)
#pragma unroll
        for (int c = 0; c < 8; c++) {
            qr[n][c] = qb[n * 6144 + c * 64 + lane];
            kr[n][c] = kb[n * 6144 + c * 64 + lane];
        }
    float s[4][4];
#pragma unroll
    for (int n = 0; n < 4; n++)
#pragma unroll
        for (int m = 0; m < 4; m++) {
            float p = 0.f;
#pragma unroll
            for (int c = 0; c < 8; c++) p += qr[n][c] * kr[m][c];
#pragma unroll
            for (int off = 32; off > 0; off >>= 1) p += __shfl_xor(p, off, 64);
            s[n][m] = p * 0.04419417382415922f;   // 1/sqrt(512)
        }
    float pm[4][4];
#pragma unroll
    for (int n = 0; n < 4; n++) {
        float mx = fmaxf(fmaxf(s[n][0], s[n][1]), fmaxf(s[n][2], s[n][3]));
        float e0 = expf(s[n][0] - mx), e1 = expf(s[n][1] - mx);
        float e2 = expf(s[n][2] - mx), e3 = expf(s[n][3] - mx);
        float inv = 1.f / (e0 + e1 + e2 + e3);
        pm[n][0] = e0 * inv; pm[n][1] = e1 * inv; pm[n][2] = e2 * inv; pm[n][3] = e3 * inv;
    }
    float* ab = att + (size_t)bh * 4 * 512;
#pragma unroll
    for (int c = 0; c < 8; c++) {
        float v0 = vb[0 * 6144 + c * 64 + lane];
        float v1 = vb[1 * 6144 + c * 64 + lane];
        float v2 = vb[2 * 6144 + c * 64 + lane];
        float v3 = vb[3 * 6144 + c * 64 + lane];
#pragma unroll
        for (int n = 0; n < 4; n++) {
            float o = pm[n][0] * v0 + pm[n][1] * v1 + pm[n][2] * v2 + pm[n][3] * v3;
            ab[n * 512 + c * 64 + lane] = o;
        }
    }
}

// ---------------- conv 3x3 VALID + relu ----------------
__global__ void conv_relu(const float* __restrict__ att, const float* __restrict__ cw,
                          const float* __restrict__ cb, float* __restrict__ c) {
    __shared__ float w[144];
    __shared__ float bias[4];
    int t = threadIdx.x;
    if (t < 144) w[t] = cw[t];
    if (t < 4) bias[t] = cb[t];
    __syncthreads();
    int i = blockIdx.x * 256 + t;
    if (i >= 1024 * 4 * 2 * 510) return;
    int wo = i % 510;
    int r = i / 510;
    int ho = r & 1; r >>= 1;
    int co = r & 3; int b = r >> 2;
    float acc = bias[co];
#pragma unroll
    for (int ci = 0; ci < 4; ci++)
#pragma unroll
        for (int kh = 0; kh < 3; kh++)
#pragma unroll
            for (int kw = 0; kw < 3; kw++)
                acc += att[(((size_t)b * 4 + ci) * 4 + ho + kh) * 512 + wo + kw] *
                       w[((co * 4 + ci) * 3 + kh) * 3 + kw];
    c[i] = fmaxf(acc, 0.f);
}

// ---------------- host side ----------------
static inline void launch_gemm(const float* A, const float* W, const float* b, float* C,
                               int M, int N, int K, bool relu, hipStream_t s) {
    dim3 g((N + 127) / 128, (M + 127) / 128);
    if (relu) gemm_mfma<true><<<g, 256, 0, s>>>(A, W, b, C, M, N, K);
    else      gemm_mfma<false><<<g, 256, 0, s>>>(A, W, b, C, M, N, K);
}

static inline void launch_gemm64(const float* A, const float* W, const float* b, float* C,
                                 int M, int N, int K, bool relu, float* part, hipStream_t s) {
    int gx = (N + 63) / 64, gy = (M + 63) / 64;
    int targetSK = 1024 / (gx * gy);
    if (targetSK < 1) targetSK = 1;
    if (targetSK > 8) targetSK = 8;
    int kchunk = K, SK = 1;
    if (targetSK > 1) {
        kchunk = (((K + targetSK - 1) / targetSK) + 127) & ~127;
        SK = (K + kchunk - 1) / kchunk;
    }
    if (SK <= 1) {
        dim3 g(gx, gy);
        if (relu) gemm64<true, false><<<g, 256, 0, s>>>(A, W, b, C, M, N, K, K);
        else      gemm64<false, false><<<g, 256, 0, s>>>(A, W, b, C, M, N, K, K);
    } else {
        dim3 g(gx, gy, SK);
        gemm64<false, true><<<g, 256, 0, s>>>(A, W, nullptr, part, M, N, K, kchunk);
        int MN = M * N;
        if (relu) reduce_partial<true><<<(MN + 255) / 256, 256, 0, s>>>(part, b, C, MN, N, SK);
        else      reduce_partial<false><<<(MN + 255) / 256, 256, 0, s>>>(part, b, C, MN, N, SK);
    }
}

extern "C" void kernel_launch(void* const* d_in, const int* in_sizes, int n_in,
                              void* d_out, int out_size, void* d_ws, size_t ws_size,
                              hipStream_t stream) {
    const float* x       = (const float*)d_in[0];
    const int*   edge    = (const int*)d_in[1];
    const int*   hedge   = (const int*)d_in[3];
    const float* fp      = (const float*)d_in[4];
    const float* text_em = (const float*)d_in[5];
    const float* fc1_W = (const float*)d_in[7];  const float* fc1_b = (const float*)d_in[8];
    const float* fc2_W = (const float*)d_in[9];  const float* fc2_b = (const float*)d_in[10];
    const float* fc3_W = (const float*)d_in[11]; const float* fc3_b = (const float*)d_in[12];
    const float* fcg1_W = (const float*)d_in[13]; const float* fcg1_b = (const float*)d_in[14];
    const float* fcg2_W = (const float*)d_in[15]; const float* fcg2_b = (const float*)d_in[16];
    const float* fchg1_W = (const float*)d_in[17]; const float* fchg1_b = (const float*)d_in[18];
    const float* fchg2_W = (const float*)d_in[19]; const float* fchg2_b = (const float*)d_in[20];
    const float* gin1_W = (const float*)d_in[21]; const float* gin1_b = (const float*)d_in[22];
    const float* gin2_W = (const float*)d_in[23]; const float* gin2_b = (const float*)d_in[24];
    const float* h3_W = (const float*)d_in[25]; const float* h3_b = (const float*)d_in[26];
    const float* h4_W = (const float*)d_in[27]; const float* h4_b = (const float*)d_in[28];
    const float* Wq = (const float*)d_in[29];
    const float* Wk = (const float*)d_in[30];
    const float* Wv = (const float*)d_in[31];
    const float* conv_W = (const float*)d_in[32]; const float* conv_b = (const float*)d_in[33];
    const float* mlp1_W = (const float*)d_in[34]; const float* mlp1_b = (const float*)d_in[35];
    const float* mlp2_W = (const float*)d_in[36]; const float* mlp2_b = (const float*)d_in[37];

    const int* e_src = edge;
    const int* e_dst = edge + N_EDGES;
    const int* h_nid = hedge;
    const int* h_eid = hedge + N_HNNZ;

    float* ws = (float*)d_ws;
    const size_t ZONE = 51609600;
    // ---- phase A (GIN), all f32 ----
    float* xin1 = ws;                               // 4,300,800
    float* xg1  = ws + 4300800;                     // 4,300,800
    float* xin2 = ws + 8601600;                     // 4,300,800
    // ---- phase H (hypergraph, linearity-reordered), all f32 ----
    float* eagg   = ws;                             // 860,160
    float* e1_32  = ws + 860160;                    // 1,720,320
    float* hnode  = ws + 2580480;                   // 8,601,600
    float* hnodet = ws + 11182080;                  // 8,601,600
    float* eagg2  = ws + 19783680;                  // 1,720,320
    float* e2_32  = ws + 21504000;                  // 2,621,440
    float* hn2    = ws + 24125440;                  // 13,107,200 (ends 37,232,640)
    // ---- phase D (attention) ----
    float* in_t = ws;                               // 2,097,152
    float* qkv  = ws + 2097152;                     // 25,165,824 (4096x6144)
    float* att  = ws + 27262976;                    // 8,388,608
    float* cbuf = ws + 35651584;                    // 4,177,920
    float* m1   = ws + 39829504;                    // 1,048,576
    float* Wqkv = ws + 40878080;                    // 3,145,728 (ends 44,023,808)
    float* part = ws;                               // split-K scratch (zone-dead windows, <4.2M)
    // ---- CSR region (above all phase high-water marks, inside ZONE) ----
    int* cnt_g = (int*)(ws + 45000000);             // 51,200   (becomes cursor)
    int* off_g = (int*)(ws + 45051200);             // 51,201
    int* pay_g = (int*)(ws + 45102401);             // 204,800
    int* cnt_e = (int*)(ws + 45307201);             // 10,240
    int* off_e = (int*)(ws + 45317441);             // 10,241
    int* pay_e = (int*)(ws + 45327682);             // 102,400
    int* cnt_n = (int*)(ws + 45430082);             // 51,200
    int* off_n = (int*)(ws + 45481282);             // 51,201
    int* pay_n = (int*)(ws + 45532483);             // 102,400 (ends 45,634,883 < ZONE)
    // ---- persistent ----
    float* xg_raw = ws + ZONE;
    float* xg_mid = ws + ZONE + 1720320;
    float* hx_raw = ws + ZONE + 2768896;
    float* hx_mid = ws + ZONE + 3293184;
    float* h1     = ws + ZONE + 4341760;
    float* fp_o   = ws + ZONE + 4472832;
    float* tt     = ws + ZONE + 4997120;
    const size_t NEED = (ZONE + 5582848) * sizeof(float);
    if (ws_size < NEED) return;

    float* out_y  = (float*)d_out;
    float* xg_out = out_y + 1024;
    float* hx_out = out_y + 1024 + 1024 * 512;

    // ---------- build 3 CSR structures ----------
    hipMemsetAsync(cnt_g, 0, N_NODES * 4, stream);
    hipMemsetAsync(cnt_e, 0, N_HEDGES * 4, stream);
    hipMemsetAsync(cnt_n, 0, N_NODES * 4, stream);
    histo_i<<<(N_EDGES + 255) / 256, 256, 0, stream>>>(e_dst, cnt_g, N_EDGES);
    histo_i<<<(N_HNNZ + 255) / 256, 256, 0, stream>>>(h_eid, cnt_e, N_HNNZ);
    histo_i<<<(N_HNNZ + 255) / 256, 256, 0, stream>>>(h_nid, cnt_n, N_HNNZ);
    exscan3<<<3, 1024, 0, stream>>>(cnt_g, off_g, N_NODES, cnt_e, off_e, N_HEDGES, cnt_n, off_n, N_NODES);
    hipMemcpyAsync(cnt_g, off_g, N_NODES * 4, hipMemcpyDeviceToDevice, stream);
    hipMemcpyAsync(cnt_e, off_e, N_HEDGES * 4, hipMemcpyDeviceToDevice, stream);
    hipMemcpyAsync(cnt_n, off_n, N_NODES * 4, hipMemcpyDeviceToDevice, stream);
    place_pay<<<(N_EDGES + 255) / 256, 256, 0, stream>>>(e_dst, e_src, cnt_g, pay_g, N_EDGES);
    place_pay<<<(N_HNNZ + 255) / 256, 256, 0, stream>>>(h_eid, h_nid, cnt_e, pay_e, N_HNNZ);
    place_pay<<<(N_HNNZ + 255) / 256, 256, 0, stream>>>(h_nid, h_eid, cnt_n, pay_n, N_HNNZ);

    // ---------- GIN branch ----------
    gather_rows<true, false><<<(N_NODES * FXD + 255) / 256, 256, 0, stream>>>(
        x, off_g, pay_g, x, xin1, N_NODES, FXD);
    launch_gemm(xin1, gin1_W, gin1_b, xg1, N_NODES, FXD, FXD, true, stream);
    gather_rows<true, false><<<(N_NODES * FXD + 255) / 256, 256, 0, stream>>>(
        xg1, off_g, pay_g, xg1, xin2, N_NODES, FXD);
    gin2pool<<<NB, 256, 0, stream>>>(xin2, gin2_W, gin2_b, xg_raw);
    launch_gemm64(xg_raw, fcg1_W, fcg1_b, xg_mid, NB, 1024, 1680, true, part, stream);
    launch_gemm64(xg_mid, fcg2_W, fcg2_b, xg_out, NB, 512, 1024, false, part, stream);

    // ---------- hypergraph branch (GEMM commutes with segment-sum) ----------
    gather_rows<false, true><<<(N_HEDGES * FXD + 255) / 256, 256, 0, stream>>>(
        x, off_e, pay_e, nullptr, eagg, N_HEDGES, FXD);
    launch_gemm64(eagg, h3_W, nullptr, e1_32, N_HEDGES, 168, FXD, false, part, stream);
    gather_rows<false, false><<<(N_NODES * 168 + 255) / 256, 256, 0, stream>>>(
        e1_32, off_n, pay_n, nullptr, hnode, N_NODES, 168);
    transform_dinv_bias<<<(N_NODES * 168 + 255) / 256, 256, 0, stream>>>(
        hnode, off_n, h3_b, hnodet, N_NODES, 168);
    gather_rows<false, true><<<(N_HEDGES * 168 + 255) / 256, 256, 0, stream>>>(
        hnodet, off_e, pay_e, nullptr, eagg2, N_HEDGES, 168);
    launch_gemm64(eagg2, h4_W, nullptr, e2_32, N_HEDGES, 256, 168, false, part, stream);
    gather_rows<false, false><<<(N_NODES * 256 + 255) / 256, 256, 0, stream>>>(
        e2_32, off_n, pay_n, nullptr, hn2, N_NODES, 256);
    pool_hyper<<<(NB * 256 + 255) / 256, 256, 0, stream>>>(hn2, off_n, h4_b, hx_raw);
    launch_gemm64(hx_raw, fchg1_W, fchg1_b, hx_mid, NB, 1024, 512, true, part, stream);
    launch_gemm64(hx_mid, fchg2_W, fchg2_b, hx_out, NB, 512, 1024, false, part, stream);

    // ---------- fingerprint + text ----------
    launch_gemm64(fp, fc1_W, fc1_b, h1, NB, FP2, FP_DIM, true, part, stream);
    launch_gemm64(h1, fc2_W, fc2_b, fp_o, NB, HID, FP2, false, part, stream);
    launch_gemm64(text_em, fc3_W, fc3_b, tt, NB, HID, 768, false, part, stream);

    // ---------- fusion attention ----------
    pack_tokens<<<(4096 * 512 + 255) / 256, 256, 0, stream>>>(fp_o, xg_out, hx_out, tt, in_t);
    hipMemcpyAsync(Wqkv,              (void*)Wq, (size_t)2048 * 512 * 4, hipMemcpyDeviceToDevice, stream);
    hipMemcpyAsync(Wqkv + 2048 * 512, (void*)Wk, (size_t)2048 * 512 * 4, hipMemcpyDeviceToDevice, stream);
    hipMemcpyAsync(Wqkv + 4096 * 512, (void*)Wv, (size_t)2048 * 512 * 4, hipMemcpyDeviceToDevice, stream);
    launch_gemm(in_t, Wqkv, nullptr, qkv, 4096, 6144, 512, false, stream);
    attn_kernel<<<1024, 256, 0, stream>>>(qkv, att);
    conv_relu<<<(1024 * 4 * 2 * 510 + 255) / 256, 256, 0, stream>>>(att, conv_W, conv_b, cbuf);
    launch_gemm64(cbuf, mlp1_W, mlp1_b, m1, NB, 1024, 4080, true, part, stream);
    rowdot<<<256, 256, 0, stream>>>(m1, mlp2_W, mlp2_b, out_y, NB, 1024);
}

// Round 9
// 993.365 us; speedup vs baseline: 3.6265x; 1.0908x over previous
//
#include <hip/hip_runtime.h>
#include <hip/hip_bf16.h>

// ---------------- constants ----------------
#define N_NODES 51200
#define N_EDGES 204800
#define N_HNNZ  102400
#define N_HEDGES 10240
#define NB 1024          // batch (graphs)
#define NPG 50           // nodes per graph (51200/1024)
#define FXD 84
#define FP_DIM 2513
#define FP2 128
#define HID 512

typedef __attribute__((ext_vector_type(4))) float f32x4;
typedef __attribute__((ext_vector_type(8))) __bf16 bf16x8;
typedef __attribute__((ext_vector_type(4))) short short4_t;

static __device__ __forceinline__ unsigned short f2bf(float f) {
    unsigned u = __builtin_bit_cast(unsigned, f);
    u += 0x7FFFu + ((u >> 16) & 1u);   // round-to-nearest-even
    return (unsigned short)(u >> 16);
}
static __device__ __forceinline__ float bf2f(unsigned short u) {
    unsigned x = ((unsigned)u) << 16;
    return __builtin_bit_cast(float, x);
}

// bijective XCD-aware remap (m204 formula)
static __device__ __forceinline__ int xcd_swizzle(int orig, int nwg) {
    int q = nwg >> 3, r = nwg & 7;
    int xcd = orig & 7, off = orig >> 3;
    return (xcd < r ? xcd * (q + 1) : r * (q + 1) + (xcd - r) * q) + off;
}

// load 4 elements as bf16 short4 (f32 source converts; bf16 source copies)
template<typename T>
static __device__ __forceinline__ short4_t ld4bf(const T* p, int gk, int kend, bool kvec) {
    short4_t sv;
    if constexpr (sizeof(T) == 4) {
        float v0 = 0.f, v1 = 0.f, v2 = 0.f, v3 = 0.f;
        if (kvec && gk + 4 <= kend) {
            float4 f = *(const float4*)p;
            v0 = f.x; v1 = f.y; v2 = f.z; v3 = f.w;
        } else {
            v0 = p[0];
            if (gk + 1 < kend) v1 = p[1];
            if (gk + 2 < kend) v2 = p[2];
            if (gk + 3 < kend) v3 = p[3];
        }
        sv[0] = (short)f2bf(v0); sv[1] = (short)f2bf(v1);
        sv[2] = (short)f2bf(v2); sv[3] = (short)f2bf(v3);
    } else {
        if (kvec && gk + 4 <= kend) {
            sv = *(const short4_t*)p;
        } else {
            const unsigned short* q = (const unsigned short*)p;
            sv[0] = (short)q[0];
            sv[1] = (gk + 1 < kend) ? (short)q[1] : (short)0;
            sv[2] = (gk + 2 < kend) ? (short)q[2] : (short)0;
            sv[3] = (gk + 3 < kend) ? (short)q[3] : (short)0;
        }
    }
    return sv;
}

// ---------------- CSR build ----------------
__global__ void histo_i(const int* __restrict__ keys, int* __restrict__ cnt, int n) {
    int i = blockIdx.x * 256 + threadIdx.x;
    if (i < n) atomicAdd(&cnt[keys[i]], 1);
}

__global__ __launch_bounds__(1024) void exscan3(const int* __restrict__ c0, int* __restrict__ o0, int B0,
                                                const int* __restrict__ c1, int* __restrict__ o1, int B1,
                                                const int* __restrict__ c2, int* __restrict__ o2, int B2) {
    const int* cnt = blockIdx.x == 0 ? c0 : blockIdx.x == 1 ? c1 : c2;
    int* off = blockIdx.x == 0 ? o0 : blockIdx.x == 1 ? o1 : o2;
    int B = blockIdx.x == 0 ? B0 : blockIdx.x == 1 ? B1 : B2;
    __shared__ int part[1024];
    int t = threadIdx.x;
    int C = (B + 1023) >> 10;
    int s0 = t * C, s1 = min(B, s0 + C);
    int sum = 0;
    for (int i = s0; i < s1; i++) sum += cnt[i];
    part[t] = sum;
    __syncthreads();
    for (int d = 1; d < 1024; d <<= 1) {
        int x = (t >= d) ? part[t - d] : 0;
        __syncthreads();
        part[t] += x;
        __syncthreads();
    }
    int run = (t == 0) ? 0 : part[t - 1];
    for (int i = s0; i < s1; i++) { off[i] = run; run += cnt[i]; }
    if (t == 1023) off[B] = part[1023];
}

__global__ void place_pay(const int* __restrict__ keys, const int* __restrict__ payload,
                          int* __restrict__ cursor, int* __restrict__ pay, int n) {
    int i = blockIdx.x * 256 + threadIdx.x;
    if (i < n) {
        int p = atomicAdd(&cursor[keys[i]], 1);
        pay[p] = payload[i];
    }
}

// ---------------- CSR gather (f64 register accumulation -> replay-stable) ----------------
template<bool SELF, bool SCALE>
__global__ void gather_rows(const float* __restrict__ src,
                            const int* __restrict__ off, const int* __restrict__ pay,
                            const float* __restrict__ self_src,
                            float* __restrict__ out, int R, int F) {
    int i = blockIdx.x * 256 + threadIdx.x;
    if (i >= R * F) return;
    int r = i / F, f = i - r * F;
    int b = off[r], e = off[r + 1];
    double acc = 0.0;
    for (int j = b; j < e; j++)
        acc += (double)src[(size_t)pay[j] * F + f];
    float s = (float)acc;
    if (SCALE) s *= 1.f / fmaxf((float)(e - b), 1.f);
    if (SELF) s += self_src[i];
    out[i] = s;
}

// ---------------- bf16 GEMM 128x128, BK=64, no guards (M,N %128==0, K %64==0) ----------------
// A: [M,K] bf16; B: [N,K] bf16; C: [M,N] bf16.
__global__ __launch_bounds__(256) void gemm_bf16(const unsigned short* __restrict__ A,
                                                 const unsigned short* __restrict__ B,
                                                 unsigned short* __restrict__ C,
                                                 int M, int N, int K) {
    __shared__ __align__(16) char Asm[16384];   // 128 x 64 bf16, swizzled
    __shared__ __align__(16) char Bsm[16384];
    const int tid = threadIdx.x;
    const int nwg = gridDim.x * gridDim.y;
    const int wg = xcd_swizzle(blockIdx.y * gridDim.x + blockIdx.x, nwg);
    const int bm = (wg / gridDim.x) * 128, bn = (wg % gridDim.x) * 128;
    const int wid = tid >> 6, lane = tid & 63;
    const int wm = (wid >> 1) * 64, wn = (wid & 1) * 64;
    const int lr = lane & 15, lg = lane >> 4;

    f32x4 zero = {0.f, 0.f, 0.f, 0.f};
    f32x4 acc[4][4];
#pragma unroll
    for (int i = 0; i < 4; i++)
#pragma unroll
        for (int j = 0; j < 4; j++) acc[i][j] = zero;

    for (int k0 = 0; k0 < K; k0 += 64) {
#pragma unroll
        for (int u = 0; u < 4; u++) {
            int slot = u * 256 + tid;            // 0..1023 16B-chunks
            int row = slot >> 3, ch = slot & 7;
            int off = (row * 128 + ch * 16) ^ ((row & 7) << 4);
            uint4 va = *(const uint4*)(A + (size_t)(bm + row) * K + k0 + ch * 8);
            *(uint4*)(Asm + off) = va;
            uint4 vb = *(const uint4*)(B + (size_t)(bn + row) * K + k0 + ch * 8);
            *(uint4*)(Bsm + off) = vb;
        }
        __syncthreads();
#pragma unroll
        for (int kk = 0; kk < 2; kk++) {
            bf16x8 af[4], bf[4];
#pragma unroll
            for (int m = 0; m < 4; m++) {
                int row = wm + m * 16 + lr;
                af[m] = *(const bf16x8*)(Asm + ((row * 128 + kk * 64 + lg * 16) ^ ((row & 7) << 4)));
            }
#pragma unroll
            for (int n = 0; n < 4; n++) {
                int row = wn + n * 16 + lr;
                bf[n] = *(const bf16x8*)(Bsm + ((row * 128 + kk * 64 + lg * 16) ^ ((row & 7) << 4)));
            }
#pragma unroll
            for (int m = 0; m < 4; m++)
#pragma unroll
                for (int n = 0; n < 4; n++)
                    acc[m][n] = __builtin_amdgcn_mfma_f32_16x16x32_bf16(af[m], bf[n], acc[m][n], 0, 0, 0);
        }
        __syncthreads();
    }
#pragma unroll
    for (int m = 0; m < 4; m++)
#pragma unroll
        for (int n = 0; n < 4; n++) {
            int col = bn + wn + n * 16 + lr;
#pragma unroll
            for (int r = 0; r < 4; r++) {
                int row = bm + wm + m * 16 + lg * 4 + r;
                C[(size_t)row * N + col] = f2bf(acc[m][n][r]);
            }
        }
}

// ---------------- MFMA GEMM 64x64, wave-K-split, 32KB LDS, grid.z split-K ----------------
template<bool RELU, bool PARTIAL, typename TA, typename TW>
__global__ __launch_bounds__(256) void gemm64(const TA* __restrict__ A,
                                              const TW* __restrict__ W,
                                              const float* __restrict__ bias,
                                              float* __restrict__ C,
                                              int M, int N, int K, int kchunk) {
    __shared__ __align__(16) char pool[32768];
    char* Ab = pool;
    char* Bb = pool + 16384;
    const int tid = threadIdx.x;
    const int nwg = gridDim.x * gridDim.y;
    const int wg = xcd_swizzle(blockIdx.y * gridDim.x + blockIdx.x, nwg);
    const int bm = (wg / gridDim.x) * 64, bn = (wg % gridDim.x) * 64;
    const int wid = tid >> 6, lane = tid & 63;
    const int lr = lane & 15, lg = lane >> 4;
    const int kbeg = blockIdx.z * kchunk;
    const int kend = min(K, kbeg + kchunk);
    const bool kvec = ((K & 3) == 0);

    f32x4 zero = {0.f, 0.f, 0.f, 0.f};
    f32x4 acc[4][4];
#pragma unroll
    for (int i = 0; i < 4; i++)
#pragma unroll
        for (int j = 0; j < 4; j++) acc[i][j] = zero;

    for (int kc = kbeg; kc < kend; kc += 128) {
#pragma unroll
        for (int u = 0; u < 8; u++) {
            int s = u * 256 + tid;
            int row = s >> 5, kq = (s & 31) << 2;
            int gk = kc + kq;
            int off = (row * 256 + (s & 31) * 8) ^ ((row & 7) << 4);

            short4_t sv = {0, 0, 0, 0};
            int gm = bm + row;
            if (gm < M && gk < kend)
                sv = ld4bf(A + (size_t)gm * K + gk, gk, kend, kvec);
            *(short4_t*)(Ab + off) = sv;

            short4_t sw = {0, 0, 0, 0};
            int gn = bn + row;
            if (gn < N && gk < kend)
                sw = ld4bf(W + (size_t)gn * K + gk, gk, kend, kvec);
            *(short4_t*)(Bb + off) = sw;
        }
        __syncthreads();

        bf16x8 af[4], bf[4];
        const int kb = wid * 64 + lg * 16;
#pragma unroll
        for (int m = 0; m < 4; m++) {
            int row = m * 16 + lr;
            af[m] = *(const bf16x8*)(Ab + ((row * 256 + kb) ^ ((row & 7) << 4)));
        }
#pragma unroll
        for (int n = 0; n < 4; n++) {
            int row = n * 16 + lr;
            bf[n] = *(const bf16x8*)(Bb + ((row * 256 + kb) ^ ((row & 7) << 4)));
        }
#pragma unroll
        for (int m = 0; m < 4; m++)
#pragma unroll
            for (int n = 0; n < 4; n++)
                acc[m][n] = __builtin_amdgcn_mfma_f32_16x16x32_bf16(af[m], bf[n], acc[m][n], 0, 0, 0);
        __syncthreads();
    }

    float* redA = (float*)pool;
    float* redB = (float*)(pool + 16384);
    if (wid < 2) {
        float* r = (wid == 0) ? redA : redB;
#pragma unroll
        for (int m = 0; m < 4; m++)
#pragma unroll
            for (int n = 0; n < 4; n++)
#pragma unroll
                for (int r4 = 0; r4 < 4; r4++)
                    r[(m * 16 + lg * 4 + r4) * 64 + n * 16 + lr] = acc[m][n][r4];
    }
    __syncthreads();
    if (wid >= 2) {
        float* r = (wid == 2) ? redA : redB;
#pragma unroll
        for (int m = 0; m < 4; m++)
#pragma unroll
            for (int n = 0; n < 4; n++)
#pragma unroll
                for (int r4 = 0; r4 < 4; r4++)
                    r[(m * 16 + lg * 4 + r4) * 64 + n * 16 + lr] += acc[m][n][r4];
    }
    __syncthreads();
#pragma unroll
    for (int u = 0; u < 16; u++) {
        int idx = u * 256 + tid;
        int row = idx >> 6, col = idx & 63;
        int gm = bm + row, gn = bn + col;
        if (gm >= M || gn >= N) continue;
        float s = redA[idx] + redB[idx];
        if (PARTIAL) {
            C[(size_t)blockIdx.z * M * N + (size_t)gm * N + gn] = s;
        } else {
            s += bias ? bias[gn] : 0.f;
            if (RELU) s = fmaxf(s, 0.f);
            C[(size_t)gm * N + gn] = s;
        }
    }
}

template<bool RELU>
__global__ void reduce_partial(const float* __restrict__ part, const float* __restrict__ bias,
                               float* __restrict__ C, int MN, int N, int SK) {
    int i = blockIdx.x * 256 + threadIdx.x;
    if (i >= MN) return;
    float s = 0.f;
    for (int z = 0; z < SK; z++) s += part[(size_t)z * MN + i];
    s += bias ? bias[i % N] : 0.f;
    if (RELU) s = fmaxf(s, 0.f);
    C[i] = s;
}

// ---------------- fused GIN2 GEMM + bias + relu + 50-row max/mean pool ----------------
__global__ __launch_bounds__(256) void gin2pool(const float* __restrict__ xin2,
                                                const float* __restrict__ W,
                                                const float* __restrict__ bias,
                                                float* __restrict__ out) {
    __shared__ __align__(16) char Ab[16384];
    const int tid = threadIdx.x;
    const int g = blockIdx.x;
    const int wid = tid >> 6, lane = tid & 63;
    const int lr = lane & 15, lg = lane >> 4;
    const int K = FXD;
    const int N = 840;

#pragma unroll
    for (int u = 0; u < 8; u++) {
        int s = u * 256 + tid;
        int row = s >> 5, kq = (s & 31) << 2;
        int off = (row * 256 + (s & 31) * 8) ^ ((row & 7) << 4);
        float v0 = 0.f, v1 = 0.f, v2 = 0.f, v3 = 0.f;
        if (row < NPG && kq < K) {
            float4 f = *(const float4*)(xin2 + ((size_t)g * NPG + row) * K + kq);
            v0 = f.x; v1 = f.y; v2 = f.z; v3 = f.w;
        }
        short4_t sv;
        sv[0] = (short)f2bf(v0); sv[1] = (short)f2bf(v1);
        sv[2] = (short)f2bf(v2); sv[3] = (short)f2bf(v3);
        *(short4_t*)(Ab + off) = sv;
    }
    __syncthreads();

    bf16x8 af[4][3];
#pragma unroll
    for (int m = 0; m < 4; m++)
#pragma unroll
        for (int kk = 0; kk < 3; kk++) {
            int row = m * 16 + lr;
            af[m][kk] = *(const bf16x8*)(Ab + ((row * 256 + kk * 64 + lg * 16) ^ ((row & 7) << 4)));
        }

    for (int t = 0; t < 14; t++) {
        const int n0 = t * 64 + wid * 16;
        const int wrow = n0 + lr;
        bf16x8 bf[3];
#pragma unroll
        for (int kk = 0; kk < 3; kk++) {
            int k0 = kk * 32 + lg * 8;
#pragma unroll
            for (int e = 0; e < 8; e++) {
                float v = (wrow < N && k0 + e < K) ? W[(size_t)wrow * K + k0 + e] : 0.f;
                bf[kk][e] = __builtin_bit_cast(__bf16, f2bf(v));
            }
        }
        f32x4 zero = {0.f, 0.f, 0.f, 0.f};
        f32x4 acc[4] = {zero, zero, zero, zero};
#pragma unroll
        for (int m = 0; m < 4; m++)
#pragma unroll
            for (int kk = 0; kk < 3; kk++)
                acc[m] = __builtin_amdgcn_mfma_f32_16x16x32_bf16(af[m][kk], bf[kk], acc[m], 0, 0, 0);

        const int c = n0 + lr;
        float bv = (c < N) ? bias[c] : 0.f;
        float mx = -1e30f, sm = 0.f;
#pragma unroll
        for (int m = 0; m < 4; m++)
#pragma unroll
            for (int r = 0; r < 4; r++) {
                int row = m * 16 + lg * 4 + r;
                if (row < NPG) {
                    float v = fmaxf(acc[m][r] + bv, 0.f);
                    mx = fmaxf(mx, v);
                    sm += v;
                }
            }
        mx = fmaxf(mx, __shfl_xor(mx, 16, 64));
        sm += __shfl_xor(sm, 16, 64);
        mx = fmaxf(mx, __shfl_xor(mx, 32, 64));
        sm += __shfl_xor(sm, 32, 64);
        if (lg == 0 && c < N) {
            out[(size_t)g * 1680 + c] = mx;
            out[(size_t)g * 1680 + 840 + c] = sm * (1.f / NPG);
        }
    }
}

// ---------------- N=1 GEMM ----------------
__global__ __launch_bounds__(256) void rowdot(const float* __restrict__ A,
                                              const float* __restrict__ w,
                                              const float* __restrict__ b,
                                              float* __restrict__ out, int Mrows, int K) {
    int row = blockIdx.x * 4 + (threadIdx.x >> 6);
    int lane = threadIdx.x & 63;
    if (row >= Mrows) return;
    float s = 0.f;
    for (int k = lane; k < K; k += 64) s += A[(size_t)row * K + k] * w[k];
#pragma unroll
    for (int off = 32; off > 0; off >>= 1) s += __shfl_xor(s, off, 64);
    if (lane == 0) out[row] = s + b[0];
}

// ---------------- hnode transform: h*Dinv + bias ----------------
__global__ void transform_dinv_bias(const float* __restrict__ h, const int* __restrict__ off_n,
                                    const float* __restrict__ b, float* __restrict__ o, int R, int F) {
    int i = blockIdx.x * 256 + threadIdx.x;
    if (i >= R * F) return;
    int r = i / F, f = i - r * F;
    int d = off_n[r + 1] - off_n[r];
    float inv = d > 0 ? 1.f / d : 0.f;
    o[i] = h[i] * inv + b[f];
}

// ---------------- fused hyper Dinv+bias + 50-row max/mean pool ----------------
__global__ void pool_hyper(const float* __restrict__ hn, const int* __restrict__ off_n,
                           const float* __restrict__ b, float* __restrict__ out) {
    int i = blockIdx.x * 256 + threadIdx.x;
    if (i >= NB * 256) return;
    int o = i & 255, g = i >> 8;
    float bo = b[o];
    const float* base = hn + (size_t)g * NPG * 256 + o;
    float mx = -1e30f, sm = 0.f;
    for (int n = 0; n < NPG; n++) {
        int node = g * NPG + n;
        int d = off_n[node + 1] - off_n[node];
        float inv = d > 0 ? 1.f / d : 0.f;
        float v = base[(size_t)n * 256] * inv + bo;
        mx = fmaxf(mx, v);
        sm += v;
    }
    out[(size_t)g * 512 + o] = mx;
    out[(size_t)g * 512 + 256 + o] = sm * (1.f / NPG);
}

// ---------------- pack fusion tokens -> bf16 ----------------
__global__ void pack_tokens_bf(const float* __restrict__ fp_o, const float* __restrict__ xg,
                               const float* __restrict__ hxg, const float* __restrict__ t,
                               unsigned short* __restrict__ in_t) {
    int i = blockIdx.x * 256 + threadIdx.x;
    if (i >= 4096 * 512) return;
    int d = i & 511;
    int row = i >> 9;
    int tok = row & 3, b = row >> 2;
    const float* s = (tok == 0) ? fp_o : (tok == 1) ? xg : (tok == 2) ? hxg : t;
    in_t[i] = f2bf(s[b * 512 + d]);
}

// ---------------- concat + cvt Wq|Wk|Wv -> bf16 [6144][512] ----------------
__global__ void cvt_qkv_w(const float* __restrict__ Wq, const float* __restrict__ Wk,
                          const float* __restrict__ Wv, unsigned short* __restrict__ Wb) {
    int i = blockIdx.x * 256 + threadIdx.x;
    if (i >= 6144 * 512) return;
    int n = i >> 9;
    const float* src = (n < 2048) ? Wq : (n < 4096) ? Wk : Wv;
    int nn = (n < 2048) ? n : (n < 4096) ? n - 2048 : n - 4096;
    Wb[i] = f2bf(src[(size_t)nn * 512 + (i & 511)]);
}

// ---------------- generic f32 -> bf16 ----------------
__global__ void cvt_f2b(const float* __restrict__ in, unsigned short* __restrict__ out, int n) {
    int i = blockIdx.x * 256 + threadIdx.x;
    if (i < n) out[i] = f2bf(in[i]);
}

// ---------------- fused attention + conv3x3 + relu: one block per batch b ----------------
// qkv bf16 [4096][6144]; writes cbuf bf16 [1024][4080].
__global__ __launch_bounds__(256) void attn_conv(const unsigned short* __restrict__ QKV,
                                                 const float* __restrict__ cw,
                                                 const float* __restrict__ cb,
                                                 unsigned short* __restrict__ c) {
    __shared__ float att_s[4][4][512];   // [head][token][d] = 32 KB
    __shared__ float w[144];
    __shared__ float bias[4];
    const int tid = threadIdx.x;
    const int wid = tid >> 6, lane = tid & 63;
    const int b = blockIdx.x;
    if (tid < 144) w[tid] = cw[tid];
    if (tid < 4) bias[tid] = cb[tid];

    const unsigned short* qb = QKV + (size_t)b * 4 * 6144 + wid * 512;
    const unsigned short* kb = qb + 2048;
    const unsigned short* vb = qb + 4096;
    float qr[4][8], kr[4][8];
#pragma unroll
    for (int n = 0; n < 4; n++)
#pragma unroll
        for (int cc = 0; cc < 8; cc++) {
            qr[n][cc] = bf2f(qb[n * 6144 + cc * 64 + lane]);
            kr[n][cc] = bf2f(kb[n * 6144 + cc * 64 + lane]);
        }
    float s[4][4];
#pragma unroll
    for (int n = 0; n < 4; n++)
#pragma unroll
        for (int m = 0; m < 4; m++) {
            float p = 0.f;
#pragma unroll
            for (int cc = 0; cc < 8; cc++) p += qr[n][cc] * kr[m][cc];
#pragma unroll
            for (int off = 32; off > 0; off >>= 1) p += __shfl_xor(p, off, 64);
            s[n][m] = p * 0.04419417382415922f;   // 1/sqrt(512)
        }
    float pm[4][4];
#pragma unroll
    for (int n = 0; n < 4; n++) {
        float mx = fmaxf(fmaxf(s[n][0], s[n][1]), fmaxf(s[n][2], s[n][3]));
        float e0 = expf(s[n][0] - mx), e1 = expf(s[n][1] - mx);
        float e2 = expf(s[n][2] - mx), e3 = expf(s[n][3] - mx);
        float inv = 1.f / (e0 + e1 + e2 + e3);
        pm[n][0] = e0 * inv; pm[n][1] = e1 * inv; pm[n][2] = e2 * inv; pm[n][3] = e3 * inv;
    }
#pragma unroll
    for (int cc = 0; cc < 8; cc++) {
        float v0 = bf2f(vb[0 * 6144 + cc * 64 + lane]);
        float v1 = bf2f(vb[1 * 6144 + cc * 64 + lane]);
        float v2 = bf2f(vb[2 * 6144 + cc * 64 + lane]);
        float v3 = bf2f(vb[3 * 6144 + cc * 64 + lane]);
#pragma unroll
        for (int n = 0; n < 4; n++)
            att_s[wid][n][cc * 64 + lane] = pm[n][0] * v0 + pm[n][1] * v1 + pm[n][2] * v2 + pm[n][3] * v3;
    }
    __syncthreads();

    // conv 3x3 VALID on [4ch,4,512] -> relu -> cbuf[b][4080] (bf16)
    for (int it = 0; it < 16; it++) {
        int j = it * 256 + tid;
        if (j >= 4080) break;
        int wo = j % 510;
        int r = j / 510;
        int ho = r & 1, co = r >> 1;
        float acc = bias[co];
#pragma unroll
        for (int ci = 0; ci < 4; ci++)
#pragma unroll
            for (int kh = 0; kh < 3; kh++)
#pragma unroll
                for (int kw = 0; kw < 3; kw++)
                    acc += att_s[ci][ho + kh][wo + kw] * w[((co * 4 + ci) * 3 + kh) * 3 + kw];
        c[(size_t)b * 4080 + j] = f2bf(fmaxf(acc, 0.f));
    }
}

// ---------------- host side ----------------
template<typename TA, typename TW>
static inline void launch_gemm64(const TA* A, const TW* W, const float* b, float* C,
                                 int M, int N, int K, bool relu, float* part, hipStream_t s) {
    int gx = (N + 63) / 64, gy = (M + 63) / 64;
    int targetSK = 1024 / (gx * gy);
    if (targetSK < 1) targetSK = 1;
    if (targetSK > 8) targetSK = 8;
    int kchunk = K, SK = 1;
    if (targetSK > 1) {
        kchunk = (((K + targetSK - 1) / targetSK) + 127) & ~127;
        SK = (K + kchunk - 1) / kchunk;
    }
    if (SK <= 1) {
        dim3 g(gx, gy);
        if (relu) gemm64<true, false, TA, TW><<<g, 256, 0, s>>>(A, W, b, C, M, N, K, K);
        else      gemm64<false, false, TA, TW><<<g, 256, 0, s>>>(A, W, b, C, M, N, K, K);
    } else {
        dim3 g(gx, gy, SK);
        gemm64<false, true, TA, TW><<<g, 256, 0, s>>>(A, W, nullptr, part, M, N, K, kchunk);
        int MN = M * N;
        if (relu) reduce_partial<true><<<(MN + 255) / 256, 256, 0, s>>>(part, b, C, MN, N, SK);
        else      reduce_partial<false><<<(MN + 255) / 256, 256, 0, s>>>(part, b, C, MN, N, SK);
    }
}

extern "C" void kernel_launch(void* const* d_in, const int* in_sizes, int n_in,
                              void* d_out, int out_size, void* d_ws, size_t ws_size,
                              hipStream_t stream) {
    const float* x       = (const float*)d_in[0];
    const int*   edge    = (const int*)d_in[1];
    const int*   hedge   = (const int*)d_in[3];
    const float* fp      = (const float*)d_in[4];
    const float* text_em = (const float*)d_in[5];
    const float* fc1_W = (const float*)d_in[7];  const float* fc1_b = (const float*)d_in[8];
    const float* fc2_W = (const float*)d_in[9];  const float* fc2_b = (const float*)d_in[10];
    const float* fc3_W = (const float*)d_in[11]; const float* fc3_b = (const float*)d_in[12];
    const float* fcg1_W = (const float*)d_in[13]; const float* fcg1_b = (const float*)d_in[14];
    const float* fcg2_W = (const float*)d_in[15]; const float* fcg2_b = (const float*)d_in[16];
    const float* fchg1_W = (const float*)d_in[17]; const float* fchg1_b = (const float*)d_in[18];
    const float* fchg2_W = (const float*)d_in[19]; const float* fchg2_b = (const float*)d_in[20];
    const float* gin1_W = (const float*)d_in[21]; const float* gin1_b = (const float*)d_in[22];
    const float* gin2_W = (const float*)d_in[23]; const float* gin2_b = (const float*)d_in[24];
    const float* h3_W = (const float*)d_in[25]; const float* h3_b = (const float*)d_in[26];
    const float* h4_W = (const float*)d_in[27]; const float* h4_b = (const float*)d_in[28];
    const float* Wq = (const float*)d_in[29];
    const float* Wk = (const float*)d_in[30];
    const float* Wv = (const float*)d_in[31];
    const float* conv_W = (const float*)d_in[32]; const float* conv_b = (const float*)d_in[33];
    const float* mlp1_W = (const float*)d_in[34]; const float* mlp1_b = (const float*)d_in[35];
    const float* mlp2_W = (const float*)d_in[36]; const float* mlp2_b = (const float*)d_in[37];

    const int* e_src = edge;
    const int* e_dst = edge + N_EDGES;
    const int* h_nid = hedge;
    const int* h_eid = hedge + N_HNNZ;

    float* ws = (float*)d_ws;
    const size_t ZONE = 51609600;
    // ---- phase A (GIN) ----
    float* xin1 = ws;                               // 4,300,800
    float* xg1  = ws + 4300800;                     // 4,300,800
    float* xin2 = ws + 8601600;                     // 4,300,800
    // ---- phase H (hypergraph) ----
    float* eagg   = ws;                             // 860,160
    float* e1_32  = ws + 860160;                    // 1,720,320
    float* hnode  = ws + 2580480;                   // 8,601,600
    float* hnodet = ws + 11182080;                  // 8,601,600
    float* eagg2  = ws + 19783680;                  // 1,720,320
    float* e2_32  = ws + 21504000;                  // 2,621,440
    float* hn2    = ws + 24125440;                  // 13,107,200 (ends 37,232,640)
    // ---- phase D (attention) ----
    unsigned short* in_t_bf  = (unsigned short*)ws;                 // 2,097,152 us = 1,048,576 f
    unsigned short* qkv_bf   = (unsigned short*)(ws + 2097152);     // 25,165,824 us = 12,582,912 f
    unsigned short* cbuf_bf  = (unsigned short*)(ws + 35651584);    // 4,177,920 us
    float* m1   = ws + 39829504;                                    // 1,048,576
    unsigned short* Wqkv_bf  = (unsigned short*)(ws + 40878080);    // 3,145,728 us = 1,572,864 f
    unsigned short* mlp1W_bf = (unsigned short*)(ws + 42450944);    // 4,177,920 us = 2,088,960 f (ends 44,539,904)
    float* part = ws;                               // split-K scratch (zone-dead windows)
    // ---- CSR region ----
    int* cnt_g = (int*)(ws + 45000000);
    int* off_g = (int*)(ws + 45051200);
    int* pay_g = (int*)(ws + 45102401);
    int* cnt_e = (int*)(ws + 45307201);
    int* off_e = (int*)(ws + 45317441);
    int* pay_e = (int*)(ws + 45327682);
    int* cnt_n = (int*)(ws + 45430082);
    int* off_n = (int*)(ws + 45481282);
    int* pay_n = (int*)(ws + 45532483);             // ends 45,634,883 < ZONE
    // ---- persistent ----
    float* xg_raw = ws + ZONE;
    float* xg_mid = ws + ZONE + 1720320;
    float* hx_raw = ws + ZONE + 2768896;
    float* hx_mid = ws + ZONE + 3293184;
    float* h1     = ws + ZONE + 4341760;
    float* fp_o   = ws + ZONE + 4472832;
    float* tt     = ws + ZONE + 4997120;
    const size_t NEED = (ZONE + 5582848) * sizeof(float);
    if (ws_size < NEED) return;

    float* out_y  = (float*)d_out;
    float* xg_out = out_y + 1024;
    float* hx_out = out_y + 1024 + 1024 * 512;

    // ---------- build 3 CSR structures ----------
    hipMemsetAsync(cnt_g, 0, N_NODES * 4, stream);
    hipMemsetAsync(cnt_e, 0, N_HEDGES * 4, stream);
    hipMemsetAsync(cnt_n, 0, N_NODES * 4, stream);
    histo_i<<<(N_EDGES + 255) / 256, 256, 0, stream>>>(e_dst, cnt_g, N_EDGES);
    histo_i<<<(N_HNNZ + 255) / 256, 256, 0, stream>>>(h_eid, cnt_e, N_HNNZ);
    histo_i<<<(N_HNNZ + 255) / 256, 256, 0, stream>>>(h_nid, cnt_n, N_HNNZ);
    exscan3<<<3, 1024, 0, stream>>>(cnt_g, off_g, N_NODES, cnt_e, off_e, N_HEDGES, cnt_n, off_n, N_NODES);
    hipMemcpyAsync(cnt_g, off_g, N_NODES * 4, hipMemcpyDeviceToDevice, stream);
    hipMemcpyAsync(cnt_e, off_e, N_HEDGES * 4, hipMemcpyDeviceToDevice, stream);
    hipMemcpyAsync(cnt_n, off_n, N_NODES * 4, hipMemcpyDeviceToDevice, stream);
    place_pay<<<(N_EDGES + 255) / 256, 256, 0, stream>>>(e_dst, e_src, cnt_g, pay_g, N_EDGES);
    place_pay<<<(N_HNNZ + 255) / 256, 256, 0, stream>>>(h_eid, h_nid, cnt_e, pay_e, N_HNNZ);
    place_pay<<<(N_HNNZ + 255) / 256, 256, 0, stream>>>(h_nid, h_eid, cnt_n, pay_n, N_HNNZ);

    // ---------- GIN branch ----------
    gather_rows<true, false><<<(N_NODES * FXD + 255) / 256, 256, 0, stream>>>(
        x, off_g, pay_g, x, xin1, N_NODES, FXD);
    launch_gemm64(xin1, gin1_W, gin1_b, xg1, N_NODES, FXD, FXD, true, part, stream);
    gather_rows<true, false><<<(N_NODES * FXD + 255) / 256, 256, 0, stream>>>(
        xg1, off_g, pay_g, xg1, xin2, N_NODES, FXD);
    gin2pool<<<NB, 256, 0, stream>>>(xin2, gin2_W, gin2_b, xg_raw);
    launch_gemm64(xg_raw, fcg1_W, fcg1_b, xg_mid, NB, 1024, 1680, true, part, stream);
    launch_gemm64(xg_mid, fcg2_W, fcg2_b, xg_out, NB, 512, 1024, false, part, stream);

    // ---------- hypergraph branch ----------
    gather_rows<false, true><<<(N_HEDGES * FXD + 255) / 256, 256, 0, stream>>>(
        x, off_e, pay_e, nullptr, eagg, N_HEDGES, FXD);
    launch_gemm64(eagg, h3_W, (const float*)nullptr, e1_32, N_HEDGES, 168, FXD, false, part, stream);
    gather_rows<false, false><<<(N_NODES * 168 + 255) / 256, 256, 0, stream>>>(
        e1_32, off_n, pay_n, nullptr, hnode, N_NODES, 168);
    transform_dinv_bias<<<(N_NODES * 168 + 255) / 256, 256, 0, stream>>>(
        hnode, off_n, h3_b, hnodet, N_NODES, 168);
    gather_rows<false, true><<<(N_HEDGES * 168 + 255) / 256, 256, 0, stream>>>(
        hnodet, off_e, pay_e, nullptr, eagg2, N_HEDGES, 168);
    launch_gemm64(eagg2, h4_W, (const float*)nullptr, e2_32, N_HEDGES, 256, 168, false, part, stream);
    gather_rows<false, false><<<(N_NODES * 256 + 255) / 256, 256, 0, stream>>>(
        e2_32, off_n, pay_n, nullptr, hn2, N_NODES, 256);
    pool_hyper<<<(NB * 256 + 255) / 256, 256, 0, stream>>>(hn2, off_n, h4_b, hx_raw);
    launch_gemm64(hx_raw, fchg1_W, fchg1_b, hx_mid, NB, 1024, 512, true, part, stream);
    launch_gemm64(hx_mid, fchg2_W, fchg2_b, hx_out, NB, 512, 1024, false, part, stream);

    // ---------- fingerprint + text ----------
    launch_gemm64(fp, fc1_W, fc1_b, h1, NB, FP2, FP_DIM, true, part, stream);
    launch_gemm64(h1, fc2_W, fc2_b, fp_o, NB, HID, FP2, false, part, stream);
    launch_gemm64(text_em, fc3_W, fc3_b, tt, NB, HID, 768, false, part, stream);

    // ---------- fusion attention (bf16 pipeline) ----------
    pack_tokens_bf<<<(4096 * 512 + 255) / 256, 256, 0, stream>>>(fp_o, xg_out, hx_out, tt, in_t_bf);
    cvt_qkv_w<<<(6144 * 512 + 255) / 256, 256, 0, stream>>>(Wq, Wk, Wv, Wqkv_bf);
    gemm_bf16<<<dim3(6144 / 128, 4096 / 128), 256, 0, stream>>>(in_t_bf, Wqkv_bf, qkv_bf, 4096, 6144, 512);
    attn_conv<<<NB, 256, 0, stream>>>(qkv_bf, conv_W, conv_b, cbuf_bf);
    cvt_f2b<<<(1024 * 4080 + 255) / 256, 256, 0, stream>>>(mlp1_W, mlp1W_bf, 1024 * 4080);
    launch_gemm64(cbuf_bf, mlp1W_bf, mlp1_b, m1, NB, 1024, 4080, true, part, stream);
    rowdot<<<256, 256, 0, stream>>>(m1, mlp2_W, mlp2_b, out_y, NB, 1024);
}

// Round 10
// 983.714 us; speedup vs baseline: 3.6620x; 1.0098x over previous
//
#include <hip/hip_runtime.h>
#include <hip/hip_bf16.h>

// ---------------- constants ----------------
#define N_NODES 51200
#define N_EDGES 204800
#define N_HNNZ  102400
#define N_HEDGES 10240
#define NB 1024          // batch (graphs)
#define NPG 50           // nodes per graph (51200/1024)
#define FXD 84
#define FP_DIM 2513
#define FP2 128
#define HID 512

typedef __attribute__((ext_vector_type(4))) float f32x4;
typedef __attribute__((ext_vector_type(8))) __bf16 bf16x8;
typedef __attribute__((ext_vector_type(4))) short short4_t;

static __device__ __forceinline__ unsigned short f2bf(float f) {
    unsigned u = __builtin_bit_cast(unsigned, f);
    u += 0x7FFFu + ((u >> 16) & 1u);   // round-to-nearest-even
    return (unsigned short)(u >> 16);
}
static __device__ __forceinline__ float bf2f(unsigned short u) {
    unsigned x = ((unsigned)u) << 16;
    return __builtin_bit_cast(float, x);
}

// bijective XCD-aware remap (m204 formula)
static __device__ __forceinline__ int xcd_swizzle(int orig, int nwg) {
    int q = nwg >> 3, r = nwg & 7;
    int xcd = orig & 7, off = orig >> 3;
    return (xcd < r ? xcd * (q + 1) : r * (q + 1) + (xcd - r) * q) + off;
}

// load 4 f32 as bf16 short4 with K-guards
static __device__ __forceinline__ short4_t ld4bf_f32(const float* p, int gk, int kend, bool kvec) {
    short4_t sv;
    float v0 = 0.f, v1 = 0.f, v2 = 0.f, v3 = 0.f;
    if (kvec && gk + 4 <= kend) {
        float4 f = *(const float4*)p;
        v0 = f.x; v1 = f.y; v2 = f.z; v3 = f.w;
    } else {
        v0 = p[0];
        if (gk + 1 < kend) v1 = p[1];
        if (gk + 2 < kend) v2 = p[2];
        if (gk + 3 < kend) v3 = p[3];
    }
    sv[0] = (short)f2bf(v0); sv[1] = (short)f2bf(v1);
    sv[2] = (short)f2bf(v2); sv[3] = (short)f2bf(v3);
    return sv;
}

// ---------------- CSR build ----------------
__global__ void histo_i(const int* __restrict__ keys, int* __restrict__ cnt, int n) {
    int i = blockIdx.x * 256 + threadIdx.x;
    if (i < n) atomicAdd(&cnt[keys[i]], 1);
}

__global__ __launch_bounds__(1024) void exscan3(const int* __restrict__ c0, int* __restrict__ o0, int B0,
                                                const int* __restrict__ c1, int* __restrict__ o1, int B1,
                                                const int* __restrict__ c2, int* __restrict__ o2, int B2) {
    const int* cnt = blockIdx.x == 0 ? c0 : blockIdx.x == 1 ? c1 : c2;
    int* off = blockIdx.x == 0 ? o0 : blockIdx.x == 1 ? o1 : o2;
    int B = blockIdx.x == 0 ? B0 : blockIdx.x == 1 ? B1 : B2;
    __shared__ int part[1024];
    int t = threadIdx.x;
    int C = (B + 1023) >> 10;
    int s0 = t * C, s1 = min(B, s0 + C);
    int sum = 0;
    for (int i = s0; i < s1; i++) sum += cnt[i];
    part[t] = sum;
    __syncthreads();
    for (int d = 1; d < 1024; d <<= 1) {
        int x = (t >= d) ? part[t - d] : 0;
        __syncthreads();
        part[t] += x;
        __syncthreads();
    }
    int run = (t == 0) ? 0 : part[t - 1];
    for (int i = s0; i < s1; i++) { off[i] = run; run += cnt[i]; }
    if (t == 1023) off[B] = part[1023];
}

__global__ void place_pay(const int* __restrict__ keys, const int* __restrict__ payload,
                          int* __restrict__ cursor, int* __restrict__ pay, int n) {
    int i = blockIdx.x * 256 + threadIdx.x;
    if (i < n) {
        int p = atomicAdd(&cursor[keys[i]], 1);
        pay[p] = payload[i];
    }
}

// ---------------- CSR gather, float4-vectorized (f64 reg accumulation -> replay-stable) ----------------
// F % 4 == 0 and rows 16B-aligned for all uses (F = 84/168/256).
template<bool SELF, bool SCALE>
__global__ void gather_rows4(const float* __restrict__ src,
                             const int* __restrict__ off, const int* __restrict__ pay,
                             const float* __restrict__ self_src,
                             float* __restrict__ out, int R, int F4) {
    int i = blockIdx.x * 256 + threadIdx.x;
    if (i >= R * F4) return;
    int r = i / F4, f4 = i - r * F4;
    int b = off[r], e = off[r + 1];
    double a0 = 0.0, a1 = 0.0, a2 = 0.0, a3 = 0.0;
    for (int j = b; j < e; j++) {
        float4 v = *((const float4*)(src + (size_t)pay[j] * F4 * 4) + f4);
        a0 += v.x; a1 += v.y; a2 += v.z; a3 += v.w;
    }
    float s0 = (float)a0, s1 = (float)a1, s2 = (float)a2, s3 = (float)a3;
    if (SCALE) {
        float inv = 1.f / fmaxf((float)(e - b), 1.f);
        s0 *= inv; s1 *= inv; s2 *= inv; s3 *= inv;
    }
    if (SELF) {
        float4 sv = *((const float4*)self_src + i);
        s0 += sv.x; s1 += sv.y; s2 += sv.z; s3 += sv.w;
    }
    float4 o = {s0, s1, s2, s3};
    *((float4*)out + i) = o;
}

// ---------------- bf16 GEMM 128x128, BK=64, reg-prefetch, no guards ----------------
// A: [M,K] bf16; B: [N,K] bf16; C: [M,N] bf16. M,N %128==0, K %64==0.
__global__ __launch_bounds__(256) void gemm_bf16(const unsigned short* __restrict__ A,
                                                 const unsigned short* __restrict__ B,
                                                 unsigned short* __restrict__ C,
                                                 int M, int N, int K) {
    __shared__ __align__(16) char Asm[16384];   // 128 x 64 bf16, swizzled
    __shared__ __align__(16) char Bsm[16384];
    const int tid = threadIdx.x;
    const int nwg = gridDim.x * gridDim.y;
    const int wg = xcd_swizzle(blockIdx.y * gridDim.x + blockIdx.x, nwg);
    const int bm = (wg / gridDim.x) * 128, bn = (wg % gridDim.x) * 128;
    const int wid = tid >> 6, lane = tid & 63;
    const int wm = (wid >> 1) * 64, wn = (wid & 1) * 64;
    const int lr = lane & 15, lg = lane >> 4;

    f32x4 zero = {0.f, 0.f, 0.f, 0.f};
    f32x4 acc[4][4];
#pragma unroll
    for (int i = 0; i < 4; i++)
#pragma unroll
        for (int j = 0; j < 4; j++) acc[i][j] = zero;

    uint4 ra[4], rb[4];
    auto load_chunk = [&](int k0) {
#pragma unroll
        for (int u = 0; u < 4; u++) {
            int slot = u * 256 + tid;            // 0..1023 16B-chunks
            int row = slot >> 3, ch = slot & 7;
            ra[u] = *(const uint4*)(A + (size_t)(bm + row) * K + k0 + ch * 8);
            rb[u] = *(const uint4*)(B + (size_t)(bn + row) * K + k0 + ch * 8);
        }
    };
    load_chunk(0);

    for (int k0 = 0; k0 < K; k0 += 64) {
#pragma unroll
        for (int u = 0; u < 4; u++) {
            int slot = u * 256 + tid;
            int row = slot >> 3, ch = slot & 7;
            int off = (row * 128 + ch * 16) ^ ((row & 7) << 4);
            *(uint4*)(Asm + off) = ra[u];
            *(uint4*)(Bsm + off) = rb[u];
        }
        __syncthreads();
        if (k0 + 64 < K) load_chunk(k0 + 64);
#pragma unroll
        for (int kk = 0; kk < 2; kk++) {
            bf16x8 af[4], bf[4];
#pragma unroll
            for (int m = 0; m < 4; m++) {
                int row = wm + m * 16 + lr;
                af[m] = *(const bf16x8*)(Asm + ((row * 128 + kk * 64 + lg * 16) ^ ((row & 7) << 4)));
            }
#pragma unroll
            for (int n = 0; n < 4; n++) {
                int row = wn + n * 16 + lr;
                bf[n] = *(const bf16x8*)(Bsm + ((row * 128 + kk * 64 + lg * 16) ^ ((row & 7) << 4)));
            }
#pragma unroll
            for (int m = 0; m < 4; m++)
#pragma unroll
                for (int n = 0; n < 4; n++)
                    acc[m][n] = __builtin_amdgcn_mfma_f32_16x16x32_bf16(af[m], bf[n], acc[m][n], 0, 0, 0);
        }
        __syncthreads();
    }
#pragma unroll
    for (int m = 0; m < 4; m++)
#pragma unroll
        for (int n = 0; n < 4; n++) {
            int col = bn + wn + n * 16 + lr;
#pragma unroll
            for (int r = 0; r < 4; r++) {
                int row = bm + wm + m * 16 + lg * 4 + r;
                C[(size_t)row * N + col] = f2bf(acc[m][n][r]);
            }
        }
}

// ---------------- MFMA GEMM 64x64, wave-K-split, reg-prefetch, 32KB LDS, grid.z split-K ----------------
template<bool RELU, bool PARTIAL, typename TA, typename TW>
__global__ __launch_bounds__(256) void gemm64(const TA* __restrict__ A,
                                              const TW* __restrict__ W,
                                              const float* __restrict__ bias,
                                              float* __restrict__ C,
                                              int M, int N, int K, int kchunk) {
    __shared__ __align__(16) char pool[32768];
    char* Ab = pool;
    char* Bb = pool + 16384;
    const int tid = threadIdx.x;
    const int nwg = gridDim.x * gridDim.y;
    const int wg = xcd_swizzle(blockIdx.y * gridDim.x + blockIdx.x, nwg);
    const int bm = (wg / gridDim.x) * 64, bn = (wg % gridDim.x) * 64;
    const int wid = tid >> 6, lane = tid & 63;
    const int lr = lane & 15, lg = lane >> 4;
    const int kbeg = blockIdx.z * kchunk;
    const int kend = min(K, kbeg + kchunk);
    const bool kvec = ((K & 3) == 0);

    f32x4 zero = {0.f, 0.f, 0.f, 0.f};
    f32x4 acc[4][4];
#pragma unroll
    for (int i = 0; i < 4; i++)
#pragma unroll
        for (int j = 0; j < 4; j++) acc[i][j] = zero;

    // staging registers (per matrix: 2-byte src -> 4x uint4; 4-byte src -> 8x short4)
    uint4 ra16[4], rb16[4];
    short4_t ra4[8], rb4[8];

    auto load_A = [&](int kc2) {
        if constexpr (sizeof(TA) == 2) {
#pragma unroll
            for (int u = 0; u < 4; u++) {
                int s = u * 256 + tid;
                int row = s >> 4, k8 = (s & 15) << 3;
                int gk = kc2 + k8, gm = bm + row;
                uint4 v = {0u, 0u, 0u, 0u};
                if (gm < M && gk + 8 <= kend) {
                    v = *(const uint4*)((const unsigned short*)A + (size_t)gm * K + gk);
                } else if (gm < M && gk < kend) {
                    unsigned short tmp[8];
#pragma unroll
                    for (int e = 0; e < 8; e++)
                        tmp[e] = (gk + e < kend) ? ((const unsigned short*)A)[(size_t)gm * K + gk + e] : 0;
                    v = *(const uint4*)tmp;
                }
                ra16[u] = v;
            }
        } else {
#pragma unroll
            for (int u = 0; u < 8; u++) {
                int s = u * 256 + tid;
                int row = s >> 5, kq = (s & 31) << 2;
                int gk = kc2 + kq, gm = bm + row;
                short4_t sv = {0, 0, 0, 0};
                if (gm < M && gk < kend)
                    sv = ld4bf_f32((const float*)A + (size_t)gm * K + gk, gk, kend, kvec);
                ra4[u] = sv;
            }
        }
    };
    auto load_B = [&](int kc2) {
        if constexpr (sizeof(TW) == 2) {
#pragma unroll
            for (int u = 0; u < 4; u++) {
                int s = u * 256 + tid;
                int row = s >> 4, k8 = (s & 15) << 3;
                int gk = kc2 + k8, gn = bn + row;
                uint4 v = {0u, 0u, 0u, 0u};
                if (gn < N && gk + 8 <= kend) {
                    v = *(const uint4*)((const unsigned short*)W + (size_t)gn * K + gk);
                } else if (gn < N && gk < kend) {
                    unsigned short tmp[8];
#pragma unroll
                    for (int e = 0; e < 8; e++)
                        tmp[e] = (gk + e < kend) ? ((const unsigned short*)W)[(size_t)gn * K + gk + e] : 0;
                    v = *(const uint4*)tmp;
                }
                rb16[u] = v;
            }
        } else {
#pragma unroll
            for (int u = 0; u < 8; u++) {
                int s = u * 256 + tid;
                int row = s >> 5, kq = (s & 31) << 2;
                int gk = kc2 + kq, gn = bn + row;
                short4_t sv = {0, 0, 0, 0};
                if (gn < N && gk < kend)
                    sv = ld4bf_f32((const float*)W + (size_t)gn * K + gk, gk, kend, kvec);
                rb4[u] = sv;
            }
        }
    };
    auto write_A = [&]() {
        if constexpr (sizeof(TA) == 2) {
#pragma unroll
            for (int u = 0; u < 4; u++) {
                int s = u * 256 + tid;
                int row = s >> 4, k8 = (s & 15) << 3;
                int off = (row * 256 + k8 * 2) ^ ((row & 7) << 4);
                *(uint4*)(Ab + off) = ra16[u];
            }
        } else {
#pragma unroll
            for (int u = 0; u < 8; u++) {
                int s = u * 256 + tid;
                int row = s >> 5, kq = (s & 31) << 2;
                int off = (row * 256 + kq * 2) ^ ((row & 7) << 4);
                *(short4_t*)(Ab + off) = ra4[u];
            }
        }
    };
    auto write_B = [&]() {
        if constexpr (sizeof(TW) == 2) {
#pragma unroll
            for (int u = 0; u < 4; u++) {
                int s = u * 256 + tid;
                int row = s >> 4, k8 = (s & 15) << 3;
                int off = (row * 256 + k8 * 2) ^ ((row & 7) << 4);
                *(uint4*)(Bb + off) = rb16[u];
            }
        } else {
#pragma unroll
            for (int u = 0; u < 8; u++) {
                int s = u * 256 + tid;
                int row = s >> 5, kq = (s & 31) << 2;
                int off = (row * 256 + kq * 2) ^ ((row & 7) << 4);
                *(short4_t*)(Bb + off) = rb4[u];
            }
        }
    };

    load_A(kbeg);
    load_B(kbeg);
    for (int kc = kbeg; kc < kend; kc += 128) {
        write_A();
        write_B();
        __syncthreads();
        if (kc + 128 < kend) { load_A(kc + 128); load_B(kc + 128); }

        bf16x8 af[4], bf[4];
        const int kb = wid * 64 + lg * 16;
#pragma unroll
        for (int m = 0; m < 4; m++) {
            int row = m * 16 + lr;
            af[m] = *(const bf16x8*)(Ab + ((row * 256 + kb) ^ ((row & 7) << 4)));
        }
#pragma unroll
        for (int n = 0; n < 4; n++) {
            int row = n * 16 + lr;
            bf[n] = *(const bf16x8*)(Bb + ((row * 256 + kb) ^ ((row & 7) << 4)));
        }
#pragma unroll
        for (int m = 0; m < 4; m++)
#pragma unroll
            for (int n = 0; n < 4; n++)
                acc[m][n] = __builtin_amdgcn_mfma_f32_16x16x32_bf16(af[m], bf[n], acc[m][n], 0, 0, 0);
        __syncthreads();
    }

    float* redA = (float*)pool;
    float* redB = (float*)(pool + 16384);
    if (wid < 2) {
        float* r = (wid == 0) ? redA : redB;
#pragma unroll
        for (int m = 0; m < 4; m++)
#pragma unroll
            for (int n = 0; n < 4; n++)
#pragma unroll
                for (int r4 = 0; r4 < 4; r4++)
                    r[(m * 16 + lg * 4 + r4) * 64 + n * 16 + lr] = acc[m][n][r4];
    }
    __syncthreads();
    if (wid >= 2) {
        float* r = (wid == 2) ? redA : redB;
#pragma unroll
        for (int m = 0; m < 4; m++)
#pragma unroll
            for (int n = 0; n < 4; n++)
#pragma unroll
                for (int r4 = 0; r4 < 4; r4++)
                    r[(m * 16 + lg * 4 + r4) * 64 + n * 16 + lr] += acc[m][n][r4];
    }
    __syncthreads();
#pragma unroll
    for (int u = 0; u < 16; u++) {
        int idx = u * 256 + tid;
        int row = idx >> 6, col = idx & 63;
        int gm = bm + row, gn = bn + col;
        if (gm >= M || gn >= N) continue;
        float s = redA[idx] + redB[idx];
        if (PARTIAL) {
            C[(size_t)blockIdx.z * M * N + (size_t)gm * N + gn] = s;
        } else {
            s += bias ? bias[gn] : 0.f;
            if (RELU) s = fmaxf(s, 0.f);
            C[(size_t)gm * N + gn] = s;
        }
    }
}

template<bool RELU>
__global__ void reduce_partial(const float* __restrict__ part, const float* __restrict__ bias,
                               float* __restrict__ C, int MN, int N, int SK) {
    int i = blockIdx.x * 256 + threadIdx.x;
    if (i >= MN) return;
    float s = 0.f;
    for (int z = 0; z < SK; z++) s += part[(size_t)z * MN + i];
    s += bias ? bias[i % N] : 0.f;
    if (RELU) s = fmaxf(s, 0.f);
    C[i] = s;
}

// ---------------- fused GIN2 GEMM + bias + relu + 50-row max/mean pool ----------------
__global__ __launch_bounds__(256) void gin2pool(const float* __restrict__ xin2,
                                                const float* __restrict__ W,
                                                const float* __restrict__ bias,
                                                float* __restrict__ out) {
    __shared__ __align__(16) char Ab[16384];
    const int tid = threadIdx.x;
    const int g = blockIdx.x;
    const int wid = tid >> 6, lane = tid & 63;
    const int lr = lane & 15, lg = lane >> 4;
    const int K = FXD;
    const int N = 840;

#pragma unroll
    for (int u = 0; u < 8; u++) {
        int s = u * 256 + tid;
        int row = s >> 5, kq = (s & 31) << 2;
        int off = (row * 256 + (s & 31) * 8) ^ ((row & 7) << 4);
        float v0 = 0.f, v1 = 0.f, v2 = 0.f, v3 = 0.f;
        if (row < NPG && kq < K) {
            float4 f = *(const float4*)(xin2 + ((size_t)g * NPG + row) * K + kq);
            v0 = f.x; v1 = f.y; v2 = f.z; v3 = f.w;
        }
        short4_t sv;
        sv[0] = (short)f2bf(v0); sv[1] = (short)f2bf(v1);
        sv[2] = (short)f2bf(v2); sv[3] = (short)f2bf(v3);
        *(short4_t*)(Ab + off) = sv;
    }
    __syncthreads();

    bf16x8 af[4][3];
#pragma unroll
    for (int m = 0; m < 4; m++)
#pragma unroll
        for (int kk = 0; kk < 3; kk++) {
            int row = m * 16 + lr;
            af[m][kk] = *(const bf16x8*)(Ab + ((row * 256 + kk * 64 + lg * 16) ^ ((row & 7) << 4)));
        }

    for (int t = 0; t < 14; t++) {
        const int n0 = t * 64 + wid * 16;
        const int wrow = n0 + lr;
        bf16x8 bf[3];
#pragma unroll
        for (int kk = 0; kk < 3; kk++) {
            int k0 = kk * 32 + lg * 8;
#pragma unroll
            for (int e = 0; e < 8; e++) {
                float v = (wrow < N && k0 + e < K) ? W[(size_t)wrow * K + k0 + e] : 0.f;
                bf[kk][e] = __builtin_bit_cast(__bf16, f2bf(v));
            }
        }
        f32x4 zero = {0.f, 0.f, 0.f, 0.f};
        f32x4 acc[4] = {zero, zero, zero, zero};
#pragma unroll
        for (int m = 0; m < 4; m++)
#pragma unroll
            for (int kk = 0; kk < 3; kk++)
                acc[m] = __builtin_amdgcn_mfma_f32_16x16x32_bf16(af[m][kk], bf[kk], acc[m], 0, 0, 0);

        const int c = n0 + lr;
        float bv = (c < N) ? bias[c] : 0.f;
        float mx = -1e30f, sm = 0.f;
#pragma unroll
        for (int m = 0; m < 4; m++)
#pragma unroll
            for (int r = 0; r < 4; r++) {
                int row = m * 16 + lg * 4 + r;
                if (row < NPG) {
                    float v = fmaxf(acc[m][r] + bv, 0.f);
                    mx = fmaxf(mx, v);
                    sm += v;
                }
            }
        mx = fmaxf(mx, __shfl_xor(mx, 16, 64));
        sm += __shfl_xor(sm, 16, 64);
        mx = fmaxf(mx, __shfl_xor(mx, 32, 64));
        sm += __shfl_xor(sm, 32, 64);
        if (lg == 0 && c < N) {
            out[(size_t)g * 1680 + c] = mx;
            out[(size_t)g * 1680 + 840 + c] = sm * (1.f / NPG);
        }
    }
}

// ---------------- N=1 GEMM ----------------
__global__ __launch_bounds__(256) void rowdot(const float* __restrict__ A,
                                              const float* __restrict__ w,
                                              const float* __restrict__ b,
                                              float* __restrict__ out, int Mrows, int K) {
    int row = blockIdx.x * 4 + (threadIdx.x >> 6);
    int lane = threadIdx.x & 63;
    if (row >= Mrows) return;
    float s = 0.f;
    for (int k = lane; k < K; k += 64) s += A[(size_t)row * K + k] * w[k];
#pragma unroll
    for (int off = 32; off > 0; off >>= 1) s += __shfl_xor(s, off, 64);
    if (lane == 0) out[row] = s + b[0];
}

// ---------------- hnode transform: h*Dinv + bias ----------------
__global__ void transform_dinv_bias(const float* __restrict__ h, const int* __restrict__ off_n,
                                    const float* __restrict__ b, float* __restrict__ o, int R, int F) {
    int i = blockIdx.x * 256 + threadIdx.x;
    if (i >= R * F) return;
    int r = i / F, f = i - r * F;
    int d = off_n[r + 1] - off_n[r];
    float inv = d > 0 ? 1.f / d : 0.f;
    o[i] = h[i] * inv + b[f];
}

// ---------------- fused hyper Dinv+bias + 50-row max/mean pool ----------------
__global__ void pool_hyper(const float* __restrict__ hn, const int* __restrict__ off_n,
                           const float* __restrict__ b, float* __restrict__ out) {
    int i = blockIdx.x * 256 + threadIdx.x;
    if (i >= NB * 256) return;
    int o = i & 255, g = i >> 8;
    float bo = b[o];
    const float* base = hn + (size_t)g * NPG * 256 + o;
    float mx = -1e30f, sm = 0.f;
    for (int n = 0; n < NPG; n++) {
        int node = g * NPG + n;
        int d = off_n[node + 1] - off_n[node];
        float inv = d > 0 ? 1.f / d : 0.f;
        float v = base[(size_t)n * 256] * inv + bo;
        mx = fmaxf(mx, v);
        sm += v;
    }
    out[(size_t)g * 512 + o] = mx;
    out[(size_t)g * 512 + 256 + o] = sm * (1.f / NPG);
}

// ---------------- pack fusion tokens -> bf16 ----------------
__global__ void pack_tokens_bf(const float* __restrict__ fp_o, const float* __restrict__ xg,
                               const float* __restrict__ hxg, const float* __restrict__ t,
                               unsigned short* __restrict__ in_t) {
    int i = blockIdx.x * 256 + threadIdx.x;
    if (i >= 4096 * 512) return;
    int d = i & 511;
    int row = i >> 9;
    int tok = row & 3, b = row >> 2;
    const float* s = (tok == 0) ? fp_o : (tok == 1) ? xg : (tok == 2) ? hxg : t;
    in_t[i] = f2bf(s[b * 512 + d]);
}

// ---------------- concat + cvt Wq|Wk|Wv -> bf16 [6144][512] ----------------
__global__ void cvt_qkv_w(const float* __restrict__ Wq, const float* __restrict__ Wk,
                          const float* __restrict__ Wv, unsigned short* __restrict__ Wb) {
    int i = blockIdx.x * 256 + threadIdx.x;
    if (i >= 6144 * 512) return;
    int n = i >> 9;
    const float* src = (n < 2048) ? Wq : (n < 4096) ? Wk : Wv;
    int nn = (n < 2048) ? n : (n < 4096) ? n - 2048 : n - 4096;
    Wb[i] = f2bf(src[(size_t)nn * 512 + (i & 511)]);
}

// ---------------- generic f32 -> bf16 ----------------
__global__ void cvt_f2b(const float* __restrict__ in, unsigned short* __restrict__ out, int n) {
    int i = blockIdx.x * 256 + threadIdx.x;
    if (i < n) out[i] = f2bf(in[i]);
}

// ---------------- fused attention + conv3x3 + relu: one block per batch b ----------------
__global__ __launch_bounds__(256) void attn_conv(const unsigned short* __restrict__ QKV,
                                                 const float* __restrict__ cw,
                                                 const float* __restrict__ cb,
                                                 unsigned short* __restrict__ c) {
    __shared__ float att_s[4][4][512];   // [head][token][d] = 32 KB
    __shared__ float w[144];
    __shared__ float bias[4];
    const int tid = threadIdx.x;
    const int wid = tid >> 6, lane = tid & 63;
    const int b = blockIdx.x;
    if (tid < 144) w[tid] = cw[tid];
    if (tid < 4) bias[tid] = cb[tid];

    const unsigned short* qb = QKV + (size_t)b * 4 * 6144 + wid * 512;
    const unsigned short* kb = qb + 2048;
    const unsigned short* vb = qb + 4096;
    float qr[4][8], kr[4][8];
#pragma unroll
    for (int n = 0; n < 4; n++)
#pragma unroll
        for (int cc = 0; cc < 8; cc++) {
            qr[n][cc] = bf2f(qb[n * 6144 + cc * 64 + lane]);
            kr[n][cc] = bf2f(kb[n * 6144 + cc * 64 + lane]);
        }
    float s[4][4];
#pragma unroll
    for (int n = 0; n < 4; n++)
#pragma unroll
        for (int m = 0; m < 4; m++) {
            float p = 0.f;
#pragma unroll
            for (int cc = 0; cc < 8; cc++) p += qr[n][cc] * kr[m][cc];
#pragma unroll
            for (int off = 32; off > 0; off >>= 1) p += __shfl_xor(p, off, 64);
            s[n][m] = p * 0.04419417382415922f;   // 1/sqrt(512)
        }
    float pm[4][4];
#pragma unroll
    for (int n = 0; n < 4; n++) {
        float mx = fmaxf(fmaxf(s[n][0], s[n][1]), fmaxf(s[n][2], s[n][3]));
        float e0 = expf(s[n][0] - mx), e1 = expf(s[n][1] - mx);
        float e2 = expf(s[n][2] - mx), e3 = expf(s[n][3] - mx);
        float inv = 1.f / (e0 + e1 + e2 + e3);
        pm[n][0] = e0 * inv; pm[n][1] = e1 * inv; pm[n][2] = e2 * inv; pm[n][3] = e3 * inv;
    }
#pragma unroll
    for (int cc = 0; cc < 8; cc++) {
        float v0 = bf2f(vb[0 * 6144 + cc * 64 + lane]);
        float v1 = bf2f(vb[1 * 6144 + cc * 64 + lane]);
        float v2 = bf2f(vb[2 * 6144 + cc * 64 + lane]);
        float v3 = bf2f(vb[3 * 6144 + cc * 64 + lane]);
#pragma unroll
        for (int n = 0; n < 4; n++)
            att_s[wid][n][cc * 64 + lane] = pm[n][0] * v0 + pm[n][1] * v1 + pm[n][2] * v2 + pm[n][3] * v3;
    }
    __syncthreads();

    for (int it = 0; it < 16; it++) {
        int j = it * 256 + tid;
        if (j >= 4080) break;
        int wo = j % 510;
        int r = j / 510;
        int ho = r & 1, co = r >> 1;
        float acc = bias[co];
#pragma unroll
        for (int ci = 0; ci < 4; ci++)
#pragma unroll
            for (int kh = 0; kh < 3; kh++)
#pragma unroll
                for (int kw = 0; kw < 3; kw++)
                    acc += att_s[ci][ho + kh][wo + kw] * w[((co * 4 + ci) * 3 + kh) * 3 + kw];
        c[(size_t)b * 4080 + j] = f2bf(fmaxf(acc, 0.f));
    }
}

// ---------------- host side ----------------
template<typename TA, typename TW>
static inline void launch_gemm64(const TA* A, const TW* W, const float* b, float* C,
                                 int M, int N, int K, bool relu, float* part, hipStream_t s) {
    int gx = (N + 63) / 64, gy = (M + 63) / 64;
    int targetSK = 1024 / (gx * gy);
    if (targetSK < 1) targetSK = 1;
    if (targetSK > 8) targetSK = 8;
    int kchunk = K, SK = 1;
    if (targetSK > 1) {
        kchunk = (((K + targetSK - 1) / targetSK) + 127) & ~127;
        SK = (K + kchunk - 1) / kchunk;
    }
    if (SK <= 1) {
        dim3 g(gx, gy);
        if (relu) gemm64<true, false, TA, TW><<<g, 256, 0, s>>>(A, W, b, C, M, N, K, K);
        else      gemm64<false, false, TA, TW><<<g, 256, 0, s>>>(A, W, b, C, M, N, K, K);
    } else {
        dim3 g(gx, gy, SK);
        gemm64<false, true, TA, TW><<<g, 256, 0, s>>>(A, W, nullptr, part, M, N, K, kchunk);
        int MN = M * N;
        if (relu) reduce_partial<true><<<(MN + 255) / 256, 256, 0, s>>>(part, b, C, MN, N, SK);
        else      reduce_partial<false><<<(MN + 255) / 256, 256, 0, s>>>(part, b, C, MN, N, SK);
    }
}

extern "C" void kernel_launch(void* const* d_in, const int* in_sizes, int n_in,
                              void* d_out, int out_size, void* d_ws, size_t ws_size,
                              hipStream_t stream) {
    const float* x       = (const float*)d_in[0];
    const int*   edge    = (const int*)d_in[1];
    const int*   hedge   = (const int*)d_in[3];
    const float* fp      = (const float*)d_in[4];
    const float* text_em = (const float*)d_in[5];
    const float* fc1_W = (const float*)d_in[7];  const float* fc1_b = (const float*)d_in[8];
    const float* fc2_W = (const float*)d_in[9];  const float* fc2_b = (const float*)d_in[10];
    const float* fc3_W = (const float*)d_in[11]; const float* fc3_b = (const float*)d_in[12];
    const float* fcg1_W = (const float*)d_in[13]; const float* fcg1_b = (const float*)d_in[14];
    const float* fcg2_W = (const float*)d_in[15]; const float* fcg2_b = (const float*)d_in[16];
    const float* fchg1_W = (const float*)d_in[17]; const float* fchg1_b = (const float*)d_in[18];
    const float* fchg2_W = (const float*)d_in[19]; const float* fchg2_b = (const float*)d_in[20];
    const float* gin1_W = (const float*)d_in[21]; const float* gin1_b = (const float*)d_in[22];
    const float* gin2_W = (const float*)d_in[23]; const float* gin2_b = (const float*)d_in[24];
    const float* h3_W = (const float*)d_in[25]; const float* h3_b = (const float*)d_in[26];
    const float* h4_W = (const float*)d_in[27]; const float* h4_b = (const float*)d_in[28];
    const float* Wq = (const float*)d_in[29];
    const float* Wk = (const float*)d_in[30];
    const float* Wv = (const float*)d_in[31];
    const float* conv_W = (const float*)d_in[32]; const float* conv_b = (const float*)d_in[33];
    const float* mlp1_W = (const float*)d_in[34]; const float* mlp1_b = (const float*)d_in[35];
    const float* mlp2_W = (const float*)d_in[36]; const float* mlp2_b = (const float*)d_in[37];

    const int* e_src = edge;
    const int* e_dst = edge + N_EDGES;
    const int* h_nid = hedge;
    const int* h_eid = hedge + N_HNNZ;

    float* ws = (float*)d_ws;
    const size_t ZONE = 51609600;
    // ---- phase A (GIN) ----
    float* xin1 = ws;                               // 4,300,800
    float* xg1  = ws + 4300800;                     // 4,300,800
    float* xin2 = ws + 8601600;                     // 4,300,800
    // ---- phase H (hypergraph) ----
    float* eagg   = ws;                             // 860,160
    float* e1_32  = ws + 860160;                    // 1,720,320
    float* hnode  = ws + 2580480;                   // 8,601,600
    float* hnodet = ws + 11182080;                  // 8,601,600
    float* eagg2  = ws + 19783680;                  // 1,720,320
    float* e2_32  = ws + 21504000;                  // 2,621,440
    float* hn2    = ws + 24125440;                  // 13,107,200 (ends 37,232,640)
    // ---- phase D (attention) ----
    unsigned short* in_t_bf  = (unsigned short*)ws;                 // 2,097,152 us = 1,048,576 f
    unsigned short* qkv_bf   = (unsigned short*)(ws + 2097152);     // 25,165,824 us = 12,582,912 f
    unsigned short* cbuf_bf  = (unsigned short*)(ws + 35651584);    // 4,177,920 us
    float* m1   = ws + 39829504;                                    // 1,048,576
    unsigned short* Wqkv_bf  = (unsigned short*)(ws + 40878080);    // 3,145,728 us
    unsigned short* mlp1W_bf = (unsigned short*)(ws + 42450944);    // 4,177,920 us (ends 44,539,904)
    float* part = ws;                               // split-K scratch (zone-dead windows)
    // ---- CSR region ----
    int* cnt_g = (int*)(ws + 45000000);
    int* off_g = (int*)(ws + 45051200);
    int* pay_g = (int*)(ws + 45102401);
    int* cnt_e = (int*)(ws + 45307201);
    int* off_e = (int*)(ws + 45317441);
    int* pay_e = (int*)(ws + 45327682);
    int* cnt_n = (int*)(ws + 45430082);
    int* off_n = (int*)(ws + 45481282);
    int* pay_n = (int*)(ws + 45532483);             // ends 45,634,883 < ZONE
    // ---- persistent ----
    float* xg_raw = ws + ZONE;
    float* xg_mid = ws + ZONE + 1720320;
    float* hx_raw = ws + ZONE + 2768896;
    float* hx_mid = ws + ZONE + 3293184;
    float* h1     = ws + ZONE + 4341760;
    float* fp_o   = ws + ZONE + 4472832;
    float* tt     = ws + ZONE + 4997120;
    const size_t NEED = (ZONE + 5582848) * sizeof(float);
    if (ws_size < NEED) return;

    float* out_y  = (float*)d_out;
    float* xg_out = out_y + 1024;
    float* hx_out = out_y + 1024 + 1024 * 512;

    // ---------- build 3 CSR structures ----------
    hipMemsetAsync(cnt_g, 0, N_NODES * 4, stream);
    hipMemsetAsync(cnt_e, 0, N_HEDGES * 4, stream);
    hipMemsetAsync(cnt_n, 0, N_NODES * 4, stream);
    histo_i<<<(N_EDGES + 255) / 256, 256, 0, stream>>>(e_dst, cnt_g, N_EDGES);
    histo_i<<<(N_HNNZ + 255) / 256, 256, 0, stream>>>(h_eid, cnt_e, N_HNNZ);
    histo_i<<<(N_HNNZ + 255) / 256, 256, 0, stream>>>(h_nid, cnt_n, N_HNNZ);
    exscan3<<<3, 1024, 0, stream>>>(cnt_g, off_g, N_NODES, cnt_e, off_e, N_HEDGES, cnt_n, off_n, N_NODES);
    hipMemcpyAsync(cnt_g, off_g, N_NODES * 4, hipMemcpyDeviceToDevice, stream);
    hipMemcpyAsync(cnt_e, off_e, N_HEDGES * 4, hipMemcpyDeviceToDevice, stream);
    hipMemcpyAsync(cnt_n, off_n, N_NODES * 4, hipMemcpyDeviceToDevice, stream);
    place_pay<<<(N_EDGES + 255) / 256, 256, 0, stream>>>(e_dst, e_src, cnt_g, pay_g, N_EDGES);
    place_pay<<<(N_HNNZ + 255) / 256, 256, 0, stream>>>(h_eid, h_nid, cnt_e, pay_e, N_HNNZ);
    place_pay<<<(N_HNNZ + 255) / 256, 256, 0, stream>>>(h_nid, h_eid, cnt_n, pay_n, N_HNNZ);

    // ---------- GIN branch ----------
    gather_rows4<true, false><<<(N_NODES * (FXD / 4) + 255) / 256, 256, 0, stream>>>(
        x, off_g, pay_g, x, xin1, N_NODES, FXD / 4);
    launch_gemm64(xin1, gin1_W, gin1_b, xg1, N_NODES, FXD, FXD, true, part, stream);
    gather_rows4<true, false><<<(N_NODES * (FXD / 4) + 255) / 256, 256, 0, stream>>>(
        xg1, off_g, pay_g, xg1, xin2, N_NODES, FXD / 4);
    gin2pool<<<NB, 256, 0, stream>>>(xin2, gin2_W, gin2_b, xg_raw);
    launch_gemm64(xg_raw, fcg1_W, fcg1_b, xg_mid, NB, 1024, 1680, true, part, stream);
    launch_gemm64(xg_mid, fcg2_W, fcg2_b, xg_out, NB, 512, 1024, false, part, stream);

    // ---------- hypergraph branch ----------
    gather_rows4<false, true><<<(N_HEDGES * (FXD / 4) + 255) / 256, 256, 0, stream>>>(
        x, off_e, pay_e, nullptr, eagg, N_HEDGES, FXD / 4);
    launch_gemm64(eagg, h3_W, (const float*)nullptr, e1_32, N_HEDGES, 168, FXD, false, part, stream);
    gather_rows4<false, false><<<(N_NODES * 42 + 255) / 256, 256, 0, stream>>>(
        e1_32, off_n, pay_n, nullptr, hnode, N_NODES, 42);
    transform_dinv_bias<<<(N_NODES * 168 + 255) / 256, 256, 0, stream>>>(
        hnode, off_n, h3_b, hnodet, N_NODES, 168);
    gather_rows4<false, true><<<(N_HEDGES * 42 + 255) / 256, 256, 0, stream>>>(
        hnodet, off_e, pay_e, nullptr, eagg2, N_HEDGES, 42);
    launch_gemm64(eagg2, h4_W, (const float*)nullptr, e2_32, N_HEDGES, 256, 168, false, part, stream);
    gather_rows4<false, false><<<(N_NODES * 64 + 255) / 256, 256, 0, stream>>>(
        e2_32, off_n, pay_n, nullptr, hn2, N_NODES, 64);
    pool_hyper<<<(NB * 256 + 255) / 256, 256, 0, stream>>>(hn2, off_n, h4_b, hx_raw);
    launch_gemm64(hx_raw, fchg1_W, fchg1_b, hx_mid, NB, 1024, 512, true, part, stream);
    launch_gemm64(hx_mid, fchg2_W, fchg2_b, hx_out, NB, 512, 1024, false, part, stream);

    // ---------- fingerprint + text ----------
    launch_gemm64(fp, fc1_W, fc1_b, h1, NB, FP2, FP_DIM, true, part, stream);
    launch_gemm64(h1, fc2_W, fc2_b, fp_o, NB, HID, FP2, false, part, stream);
    launch_gemm64(text_em, fc3_W, fc3_b, tt, NB, HID, 768, false, part, stream);

    // ---------- fusion attention (bf16 pipeline) ----------
    pack_tokens_bf<<<(4096 * 512 + 255) / 256, 256, 0, stream>>>(fp_o, xg_out, hx_out, tt, in_t_bf);
    cvt_qkv_w<<<(6144 * 512 + 255) / 256, 256, 0, stream>>>(Wq, Wk, Wv, Wqkv_bf);
    gemm_bf16<<<dim3(6144 / 128, 4096 / 128), 256, 0, stream>>>(in_t_bf, Wqkv_bf, qkv_bf, 4096, 6144, 512);
    attn_conv<<<NB, 256, 0, stream>>>(qkv_bf, conv_W, conv_b, cbuf_bf);
    cvt_f2b<<<(1024 * 4080 + 255) / 256, 256, 0, stream>>>(mlp1_W, mlp1W_bf, 1024 * 4080);
    launch_gemm64(cbuf_bf, mlp1W_bf, mlp1_b, m1, NB, 1024, 4080, true, part, stream);
    rowdot<<<256, 256, 0, stream>>>(m1, mlp2_W, mlp2_b, out_y, NB, 1024);
}

// Round 11
// 879.735 us; speedup vs baseline: 4.0949x; 1.1182x over previous
//
#include <hip/hip_runtime.h>
#include <hip/hip_bf16.h>

// ---------------- constants ----------------
#define N_NODES 51200
#define N_EDGES 204800
#define N_HNNZ  102400
#define N_HEDGES 10240
#define NB 1024          // batch (graphs)
#define NPG 50           // nodes per graph (51200/1024)
#define FXD 84
#define FP_DIM 2513
#define FP2 128
#define HID 512

typedef __attribute__((ext_vector_type(4))) float f32x4;
typedef __attribute__((ext_vector_type(8))) __bf16 bf16x8;
typedef __attribute__((ext_vector_type(4))) short short4_t;

static __device__ __forceinline__ unsigned short f2bf(float f) {
    unsigned u = __builtin_bit_cast(unsigned, f);
    u += 0x7FFFu + ((u >> 16) & 1u);   // round-to-nearest-even
    return (unsigned short)(u >> 16);
}
static __device__ __forceinline__ float bf2f(unsigned short u) {
    unsigned x = ((unsigned)u) << 16;
    return __builtin_bit_cast(float, x);
}

// bijective XCD-aware remap (m204 formula)
static __device__ __forceinline__ int xcd_swizzle(int orig, int nwg) {
    int q = nwg >> 3, r = nwg & 7;
    int xcd = orig & 7, off = orig >> 3;
    return (xcd < r ? xcd * (q + 1) : r * (q + 1) + (xcd - r) * q) + off;
}

// load 4 f32 as bf16 short4 with K-guards
static __device__ __forceinline__ short4_t ld4bf_f32(const float* p, int gk, int kend, bool kvec) {
    short4_t sv;
    float v0 = 0.f, v1 = 0.f, v2 = 0.f, v3 = 0.f;
    if (kvec && gk + 4 <= kend) {
        float4 f = *(const float4*)p;
        v0 = f.x; v1 = f.y; v2 = f.z; v3 = f.w;
    } else {
        v0 = p[0];
        if (gk + 1 < kend) v1 = p[1];
        if (gk + 2 < kend) v2 = p[2];
        if (gk + 3 < kend) v3 = p[3];
    }
    sv[0] = (short)f2bf(v0); sv[1] = (short)f2bf(v1);
    sv[2] = (short)f2bf(v2); sv[3] = (short)f2bf(v3);
    return sv;
}

// ---------------- CSR build ----------------
__global__ void histo_i(const int* __restrict__ keys, int* __restrict__ cnt, int n) {
    int i = blockIdx.x * 256 + threadIdx.x;
    if (i < n) atomicAdd(&cnt[keys[i]], 1);
}

__global__ __launch_bounds__(1024) void exscan3(const int* __restrict__ c0, int* __restrict__ o0, int B0,
                                                const int* __restrict__ c1, int* __restrict__ o1, int B1,
                                                const int* __restrict__ c2, int* __restrict__ o2, int B2) {
    const int* cnt = blockIdx.x == 0 ? c0 : blockIdx.x == 1 ? c1 : c2;
    int* off = blockIdx.x == 0 ? o0 : blockIdx.x == 1 ? o1 : o2;
    int B = blockIdx.x == 0 ? B0 : blockIdx.x == 1 ? B1 : B2;
    __shared__ int part[1024];
    int t = threadIdx.x;
    int C = (B + 1023) >> 10;
    int s0 = t * C, s1 = min(B, s0 + C);
    int sum = 0;
    for (int i = s0; i < s1; i++) sum += cnt[i];
    part[t] = sum;
    __syncthreads();
    for (int d = 1; d < 1024; d <<= 1) {
        int x = (t >= d) ? part[t - d] : 0;
        __syncthreads();
        part[t] += x;
        __syncthreads();
    }
    int run = (t == 0) ? 0 : part[t - 1];
    for (int i = s0; i < s1; i++) { off[i] = run; run += cnt[i]; }
    if (t == 1023) off[B] = part[1023];
}

__global__ void place_pay(const int* __restrict__ keys, const int* __restrict__ payload,
                          int* __restrict__ cursor, int* __restrict__ pay, int n) {
    int i = blockIdx.x * 256 + threadIdx.x;
    if (i < n) {
        int p = atomicAdd(&cursor[keys[i]], 1);
        pay[p] = payload[i];
    }
}

// ---------------- CSR gather, float4-vectorized (f64 reg accumulation -> replay-stable) ----------------
template<bool SELF, bool SCALE>
__global__ void gather_rows4(const float* __restrict__ src,
                             const int* __restrict__ off, const int* __restrict__ pay,
                             const float* __restrict__ self_src,
                             float* __restrict__ out, int R, int F4) {
    int i = blockIdx.x * 256 + threadIdx.x;
    if (i >= R * F4) return;
    int r = i / F4, f4 = i - r * F4;
    int b = off[r], e = off[r + 1];
    double a0 = 0.0, a1 = 0.0, a2 = 0.0, a3 = 0.0;
    for (int j = b; j < e; j++) {
        float4 v = *((const float4*)(src + (size_t)pay[j] * F4 * 4) + f4);
        a0 += v.x; a1 += v.y; a2 += v.z; a3 += v.w;
    }
    float s0 = (float)a0, s1 = (float)a1, s2 = (float)a2, s3 = (float)a3;
    if (SCALE) {
        float inv = 1.f / fmaxf((float)(e - b), 1.f);
        s0 *= inv; s1 *= inv; s2 *= inv; s3 *= inv;
    }
    if (SELF) {
        float4 sv = *((const float4*)self_src + i);
        s0 += sv.x; s1 += sv.y; s2 += sv.z; s3 += sv.w;
    }
    float4 o = {s0, s1, s2, s3};
    *((float4*)out + i) = o;
}

// ---------------- bf16 GEMM 128x128, BK=64, direct staging (no reg-prefetch: avoids spill) ----------------
// A: [M,K] bf16; B: [N,K] bf16; C: [M,N] bf16. M,N %128==0, K %64==0.
__global__ __launch_bounds__(256) void gemm_bf16(const unsigned short* __restrict__ A,
                                                 const unsigned short* __restrict__ B,
                                                 unsigned short* __restrict__ C,
                                                 int M, int N, int K) {
    __shared__ __align__(16) char Asm[16384];   // 128 x 64 bf16, swizzled
    __shared__ __align__(16) char Bsm[16384];
    const int tid = threadIdx.x;
    const int nwg = gridDim.x * gridDim.y;
    const int wg = xcd_swizzle(blockIdx.y * gridDim.x + blockIdx.x, nwg);
    const int bm = (wg / gridDim.x) * 128, bn = (wg % gridDim.x) * 128;
    const int wid = tid >> 6, lane = tid & 63;
    const int wm = (wid >> 1) * 64, wn = (wid & 1) * 64;
    const int lr = lane & 15, lg = lane >> 4;

    f32x4 zero = {0.f, 0.f, 0.f, 0.f};
    f32x4 acc[4][4];
#pragma unroll
    for (int i = 0; i < 4; i++)
#pragma unroll
        for (int j = 0; j < 4; j++) acc[i][j] = zero;

    for (int k0 = 0; k0 < K; k0 += 64) {
#pragma unroll
        for (int u = 0; u < 4; u++) {
            int slot = u * 256 + tid;            // 0..1023 16B-chunks
            int row = slot >> 3, ch = slot & 7;
            int off = (row * 128 + ch * 16) ^ ((row & 7) << 4);
            uint4 va = *(const uint4*)(A + (size_t)(bm + row) * K + k0 + ch * 8);
            *(uint4*)(Asm + off) = va;
            uint4 vb = *(const uint4*)(B + (size_t)(bn + row) * K + k0 + ch * 8);
            *(uint4*)(Bsm + off) = vb;
        }
        __syncthreads();
#pragma unroll
        for (int kk = 0; kk < 2; kk++) {
            bf16x8 af[4], bf[4];
#pragma unroll
            for (int m = 0; m < 4; m++) {
                int row = wm + m * 16 + lr;
                af[m] = *(const bf16x8*)(Asm + ((row * 128 + kk * 64 + lg * 16) ^ ((row & 7) << 4)));
            }
#pragma unroll
            for (int n = 0; n < 4; n++) {
                int row = wn + n * 16 + lr;
                bf[n] = *(const bf16x8*)(Bsm + ((row * 128 + kk * 64 + lg * 16) ^ ((row & 7) << 4)));
            }
#pragma unroll
            for (int m = 0; m < 4; m++)
#pragma unroll
                for (int n = 0; n < 4; n++)
                    acc[m][n] = __builtin_amdgcn_mfma_f32_16x16x32_bf16(af[m], bf[n], acc[m][n], 0, 0, 0);
        }
        __syncthreads();
    }
#pragma unroll
    for (int m = 0; m < 4; m++)
#pragma unroll
        for (int n = 0; n < 4; n++) {
            int col = bn + wn + n * 16 + lr;
#pragma unroll
            for (int r = 0; r < 4; r++) {
                int row = bm + wm + m * 16 + lg * 4 + r;
                C[(size_t)row * N + col] = f2bf(acc[m][n][r]);
            }
        }
}

// ---------------- MFMA GEMM 64x64, wave-K-split, reg-prefetch, 32KB LDS, grid.z split-K ----------------
template<bool RELU, bool PARTIAL, typename TA, typename TW>
__global__ __launch_bounds__(256) void gemm64(const TA* __restrict__ A,
                                              const TW* __restrict__ W,
                                              const float* __restrict__ bias,
                                              float* __restrict__ C,
                                              int M, int N, int K, int kchunk) {
    __shared__ __align__(16) char pool[32768];
    char* Ab = pool;
    char* Bb = pool + 16384;
    const int tid = threadIdx.x;
    const int nwg = gridDim.x * gridDim.y;
    const int wg = xcd_swizzle(blockIdx.y * gridDim.x + blockIdx.x, nwg);
    const int bm = (wg / gridDim.x) * 64, bn = (wg % gridDim.x) * 64;
    const int wid = tid >> 6, lane = tid & 63;
    const int lr = lane & 15, lg = lane >> 4;
    const int kbeg = blockIdx.z * kchunk;
    const int kend = min(K, kbeg + kchunk);
    const bool kvec = ((K & 3) == 0);

    f32x4 zero = {0.f, 0.f, 0.f, 0.f};
    f32x4 acc[4][4];
#pragma unroll
    for (int i = 0; i < 4; i++)
#pragma unroll
        for (int j = 0; j < 4; j++) acc[i][j] = zero;

    // staging registers (per matrix: 2-byte src -> 4x uint4; 4-byte src -> 8x short4)
    uint4 ra16[4], rb16[4];
    short4_t ra4[8], rb4[8];

    auto load_A = [&](int kc2) {
        if constexpr (sizeof(TA) == 2) {
#pragma unroll
            for (int u = 0; u < 4; u++) {
                int s = u * 256 + tid;
                int row = s >> 4, k8 = (s & 15) << 3;
                int gk = kc2 + k8, gm = bm + row;
                uint4 v = {0u, 0u, 0u, 0u};
                if (gm < M && gk + 8 <= kend) {
                    v = *(const uint4*)((const unsigned short*)A + (size_t)gm * K + gk);
                } else if (gm < M && gk < kend) {
                    unsigned short tmp[8];
#pragma unroll
                    for (int e = 0; e < 8; e++)
                        tmp[e] = (gk + e < kend) ? ((const unsigned short*)A)[(size_t)gm * K + gk + e] : 0;
                    v = *(const uint4*)tmp;
                }
                ra16[u] = v;
            }
        } else {
#pragma unroll
            for (int u = 0; u < 8; u++) {
                int s = u * 256 + tid;
                int row = s >> 5, kq = (s & 31) << 2;
                int gk = kc2 + kq, gm = bm + row;
                short4_t sv = {0, 0, 0, 0};
                if (gm < M && gk < kend)
                    sv = ld4bf_f32((const float*)A + (size_t)gm * K + gk, gk, kend, kvec);
                ra4[u] = sv;
            }
        }
    };
    auto load_B = [&](int kc2) {
        if constexpr (sizeof(TW) == 2) {
#pragma unroll
            for (int u = 0; u < 4; u++) {
                int s = u * 256 + tid;
                int row = s >> 4, k8 = (s & 15) << 3;
                int gk = kc2 + k8, gn = bn + row;
                uint4 v = {0u, 0u, 0u, 0u};
                if (gn < N && gk + 8 <= kend) {
                    v = *(const uint4*)((const unsigned short*)W + (size_t)gn * K + gk);
                } else if (gn < N && gk < kend) {
                    unsigned short tmp[8];
#pragma unroll
                    for (int e = 0; e < 8; e++)
                        tmp[e] = (gk + e < kend) ? ((const unsigned short*)W)[(size_t)gn * K + gk + e] : 0;
                    v = *(const uint4*)tmp;
                }
                rb16[u] = v;
            }
        } else {
#pragma unroll
            for (int u = 0; u < 8; u++) {
                int s = u * 256 + tid;
                int row = s >> 5, kq = (s & 31) << 2;
                int gk = kc2 + kq, gn = bn + row;
                short4_t sv = {0, 0, 0, 0};
                if (gn < N && gk < kend)
                    sv = ld4bf_f32((const float*)W + (size_t)gn * K + gk, gk, kend, kvec);
                rb4[u] = sv;
            }
        }
    };
    auto write_A = [&]() {
        if constexpr (sizeof(TA) == 2) {
#pragma unroll
            for (int u = 0; u < 4; u++) {
                int s = u * 256 + tid;
                int row = s >> 4, k8 = (s & 15) << 3;
                int off = (row * 256 + k8 * 2) ^ ((row & 7) << 4);
                *(uint4*)(Ab + off) = ra16[u];
            }
        } else {
#pragma unroll
            for (int u = 0; u < 8; u++) {
                int s = u * 256 + tid;
                int row = s >> 5, kq = (s & 31) << 2;
                int off = (row * 256 + kq * 2) ^ ((row & 7) << 4);
                *(short4_t*)(Ab + off) = ra4[u];
            }
        }
    };
    auto write_B = [&]() {
        if constexpr (sizeof(TW) == 2) {
#pragma unroll
            for (int u = 0; u < 4; u++) {
                int s = u * 256 + tid;
                int row = s >> 4, k8 = (s & 15) << 3;
                int off = (row * 256 + k8 * 2) ^ ((row & 7) << 4);
                *(uint4*)(Bb + off) = rb16[u];
            }
        } else {
#pragma unroll
            for (int u = 0; u < 8; u++) {
                int s = u * 256 + tid;
                int row = s >> 5, kq = (s & 31) << 2;
                int off = (row * 256 + kq * 2) ^ ((row & 7) << 4);
                *(short4_t*)(Bb + off) = rb4[u];
            }
        }
    };

    load_A(kbeg);
    load_B(kbeg);
    for (int kc = kbeg; kc < kend; kc += 128) {
        write_A();
        write_B();
        __syncthreads();
        if (kc + 128 < kend) { load_A(kc + 128); load_B(kc + 128); }

        bf16x8 af[4], bf[4];
        const int kb = wid * 64 + lg * 16;
#pragma unroll
        for (int m = 0; m < 4; m++) {
            int row = m * 16 + lr;
            af[m] = *(const bf16x8*)(Ab + ((row * 256 + kb) ^ ((row & 7) << 4)));
        }
#pragma unroll
        for (int n = 0; n < 4; n++) {
            int row = n * 16 + lr;
            bf[n] = *(const bf16x8*)(Bb + ((row * 256 + kb) ^ ((row & 7) << 4)));
        }
#pragma unroll
        for (int m = 0; m < 4; m++)
#pragma unroll
            for (int n = 0; n < 4; n++)
                acc[m][n] = __builtin_amdgcn_mfma_f32_16x16x32_bf16(af[m], bf[n], acc[m][n], 0, 0, 0);
        __syncthreads();
    }

    float* redA = (float*)pool;
    float* redB = (float*)(pool + 16384);
    if (wid < 2) {
        float* r = (wid == 0) ? redA : redB;
#pragma unroll
        for (int m = 0; m < 4; m++)
#pragma unroll
            for (int n = 0; n < 4; n++)
#pragma unroll
                for (int r4 = 0; r4 < 4; r4++)
                    r[(m * 16 + lg * 4 + r4) * 64 + n * 16 + lr] = acc[m][n][r4];
    }
    __syncthreads();
    if (wid >= 2) {
        float* r = (wid == 2) ? redA : redB;
#pragma unroll
        for (int m = 0; m < 4; m++)
#pragma unroll
            for (int n = 0; n < 4; n++)
#pragma unroll
                for (int r4 = 0; r4 < 4; r4++)
                    r[(m * 16 + lg * 4 + r4) * 64 + n * 16 + lr] += acc[m][n][r4];
    }
    __syncthreads();
#pragma unroll
    for (int u = 0; u < 16; u++) {
        int idx = u * 256 + tid;
        int row = idx >> 6, col = idx & 63;
        int gm = bm + row, gn = bn + col;
        if (gm >= M || gn >= N) continue;
        float s = redA[idx] + redB[idx];
        if (PARTIAL) {
            C[(size_t)blockIdx.z * M * N + (size_t)gm * N + gn] = s;
        } else {
            s += bias ? bias[gn] : 0.f;
            if (RELU) s = fmaxf(s, 0.f);
            C[(size_t)gm * N + gn] = s;
        }
    }
}

template<bool RELU>
__global__ void reduce_partial(const float* __restrict__ part, const float* __restrict__ bias,
                               float* __restrict__ C, int MN, int N, int SK) {
    int i = blockIdx.x * 256 + threadIdx.x;
    if (i >= MN) return;
    float s = 0.f;
    for (int z = 0; z < SK; z++) s += part[(size_t)z * MN + i];
    s += bias ? bias[i % N] : 0.f;
    if (RELU) s = fmaxf(s, 0.f);
    C[i] = s;
}

// ---------------- fused GIN2 GEMM + bias + relu + 50-row max/mean pool ----------------
__global__ __launch_bounds__(256) void gin2pool(const float* __restrict__ xin2,
                                                const float* __restrict__ W,
                                                const float* __restrict__ bias,
                                                float* __restrict__ out) {
    __shared__ __align__(16) char Ab[16384];
    const int tid = threadIdx.x;
    const int g = blockIdx.x;
    const int wid = tid >> 6, lane = tid & 63;
    const int lr = lane & 15, lg = lane >> 4;
    const int K = FXD;
    const int N = 840;

#pragma unroll
    for (int u = 0; u < 8; u++) {
        int s = u * 256 + tid;
        int row = s >> 5, kq = (s & 31) << 2;
        int off = (row * 256 + (s & 31) * 8) ^ ((row & 7) << 4);
        float v0 = 0.f, v1 = 0.f, v2 = 0.f, v3 = 0.f;
        if (row < NPG && kq < K) {
            float4 f = *(const float4*)(xin2 + ((size_t)g * NPG + row) * K + kq);
            v0 = f.x; v1 = f.y; v2 = f.z; v3 = f.w;
        }
        short4_t sv;
        sv[0] = (short)f2bf(v0); sv[1] = (short)f2bf(v1);
        sv[2] = (short)f2bf(v2); sv[3] = (short)f2bf(v3);
        *(short4_t*)(Ab + off) = sv;
    }
    __syncthreads();

    bf16x8 af[4][3];
#pragma unroll
    for (int m = 0; m < 4; m++)
#pragma unroll
        for (int kk = 0; kk < 3; kk++) {
            int row = m * 16 + lr;
            af[m][kk] = *(const bf16x8*)(Ab + ((row * 256 + kk * 64 + lg * 16) ^ ((row & 7) << 4)));
        }

    for (int t = 0; t < 14; t++) {
        const int n0 = t * 64 + wid * 16;
        const int wrow = n0 + lr;
        bf16x8 bf[3];
#pragma unroll
        for (int kk = 0; kk < 3; kk++) {
            int k0 = kk * 32 + lg * 8;
#pragma unroll
            for (int e = 0; e < 8; e++) {
                float v = (wrow < N && k0 + e < K) ? W[(size_t)wrow * K + k0 + e] : 0.f;
                bf[kk][e] = __builtin_bit_cast(__bf16, f2bf(v));
            }
        }
        f32x4 zero = {0.f, 0.f, 0.f, 0.f};
        f32x4 acc[4] = {zero, zero, zero, zero};
#pragma unroll
        for (int m = 0; m < 4; m++)
#pragma unroll
            for (int kk = 0; kk < 3; kk++)
                acc[m] = __builtin_amdgcn_mfma_f32_16x16x32_bf16(af[m][kk], bf[kk], acc[m], 0, 0, 0);

        const int c = n0 + lr;
        float bv = (c < N) ? bias[c] : 0.f;
        float mx = -1e30f, sm = 0.f;
#pragma unroll
        for (int m = 0; m < 4; m++)
#pragma unroll
            for (int r = 0; r < 4; r++) {
                int row = m * 16 + lg * 4 + r;
                if (row < NPG) {
                    float v = fmaxf(acc[m][r] + bv, 0.f);
                    mx = fmaxf(mx, v);
                    sm += v;
                }
            }
        mx = fmaxf(mx, __shfl_xor(mx, 16, 64));
        sm += __shfl_xor(sm, 16, 64);
        mx = fmaxf(mx, __shfl_xor(mx, 32, 64));
        sm += __shfl_xor(sm, 32, 64);
        if (lg == 0 && c < N) {
            out[(size_t)g * 1680 + c] = mx;
            out[(size_t)g * 1680 + 840 + c] = sm * (1.f / NPG);
        }
    }
}

// ---------------- N=1 GEMM ----------------
__global__ __launch_bounds__(256) void rowdot(const float* __restrict__ A,
                                              const float* __restrict__ w,
                                              const float* __restrict__ b,
                                              float* __restrict__ out, int Mrows, int K) {
    int row = blockIdx.x * 4 + (threadIdx.x >> 6);
    int lane = threadIdx.x & 63;
    if (row >= Mrows) return;
    float s = 0.f;
    for (int k = lane; k < K; k += 64) s += A[(size_t)row * K + k] * w[k];
#pragma unroll
    for (int off = 32; off > 0; off >>= 1) s += __shfl_xor(s, off, 64);
    if (lane == 0) out[row] = s + b[0];
}

// ---------------- hnode transform: h*Dinv + bias ----------------
__global__ void transform_dinv_bias(const float* __restrict__ h, const int* __restrict__ off_n,
                                    const float* __restrict__ b, float* __restrict__ o, int R, int F) {
    int i = blockIdx.x * 256 + threadIdx.x;
    if (i >= R * F) return;
    int r = i / F, f = i - r * F;
    int d = off_n[r + 1] - off_n[r];
    float inv = d > 0 ? 1.f / d : 0.f;
    o[i] = h[i] * inv + b[f];
}

// ---------------- fused hyper Dinv+bias + 50-row max/mean pool ----------------
__global__ void pool_hyper(const float* __restrict__ hn, const int* __restrict__ off_n,
                           const float* __restrict__ b, float* __restrict__ out) {
    int i = blockIdx.x * 256 + threadIdx.x;
    if (i >= NB * 256) return;
    int o = i & 255, g = i >> 8;
    float bo = b[o];
    const float* base = hn + (size_t)g * NPG * 256 + o;
    float mx = -1e30f, sm = 0.f;
    for (int n = 0; n < NPG; n++) {
        int node = g * NPG + n;
        int d = off_n[node + 1] - off_n[node];
        float inv = d > 0 ? 1.f / d : 0.f;
        float v = base[(size_t)n * 256] * inv + bo;
        mx = fmaxf(mx, v);
        sm += v;
    }
    out[(size_t)g * 512 + o] = mx;
    out[(size_t)g * 512 + 256 + o] = sm * (1.f / NPG);
}

// ---------------- pack fusion tokens -> bf16 ----------------
__global__ void pack_tokens_bf(const float* __restrict__ fp_o, const float* __restrict__ xg,
                               const float* __restrict__ hxg, const float* __restrict__ t,
                               unsigned short* __restrict__ in_t) {
    int i = blockIdx.x * 256 + threadIdx.x;
    if (i >= 4096 * 512) return;
    int d = i & 511;
    int row = i >> 9;
    int tok = row & 3, b = row >> 2;
    const float* s = (tok == 0) ? fp_o : (tok == 1) ? xg : (tok == 2) ? hxg : t;
    in_t[i] = f2bf(s[b * 512 + d]);
}

// ---------------- concat + cvt Wq|Wk|Wv -> bf16 [6144][512] ----------------
__global__ void cvt_qkv_w(const float* __restrict__ Wq, const float* __restrict__ Wk,
                          const float* __restrict__ Wv, unsigned short* __restrict__ Wb) {
    int i = blockIdx.x * 256 + threadIdx.x;
    if (i >= 6144 * 512) return;
    int n = i >> 9;
    const float* src = (n < 2048) ? Wq : (n < 4096) ? Wk : Wv;
    int nn = (n < 2048) ? n : (n < 4096) ? n - 2048 : n - 4096;
    Wb[i] = f2bf(src[(size_t)nn * 512 + (i & 511)]);
}

// ---------------- generic f32 -> bf16 ----------------
__global__ void cvt_f2b(const float* __restrict__ in, unsigned short* __restrict__ out, int n) {
    int i = blockIdx.x * 256 + threadIdx.x;
    if (i < n) out[i] = f2bf(in[i]);
}

// ---------------- fused attention + conv3x3 + relu: one block per batch b ----------------
__global__ __launch_bounds__(256) void attn_conv(const unsigned short* __restrict__ QKV,
                                                 const float* __restrict__ cw,
                                                 const float* __restrict__ cb,
                                                 unsigned short* __restrict__ c) {
    __shared__ float att_s[4][4][512];   // [head][token][d] = 32 KB
    __shared__ float w[144];
    __shared__ float bias[4];
    const int tid = threadIdx.x;
    const int wid = tid >> 6, lane = tid & 63;
    const int b = blockIdx.x;
    if (tid < 144) w[tid] = cw[tid];
    if (tid < 4) bias[tid] = cb[tid];

    const unsigned short* qb = QKV + (size_t)b * 4 * 6144 + wid * 512;
    const unsigned short* kb = qb + 2048;
    const unsigned short* vb = qb + 4096;
    float qr[4][8], kr[4][8];
#pragma unroll
    for (int n = 0; n < 4; n++)
#pragma unroll
        for (int cc = 0; cc < 8; cc++) {
            qr[n][cc] = bf2f(qb[n * 6144 + cc * 64 + lane]);
            kr[n][cc] = bf2f(kb[n * 6144 + cc * 64 + lane]);
        }
    float s[4][4];
#pragma unroll
    for (int n = 0; n < 4; n++)
#pragma unroll
        for (int m = 0; m < 4; m++) {
            float p = 0.f;
#pragma unroll
            for (int cc = 0; cc < 8; cc++) p += qr[n][cc] * kr[m][cc];
#pragma unroll
            for (int off = 32; off > 0; off >>= 1) p += __shfl_xor(p, off, 64);
            s[n][m] = p * 0.04419417382415922f;   // 1/sqrt(512)
        }
    float pm[4][4];
#pragma unroll
    for (int n = 0; n < 4; n++) {
        float mx = fmaxf(fmaxf(s[n][0], s[n][1]), fmaxf(s[n][2], s[n][3]));
        float e0 = expf(s[n][0] - mx), e1 = expf(s[n][1] - mx);
        float e2 = expf(s[n][2] - mx), e3 = expf(s[n][3] - mx);
        float inv = 1.f / (e0 + e1 + e2 + e3);
        pm[n][0] = e0 * inv; pm[n][1] = e1 * inv; pm[n][2] = e2 * inv; pm[n][3] = e3 * inv;
    }
#pragma unroll
    for (int cc = 0; cc < 8; cc++) {
        float v0 = bf2f(vb[0 * 6144 + cc * 64 + lane]);
        float v1 = bf2f(vb[1 * 6144 + cc * 64 + lane]);
        float v2 = bf2f(vb[2 * 6144 + cc * 64 + lane]);
        float v3 = bf2f(vb[3 * 6144 + cc * 64 + lane]);
#pragma unroll
        for (int n = 0; n < 4; n++)
            att_s[wid][n][cc * 64 + lane] = pm[n][0] * v0 + pm[n][1] * v1 + pm[n][2] * v2 + pm[n][3] * v3;
    }
    __syncthreads();

    for (int it = 0; it < 16; it++) {
        int j = it * 256 + tid;
        if (j >= 4080) break;
        int wo = j % 510;
        int r = j / 510;
        int ho = r & 1, co = r >> 1;
        float acc = bias[co];
#pragma unroll
        for (int ci = 0; ci < 4; ci++)
#pragma unroll
            for (int kh = 0; kh < 3; kh++)
#pragma unroll
                for (int kw = 0; kw < 3; kw++)
                    acc += att_s[ci][ho + kh][wo + kw] * w[((co * 4 + ci) * 3 + kh) * 3 + kw];
        c[(size_t)b * 4080 + j] = f2bf(fmaxf(acc, 0.f));
    }
}

// ---------------- host side ----------------
template<typename TA, typename TW>
static inline void launch_gemm64(const TA* A, const TW* W, const float* b, float* C,
                                 int M, int N, int K, bool relu, float* part, hipStream_t s) {
    int gx = (N + 63) / 64, gy = (M + 63) / 64;
    int targetSK = 1024 / (gx * gy);
    if (targetSK < 1) targetSK = 1;
    if (targetSK > 8) targetSK = 8;
    int kchunk = K, SK = 1;
    if (targetSK > 1) {
        kchunk = (((K + targetSK - 1) / targetSK) + 127) & ~127;
        SK = (K + kchunk - 1) / kchunk;
    }
    if (SK <= 1) {
        dim3 g(gx, gy);
        if (relu) gemm64<true, false, TA, TW><<<g, 256, 0, s>>>(A, W, b, C, M, N, K, K);
        else      gemm64<false, false, TA, TW><<<g, 256, 0, s>>>(A, W, b, C, M, N, K, K);
    } else {
        dim3 g(gx, gy, SK);
        gemm64<false, true, TA, TW><<<g, 256, 0, s>>>(A, W, nullptr, part, M, N, K, kchunk);
        int MN = M * N;
        if (relu) reduce_partial<true><<<(MN + 255) / 256, 256, 0, s>>>(part, b, C, MN, N, SK);
        else      reduce_partial<false><<<(MN + 255) / 256, 256, 0, s>>>(part, b, C, MN, N, SK);
    }
}

extern "C" void kernel_launch(void* const* d_in, const int* in_sizes, int n_in,
                              void* d_out, int out_size, void* d_ws, size_t ws_size,
                              hipStream_t stream) {
    const float* x       = (const float*)d_in[0];
    const int*   edge    = (const int*)d_in[1];
    const int*   hedge   = (const int*)d_in[3];
    const float* fp      = (const float*)d_in[4];
    const float* text_em = (const float*)d_in[5];
    const float* fc1_W = (const float*)d_in[7];  const float* fc1_b = (const float*)d_in[8];
    const float* fc2_W = (const float*)d_in[9];  const float* fc2_b = (const float*)d_in[10];
    const float* fc3_W = (const float*)d_in[11]; const float* fc3_b = (const float*)d_in[12];
    const float* fcg1_W = (const float*)d_in[13]; const float* fcg1_b = (const float*)d_in[14];
    const float* fcg2_W = (const float*)d_in[15]; const float* fcg2_b = (const float*)d_in[16];
    const float* fchg1_W = (const float*)d_in[17]; const float* fchg1_b = (const float*)d_in[18];
    const float* fchg2_W = (const float*)d_in[19]; const float* fchg2_b = (const float*)d_in[20];
    const float* gin1_W = (const float*)d_in[21]; const float* gin1_b = (const float*)d_in[22];
    const float* gin2_W = (const float*)d_in[23]; const float* gin2_b = (const float*)d_in[24];
    const float* h3_W = (const float*)d_in[25]; const float* h3_b = (const float*)d_in[26];
    const float* h4_W = (const float*)d_in[27]; const float* h4_b = (const float*)d_in[28];
    const float* Wq = (const float*)d_in[29];
    const float* Wk = (const float*)d_in[30];
    const float* Wv = (const float*)d_in[31];
    const float* conv_W = (const float*)d_in[32]; const float* conv_b = (const float*)d_in[33];
    const float* mlp1_W = (const float*)d_in[34]; const float* mlp1_b = (const float*)d_in[35];
    const float* mlp2_W = (const float*)d_in[36]; const float* mlp2_b = (const float*)d_in[37];

    const int* e_src = edge;
    const int* e_dst = edge + N_EDGES;
    const int* h_nid = hedge;
    const int* h_eid = hedge + N_HNNZ;

    float* ws = (float*)d_ws;
    const size_t ZONE = 51609600;
    // ---- phase A (GIN) ----
    float* xin1 = ws;                               // 4,300,800
    float* xg1  = ws + 4300800;                     // 4,300,800
    float* xin2 = ws + 8601600;                     // 4,300,800
    // ---- phase H (hypergraph) ----
    float* eagg   = ws;                             // 860,160
    float* e1_32  = ws + 860160;                    // 1,720,320
    float* hnode  = ws + 2580480;                   // 8,601,600
    float* hnodet = ws + 11182080;                  // 8,601,600
    float* eagg2  = ws + 19783680;                  // 1,720,320
    float* e2_32  = ws + 21504000;                  // 2,621,440
    float* hn2    = ws + 24125440;                  // 13,107,200 (ends 37,232,640)
    // ---- phase D (attention) ----
    unsigned short* in_t_bf  = (unsigned short*)ws;                 // 2,097,152 us
    unsigned short* qkv_bf   = (unsigned short*)(ws + 2097152);     // 25,165,824 us
    unsigned short* cbuf_bf  = (unsigned short*)(ws + 35651584);    // 4,177,920 us
    float* m1   = ws + 39829504;                                    // 1,048,576
    unsigned short* Wqkv_bf  = (unsigned short*)(ws + 40878080);    // 3,145,728 us
    unsigned short* mlp1W_bf = (unsigned short*)(ws + 42450944);    // 4,177,920 us (ends 44,539,904)
    float* part = ws;                               // split-K scratch (zone-dead windows)
    // ---- CSR region ----
    int* cnt_g = (int*)(ws + 45000000);
    int* off_g = (int*)(ws + 45051200);
    int* pay_g = (int*)(ws + 45102401);
    int* cnt_e = (int*)(ws + 45307201);
    int* off_e = (int*)(ws + 45317441);
    int* pay_e = (int*)(ws + 45327682);
    int* cnt_n = (int*)(ws + 45430082);
    int* off_n = (int*)(ws + 45481282);
    int* pay_n = (int*)(ws + 45532483);             // ends 45,634,883 < ZONE
    // ---- persistent ----
    float* xg_raw = ws + ZONE;
    float* xg_mid = ws + ZONE + 1720320;
    float* hx_raw = ws + ZONE + 2768896;
    float* hx_mid = ws + ZONE + 3293184;
    float* h1     = ws + ZONE + 4341760;
    float* fp_o   = ws + ZONE + 4472832;
    float* tt     = ws + ZONE + 4997120;
    const size_t NEED = (ZONE + 5582848) * sizeof(float);
    if (ws_size < NEED) return;

    float* out_y  = (float*)d_out;
    float* xg_out = out_y + 1024;
    float* hx_out = out_y + 1024 + 1024 * 512;

    // ---------- build 3 CSR structures ----------
    hipMemsetAsync(cnt_g, 0, N_NODES * 4, stream);
    hipMemsetAsync(cnt_e, 0, N_HEDGES * 4, stream);
    hipMemsetAsync(cnt_n, 0, N_NODES * 4, stream);
    histo_i<<<(N_EDGES + 255) / 256, 256, 0, stream>>>(e_dst, cnt_g, N_EDGES);
    histo_i<<<(N_HNNZ + 255) / 256, 256, 0, stream>>>(h_eid, cnt_e, N_HNNZ);
    histo_i<<<(N_HNNZ + 255) / 256, 256, 0, stream>>>(h_nid, cnt_n, N_HNNZ);
    exscan3<<<3, 1024, 0, stream>>>(cnt_g, off_g, N_NODES, cnt_e, off_e, N_HEDGES, cnt_n, off_n, N_NODES);
    hipMemcpyAsync(cnt_g, off_g, N_NODES * 4, hipMemcpyDeviceToDevice, stream);
    hipMemcpyAsync(cnt_e, off_e, N_HEDGES * 4, hipMemcpyDeviceToDevice, stream);
    hipMemcpyAsync(cnt_n, off_n, N_NODES * 4, hipMemcpyDeviceToDevice, stream);
    place_pay<<<(N_EDGES + 255) / 256, 256, 0, stream>>>(e_dst, e_src, cnt_g, pay_g, N_EDGES);
    place_pay<<<(N_HNNZ + 255) / 256, 256, 0, stream>>>(h_eid, h_nid, cnt_e, pay_e, N_HNNZ);
    place_pay<<<(N_HNNZ + 255) / 256, 256, 0, stream>>>(h_nid, h_eid, cnt_n, pay_n, N_HNNZ);

    // ---------- GIN branch ----------
    gather_rows4<true, false><<<(N_NODES * (FXD / 4) + 255) / 256, 256, 0, stream>>>(
        x, off_g, pay_g, x, xin1, N_NODES, FXD / 4);
    launch_gemm64(xin1, gin1_W, gin1_b, xg1, N_NODES, FXD, FXD, true, part, stream);
    gather_rows4<true, false><<<(N_NODES * (FXD / 4) + 255) / 256, 256, 0, stream>>>(
        xg1, off_g, pay_g, xg1, xin2, N_NODES, FXD / 4);
    gin2pool<<<NB, 256, 0, stream>>>(xin2, gin2_W, gin2_b, xg_raw);
    launch_gemm64(xg_raw, fcg1_W, fcg1_b, xg_mid, NB, 1024, 1680, true, part, stream);
    launch_gemm64(xg_mid, fcg2_W, fcg2_b, xg_out, NB, 512, 1024, false, part, stream);

    // ---------- hypergraph branch ----------
    gather_rows4<false, true><<<(N_HEDGES * (FXD / 4) + 255) / 256, 256, 0, stream>>>(
        x, off_e, pay_e, nullptr, eagg, N_HEDGES, FXD / 4);
    launch_gemm64(eagg, h3_W, (const float*)nullptr, e1_32, N_HEDGES, 168, FXD, false, part, stream);
    gather_rows4<false, false><<<(N_NODES * 42 + 255) / 256, 256, 0, stream>>>(
        e1_32, off_n, pay_n, nullptr, hnode, N_NODES, 42);
    transform_dinv_bias<<<(N_NODES * 168 + 255) / 256, 256, 0, stream>>>(
        hnode, off_n, h3_b, hnodet, N_NODES, 168);
    gather_rows4<false, true><<<(N_HEDGES * 42 + 255) / 256, 256, 0, stream>>>(
        hnodet, off_e, pay_e, nullptr, eagg2, N_HEDGES, 42);
    launch_gemm64(eagg2, h4_W, (const float*)nullptr, e2_32, N_HEDGES, 256, 168, false, part, stream);
    gather_rows4<false, false><<<(N_NODES * 64 + 255) / 256, 256, 0, stream>>>(
        e2_32, off_n, pay_n, nullptr, hn2, N_NODES, 64);
    pool_hyper<<<(NB * 256 + 255) / 256, 256, 0, stream>>>(hn2, off_n, h4_b, hx_raw);
    launch_gemm64(hx_raw, fchg1_W, fchg1_b, hx_mid, NB, 1024, 512, true, part, stream);
    launch_gemm64(hx_mid, fchg2_W, fchg2_b, hx_out, NB, 512, 1024, false, part, stream);

    // ---------- fingerprint + text ----------
    launch_gemm64(fp, fc1_W, fc1_b, h1, NB, FP2, FP_DIM, true, part, stream);
    launch_gemm64(h1, fc2_W, fc2_b, fp_o, NB, HID, FP2, false, part, stream);
    launch_gemm64(text_em, fc3_W, fc3_b, tt, NB, HID, 768, false, part, stream);

    // ---------- fusion attention (bf16 pipeline) ----------
    pack_tokens_bf<<<(4096 * 512 + 255) / 256, 256, 0, stream>>>(fp_o, xg_out, hx_out, tt, in_t_bf);
    cvt_qkv_w<<<(6144 * 512 + 255) / 256, 256, 0, stream>>>(Wq, Wk, Wv, Wqkv_bf);
    gemm_bf16<<<dim3(6144 / 128, 4096 / 128), 256, 0, stream>>>(in_t_bf, Wqkv_bf, qkv_bf, 4096, 6144, 512);
    attn_conv<<<NB, 256, 0, stream>>>(qkv_bf, conv_W, conv_b, cbuf_bf);
    cvt_f2b<<<(1024 * 4080 + 255) / 256, 256, 0, stream>>>(mlp1_W, mlp1W_bf, 1024 * 4080);
    launch_gemm64(cbuf_bf, mlp1W_bf, mlp1_b, m1, NB, 1024, 4080, true, part, stream);
    rowdot<<<256, 256, 0, stream>>>(m1, mlp2_W, mlp2_b, out_y, NB, 1024);
}

// Round 12
// 852.062 us; speedup vs baseline: 4.2278x; 1.0325x over previous
//
#include <hip/hip_runtime.h>
#include <hip/hip_bf16.h>

// ---------------- constants ----------------
#define N_NODES 51200
#define N_EDGES 204800
#define N_HNNZ  102400
#define N_HEDGES 10240
#define NB 1024          // batch (graphs)
#define NPG 50           // nodes per graph (51200/1024)
#define FXD 84
#define FP_DIM 2513
#define FP2 128
#define HID 512

typedef __attribute__((ext_vector_type(4))) float f32x4;
typedef __attribute__((ext_vector_type(8))) __bf16 bf16x8;
typedef __attribute__((ext_vector_type(4))) short short4_t;

static __device__ __forceinline__ unsigned short f2bf(float f) {
    unsigned u = __builtin_bit_cast(unsigned, f);
    u += 0x7FFFu + ((u >> 16) & 1u);   // round-to-nearest-even
    return (unsigned short)(u >> 16);
}
static __device__ __forceinline__ float bf2f(unsigned short u) {
    unsigned x = ((unsigned)u) << 16;
    return __builtin_bit_cast(float, x);
}

// bijective XCD-aware remap (m204 formula)
static __device__ __forceinline__ int xcd_swizzle(int orig, int nwg) {
    int q = nwg >> 3, r = nwg & 7;
    int xcd = orig & 7, off = orig >> 3;
    return (xcd < r ? xcd * (q + 1) : r * (q + 1) + (xcd - r) * q) + off;
}

// load 4 f32 as bf16 short4 with K-guards
static __device__ __forceinline__ short4_t ld4bf_f32(const float* p, int gk, int kend, bool kvec) {
    short4_t sv;
    float v0 = 0.f, v1 = 0.f, v2 = 0.f, v3 = 0.f;
    if (kvec && gk + 4 <= kend) {
        float4 f = *(const float4*)p;
        v0 = f.x; v1 = f.y; v2 = f.z; v3 = f.w;
    } else {
        v0 = p[0];
        if (gk + 1 < kend) v1 = p[1];
        if (gk + 2 < kend) v2 = p[2];
        if (gk + 3 < kend) v3 = p[3];
    }
    sv[0] = (short)f2bf(v0); sv[1] = (short)f2bf(v1);
    sv[2] = (short)f2bf(v2); sv[3] = (short)f2bf(v3);
    return sv;
}

// ---------------- CSR build ----------------
__global__ void histo_i(const int* __restrict__ keys, int* __restrict__ cnt, int n) {
    int i = blockIdx.x * 256 + threadIdx.x;
    if (i < n) atomicAdd(&cnt[keys[i]], 1);
}

__global__ __launch_bounds__(1024) void exscan3(const int* __restrict__ c0, int* __restrict__ o0, int B0,
                                                const int* __restrict__ c1, int* __restrict__ o1, int B1,
                                                const int* __restrict__ c2, int* __restrict__ o2, int B2) {
    const int* cnt = blockIdx.x == 0 ? c0 : blockIdx.x == 1 ? c1 : c2;
    int* off = blockIdx.x == 0 ? o0 : blockIdx.x == 1 ? o1 : o2;
    int B = blockIdx.x == 0 ? B0 : blockIdx.x == 1 ? B1 : B2;
    __shared__ int part[1024];
    int t = threadIdx.x;
    int C = (B + 1023) >> 10;
    int s0 = t * C, s1 = min(B, s0 + C);
    int sum = 0;
    for (int i = s0; i < s1; i++) sum += cnt[i];
    part[t] = sum;
    __syncthreads();
    for (int d = 1; d < 1024; d <<= 1) {
        int x = (t >= d) ? part[t - d] : 0;
        __syncthreads();
        part[t] += x;
        __syncthreads();
    }
    int run = (t == 0) ? 0 : part[t - 1];
    for (int i = s0; i < s1; i++) { off[i] = run; run += cnt[i]; }
    if (t == 1023) off[B] = part[1023];
}

__global__ void place_pay(const int* __restrict__ keys, const int* __restrict__ payload,
                          int* __restrict__ cursor, int* __restrict__ pay, int n) {
    int i = blockIdx.x * 256 + threadIdx.x;
    if (i < n) {
        int p = atomicAdd(&cursor[keys[i]], 1);
        pay[p] = payload[i];
    }
}

// ---------------- CSR gather, float4-vectorized (f64 reg accumulation -> replay-stable) ----------------
template<bool SELF, bool SCALE>
__global__ void gather_rows4(const float* __restrict__ src,
                             const int* __restrict__ off, const int* __restrict__ pay,
                             const float* __restrict__ self_src,
                             float* __restrict__ out, int R, int F4) {
    int i = blockIdx.x * 256 + threadIdx.x;
    if (i >= R * F4) return;
    int r = i / F4, f4 = i - r * F4;
    int b = off[r], e = off[r + 1];
    double a0 = 0.0, a1 = 0.0, a2 = 0.0, a3 = 0.0;
    for (int j = b; j < e; j++) {
        float4 v = *((const float4*)(src + (size_t)pay[j] * F4 * 4) + f4);
        a0 += v.x; a1 += v.y; a2 += v.z; a3 += v.w;
    }
    float s0 = (float)a0, s1 = (float)a1, s2 = (float)a2, s3 = (float)a3;
    if (SCALE) {
        float inv = 1.f / fmaxf((float)(e - b), 1.f);
        s0 *= inv; s1 *= inv; s2 *= inv; s3 *= inv;
    }
    if (SELF) {
        float4 sv = *((const float4*)self_src + i);
        s0 += sv.x; s1 += sv.y; s2 += sv.z; s3 += sv.w;
    }
    float4 o = {s0, s1, s2, s3};
    *((float4*)out + i) = o;
}

// ---------------- bf16 GEMM 128x128, BK=64, direct staging ----------------
__global__ __launch_bounds__(256) void gemm_bf16(const unsigned short* __restrict__ A,
                                                 const unsigned short* __restrict__ B,
                                                 unsigned short* __restrict__ C,
                                                 int M, int N, int K) {
    __shared__ __align__(16) char Asm[16384];   // 128 x 64 bf16, swizzled
    __shared__ __align__(16) char Bsm[16384];
    const int tid = threadIdx.x;
    const int nwg = gridDim.x * gridDim.y;
    const int wg = xcd_swizzle(blockIdx.y * gridDim.x + blockIdx.x, nwg);
    const int bm = (wg / gridDim.x) * 128, bn = (wg % gridDim.x) * 128;
    const int wid = tid >> 6, lane = tid & 63;
    const int wm = (wid >> 1) * 64, wn = (wid & 1) * 64;
    const int lr = lane & 15, lg = lane >> 4;

    f32x4 zero = {0.f, 0.f, 0.f, 0.f};
    f32x4 acc[4][4];
#pragma unroll
    for (int i = 0; i < 4; i++)
#pragma unroll
        for (int j = 0; j < 4; j++) acc[i][j] = zero;

    for (int k0 = 0; k0 < K; k0 += 64) {
#pragma unroll
        for (int u = 0; u < 4; u++) {
            int slot = u * 256 + tid;            // 0..1023 16B-chunks
            int row = slot >> 3, ch = slot & 7;
            int off = (row * 128 + ch * 16) ^ ((row & 7) << 4);
            uint4 va = *(const uint4*)(A + (size_t)(bm + row) * K + k0 + ch * 8);
            *(uint4*)(Asm + off) = va;
            uint4 vb = *(const uint4*)(B + (size_t)(bn + row) * K + k0 + ch * 8);
            *(uint4*)(Bsm + off) = vb;
        }
        __syncthreads();
#pragma unroll
        for (int kk = 0; kk < 2; kk++) {
            bf16x8 af[4], bf[4];
#pragma unroll
            for (int m = 0; m < 4; m++) {
                int row = wm + m * 16 + lr;
                af[m] = *(const bf16x8*)(Asm + ((row * 128 + kk * 64 + lg * 16) ^ ((row & 7) << 4)));
            }
#pragma unroll
            for (int n = 0; n < 4; n++) {
                int row = wn + n * 16 + lr;
                bf[n] = *(const bf16x8*)(Bsm + ((row * 128 + kk * 64 + lg * 16) ^ ((row & 7) << 4)));
            }
#pragma unroll
            for (int m = 0; m < 4; m++)
#pragma unroll
                for (int n = 0; n < 4; n++)
                    acc[m][n] = __builtin_amdgcn_mfma_f32_16x16x32_bf16(af[m], bf[n], acc[m][n], 0, 0, 0);
        }
        __syncthreads();
    }
#pragma unroll
    for (int m = 0; m < 4; m++)
#pragma unroll
        for (int n = 0; n < 4; n++) {
            int col = bn + wn + n * 16 + lr;
#pragma unroll
            for (int r = 0; r < 4; r++) {
                int row = bm + wm + m * 16 + lg * 4 + r;
                C[(size_t)row * N + col] = f2bf(acc[m][n][r]);
            }
        }
}

// ---------------- MFMA GEMM 64x64, wave-K-split, reg-prefetch, 32KB LDS, grid.z split-K ----------------
template<bool RELU, bool PARTIAL, typename TA, typename TW>
__global__ __launch_bounds__(256) void gemm64(const TA* __restrict__ A,
                                              const TW* __restrict__ W,
                                              const float* __restrict__ bias,
                                              float* __restrict__ C,
                                              int M, int N, int K, int kchunk) {
    __shared__ __align__(16) char pool[32768];
    char* Ab = pool;
    char* Bb = pool + 16384;
    const int tid = threadIdx.x;
    const int nwg = gridDim.x * gridDim.y;
    const int wg = xcd_swizzle(blockIdx.y * gridDim.x + blockIdx.x, nwg);
    const int bm = (wg / gridDim.x) * 64, bn = (wg % gridDim.x) * 64;
    const int wid = tid >> 6, lane = tid & 63;
    const int lr = lane & 15, lg = lane >> 4;
    const int kbeg = blockIdx.z * kchunk;
    const int kend = min(K, kbeg + kchunk);
    const bool kvec = ((K & 3) == 0);

    f32x4 zero = {0.f, 0.f, 0.f, 0.f};
    f32x4 acc[4][4];
#pragma unroll
    for (int i = 0; i < 4; i++)
#pragma unroll
        for (int j = 0; j < 4; j++) acc[i][j] = zero;

    uint4 ra16[4], rb16[4];
    short4_t ra4[8], rb4[8];

    auto load_A = [&](int kc2) {
        if constexpr (sizeof(TA) == 2) {
#pragma unroll
            for (int u = 0; u < 4; u++) {
                int s = u * 256 + tid;
                int row = s >> 4, k8 = (s & 15) << 3;
                int gk = kc2 + k8, gm = bm + row;
                uint4 v = {0u, 0u, 0u, 0u};
                if (gm < M && gk + 8 <= kend) {
                    v = *(const uint4*)((const unsigned short*)A + (size_t)gm * K + gk);
                } else if (gm < M && gk < kend) {
                    unsigned short tmp[8];
#pragma unroll
                    for (int e = 0; e < 8; e++)
                        tmp[e] = (gk + e < kend) ? ((const unsigned short*)A)[(size_t)gm * K + gk + e] : 0;
                    v = *(const uint4*)tmp;
                }
                ra16[u] = v;
            }
        } else {
#pragma unroll
            for (int u = 0; u < 8; u++) {
                int s = u * 256 + tid;
                int row = s >> 5, kq = (s & 31) << 2;
                int gk = kc2 + kq, gm = bm + row;
                short4_t sv = {0, 0, 0, 0};
                if (gm < M && gk < kend)
                    sv = ld4bf_f32((const float*)A + (size_t)gm * K + gk, gk, kend, kvec);
                ra4[u] = sv;
            }
        }
    };
    auto load_B = [&](int kc2) {
        if constexpr (sizeof(TW) == 2) {
#pragma unroll
            for (int u = 0; u < 4; u++) {
                int s = u * 256 + tid;
                int row = s >> 4, k8 = (s & 15) << 3;
                int gk = kc2 + k8, gn = bn + row;
                uint4 v = {0u, 0u, 0u, 0u};
                if (gn < N && gk + 8 <= kend) {
                    v = *(const uint4*)((const unsigned short*)W + (size_t)gn * K + gk);
                } else if (gn < N && gk < kend) {
                    unsigned short tmp[8];
#pragma unroll
                    for (int e = 0; e < 8; e++)
                        tmp[e] = (gk + e < kend) ? ((const unsigned short*)W)[(size_t)gn * K + gk + e] : 0;
                    v = *(const uint4*)tmp;
                }
                rb16[u] = v;
            }
        } else {
#pragma unroll
            for (int u = 0; u < 8; u++) {
                int s = u * 256 + tid;
                int row = s >> 5, kq = (s & 31) << 2;
                int gk = kc2 + kq, gn = bn + row;
                short4_t sv = {0, 0, 0, 0};
                if (gn < N && gk < kend)
                    sv = ld4bf_f32((const float*)W + (size_t)gn * K + gk, gk, kend, kvec);
                rb4[u] = sv;
            }
        }
    };
    auto write_A = [&]() {
        if constexpr (sizeof(TA) == 2) {
#pragma unroll
            for (int u = 0; u < 4; u++) {
                int s = u * 256 + tid;
                int row = s >> 4, k8 = (s & 15) << 3;
                int off = (row * 256 + k8 * 2) ^ ((row & 7) << 4);
                *(uint4*)(Ab + off) = ra16[u];
            }
        } else {
#pragma unroll
            for (int u = 0; u < 8; u++) {
                int s = u * 256 + tid;
                int row = s >> 5, kq = (s & 31) << 2;
                int off = (row * 256 + kq * 2) ^ ((row & 7) << 4);
                *(short4_t*)(Ab + off) = ra4[u];
            }
        }
    };
    auto write_B = [&]() {
        if constexpr (sizeof(TW) == 2) {
#pragma unroll
            for (int u = 0; u < 4; u++) {
                int s = u * 256 + tid;
                int row = s >> 4, k8 = (s & 15) << 3;
                int off = (row * 256 + k8 * 2) ^ ((row & 7) << 4);
                *(uint4*)(Bb + off) = rb16[u];
            }
        } else {
#pragma unroll
            for (int u = 0; u < 8; u++) {
                int s = u * 256 + tid;
                int row = s >> 5, kq = (s & 31) << 2;
                int off = (row * 256 + kq * 2) ^ ((row & 7) << 4);
                *(short4_t*)(Bb + off) = rb4[u];
            }
        }
    };

    load_A(kbeg);
    load_B(kbeg);
    for (int kc = kbeg; kc < kend; kc += 128) {
        write_A();
        write_B();
        __syncthreads();
        if (kc + 128 < kend) { load_A(kc + 128); load_B(kc + 128); }

        bf16x8 af[4], bf[4];
        const int kb = wid * 64 + lg * 16;
#pragma unroll
        for (int m = 0; m < 4; m++) {
            int row = m * 16 + lr;
            af[m] = *(const bf16x8*)(Ab + ((row * 256 + kb) ^ ((row & 7) << 4)));
        }
#pragma unroll
        for (int n = 0; n < 4; n++) {
            int row = n * 16 + lr;
            bf[n] = *(const bf16x8*)(Bb + ((row * 256 + kb) ^ ((row & 7) << 4)));
        }
#pragma unroll
        for (int m = 0; m < 4; m++)
#pragma unroll
            for (int n = 0; n < 4; n++)
                acc[m][n] = __builtin_amdgcn_mfma_f32_16x16x32_bf16(af[m], bf[n], acc[m][n], 0, 0, 0);
        __syncthreads();
    }

    float* redA = (float*)pool;
    float* redB = (float*)(pool + 16384);
    if (wid < 2) {
        float* r = (wid == 0) ? redA : redB;
#pragma unroll
        for (int m = 0; m < 4; m++)
#pragma unroll
            for (int n = 0; n < 4; n++)
#pragma unroll
                for (int r4 = 0; r4 < 4; r4++)
                    r[(m * 16 + lg * 4 + r4) * 64 + n * 16 + lr] = acc[m][n][r4];
    }
    __syncthreads();
    if (wid >= 2) {
        float* r = (wid == 2) ? redA : redB;
#pragma unroll
        for (int m = 0; m < 4; m++)
#pragma unroll
            for (int n = 0; n < 4; n++)
#pragma unroll
                for (int r4 = 0; r4 < 4; r4++)
                    r[(m * 16 + lg * 4 + r4) * 64 + n * 16 + lr] += acc[m][n][r4];
    }
    __syncthreads();
#pragma unroll
    for (int u = 0; u < 16; u++) {
        int idx = u * 256 + tid;
        int row = idx >> 6, col = idx & 63;
        int gm = bm + row, gn = bn + col;
        if (gm >= M || gn >= N) continue;
        float s = redA[idx] + redB[idx];
        if (PARTIAL) {
            C[(size_t)blockIdx.z * M * N + (size_t)gm * N + gn] = s;
        } else {
            s += bias ? bias[gn] : 0.f;
            if (RELU) s = fmaxf(s, 0.f);
            C[(size_t)gm * N + gn] = s;
        }
    }
}

template<bool RELU>
__global__ void reduce_partial(const float* __restrict__ part, const float* __restrict__ bias,
                               float* __restrict__ C, int MN, int N, int SK) {
    int i = blockIdx.x * 256 + threadIdx.x;
    if (i >= MN) return;
    float s = 0.f;
    for (int z = 0; z < SK; z++) s += part[(size_t)z * MN + i];
    s += bias ? bias[i % N] : 0.f;
    if (RELU) s = fmaxf(s, 0.f);
    C[i] = s;
}

// ---------------- cvt gin2_W [840][84] f32 -> [840][96] bf16 (zero-padded K) ----------------
__global__ void cvt_gin2w(const float* __restrict__ W, unsigned short* __restrict__ Wb) {
    int i = blockIdx.x * 256 + threadIdx.x;
    if (i >= 840 * 96) return;
    int r = i / 96, k = i - r * 96;
    Wb[i] = (k < 84) ? f2bf(W[r * 84 + k]) : (unsigned short)0;
}

// ---------------- fused GIN2 GEMM + bias + relu + 50-row max/mean pool ----------------
// B fragments now single 16B loads from pre-converted bf16 W [840][96].
__global__ __launch_bounds__(256) void gin2pool(const float* __restrict__ xin2,
                                                const unsigned short* __restrict__ Wbf,
                                                const float* __restrict__ bias,
                                                float* __restrict__ out) {
    __shared__ __align__(16) char Ab[16384];
    const int tid = threadIdx.x;
    const int g = blockIdx.x;
    const int wid = tid >> 6, lane = tid & 63;
    const int lr = lane & 15, lg = lane >> 4;
    const int K = FXD;
    const int N = 840;

#pragma unroll
    for (int u = 0; u < 8; u++) {
        int s = u * 256 + tid;
        int row = s >> 5, kq = (s & 31) << 2;
        int off = (row * 256 + (s & 31) * 8) ^ ((row & 7) << 4);
        float v0 = 0.f, v1 = 0.f, v2 = 0.f, v3 = 0.f;
        if (row < NPG && kq < K) {
            float4 f = *(const float4*)(xin2 + ((size_t)g * NPG + row) * K + kq);
            v0 = f.x; v1 = f.y; v2 = f.z; v3 = f.w;
        }
        short4_t sv;
        sv[0] = (short)f2bf(v0); sv[1] = (short)f2bf(v1);
        sv[2] = (short)f2bf(v2); sv[3] = (short)f2bf(v3);
        *(short4_t*)(Ab + off) = sv;
    }
    __syncthreads();

    bf16x8 af[4][3];
#pragma unroll
    for (int m = 0; m < 4; m++)
#pragma unroll
        for (int kk = 0; kk < 3; kk++) {
            int row = m * 16 + lr;
            af[m][kk] = *(const bf16x8*)(Ab + ((row * 256 + kk * 64 + lg * 16) ^ ((row & 7) << 4)));
        }

    for (int t = 0; t < 14; t++) {
        const int n0 = t * 64 + wid * 16;
        const int wrow = n0 + lr;
        bf16x8 bf[3];
#pragma unroll
        for (int kk = 0; kk < 3; kk++) {
            int k0 = kk * 32 + lg * 8;
            uint4 raw = {0u, 0u, 0u, 0u};
            if (wrow < N) raw = *(const uint4*)(Wbf + (size_t)wrow * 96 + k0);
            bf[kk] = __builtin_bit_cast(bf16x8, raw);
        }
        f32x4 zero = {0.f, 0.f, 0.f, 0.f};
        f32x4 acc[4] = {zero, zero, zero, zero};
#pragma unroll
        for (int m = 0; m < 4; m++)
#pragma unroll
            for (int kk = 0; kk < 3; kk++)
                acc[m] = __builtin_amdgcn_mfma_f32_16x16x32_bf16(af[m][kk], bf[kk], acc[m], 0, 0, 0);

        const int c = n0 + lr;
        float bv = (c < N) ? bias[c] : 0.f;
        float mx = -1e30f, sm = 0.f;
#pragma unroll
        for (int m = 0; m < 4; m++)
#pragma unroll
            for (int r = 0; r < 4; r++) {
                int row = m * 16 + lg * 4 + r;
                if (row < NPG) {
                    float v = fmaxf(acc[m][r] + bv, 0.f);
                    mx = fmaxf(mx, v);
                    sm += v;
                }
            }
        mx = fmaxf(mx, __shfl_xor(mx, 16, 64));
        sm += __shfl_xor(sm, 16, 64);
        mx = fmaxf(mx, __shfl_xor(mx, 32, 64));
        sm += __shfl_xor(sm, 32, 64);
        if (lg == 0 && c < N) {
            out[(size_t)g * 1680 + c] = mx;
            out[(size_t)g * 1680 + 840 + c] = sm * (1.f / NPG);
        }
    }
}

// ---------------- N=1 GEMM ----------------
__global__ __launch_bounds__(256) void rowdot(const float* __restrict__ A,
                                              const float* __restrict__ w,
                                              const float* __restrict__ b,
                                              float* __restrict__ out, int Mrows, int K) {
    int row = blockIdx.x * 4 + (threadIdx.x >> 6);
    int lane = threadIdx.x & 63;
    if (row >= Mrows) return;
    float s = 0.f;
    for (int k = lane; k < K; k += 64) s += A[(size_t)row * K + k] * w[k];
#pragma unroll
    for (int off = 32; off > 0; off >>= 1) s += __shfl_xor(s, off, 64);
    if (lane == 0) out[row] = s + b[0];
}

// ---------------- hnode transform: h*Dinv + bias ----------------
__global__ void transform_dinv_bias(const float* __restrict__ h, const int* __restrict__ off_n,
                                    const float* __restrict__ b, float* __restrict__ o, int R, int F) {
    int i = blockIdx.x * 256 + threadIdx.x;
    if (i >= R * F) return;
    int r = i / F, f = i - r * F;
    int d = off_n[r + 1] - off_n[r];
    float inv = d > 0 ? 1.f / d : 0.f;
    o[i] = h[i] * inv + b[f];
}

// ---------------- fused hyper Dinv+bias + 50-row max/mean pool ----------------
__global__ void pool_hyper(const float* __restrict__ hn, const int* __restrict__ off_n,
                           const float* __restrict__ b, float* __restrict__ out) {
    int i = blockIdx.x * 256 + threadIdx.x;
    if (i >= NB * 256) return;
    int o = i & 255, g = i >> 8;
    float bo = b[o];
    const float* base = hn + (size_t)g * NPG * 256 + o;
    float mx = -1e30f, sm = 0.f;
    for (int n = 0; n < NPG; n++) {
        int node = g * NPG + n;
        int d = off_n[node + 1] - off_n[node];
        float inv = d > 0 ? 1.f / d : 0.f;
        float v = base[(size_t)n * 256] * inv + bo;
        mx = fmaxf(mx, v);
        sm += v;
    }
    out[(size_t)g * 512 + o] = mx;
    out[(size_t)g * 512 + 256 + o] = sm * (1.f / NPG);
}

// ---------------- pack fusion tokens -> bf16 ----------------
__global__ void pack_tokens_bf(const float* __restrict__ fp_o, const float* __restrict__ xg,
                               const float* __restrict__ hxg, const float* __restrict__ t,
                               unsigned short* __restrict__ in_t) {
    int i = blockIdx.x * 256 + threadIdx.x;
    if (i >= 4096 * 512) return;
    int d = i & 511;
    int row = i >> 9;
    int tok = row & 3, b = row >> 2;
    const float* s = (tok == 0) ? fp_o : (tok == 1) ? xg : (tok == 2) ? hxg : t;
    in_t[i] = f2bf(s[b * 512 + d]);
}

// ---------------- concat + cvt Wq|Wk|Wv -> bf16 [6144][512] ----------------
__global__ void cvt_qkv_w(const float* __restrict__ Wq, const float* __restrict__ Wk,
                          const float* __restrict__ Wv, unsigned short* __restrict__ Wb) {
    int i = blockIdx.x * 256 + threadIdx.x;
    if (i >= 6144 * 512) return;
    int n = i >> 9;
    const float* src = (n < 2048) ? Wq : (n < 4096) ? Wk : Wv;
    int nn = (n < 2048) ? n : (n < 4096) ? n - 2048 : n - 4096;
    Wb[i] = f2bf(src[(size_t)nn * 512 + (i & 511)]);
}

// ---------------- generic f32 -> bf16 ----------------
__global__ void cvt_f2b(const float* __restrict__ in, unsigned short* __restrict__ out, int n) {
    int i = blockIdx.x * 256 + threadIdx.x;
    if (i < n) out[i] = f2bf(in[i]);
}

// ---------------- fused attention + conv3x3 + relu: one block per batch b ----------------
__global__ __launch_bounds__(256) void attn_conv(const unsigned short* __restrict__ QKV,
                                                 const float* __restrict__ cw,
                                                 const float* __restrict__ cb,
                                                 unsigned short* __restrict__ c) {
    __shared__ float att_s[4][4][512];   // [head][token][d] = 32 KB
    __shared__ float w[144];
    __shared__ float bias[4];
    const int tid = threadIdx.x;
    const int wid = tid >> 6, lane = tid & 63;
    const int b = blockIdx.x;
    if (tid < 144) w[tid] = cw[tid];
    if (tid < 4) bias[tid] = cb[tid];

    const unsigned short* qb = QKV + (size_t)b * 4 * 6144 + wid * 512;
    const unsigned short* kb = qb + 2048;
    const unsigned short* vb = qb + 4096;
    float qr[4][8], kr[4][8];
#pragma unroll
    for (int n = 0; n < 4; n++)
#pragma unroll
        for (int cc = 0; cc < 8; cc++) {
            qr[n][cc] = bf2f(qb[n * 6144 + cc * 64 + lane]);
            kr[n][cc] = bf2f(kb[n * 6144 + cc * 64 + lane]);
        }
    float s[4][4];
#pragma unroll
    for (int n = 0; n < 4; n++)
#pragma unroll
        for (int m = 0; m < 4; m++) {
            float p = 0.f;
#pragma unroll
            for (int cc = 0; cc < 8; cc++) p += qr[n][cc] * kr[m][cc];
#pragma unroll
            for (int off = 32; off > 0; off >>= 1) p += __shfl_xor(p, off, 64);
            s[n][m] = p * 0.04419417382415922f;   // 1/sqrt(512)
        }
    float pm[4][4];
#pragma unroll
    for (int n = 0; n < 4; n++) {
        float mx = fmaxf(fmaxf(s[n][0], s[n][1]), fmaxf(s[n][2], s[n][3]));
        float e0 = expf(s[n][0] - mx), e1 = expf(s[n][1] - mx);
        float e2 = expf(s[n][2] - mx), e3 = expf(s[n][3] - mx);
        float inv = 1.f / (e0 + e1 + e2 + e3);
        pm[n][0] = e0 * inv; pm[n][1] = e1 * inv; pm[n][2] = e2 * inv; pm[n][3] = e3 * inv;
    }
#pragma unroll
    for (int cc = 0; cc < 8; cc++) {
        float v0 = bf2f(vb[0 * 6144 + cc * 64 + lane]);
        float v1 = bf2f(vb[1 * 6144 + cc * 64 + lane]);
        float v2 = bf2f(vb[2 * 6144 + cc * 64 + lane]);
        float v3 = bf2f(vb[3 * 6144 + cc * 64 + lane]);
#pragma unroll
        for (int n = 0; n < 4; n++)
            att_s[wid][n][cc * 64 + lane] = pm[n][0] * v0 + pm[n][1] * v1 + pm[n][2] * v2 + pm[n][3] * v3;
    }
    __syncthreads();

    for (int it = 0; it < 16; it++) {
        int j = it * 256 + tid;
        if (j >= 4080) break;
        int wo = j % 510;
        int r = j / 510;
        int ho = r & 1, co = r >> 1;
        float acc = bias[co];
#pragma unroll
        for (int ci = 0; ci < 4; ci++)
#pragma unroll
            for (int kh = 0; kh < 3; kh++)
#pragma unroll
                for (int kw = 0; kw < 3; kw++)
                    acc += att_s[ci][ho + kh][wo + kw] * w[((co * 4 + ci) * 3 + kh) * 3 + kw];
        c[(size_t)b * 4080 + j] = f2bf(fmaxf(acc, 0.f));
    }
}

// ---------------- host side ----------------
template<typename TA, typename TW>
static inline void launch_gemm64(const TA* A, const TW* W, const float* b, float* C,
                                 int M, int N, int K, bool relu, float* part, hipStream_t s) {
    int gx = (N + 63) / 64, gy = (M + 63) / 64;
    int targetSK = 2048 / (gx * gy);
    if (targetSK < 1) targetSK = 1;
    if (targetSK > 8) targetSK = 8;
    int kchunk = K, SK = 1;
    if (targetSK > 1) {
        kchunk = (((K + targetSK - 1) / targetSK) + 127) & ~127;
        SK = (K + kchunk - 1) / kchunk;
    }
    if (SK <= 1) {
        dim3 g(gx, gy);
        if (relu) gemm64<true, false, TA, TW><<<g, 256, 0, s>>>(A, W, b, C, M, N, K, K);
        else      gemm64<false, false, TA, TW><<<g, 256, 0, s>>>(A, W, b, C, M, N, K, K);
    } else {
        dim3 g(gx, gy, SK);
        gemm64<false, true, TA, TW><<<g, 256, 0, s>>>(A, W, nullptr, part, M, N, K, kchunk);
        int MN = M * N;
        if (relu) reduce_partial<true><<<(MN + 255) / 256, 256, 0, s>>>(part, b, C, MN, N, SK);
        else      reduce_partial<false><<<(MN + 255) / 256, 256, 0, s>>>(part, b, C, MN, N, SK);
    }
}

extern "C" void kernel_launch(void* const* d_in, const int* in_sizes, int n_in,
                              void* d_out, int out_size, void* d_ws, size_t ws_size,
                              hipStream_t stream) {
    const float* x       = (const float*)d_in[0];
    const int*   edge    = (const int*)d_in[1];
    const int*   hedge   = (const int*)d_in[3];
    const float* fp      = (const float*)d_in[4];
    const float* text_em = (const float*)d_in[5];
    const float* fc1_W = (const float*)d_in[7];  const float* fc1_b = (const float*)d_in[8];
    const float* fc2_W = (const float*)d_in[9];  const float* fc2_b = (const float*)d_in[10];
    const float* fc3_W = (const float*)d_in[11]; const float* fc3_b = (const float*)d_in[12];
    const float* fcg1_W = (const float*)d_in[13]; const float* fcg1_b = (const float*)d_in[14];
    const float* fcg2_W = (const float*)d_in[15]; const float* fcg2_b = (const float*)d_in[16];
    const float* fchg1_W = (const float*)d_in[17]; const float* fchg1_b = (const float*)d_in[18];
    const float* fchg2_W = (const float*)d_in[19]; const float* fchg2_b = (const float*)d_in[20];
    const float* gin1_W = (const float*)d_in[21]; const float* gin1_b = (const float*)d_in[22];
    const float* gin2_W = (const float*)d_in[23]; const float* gin2_b = (const float*)d_in[24];
    const float* h3_W = (const float*)d_in[25]; const float* h3_b = (const float*)d_in[26];
    const float* h4_W = (const float*)d_in[27]; const float* h4_b = (const float*)d_in[28];
    const float* Wq = (const float*)d_in[29];
    const float* Wk = (const float*)d_in[30];
    const float* Wv = (const float*)d_in[31];
    const float* conv_W = (const float*)d_in[32]; const float* conv_b = (const float*)d_in[33];
    const float* mlp1_W = (const float*)d_in[34]; const float* mlp1_b = (const float*)d_in[35];
    const float* mlp2_W = (const float*)d_in[36]; const float* mlp2_b = (const float*)d_in[37];

    const int* e_src = edge;
    const int* e_dst = edge + N_EDGES;
    const int* h_nid = hedge;
    const int* h_eid = hedge + N_HNNZ;

    float* ws = (float*)d_ws;
    const size_t ZONE = 51609600;
    // ---- phase A (GIN) ----
    float* xin1 = ws;                               // 4,300,800
    float* xg1  = ws + 4300800;                     // 4,300,800
    float* xin2 = ws + 8601600;                     // 4,300,800
    // ---- phase H (hypergraph) ----
    float* eagg   = ws;                             // 860,160
    float* e1_32  = ws + 860160;                    // 1,720,320
    float* hnode  = ws + 2580480;                   // 8,601,600
    float* hnodet = ws + 11182080;                  // 8,601,600
    float* eagg2  = ws + 19783680;                  // 1,720,320
    float* e2_32  = ws + 21504000;                  // 2,621,440
    float* hn2    = ws + 24125440;                  // 13,107,200 (ends 37,232,640)
    // ---- phase D (attention) ----
    unsigned short* in_t_bf  = (unsigned short*)ws;                 // 2,097,152 us
    unsigned short* qkv_bf   = (unsigned short*)(ws + 2097152);     // 25,165,824 us
    unsigned short* cbuf_bf  = (unsigned short*)(ws + 35651584);    // 4,177,920 us
    float* m1   = ws + 39829504;                                    // 1,048,576
    unsigned short* Wqkv_bf  = (unsigned short*)(ws + 40878080);    // 3,145,728 us
    unsigned short* mlp1W_bf = (unsigned short*)(ws + 42450944);    // 4,177,920 us (ends 44,539,904)
    float* part = ws;                               // split-K scratch (zone-dead windows)
    // ---- CSR region ----
    int* cnt_g = (int*)(ws + 45000000);
    int* off_g = (int*)(ws + 45051200);
    int* pay_g = (int*)(ws + 45102401);
    int* cnt_e = (int*)(ws + 45307201);
    int* off_e = (int*)(ws + 45317441);
    int* pay_e = (int*)(ws + 45327682);
    int* cnt_n = (int*)(ws + 45430082);
    int* off_n = (int*)(ws + 45481282);
    int* pay_n = (int*)(ws + 45532483);             // ends 45,634,883
    unsigned short* gin2Wbf = (unsigned short*)(ws + 45700000);     // 80,640 us (< ZONE)
    // ---- persistent ----
    float* xg_raw = ws + ZONE;
    float* xg_mid = ws + ZONE + 1720320;
    float* hx_raw = ws + ZONE + 2768896;
    float* hx_mid = ws + ZONE + 3293184;
    float* h1     = ws + ZONE + 4341760;
    float* fp_o   = ws + ZONE + 4472832;
    float* tt     = ws + ZONE + 4997120;
    const size_t NEED = (ZONE + 5582848) * sizeof(float);
    if (ws_size < NEED) return;

    float* out_y  = (float*)d_out;
    float* xg_out = out_y + 1024;
    float* hx_out = out_y + 1024 + 1024 * 512;

    // ---------- build 3 CSR structures ----------
    hipMemsetAsync(cnt_g, 0, N_NODES * 4, stream);
    hipMemsetAsync(cnt_e, 0, N_HEDGES * 4, stream);
    hipMemsetAsync(cnt_n, 0, N_NODES * 4, stream);
    histo_i<<<(N_EDGES + 255) / 256, 256, 0, stream>>>(e_dst, cnt_g, N_EDGES);
    histo_i<<<(N_HNNZ + 255) / 256, 256, 0, stream>>>(h_eid, cnt_e, N_HNNZ);
    histo_i<<<(N_HNNZ + 255) / 256, 256, 0, stream>>>(h_nid, cnt_n, N_HNNZ);
    exscan3<<<3, 1024, 0, stream>>>(cnt_g, off_g, N_NODES, cnt_e, off_e, N_HEDGES, cnt_n, off_n, N_NODES);
    hipMemcpyAsync(cnt_g, off_g, N_NODES * 4, hipMemcpyDeviceToDevice, stream);
    hipMemcpyAsync(cnt_e, off_e, N_HEDGES * 4, hipMemcpyDeviceToDevice, stream);
    hipMemcpyAsync(cnt_n, off_n, N_NODES * 4, hipMemcpyDeviceToDevice, stream);
    place_pay<<<(N_EDGES + 255) / 256, 256, 0, stream>>>(e_dst, e_src, cnt_g, pay_g, N_EDGES);
    place_pay<<<(N_HNNZ + 255) / 256, 256, 0, stream>>>(h_eid, h_nid, cnt_e, pay_e, N_HNNZ);
    place_pay<<<(N_HNNZ + 255) / 256, 256, 0, stream>>>(h_nid, h_eid, cnt_n, pay_n, N_HNNZ);
    cvt_gin2w<<<(840 * 96 + 255) / 256, 256, 0, stream>>>(gin2_W, gin2Wbf);

    // ---------- GIN branch ----------
    gather_rows4<true, false><<<(N_NODES * (FXD / 4) + 255) / 256, 256, 0, stream>>>(
        x, off_g, pay_g, x, xin1, N_NODES, FXD / 4);
    launch_gemm64(xin1, gin1_W, gin1_b, xg1, N_NODES, FXD, FXD, true, part, stream);
    gather_rows4<true, false><<<(N_NODES * (FXD / 4) + 255) / 256, 256, 0, stream>>>(
        xg1, off_g, pay_g, xg1, xin2, N_NODES, FXD / 4);
    gin2pool<<<NB, 256, 0, stream>>>(xin2, gin2Wbf, gin2_b, xg_raw);
    launch_gemm64(xg_raw, fcg1_W, fcg1_b, xg_mid, NB, 1024, 1680, true, part, stream);
    launch_gemm64(xg_mid, fcg2_W, fcg2_b, xg_out, NB, 512, 1024, false, part, stream);

    // ---------- hypergraph branch ----------
    gather_rows4<false, true><<<(N_HEDGES * (FXD / 4) + 255) / 256, 256, 0, stream>>>(
        x, off_e, pay_e, nullptr, eagg, N_HEDGES, FXD / 4);
    launch_gemm64(eagg, h3_W, (const float*)nullptr, e1_32, N_HEDGES, 168, FXD, false, part, stream);
    gather_rows4<false, false><<<(N_NODES * 42 + 255) / 256, 256, 0, stream>>>(
        e1_32, off_n, pay_n, nullptr, hnode, N_NODES, 42);
    transform_dinv_bias<<<(N_NODES * 168 + 255) / 256, 256, 0, stream>>>(
        hnode, off_n, h3_b, hnodet, N_NODES, 168);
    gather_rows4<false, true><<<(N_HEDGES * 42 + 255) / 256, 256, 0, stream>>>(
        hnodet, off_e, pay_e, nullptr, eagg2, N_HEDGES, 42);
    launch_gemm64(eagg2, h4_W, (const float*)nullptr, e2_32, N_HEDGES, 256, 168, false, part, stream);
    gather_rows4<false, false><<<(N_NODES * 64 + 255) / 256, 256, 0, stream>>>(
        e2_32, off_n, pay_n, nullptr, hn2, N_NODES, 64);
    pool_hyper<<<(NB * 256 + 255) / 256, 256, 0, stream>>>(hn2, off_n, h4_b, hx_raw);
    launch_gemm64(hx_raw, fchg1_W, fchg1_b, hx_mid, NB, 1024, 512, true, part, stream);
    launch_gemm64(hx_mid, fchg2_W, fchg2_b, hx_out, NB, 512, 1024, false, part, stream);

    // ---------- fingerprint + text ----------
    launch_gemm64(fp, fc1_W, fc1_b, h1, NB, FP2, FP_DIM, true, part, stream);
    launch_gemm64(h1, fc2_W, fc2_b, fp_o, NB, HID, FP2, false, part, stream);
    launch_gemm64(text_em, fc3_W, fc3_b, tt, NB, HID, 768, false, part, stream);

    // ---------- fusion attention (bf16 pipeline) ----------
    pack_tokens_bf<<<(4096 * 512 + 255) / 256, 256, 0, stream>>>(fp_o, xg_out, hx_out, tt, in_t_bf);
    cvt_qkv_w<<<(6144 * 512 + 255) / 256, 256, 0, stream>>>(Wq, Wk, Wv, Wqkv_bf);
    gemm_bf16<<<dim3(6144 / 128, 4096 / 128), 256, 0, stream>>>(in_t_bf, Wqkv_bf, qkv_bf, 4096, 6144, 512);
    attn_conv<<<NB, 256, 0, stream>>>(qkv_bf, conv_W, conv_b, cbuf_bf);
    cvt_f2b<<<(1024 * 4080 + 255) / 256, 256, 0, stream>>>(mlp1_W, mlp1W_bf, 1024 * 4080);
    launch_gemm64(cbuf_bf, mlp1W_bf, mlp1_b, m1, NB, 1024, 4080, true, part, stream);
    rowdot<<<256, 256, 0, stream>>>(m1, mlp2_W, mlp2_b, out_y, NB, 1024);
}

// Round 13
// 824.503 us; speedup vs baseline: 4.3692x; 1.0334x over previous
//
#include <hip/hip_runtime.h>
#include <hip/hip_bf16.h>

// ---------------- constants ----------------
#define N_NODES 51200
#define N_EDGES 204800
#define N_HNNZ  102400
#define N_HEDGES 10240
#define NB 1024          // batch (graphs)
#define NPG 50           // nodes per graph (51200/1024)
#define FXD 84
#define FP_DIM 2513
#define FP2 128
#define HID 512

typedef __attribute__((ext_vector_type(4))) float f32x4;
typedef __attribute__((ext_vector_type(8))) __bf16 bf16x8;
typedef __attribute__((ext_vector_type(4))) short short4_t;

static __device__ __forceinline__ unsigned short f2bf(float f) {
    unsigned u = __builtin_bit_cast(unsigned, f);
    u += 0x7FFFu + ((u >> 16) & 1u);   // round-to-nearest-even
    return (unsigned short)(u >> 16);
}
static __device__ __forceinline__ float bf2f(unsigned short u) {
    unsigned x = ((unsigned)u) << 16;
    return __builtin_bit_cast(float, x);
}

// bijective XCD-aware remap (m204 formula)
static __device__ __forceinline__ int xcd_swizzle(int orig, int nwg) {
    int q = nwg >> 3, r = nwg & 7;
    int xcd = orig & 7, off = orig >> 3;
    return (xcd < r ? xcd * (q + 1) : r * (q + 1) + (xcd - r) * q) + off;
}

// load 4 f32 as bf16 short4 with K-guards
static __device__ __forceinline__ short4_t ld4bf_f32(const float* p, int gk, int kend, bool kvec) {
    short4_t sv;
    float v0 = 0.f, v1 = 0.f, v2 = 0.f, v3 = 0.f;
    if (kvec && gk + 4 <= kend) {
        float4 f = *(const float4*)p;
        v0 = f.x; v1 = f.y; v2 = f.z; v3 = f.w;
    } else {
        v0 = p[0];
        if (gk + 1 < kend) v1 = p[1];
        if (gk + 2 < kend) v2 = p[2];
        if (gk + 3 < kend) v3 = p[3];
    }
    sv[0] = (short)f2bf(v0); sv[1] = (short)f2bf(v1);
    sv[2] = (short)f2bf(v2); sv[3] = (short)f2bf(v3);
    return sv;
}

// ---------------- CSR build ----------------
__global__ void histo_i(const int* __restrict__ keys, int* __restrict__ cnt, int n) {
    int i = blockIdx.x * 256 + threadIdx.x;
    if (i < n) atomicAdd(&cnt[keys[i]], 1);
}

__global__ __launch_bounds__(1024) void exscan3(const int* __restrict__ c0, int* __restrict__ o0, int B0,
                                                const int* __restrict__ c1, int* __restrict__ o1, int B1,
                                                const int* __restrict__ c2, int* __restrict__ o2, int B2) {
    const int* cnt = blockIdx.x == 0 ? c0 : blockIdx.x == 1 ? c1 : c2;
    int* off = blockIdx.x == 0 ? o0 : blockIdx.x == 1 ? o1 : o2;
    int B = blockIdx.x == 0 ? B0 : blockIdx.x == 1 ? B1 : B2;
    __shared__ int part[1024];
    int t = threadIdx.x;
    int C = (B + 1023) >> 10;
    int s0 = t * C, s1 = min(B, s0 + C);
    int sum = 0;
    for (int i = s0; i < s1; i++) sum += cnt[i];
    part[t] = sum;
    __syncthreads();
    for (int d = 1; d < 1024; d <<= 1) {
        int x = (t >= d) ? part[t - d] : 0;
        __syncthreads();
        part[t] += x;
        __syncthreads();
    }
    int run = (t == 0) ? 0 : part[t - 1];
    for (int i = s0; i < s1; i++) { off[i] = run; run += cnt[i]; }
    if (t == 1023) off[B] = part[1023];
}

__global__ void place_pay(const int* __restrict__ keys, const int* __restrict__ payload,
                          int* __restrict__ cursor, int* __restrict__ pay, int n) {
    int i = blockIdx.x * 256 + threadIdx.x;
    if (i < n) {
        int p = atomicAdd(&cursor[keys[i]], 1);
        pay[p] = payload[i];
    }
}

// ---------------- CSR gather, float4-vectorized (f64 reg accumulation -> replay-stable) ----------------
template<bool SELF, bool SCALE>
__global__ void gather_rows4(const float* __restrict__ src,
                             const int* __restrict__ off, const int* __restrict__ pay,
                             const float* __restrict__ self_src,
                             float* __restrict__ out, int R, int F4) {
    int i = blockIdx.x * 256 + threadIdx.x;
    if (i >= R * F4) return;
    int r = i / F4, f4 = i - r * F4;
    int b = off[r], e = off[r + 1];
    double a0 = 0.0, a1 = 0.0, a2 = 0.0, a3 = 0.0;
    for (int j = b; j < e; j++) {
        float4 v = *((const float4*)(src + (size_t)pay[j] * F4 * 4) + f4);
        a0 += v.x; a1 += v.y; a2 += v.z; a3 += v.w;
    }
    float s0 = (float)a0, s1 = (float)a1, s2 = (float)a2, s3 = (float)a3;
    if (SCALE) {
        float inv = 1.f / fmaxf((float)(e - b), 1.f);
        s0 *= inv; s1 *= inv; s2 *= inv; s3 *= inv;
    }
    if (SELF) {
        float4 sv = *((const float4*)self_src + i);
        s0 += sv.x; s1 += sv.y; s2 += sv.z; s3 += sv.w;
    }
    float4 o = {s0, s1, s2, s3};
    *((float4*)out + i) = o;
}

// ---------------- bf16 GEMM 128x128, BK=64, direct staging; optional grid.z split-K ----------------
// A: [M,K] bf16; B: [N,K] bf16. PARTIAL=false -> C bf16 [M,N]; PARTIAL=true -> Cp f32 [z][M,N].
// M,N %128==0, K %64==0, kchunk %64==0.
template<bool PARTIAL>
__global__ __launch_bounds__(256) void gemm_bf16(const unsigned short* __restrict__ A,
                                                 const unsigned short* __restrict__ B,
                                                 unsigned short* __restrict__ C,
                                                 float* __restrict__ Cp,
                                                 int M, int N, int K, int kchunk) {
    __shared__ __align__(16) char Asm[16384];   // 128 x 64 bf16, swizzled
    __shared__ __align__(16) char Bsm[16384];
    const int tid = threadIdx.x;
    const int nwg = gridDim.x * gridDim.y;
    const int wg = xcd_swizzle(blockIdx.y * gridDim.x + blockIdx.x, nwg);
    const int bm = (wg / gridDim.x) * 128, bn = (wg % gridDim.x) * 128;
    const int wid = tid >> 6, lane = tid & 63;
    const int wm = (wid >> 1) * 64, wn = (wid & 1) * 64;
    const int lr = lane & 15, lg = lane >> 4;
    const int kbeg = blockIdx.z * kchunk;
    const int kend = min(K, kbeg + kchunk);

    f32x4 zero = {0.f, 0.f, 0.f, 0.f};
    f32x4 acc[4][4];
#pragma unroll
    for (int i = 0; i < 4; i++)
#pragma unroll
        for (int j = 0; j < 4; j++) acc[i][j] = zero;

    for (int k0 = kbeg; k0 < kend; k0 += 64) {
#pragma unroll
        for (int u = 0; u < 4; u++) {
            int slot = u * 256 + tid;            // 0..1023 16B-chunks
            int row = slot >> 3, ch = slot & 7;
            int off = (row * 128 + ch * 16) ^ ((row & 7) << 4);
            uint4 va = *(const uint4*)(A + (size_t)(bm + row) * K + k0 + ch * 8);
            *(uint4*)(Asm + off) = va;
            uint4 vb = *(const uint4*)(B + (size_t)(bn + row) * K + k0 + ch * 8);
            *(uint4*)(Bsm + off) = vb;
        }
        __syncthreads();
#pragma unroll
        for (int kk = 0; kk < 2; kk++) {
            bf16x8 af[4], bf[4];
#pragma unroll
            for (int m = 0; m < 4; m++) {
                int row = wm + m * 16 + lr;
                af[m] = *(const bf16x8*)(Asm + ((row * 128 + kk * 64 + lg * 16) ^ ((row & 7) << 4)));
            }
#pragma unroll
            for (int n = 0; n < 4; n++) {
                int row = wn + n * 16 + lr;
                bf[n] = *(const bf16x8*)(Bsm + ((row * 128 + kk * 64 + lg * 16) ^ ((row & 7) << 4)));
            }
#pragma unroll
            for (int m = 0; m < 4; m++)
#pragma unroll
                for (int n = 0; n < 4; n++)
                    acc[m][n] = __builtin_amdgcn_mfma_f32_16x16x32_bf16(af[m], bf[n], acc[m][n], 0, 0, 0);
        }
        __syncthreads();
    }
#pragma unroll
    for (int m = 0; m < 4; m++)
#pragma unroll
        for (int n = 0; n < 4; n++) {
            int col = bn + wn + n * 16 + lr;
#pragma unroll
            for (int r = 0; r < 4; r++) {
                int row = bm + wm + m * 16 + lg * 4 + r;
                if (PARTIAL)
                    Cp[(size_t)blockIdx.z * M * N + (size_t)row * N + col] = acc[m][n][r];
                else
                    C[(size_t)row * N + col] = f2bf(acc[m][n][r]);
            }
        }
}

// ---------------- MFMA GEMM 64x64, wave-K-split, reg-prefetch, 32KB LDS, grid.z split-K ----------------
template<bool RELU, bool PARTIAL, typename TA, typename TW>
__global__ __launch_bounds__(256) void gemm64(const TA* __restrict__ A,
                                              const TW* __restrict__ W,
                                              const float* __restrict__ bias,
                                              float* __restrict__ C,
                                              int M, int N, int K, int kchunk) {
    __shared__ __align__(16) char pool[32768];
    char* Ab = pool;
    char* Bb = pool + 16384;
    const int tid = threadIdx.x;
    const int nwg = gridDim.x * gridDim.y;
    const int wg = xcd_swizzle(blockIdx.y * gridDim.x + blockIdx.x, nwg);
    const int bm = (wg / gridDim.x) * 64, bn = (wg % gridDim.x) * 64;
    const int wid = tid >> 6, lane = tid & 63;
    const int lr = lane & 15, lg = lane >> 4;
    const int kbeg = blockIdx.z * kchunk;
    const int kend = min(K, kbeg + kchunk);
    const bool kvec = ((K & 3) == 0);

    f32x4 zero = {0.f, 0.f, 0.f, 0.f};
    f32x4 acc[4][4];
#pragma unroll
    for (int i = 0; i < 4; i++)
#pragma unroll
        for (int j = 0; j < 4; j++) acc[i][j] = zero;

    uint4 ra16[4], rb16[4];
    short4_t ra4[8], rb4[8];

    auto load_A = [&](int kc2) {
        if constexpr (sizeof(TA) == 2) {
#pragma unroll
            for (int u = 0; u < 4; u++) {
                int s = u * 256 + tid;
                int row = s >> 4, k8 = (s & 15) << 3;
                int gk = kc2 + k8, gm = bm + row;
                uint4 v = {0u, 0u, 0u, 0u};
                if (gm < M && gk + 8 <= kend) {
                    v = *(const uint4*)((const unsigned short*)A + (size_t)gm * K + gk);
                } else if (gm < M && gk < kend) {
                    unsigned short tmp[8];
#pragma unroll
                    for (int e = 0; e < 8; e++)
                        tmp[e] = (gk + e < kend) ? ((const unsigned short*)A)[(size_t)gm * K + gk + e] : 0;
                    v = *(const uint4*)tmp;
                }
                ra16[u] = v;
            }
        } else {
#pragma unroll
            for (int u = 0; u < 8; u++) {
                int s = u * 256 + tid;
                int row = s >> 5, kq = (s & 31) << 2;
                int gk = kc2 + kq, gm = bm + row;
                short4_t sv = {0, 0, 0, 0};
                if (gm < M && gk < kend)
                    sv = ld4bf_f32((const float*)A + (size_t)gm * K + gk, gk, kend, kvec);
                ra4[u] = sv;
            }
        }
    };
    auto load_B = [&](int kc2) {
        if constexpr (sizeof(TW) == 2) {
#pragma unroll
            for (int u = 0; u < 4; u++) {
                int s = u * 256 + tid;
                int row = s >> 4, k8 = (s & 15) << 3;
                int gk = kc2 + k8, gn = bn + row;
                uint4 v = {0u, 0u, 0u, 0u};
                if (gn < N && gk + 8 <= kend) {
                    v = *(const uint4*)((const unsigned short*)W + (size_t)gn * K + gk);
                } else if (gn < N && gk < kend) {
                    unsigned short tmp[8];
#pragma unroll
                    for (int e = 0; e < 8; e++)
                        tmp[e] = (gk + e < kend) ? ((const unsigned short*)W)[(size_t)gn * K + gk + e] : 0;
                    v = *(const uint4*)tmp;
                }
                rb16[u] = v;
            }
        } else {
#pragma unroll
            for (int u = 0; u < 8; u++) {
                int s = u * 256 + tid;
                int row = s >> 5, kq = (s & 31) << 2;
                int gk = kc2 + kq, gn = bn + row;
                short4_t sv = {0, 0, 0, 0};
                if (gn < N && gk < kend)
                    sv = ld4bf_f32((const float*)W + (size_t)gn * K + gk, gk, kend, kvec);
                rb4[u] = sv;
            }
        }
    };
    auto write_A = [&]() {
        if constexpr (sizeof(TA) == 2) {
#pragma unroll
            for (int u = 0; u < 4; u++) {
                int s = u * 256 + tid;
                int row = s >> 4, k8 = (s & 15) << 3;
                int off = (row * 256 + k8 * 2) ^ ((row & 7) << 4);
                *(uint4*)(Ab + off) = ra16[u];
            }
        } else {
#pragma unroll
            for (int u = 0; u < 8; u++) {
                int s = u * 256 + tid;
                int row = s >> 5, kq = (s & 31) << 2;
                int off = (row * 256 + kq * 2) ^ ((row & 7) << 4);
                *(short4_t*)(Ab + off) = ra4[u];
            }
        }
    };
    auto write_B = [&]() {
        if constexpr (sizeof(TW) == 2) {
#pragma unroll
            for (int u = 0; u < 4; u++) {
                int s = u * 256 + tid;
                int row = s >> 4, k8 = (s & 15) << 3;
                int off = (row * 256 + k8 * 2) ^ ((row & 7) << 4);
                *(uint4*)(Bb + off) = rb16[u];
            }
        } else {
#pragma unroll
            for (int u = 0; u < 8; u++) {
                int s = u * 256 + tid;
                int row = s >> 5, kq = (s & 31) << 2;
                int off = (row * 256 + kq * 2) ^ ((row & 7) << 4);
                *(short4_t*)(Bb + off) = rb4[u];
            }
        }
    };

    load_A(kbeg);
    load_B(kbeg);
    for (int kc = kbeg; kc < kend; kc += 128) {
        write_A();
        write_B();
        __syncthreads();
        if (kc + 128 < kend) { load_A(kc + 128); load_B(kc + 128); }

        bf16x8 af[4], bf[4];
        const int kb = wid * 64 + lg * 16;
#pragma unroll
        for (int m = 0; m < 4; m++) {
            int row = m * 16 + lr;
            af[m] = *(const bf16x8*)(Ab + ((row * 256 + kb) ^ ((row & 7) << 4)));
        }
#pragma unroll
        for (int n = 0; n < 4; n++) {
            int row = n * 16 + lr;
            bf[n] = *(const bf16x8*)(Bb + ((row * 256 + kb) ^ ((row & 7) << 4)));
        }
#pragma unroll
        for (int m = 0; m < 4; m++)
#pragma unroll
            for (int n = 0; n < 4; n++)
                acc[m][n] = __builtin_amdgcn_mfma_f32_16x16x32_bf16(af[m], bf[n], acc[m][n], 0, 0, 0);
        __syncthreads();
    }

    float* redA = (float*)pool;
    float* redB = (float*)(pool + 16384);
    if (wid < 2) {
        float* r = (wid == 0) ? redA : redB;
#pragma unroll
        for (int m = 0; m < 4; m++)
#pragma unroll
            for (int n = 0; n < 4; n++)
#pragma unroll
                for (int r4 = 0; r4 < 4; r4++)
                    r[(m * 16 + lg * 4 + r4) * 64 + n * 16 + lr] = acc[m][n][r4];
    }
    __syncthreads();
    if (wid >= 2) {
        float* r = (wid == 2) ? redA : redB;
#pragma unroll
        for (int m = 0; m < 4; m++)
#pragma unroll
            for (int n = 0; n < 4; n++)
#pragma unroll
                for (int r4 = 0; r4 < 4; r4++)
                    r[(m * 16 + lg * 4 + r4) * 64 + n * 16 + lr] += acc[m][n][r4];
    }
    __syncthreads();
#pragma unroll
    for (int u = 0; u < 16; u++) {
        int idx = u * 256 + tid;
        int row = idx >> 6, col = idx & 63;
        int gm = bm + row, gn = bn + col;
        if (gm >= M || gn >= N) continue;
        float s = redA[idx] + redB[idx];
        if (PARTIAL) {
            C[(size_t)blockIdx.z * M * N + (size_t)gm * N + gn] = s;
        } else {
            s += bias ? bias[gn] : 0.f;
            if (RELU) s = fmaxf(s, 0.f);
            C[(size_t)gm * N + gn] = s;
        }
    }
}

template<bool RELU>
__global__ void reduce_partial(const float* __restrict__ part, const float* __restrict__ bias,
                               float* __restrict__ C, int MN, int N, int SK) {
    int i = blockIdx.x * 256 + threadIdx.x;
    if (i >= MN) return;
    float s = 0.f;
    for (int z = 0; z < SK; z++) s += part[(size_t)z * MN + i];
    s += bias ? bias[i % N] : 0.f;
    if (RELU) s = fmaxf(s, 0.f);
    C[i] = s;
}

// ---------------- cvt gin2_W [840][84] f32 -> [840][96] bf16 (zero-padded K) ----------------
__global__ void cvt_gin2w(const float* __restrict__ W, unsigned short* __restrict__ Wb) {
    int i = blockIdx.x * 256 + threadIdx.x;
    if (i >= 840 * 96) return;
    int r = i / 96, k = i - r * 96;
    Wb[i] = (k < 84) ? f2bf(W[r * 84 + k]) : (unsigned short)0;
}

// ---------------- cvt mlp1_W [1024][4080] f32 -> [1024][4096] bf16 (zero-padded K) ----------------
__global__ void cvt_mlp1w(const float* __restrict__ W, unsigned short* __restrict__ Wb) {
    int i = blockIdx.x * 256 + threadIdx.x;
    if (i >= 1024 * 4096) return;
    int r = i >> 12, k = i & 4095;
    Wb[i] = (k < 4080) ? f2bf(W[(size_t)r * 4080 + k]) : (unsigned short)0;
}

// ---------------- fused GIN2 GEMM + bias + relu + 50-row max/mean pool ----------------
__global__ __launch_bounds__(256) void gin2pool(const float* __restrict__ xin2,
                                                const unsigned short* __restrict__ Wbf,
                                                const float* __restrict__ bias,
                                                float* __restrict__ out) {
    __shared__ __align__(16) char Ab[16384];
    const int tid = threadIdx.x;
    const int g = blockIdx.x;
    const int wid = tid >> 6, lane = tid & 63;
    const int lr = lane & 15, lg = lane >> 4;
    const int K = FXD;
    const int N = 840;

#pragma unroll
    for (int u = 0; u < 8; u++) {
        int s = u * 256 + tid;
        int row = s >> 5, kq = (s & 31) << 2;
        int off = (row * 256 + (s & 31) * 8) ^ ((row & 7) << 4);
        float v0 = 0.f, v1 = 0.f, v2 = 0.f, v3 = 0.f;
        if (row < NPG && kq < K) {
            float4 f = *(const float4*)(xin2 + ((size_t)g * NPG + row) * K + kq);
            v0 = f.x; v1 = f.y; v2 = f.z; v3 = f.w;
        }
        short4_t sv;
        sv[0] = (short)f2bf(v0); sv[1] = (short)f2bf(v1);
        sv[2] = (short)f2bf(v2); sv[3] = (short)f2bf(v3);
        *(short4_t*)(Ab + off) = sv;
    }
    __syncthreads();

    bf16x8 af[4][3];
#pragma unroll
    for (int m = 0; m < 4; m++)
#pragma unroll
        for (int kk = 0; kk < 3; kk++) {
            int row = m * 16 + lr;
            af[m][kk] = *(const bf16x8*)(Ab + ((row * 256 + kk * 64 + lg * 16) ^ ((row & 7) << 4)));
        }

    for (int t = 0; t < 14; t++) {
        const int n0 = t * 64 + wid * 16;
        const int wrow = n0 + lr;
        bf16x8 bf[3];
#pragma unroll
        for (int kk = 0; kk < 3; kk++) {
            int k0 = kk * 32 + lg * 8;
            uint4 raw = {0u, 0u, 0u, 0u};
            if (wrow < N) raw = *(const uint4*)(Wbf + (size_t)wrow * 96 + k0);
            bf[kk] = __builtin_bit_cast(bf16x8, raw);
        }
        f32x4 zero = {0.f, 0.f, 0.f, 0.f};
        f32x4 acc[4] = {zero, zero, zero, zero};
#pragma unroll
        for (int m = 0; m < 4; m++)
#pragma unroll
            for (int kk = 0; kk < 3; kk++)
                acc[m] = __builtin_amdgcn_mfma_f32_16x16x32_bf16(af[m][kk], bf[kk], acc[m], 0, 0, 0);

        const int c = n0 + lr;
        float bv = (c < N) ? bias[c] : 0.f;
        float mx = -1e30f, sm = 0.f;
#pragma unroll
        for (int m = 0; m < 4; m++)
#pragma unroll
            for (int r = 0; r < 4; r++) {
                int row = m * 16 + lg * 4 + r;
                if (row < NPG) {
                    float v = fmaxf(acc[m][r] + bv, 0.f);
                    mx = fmaxf(mx, v);
                    sm += v;
                }
            }
        mx = fmaxf(mx, __shfl_xor(mx, 16, 64));
        sm += __shfl_xor(sm, 16, 64);
        mx = fmaxf(mx, __shfl_xor(mx, 32, 64));
        sm += __shfl_xor(sm, 32, 64);
        if (lg == 0 && c < N) {
            out[(size_t)g * 1680 + c] = mx;
            out[(size_t)g * 1680 + 840 + c] = sm * (1.f / NPG);
        }
    }
}

// ---------------- N=1 GEMM ----------------
__global__ __launch_bounds__(256) void rowdot(const float* __restrict__ A,
                                              const float* __restrict__ w,
                                              const float* __restrict__ b,
                                              float* __restrict__ out, int Mrows, int K) {
    int row = blockIdx.x * 4 + (threadIdx.x >> 6);
    int lane = threadIdx.x & 63;
    if (row >= Mrows) return;
    float s = 0.f;
    for (int k = lane; k < K; k += 64) s += A[(size_t)row * K + k] * w[k];
#pragma unroll
    for (int off = 32; off > 0; off >>= 1) s += __shfl_xor(s, off, 64);
    if (lane == 0) out[row] = s + b[0];
}

// ---------------- hnode transform: h*Dinv + bias ----------------
__global__ void transform_dinv_bias(const float* __restrict__ h, const int* __restrict__ off_n,
                                    const float* __restrict__ b, float* __restrict__ o, int R, int F) {
    int i = blockIdx.x * 256 + threadIdx.x;
    if (i >= R * F) return;
    int r = i / F, f = i - r * F;
    int d = off_n[r + 1] - off_n[r];
    float inv = d > 0 ? 1.f / d : 0.f;
    o[i] = h[i] * inv + b[f];
}

// ---------------- fused hyper Dinv+bias + 50-row max/mean pool ----------------
__global__ void pool_hyper(const float* __restrict__ hn, const int* __restrict__ off_n,
                           const float* __restrict__ b, float* __restrict__ out) {
    int i = blockIdx.x * 256 + threadIdx.x;
    if (i >= NB * 256) return;
    int o = i & 255, g = i >> 8;
    float bo = b[o];
    const float* base = hn + (size_t)g * NPG * 256 + o;
    float mx = -1e30f, sm = 0.f;
    for (int n = 0; n < NPG; n++) {
        int node = g * NPG + n;
        int d = off_n[node + 1] - off_n[node];
        float inv = d > 0 ? 1.f / d : 0.f;
        float v = base[(size_t)n * 256] * inv + bo;
        mx = fmaxf(mx, v);
        sm += v;
    }
    out[(size_t)g * 512 + o] = mx;
    out[(size_t)g * 512 + 256 + o] = sm * (1.f / NPG);
}

// ---------------- pack fusion tokens -> bf16 ----------------
__global__ void pack_tokens_bf(const float* __restrict__ fp_o, const float* __restrict__ xg,
                               const float* __restrict__ hxg, const float* __restrict__ t,
                               unsigned short* __restrict__ in_t) {
    int i = blockIdx.x * 256 + threadIdx.x;
    if (i >= 4096 * 512) return;
    int d = i & 511;
    int row = i >> 9;
    int tok = row & 3, b = row >> 2;
    const float* s = (tok == 0) ? fp_o : (tok == 1) ? xg : (tok == 2) ? hxg : t;
    in_t[i] = f2bf(s[b * 512 + d]);
}

// ---------------- concat + cvt Wq|Wk|Wv -> bf16 [6144][512] ----------------
__global__ void cvt_qkv_w(const float* __restrict__ Wq, const float* __restrict__ Wk,
                          const float* __restrict__ Wv, unsigned short* __restrict__ Wb) {
    int i = blockIdx.x * 256 + threadIdx.x;
    if (i >= 6144 * 512) return;
    int n = i >> 9;
    const float* src = (n < 2048) ? Wq : (n < 4096) ? Wk : Wv;
    int nn = (n < 2048) ? n : (n < 4096) ? n - 2048 : n - 4096;
    Wb[i] = f2bf(src[(size_t)nn * 512 + (i & 511)]);
}

// ---------------- fused attention + conv3x3 + relu: one block per batch b ----------------
// writes cbuf bf16 [1024][4096] (cols 4080..4095 zeroed for the padded mlp1 GEMM).
__global__ __launch_bounds__(256) void attn_conv(const unsigned short* __restrict__ QKV,
                                                 const float* __restrict__ cw,
                                                 const float* __restrict__ cb,
                                                 unsigned short* __restrict__ c) {
    __shared__ float att_s[4][4][512];   // [head][token][d] = 32 KB
    __shared__ float w[144];
    __shared__ float bias[4];
    const int tid = threadIdx.x;
    const int wid = tid >> 6, lane = tid & 63;
    const int b = blockIdx.x;
    if (tid < 144) w[tid] = cw[tid];
    if (tid < 4) bias[tid] = cb[tid];

    const unsigned short* qb = QKV + (size_t)b * 4 * 6144 + wid * 512;
    const unsigned short* kb = qb + 2048;
    const unsigned short* vb = qb + 4096;
    float qr[4][8], kr[4][8];
#pragma unroll
    for (int n = 0; n < 4; n++)
#pragma unroll
        for (int cc = 0; cc < 8; cc++) {
            qr[n][cc] = bf2f(qb[n * 6144 + cc * 64 + lane]);
            kr[n][cc] = bf2f(kb[n * 6144 + cc * 64 + lane]);
        }
    float s[4][4];
#pragma unroll
    for (int n = 0; n < 4; n++)
#pragma unroll
        for (int m = 0; m < 4; m++) {
            float p = 0.f;
#pragma unroll
            for (int cc = 0; cc < 8; cc++) p += qr[n][cc] * kr[m][cc];
#pragma unroll
            for (int off = 32; off > 0; off >>= 1) p += __shfl_xor(p, off, 64);
            s[n][m] = p * 0.04419417382415922f;   // 1/sqrt(512)
        }
    float pm[4][4];
#pragma unroll
    for (int n = 0; n < 4; n++) {
        float mx = fmaxf(fmaxf(s[n][0], s[n][1]), fmaxf(s[n][2], s[n][3]));
        float e0 = expf(s[n][0] - mx), e1 = expf(s[n][1] - mx);
        float e2 = expf(s[n][2] - mx), e3 = expf(s[n][3] - mx);
        float inv = 1.f / (e0 + e1 + e2 + e3);
        pm[n][0] = e0 * inv; pm[n][1] = e1 * inv; pm[n][2] = e2 * inv; pm[n][3] = e3 * inv;
    }
#pragma unroll
    for (int cc = 0; cc < 8; cc++) {
        float v0 = bf2f(vb[0 * 6144 + cc * 64 + lane]);
        float v1 = bf2f(vb[1 * 6144 + cc * 64 + lane]);
        float v2 = bf2f(vb[2 * 6144 + cc * 64 + lane]);
        float v3 = bf2f(vb[3 * 6144 + cc * 64 + lane]);
#pragma unroll
        for (int n = 0; n < 4; n++)
            att_s[wid][n][cc * 64 + lane] = pm[n][0] * v0 + pm[n][1] * v1 + pm[n][2] * v2 + pm[n][3] * v3;
    }
    __syncthreads();

    for (int it = 0; it < 16; it++) {
        int j = it * 256 + tid;            // 0..4095
        float v = 0.f;
        if (j < 4080) {
            int wo = j % 510;
            int r = j / 510;
            int ho = r & 1, co = r >> 1;
            float acc = bias[co];
#pragma unroll
            for (int ci = 0; ci < 4; ci++)
#pragma unroll
                for (int kh = 0; kh < 3; kh++)
#pragma unroll
                    for (int kw = 0; kw < 3; kw++)
                        acc += att_s[ci][ho + kh][wo + kw] * w[((co * 4 + ci) * 3 + kh) * 3 + kw];
            v = fmaxf(acc, 0.f);
        }
        c[(size_t)b * 4096 + j] = f2bf(v);
    }
}

// ---------------- host side ----------------
template<typename TA, typename TW>
static inline void launch_gemm64(const TA* A, const TW* W, const float* b, float* C,
                                 int M, int N, int K, bool relu, float* part, hipStream_t s) {
    int gx = (N + 63) / 64, gy = (M + 63) / 64;
    int targetSK = 1024 / (gx * gy);
    if (targetSK < 1) targetSK = 1;
    if (targetSK > 8) targetSK = 8;
    int kchunk = K, SK = 1;
    if (targetSK > 1) {
        kchunk = (((K + targetSK - 1) / targetSK) + 127) & ~127;
        SK = (K + kchunk - 1) / kchunk;
    }
    if (SK <= 1) {
        dim3 g(gx, gy);
        if (relu) gemm64<true, false, TA, TW><<<g, 256, 0, s>>>(A, W, b, C, M, N, K, K);
        else      gemm64<false, false, TA, TW><<<g, 256, 0, s>>>(A, W, b, C, M, N, K, K);
    } else {
        dim3 g(gx, gy, SK);
        gemm64<false, true, TA, TW><<<g, 256, 0, s>>>(A, W, nullptr, part, M, N, K, kchunk);
        int MN = M * N;
        if (relu) reduce_partial<true><<<(MN + 255) / 256, 256, 0, s>>>(part, b, C, MN, N, SK);
        else      reduce_partial<false><<<(MN + 255) / 256, 256, 0, s>>>(part, b, C, MN, N, SK);
    }
}

extern "C" void kernel_launch(void* const* d_in, const int* in_sizes, int n_in,
                              void* d_out, int out_size, void* d_ws, size_t ws_size,
                              hipStream_t stream) {
    const float* x       = (const float*)d_in[0];
    const int*   edge    = (const int*)d_in[1];
    const int*   hedge   = (const int*)d_in[3];
    const float* fp      = (const float*)d_in[4];
    const float* text_em = (const float*)d_in[5];
    const float* fc1_W = (const float*)d_in[7];  const float* fc1_b = (const float*)d_in[8];
    const float* fc2_W = (const float*)d_in[9];  const float* fc2_b = (const float*)d_in[10];
    const float* fc3_W = (const float*)d_in[11]; const float* fc3_b = (const float*)d_in[12];
    const float* fcg1_W = (const float*)d_in[13]; const float* fcg1_b = (const float*)d_in[14];
    const float* fcg2_W = (const float*)d_in[15]; const float* fcg2_b = (const float*)d_in[16];
    const float* fchg1_W = (const float*)d_in[17]; const float* fchg1_b = (const float*)d_in[18];
    const float* fchg2_W = (const float*)d_in[19]; const float* fchg2_b = (const float*)d_in[20];
    const float* gin1_W = (const float*)d_in[21]; const float* gin1_b = (const float*)d_in[22];
    const float* gin2_W = (const float*)d_in[23]; const float* gin2_b = (const float*)d_in[24];
    const float* h3_W = (const float*)d_in[25]; const float* h3_b = (const float*)d_in[26];
    const float* h4_W = (const float*)d_in[27]; const float* h4_b = (const float*)d_in[28];
    const float* Wq = (const float*)d_in[29];
    const float* Wk = (const float*)d_in[30];
    const float* Wv = (const float*)d_in[31];
    const float* conv_W = (const float*)d_in[32]; const float* conv_b = (const float*)d_in[33];
    const float* mlp1_W = (const float*)d_in[34]; const float* mlp1_b = (const float*)d_in[35];
    const float* mlp2_W = (const float*)d_in[36]; const float* mlp2_b = (const float*)d_in[37];

    const int* e_src = edge;
    const int* e_dst = edge + N_EDGES;
    const int* h_nid = hedge;
    const int* h_eid = hedge + N_HNNZ;

    float* ws = (float*)d_ws;
    const size_t ZONE = 51609600;
    // ---- phase A (GIN) ----
    float* xin1 = ws;                               // 4,300,800
    float* xg1  = ws + 4300800;                     // 4,300,800
    float* xin2 = ws + 8601600;                     // 4,300,800
    // ---- phase H (hypergraph) ----
    float* eagg   = ws;                             // 860,160
    float* e1_32  = ws + 860160;                    // 1,720,320
    float* hnode  = ws + 2580480;                   // 8,601,600
    float* hnodet = ws + 11182080;                  // 8,601,600
    float* eagg2  = ws + 19783680;                  // 1,720,320
    float* e2_32  = ws + 21504000;                  // 2,621,440
    float* hn2    = ws + 24125440;                  // 13,107,200 (ends 37,232,640)
    // ---- phase D (attention) ----
    unsigned short* in_t_bf  = (unsigned short*)ws;                 // 2,097,152 us
    unsigned short* qkv_bf   = (unsigned short*)(ws + 2097152);     // 25,165,824 us
    unsigned short* cbuf_bf  = (unsigned short*)(ws + 35651584);    // 4,194,304 us (1024x4096, ends 37,748,736)
    float* m1   = ws + 39829504;                                    // 1,048,576
    unsigned short* Wqkv_bf  = (unsigned short*)(ws + 40878080);    // 3,145,728 us
    unsigned short* mlp1W_bf = (unsigned short*)(ws + 42450944);    // 4,194,304 us (1024x4096, ends 44,548,096)
    float* part = ws;                               // split-K scratch (zone-dead windows)
    // ---- CSR region ----
    int* cnt_g = (int*)(ws + 45000000);
    int* off_g = (int*)(ws + 45051200);
    int* pay_g = (int*)(ws + 45102401);
    int* cnt_e = (int*)(ws + 45307201);
    int* off_e = (int*)(ws + 45317441);
    int* pay_e = (int*)(ws + 45327682);
    int* cnt_n = (int*)(ws + 45430082);
    int* off_n = (int*)(ws + 45481282);
    int* pay_n = (int*)(ws + 45532483);             // ends 45,634,883
    unsigned short* gin2Wbf = (unsigned short*)(ws + 45700000);     // 80,640 us (< ZONE)
    // ---- persistent ----
    float* xg_raw = ws + ZONE;
    float* xg_mid = ws + ZONE + 1720320;
    float* hx_raw = ws + ZONE + 2768896;
    float* hx_mid = ws + ZONE + 3293184;
    float* h1     = ws + ZONE + 4341760;
    float* fp_o   = ws + ZONE + 4472832;
    float* tt     = ws + ZONE + 4997120;
    const size_t NEED = (ZONE + 5582848) * sizeof(float);
    if (ws_size < NEED) return;

    float* out_y  = (float*)d_out;
    float* xg_out = out_y + 1024;
    float* hx_out = out_y + 1024 + 1024 * 512;

    // ---------- build 3 CSR structures ----------
    hipMemsetAsync(cnt_g, 0, N_NODES * 4, stream);
    hipMemsetAsync(cnt_e, 0, N_HEDGES * 4, stream);
    hipMemsetAsync(cnt_n, 0, N_NODES * 4, stream);
    histo_i<<<(N_EDGES + 255) / 256, 256, 0, stream>>>(e_dst, cnt_g, N_EDGES);
    histo_i<<<(N_HNNZ + 255) / 256, 256, 0, stream>>>(h_eid, cnt_e, N_HNNZ);
    histo_i<<<(N_HNNZ + 255) / 256, 256, 0, stream>>>(h_nid, cnt_n, N_HNNZ);
    exscan3<<<3, 1024, 0, stream>>>(cnt_g, off_g, N_NODES, cnt_e, off_e, N_HEDGES, cnt_n, off_n, N_NODES);
    hipMemcpyAsync(cnt_g, off_g, N_NODES * 4, hipMemcpyDeviceToDevice, stream);
    hipMemcpyAsync(cnt_e, off_e, N_HEDGES * 4, hipMemcpyDeviceToDevice, stream);
    hipMemcpyAsync(cnt_n, off_n, N_NODES * 4, hipMemcpyDeviceToDevice, stream);
    place_pay<<<(N_EDGES + 255) / 256, 256, 0, stream>>>(e_dst, e_src, cnt_g, pay_g, N_EDGES);
    place_pay<<<(N_HNNZ + 255) / 256, 256, 0, stream>>>(h_eid, h_nid, cnt_e, pay_e, N_HNNZ);
    place_pay<<<(N_HNNZ + 255) / 256, 256, 0, stream>>>(h_nid, h_eid, cnt_n, pay_n, N_HNNZ);
    cvt_gin2w<<<(840 * 96 + 255) / 256, 256, 0, stream>>>(gin2_W, gin2Wbf);

    // ---------- GIN branch ----------
    gather_rows4<true, false><<<(N_NODES * (FXD / 4) + 255) / 256, 256, 0, stream>>>(
        x, off_g, pay_g, x, xin1, N_NODES, FXD / 4);
    launch_gemm64(xin1, gin1_W, gin1_b, xg1, N_NODES, FXD, FXD, true, part, stream);
    gather_rows4<true, false><<<(N_NODES * (FXD / 4) + 255) / 256, 256, 0, stream>>>(
        xg1, off_g, pay_g, xg1, xin2, N_NODES, FXD / 4);
    gin2pool<<<NB, 256, 0, stream>>>(xin2, gin2Wbf, gin2_b, xg_raw);
    launch_gemm64(xg_raw, fcg1_W, fcg1_b, xg_mid, NB, 1024, 1680, true, part, stream);
    launch_gemm64(xg_mid, fcg2_W, fcg2_b, xg_out, NB, 512, 1024, false, part, stream);

    // ---------- hypergraph branch ----------
    gather_rows4<false, true><<<(N_HEDGES * (FXD / 4) + 255) / 256, 256, 0, stream>>>(
        x, off_e, pay_e, nullptr, eagg, N_HEDGES, FXD / 4);
    launch_gemm64(eagg, h3_W, (const float*)nullptr, e1_32, N_HEDGES, 168, FXD, false, part, stream);
    gather_rows4<false, false><<<(N_NODES * 42 + 255) / 256, 256, 0, stream>>>(
        e1_32, off_n, pay_n, nullptr, hnode, N_NODES, 42);
    transform_dinv_bias<<<(N_NODES * 168 + 255) / 256, 256, 0, stream>>>(
        hnode, off_n, h3_b, hnodet, N_NODES, 168);
    gather_rows4<false, true><<<(N_HEDGES * 42 + 255) / 256, 256, 0, stream>>>(
        hnodet, off_e, pay_e, nullptr, eagg2, N_HEDGES, 42);
    launch_gemm64(eagg2, h4_W, (const float*)nullptr, e2_32, N_HEDGES, 256, 168, false, part, stream);
    gather_rows4<false, false><<<(N_NODES * 64 + 255) / 256, 256, 0, stream>>>(
        e2_32, off_n, pay_n, nullptr, hn2, N_NODES, 64);
    pool_hyper<<<(NB * 256 + 255) / 256, 256, 0, stream>>>(hn2, off_n, h4_b, hx_raw);
    launch_gemm64(hx_raw, fchg1_W, fchg1_b, hx_mid, NB, 1024, 512, true, part, stream);
    launch_gemm64(hx_mid, fchg2_W, fchg2_b, hx_out, NB, 512, 1024, false, part, stream);

    // ---------- fingerprint + text ----------
    launch_gemm64(fp, fc1_W, fc1_b, h1, NB, FP2, FP_DIM, true, part, stream);
    launch_gemm64(h1, fc2_W, fc2_b, fp_o, NB, HID, FP2, false, part, stream);
    launch_gemm64(text_em, fc3_W, fc3_b, tt, NB, HID, 768, false, part, stream);

    // ---------- fusion attention (bf16 pipeline) ----------
    pack_tokens_bf<<<(4096 * 512 + 255) / 256, 256, 0, stream>>>(fp_o, xg_out, hx_out, tt, in_t_bf);
    cvt_qkv_w<<<(6144 * 512 + 255) / 256, 256, 0, stream>>>(Wq, Wk, Wv, Wqkv_bf);
    gemm_bf16<false><<<dim3(6144 / 128, 4096 / 128), 256, 0, stream>>>(
        in_t_bf, Wqkv_bf, qkv_bf, nullptr, 4096, 6144, 512, 512);
    attn_conv<<<NB, 256, 0, stream>>>(qkv_bf, conv_W, conv_b, cbuf_bf);
    cvt_mlp1w<<<(1024 * 4096 + 255) / 256, 256, 0, stream>>>(mlp1_W, mlp1W_bf);
    // mlp1 on the 128^2 bf16 structure, grid.z split-K = 8 (512 blocks), f32 partials
    gemm_bf16<true><<<dim3(8, 8, 8), 256, 0, stream>>>(
        cbuf_bf, mlp1W_bf, nullptr, part, 1024, 1024, 4096, 512);
    reduce_partial<true><<<(1024 * 1024 + 255) / 256, 256, 0, stream>>>(
        part, mlp1_b, m1, 1024 * 1024, 1024, 8);
    rowdot<<<256, 256, 0, stream>>>(m1, mlp2_W, mlp2_b, out_y, NB, 1024);
}